// Round 5
// baseline (703.313 us; speedup 1.0000x reference)
//
#include <hip/hip_runtime.h>
#include <hip/hip_bf16.h>
#include <math.h>

#define NRES 1536
#define NH 16
#define NNF 2359296ull    // NRES*NRES
#define LOG2E 1.44269504f

typedef unsigned short u16;
typedef __attribute__((ext_vector_type(8))) short short8;
typedef __attribute__((ext_vector_type(4))) float f32x4;

typedef const __attribute__((address_space(1))) void gvoid;
typedef __attribute__((address_space(3))) void lvoid;

__device__ __forceinline__ u16 f2b(float x){
    __hip_bfloat16 h = __float2bfloat16(x);
    return *reinterpret_cast<u16*>(&h);
}
__device__ __forceinline__ float b2f(u16 u){
    unsigned v = ((unsigned)u) << 16;
    return __uint_as_float(v);
}

// ===================== bf16 MFMA GEMM (templated tile-N, optional split-K) ==========
#define F_BIAS  1
#define F_SILU  2
#define F_MUL   4
#define F_RESID 8
#define F_OUTBF 16

template<int TNF>
__global__ __launch_bounds__(256) void gemm_t(
    const u16* __restrict__ A, int lda, size_t zsA,
    const u16* __restrict__ BT, int ldb, size_t zsB,
    float* __restrict__ Cf, u16* __restrict__ Cb, int ldc, size_t zsC,
    const float* __restrict__ bias, size_t zsBias,
    const float* __restrict__ resid, int ldr, size_t zsR,
    const u16* __restrict__ mulb, int ldm,
    int Ncols, int Kd, int flags, int ksl)
{
    constexpr int TN = TNF * 32;
    __shared__ u16 As[128 * 64];
    __shared__ u16 Bs[TN * 64];

    const int tid = threadIdx.x;
    const int l = tid & 63, w = tid >> 6;
    const int bz = blockIdx.z;
    const int bm = blockIdx.y * 128, bn = blockIdx.x * TN;

    A  += zsA * bz;
    BT += zsB * bz;

    const int kbeg = ksl ? bz * ksl : 0;
    const int kend = ksl ? kbeg + ksl : Kd;

    const int arow   = l >> 3;
    const int aslot  = l & 7;
    const int srcslt = aslot ^ arow;

    const u16* aBase[4];
    const u16* bBase[TN / 32];
    #pragma unroll
    for (int t = 0; t < 4; ++t) {
        int ra = bm + (w * 4 + t) * 8 + arow;
        aBase[t] = A + (size_t)ra * lda + srcslt * 8;
    }
    #pragma unroll
    for (int t = 0; t < TN / 32; ++t) {
        int rb = bn + (w * (TN / 32) + t) * 8 + arow;
        if (rb > Ncols - 1) rb = Ncols - 1;
        bBase[t] = BT + (size_t)rb * ldb + srcslt * 8;
    }

    const int wr = w >> 1, wc = w & 1;
    const int fr = l & 15;
    const int fq = l >> 4;

    f32x4 acc[4][TNF];
    #pragma unroll
    for (int i = 0; i < 4; ++i)
        #pragma unroll
        for (int j = 0; j < TNF; ++j) acc[i][j] = (f32x4){0.f, 0.f, 0.f, 0.f};

    for (int k0 = kbeg; k0 < kend; k0 += 64) {
        #pragma unroll
        for (int t = 0; t < 4; ++t)
            __builtin_amdgcn_global_load_lds((gvoid*)(aBase[t] + k0),
                (lvoid*)((char*)As + (w * 4 + t) * 1024), 16, 0, 0);
        #pragma unroll
        for (int t = 0; t < TN / 32; ++t)
            __builtin_amdgcn_global_load_lds((gvoid*)(bBase[t] + k0),
                (lvoid*)((char*)Bs + (w * (TN / 32) + t) * 1024), 16, 0, 0);
        __syncthreads();
        #pragma unroll
        for (int kk = 0; kk < 2; ++kk) {
            const int slotR = ((kk * 4) + fq) ^ (l & 7);
            short8 av[4], bv[TNF];
            #pragma unroll
            for (int m = 0; m < 4; ++m) {
                int r = wr * 64 + m * 16 + fr;
                av[m] = *(const short8*)((const char*)As + r * 128 + slotR * 16);
            }
            #pragma unroll
            for (int n = 0; n < TNF; ++n) {
                int r = wc * (TNF * 16) + n * 16 + fr;
                bv[n] = *(const short8*)((const char*)Bs + r * 128 + slotR * 16);
            }
            #pragma unroll
            for (int m = 0; m < 4; ++m)
                #pragma unroll
                for (int n = 0; n < TNF; ++n)
                    acc[m][n] = __builtin_amdgcn_mfma_f32_16x16x32_bf16(av[m], bv[n], acc[m][n], 0, 0, 0);
        }
        __syncthreads();
    }

    const float* residz = (flags & F_RESID) ? resid + zsR * bz : nullptr;
    const float* biasz  = (flags & F_BIAS)  ? bias + zsBias * bz : nullptr;
    float* cfz = Cf ? Cf + zsC * bz : nullptr;
    u16*   cbz = Cb ? Cb + zsC * bz : nullptr;

    #pragma unroll
    for (int m = 0; m < 4; ++m) {
        #pragma unroll
        for (int n = 0; n < TNF; ++n) {
            int gc = bn + wc * (TNF * 16) + n * 16 + fr;
            if (gc >= Ncols) continue;
            int gr0 = bm + wr * 64 + m * 16 + fq * 4;
            #pragma unroll
            for (int r = 0; r < 4; ++r) {
                int gr = gr0 + r;
                float v = acc[m][n][r];
                if (flags & F_BIAS)  v += biasz[gc];
                if (flags & F_SILU)  v = v / (1.f + expf(-v));
                if (flags & F_MUL)   v *= b2f(mulb[(size_t)gr * ldm + gc]);
                if (flags & F_RESID) v += residz[(size_t)gr * ldr + gc];
                if (flags & F_OUTBF) cbz[(size_t)gr * ldc + gc] = f2b(v);
                else                 cfz[(size_t)gr * ldc + gc] = v;
            }
        }
    }
}

// ===================== split-K reduce + fused epilogue =====================
__global__ __launch_bounds__(256) void reduce_epi(
    const float* __restrict__ part, size_t slice, int nsl,
    float* __restrict__ Cf, u16* __restrict__ Cb,
    const float* __restrict__ bias,
    const float* __restrict__ resid, int ldr,
    const u16* __restrict__ mulb, int ldm,
    int M, int Ncols, int flags)
{
    size_t total = (size_t)M * Ncols;
    for (size_t i = (size_t)blockIdx.x * 256 + threadIdx.x; i < total;
         i += (size_t)gridDim.x * 256) {
        int r = (int)(i / (unsigned)Ncols);
        int c = (int)(i - (size_t)r * Ncols);
        float v = 0.f;
        for (int s = 0; s < nsl; ++s) v += part[(size_t)s * slice + i];
        if (flags & F_BIAS)  v += bias[c];
        if (flags & F_SILU)  v = v / (1.f + expf(-v));
        if (flags & F_MUL)   v *= b2f(mulb[(size_t)r * ldm + c]);
        if (flags & F_RESID) v += resid[(size_t)r * ldr + c];
        if (flags & F_OUTBF) Cb[i] = f2b(v);
        else                 Cf[i] = v;
    }
}

// ===================== fused flash attention v2 (split-KV, high occupancy) ==========
// grid (24 q-tiles, 16 heads, 2 kv-halves), 256 threads (4 waves, 2x2).
// QBLK=64, KVBLK=64. LDS ~53KB -> 3 blocks/CU; launch_bounds(256,3) caps VGPR.
// Outputs UNNORMALIZED O partials [z][h][row][96] + (m,l) [z][h][row][2].
__global__ __launch_bounds__(256, 3) void attn_kernel(
    const u16* __restrict__ qe, const u16* __restrict__ ke,
    const u16* __restrict__ vt, const float* __restrict__ pb,
    float* __restrict__ Opart, float* __restrict__ mlpart)
{
    __shared__ u16 Qs[64 * 128];     // 16 KB, rows 256B, 16 slots XOR-swizzled
    __shared__ u16 Ks[64 * 128];     // 16 KB
    __shared__ u16 Vs[96 * 64];      // 12 KB, [channel][j], rows 128B
    __shared__ u16 Ps[64 * 64];      //  8 KB, rows 128B
    __shared__ float redm[2][2][32];
    __shared__ float redl[2][2][32];

    const int tid = threadIdx.x;
    const int l = tid & 63, w = tid >> 6;
    const int h = blockIdx.y;
    const int q0 = blockIdx.x * 64;
    const int z = blockIdx.z;
    const int wr = w >> 1, wc = w & 1;
    const int fr = l & 15, fq = l >> 4;

    const u16* qeh = qe + (size_t)h * NRES * 128;
    const u16* keh = ke + (size_t)h * NRES * 128;
    const u16* vth = vt + (size_t)h * 96 * NRES;

    // ---- stage Q tile once (64 rows x 256 B), 4 instr/wave ----
    {
        int rloc = l >> 4, s16v = l & 15;
        #pragma unroll
        for (int t = 0; t < 4; ++t) {
            int row = w * 16 + t * 4 + rloc;
            int ss = s16v ^ (row & 7);
            __builtin_amdgcn_global_load_lds(
                (gvoid*)(qeh + (size_t)(q0 + row) * 128 + ss * 8),
                (lvoid*)((char*)Qs + (w * 16 + t * 4) * 256), 16, 0, 0);
        }
    }

    float m_run[2][4], l_run[2][4];
    f32x4 oacc[2][3];
    #pragma unroll
    for (int m = 0; m < 2; ++m)
        #pragma unroll
        for (int r = 0; r < 4; ++r) { m_run[m][r] = -1e30f; l_run[m][r] = 0.f; }
    #pragma unroll
    for (int m = 0; m < 2; ++m)
        #pragma unroll
        for (int n = 0; n < 3; ++n) oacc[m][n] = (f32x4){0.f, 0.f, 0.f, 0.f};

    for (int it = 0; it < NRES / 64 / 2; ++it) {
        const int j0 = z * (NRES / 2) + it * 64;

        // ---- stage K (64 rows x 256B) ----
        {
            int rloc = l >> 4, s16v = l & 15;
            #pragma unroll
            for (int t = 0; t < 4; ++t) {
                int row = w * 16 + t * 4 + rloc;
                int ss = s16v ^ (row & 7);
                __builtin_amdgcn_global_load_lds(
                    (gvoid*)(keh + (size_t)(j0 + row) * 128 + ss * 8),
                    (lvoid*)((char*)Ks + (w * 16 + t * 4) * 256), 16, 0, 0);
            }
        }
        // ---- stage V (96 rows x 128B) ----
        {
            int rloc = l >> 3, s8 = l & 7;
            #pragma unroll
            for (int t = 0; t < 3; ++t) {
                int row = w * 24 + t * 8 + rloc;
                int ss = s8 ^ (row & 7);
                __builtin_amdgcn_global_load_lds(
                    (gvoid*)(vth + (size_t)row * NRES + j0 + ss * 8),
                    (lvoid*)((char*)Vs + (w * 24 + t * 8) * 128), 16, 0, 0);
            }
        }

        // ---- pb prefetch (overlaps staging drain) ----
        f32x4 pbv[2][2];
        const float* pbb = pb + ((size_t)h * NRES + (q0 + wr * 32 + fq * 4)) * NRES
                              + j0 + wc * 32 + fr;
        #pragma unroll
        for (int m = 0; m < 2; ++m)
            #pragma unroll
            for (int n = 0; n < 2; ++n)
                #pragma unroll
                for (int r = 0; r < 4; ++r)
                    pbv[m][n][r] = pbb[(size_t)(m * 16 + r) * NRES + n * 16];

        __syncthreads();

        // ---- S = Q K^T + pb ----
        f32x4 sacc[2][2];
        #pragma unroll
        for (int m = 0; m < 2; ++m)
            #pragma unroll
            for (int n = 0; n < 2; ++n) sacc[m][n] = (f32x4){0.f, 0.f, 0.f, 0.f};
        #pragma unroll
        for (int kk = 0; kk < 4; ++kk) {
            const int slotR = (kk * 4 + fq) ^ (fr & 7);
            short8 av[2], bv[2];
            #pragma unroll
            for (int m = 0; m < 2; ++m)
                av[m] = *(const short8*)((const char*)Qs + (wr * 32 + m * 16 + fr) * 256 + slotR * 16);
            #pragma unroll
            for (int n = 0; n < 2; ++n)
                bv[n] = *(const short8*)((const char*)Ks + (wc * 32 + n * 16 + fr) * 256 + slotR * 16);
            #pragma unroll
            for (int m = 0; m < 2; ++m)
                #pragma unroll
                for (int n = 0; n < 2; ++n)
                    sacc[m][n] = __builtin_amdgcn_mfma_f32_16x16x32_bf16(av[m], bv[n], sacc[m][n], 0, 0, 0);
        }
        #pragma unroll
        for (int m = 0; m < 2; ++m)
            #pragma unroll
            for (int n = 0; n < 2; ++n)
                sacc[m][n] += pbv[m][n];

        // ---- row max ----
        #pragma unroll
        for (int m = 0; m < 2; ++m)
            #pragma unroll
            for (int r = 0; r < 4; ++r) {
                float v = fmaxf(sacc[m][0][r], sacc[m][1][r]);
                v = fmaxf(v, __shfl_xor(v, 1, 64));
                v = fmaxf(v, __shfl_xor(v, 2, 64));
                v = fmaxf(v, __shfl_xor(v, 4, 64));
                v = fmaxf(v, __shfl_xor(v, 8, 64));
                if (fr == 0) redm[wc][wr][m * 16 + fq * 4 + r] = v;
            }
        __syncthreads();

        float alpha[2][4];
        #pragma unroll
        for (int m = 0; m < 2; ++m)
            #pragma unroll
            for (int r = 0; r < 4; ++r) {
                int row = m * 16 + fq * 4 + r;
                float t = fmaxf(redm[0][wr][row], redm[1][wr][row]);
                float mn = fmaxf(m_run[m][r], t);
                alpha[m][r] = exp2f((m_run[m][r] - mn) * LOG2E);
                m_run[m][r] = mn;
            }

        // ---- P = exp(S - m) -> Ps (swizzled) + partial sums ----
        float psum[2][4];
        #pragma unroll
        for (int m = 0; m < 2; ++m)
            #pragma unroll
            for (int r = 0; r < 4; ++r) psum[m][r] = 0.f;
        #pragma unroll
        for (int m = 0; m < 2; ++m) {
            #pragma unroll
            for (int n = 0; n < 2; ++n) {
                int col = wc * 32 + n * 16 + fr;
                #pragma unroll
                for (int r = 0; r < 4; ++r) {
                    float p = exp2f((sacc[m][n][r] - m_run[m][r]) * LOG2E);
                    psum[m][r] += p;
                    int rowf = wr * 32 + m * 16 + fq * 4 + r;
                    int byte = rowf * 128 + (((col >> 3) ^ (rowf & 7)) * 16) + (col & 7) * 2;
                    *(u16*)((char*)Ps + byte) = f2b(p);
                }
            }
        }
        #pragma unroll
        for (int m = 0; m < 2; ++m)
            #pragma unroll
            for (int r = 0; r < 4; ++r) {
                float v = psum[m][r];
                v += __shfl_xor(v, 1, 64);
                v += __shfl_xor(v, 2, 64);
                v += __shfl_xor(v, 4, 64);
                v += __shfl_xor(v, 8, 64);
                if (fr == 0) redl[wc][wr][m * 16 + fq * 4 + r] = v;
            }
        __syncthreads();

        #pragma unroll
        for (int m = 0; m < 2; ++m)
            #pragma unroll
            for (int r = 0; r < 4; ++r) {
                int row = m * 16 + fq * 4 + r;
                l_run[m][r] = l_run[m][r] * alpha[m][r] + redl[0][wr][row] + redl[1][wr][row];
            }
        #pragma unroll
        for (int m = 0; m < 2; ++m)
            #pragma unroll
            for (int n = 0; n < 3; ++n)
                #pragma unroll
                for (int r = 0; r < 4; ++r)
                    oacc[m][n][r] *= alpha[m][r];

        // ---- O += P V ----
        #pragma unroll
        for (int kk = 0; kk < 2; ++kk) {
            const int slotR = (kk * 4 + fq) ^ (fr & 7);
            short8 pa[2], vv[3];
            #pragma unroll
            for (int m = 0; m < 2; ++m)
                pa[m] = *(const short8*)((const char*)Ps + (wr * 32 + m * 16 + fr) * 128 + slotR * 16);
            #pragma unroll
            for (int n = 0; n < 3; ++n)
                vv[n] = *(const short8*)((const char*)Vs + (wc * 48 + n * 16 + fr) * 128 + slotR * 16);
            #pragma unroll
            for (int m = 0; m < 2; ++m)
                #pragma unroll
                for (int n = 0; n < 3; ++n)
                    oacc[m][n] = __builtin_amdgcn_mfma_f32_16x16x32_bf16(pa[m], vv[n], oacc[m][n], 0, 0, 0);
        }
        __syncthreads();
    }

    // ---- epilogue: unnormalized O + (m,l) partials ----
    float* Oz = Opart + ((size_t)z * NH + h) * NRES * 96;
    #pragma unroll
    for (int m = 0; m < 2; ++m) {
        #pragma unroll
        for (int n = 0; n < 3; ++n) {
            int c = wc * 48 + n * 16 + fr;
            #pragma unroll
            for (int r = 0; r < 4; ++r) {
                int row = q0 + wr * 32 + m * 16 + fq * 4 + r;
                Oz[(size_t)row * 96 + c] = oacc[m][n][r];
            }
        }
    }
    if (wc == 0 && fr == 0) {
        float* mlz = mlpart + (((size_t)z * NH + h) * NRES) * 2;
        #pragma unroll
        for (int m = 0; m < 2; ++m)
            #pragma unroll
            for (int r = 0; r < 4; ++r) {
                int row = q0 + wr * 32 + m * 16 + fq * 4 + r;
                mlz[row * 2 + 0] = m_run[m][r];
                mlz[row * 2 + 1] = l_run[m][r];
            }
    }
}

// ===================== split-KV combine -> cat =====================
__global__ __launch_bounds__(256) void combine_kernel(
    const float* __restrict__ Opart, const float* __restrict__ mlpart,
    float* __restrict__ cat)
{
    int idx = blockIdx.x * 256 + threadIdx.x;
    if (idx >= NH * NRES * 88) return;
    int c = idx % 88;
    int rh = idx / 88;
    size_t r0 = (size_t)rh;
    size_t r1 = (size_t)NH * NRES + r0;
    float m0 = mlpart[r0 * 2], l0 = mlpart[r0 * 2 + 1];
    float m1 = mlpart[r1 * 2], l1 = mlpart[r1 * 2 + 1];
    float mm = fmaxf(m0, m1);
    float w0 = exp2f((m0 - mm) * LOG2E);
    float w1 = exp2f((m1 - mm) * LOG2E);
    float ll = l0 * w0 + l1 * w1;
    cat[r0 * 88 + c] = (Opart[r0 * 96 + c] * w0 + Opart[r1 * 96 + c] * w1) / ll;
}

// ===================== batched transpose fp32 -> bf16 [N][K] =====================
struct TP9 { const float* p[9]; };

__global__ __launch_bounds__(256) void transpose_bz(
    TP9 tp, int ldi, size_t zsi,
    u16* __restrict__ out, int ldo, size_t zso, int K, int N, int nsrc)
{
    __shared__ float t[32][33];
    int z = blockIdx.z;
    const float* in = tp.p[(z < nsrc) ? z : 0] + zsi * ((z < nsrc) ? 0 : z);
    if (nsrc == 1) in = tp.p[0] + zsi * z;
    out += zso * z;
    int k0 = blockIdx.y * 32, n0 = blockIdx.x * 32;
    int tx = threadIdx.x & 31, ty = threadIdx.x >> 5;
    #pragma unroll
    for (int j = 0; j < 4; ++j) {
        int k = k0 + ty + j * 8;
        if (k < K && n0 + tx < N) t[ty + j * 8][tx] = in[(size_t)k * ldi + n0 + tx];
    }
    __syncthreads();
    #pragma unroll
    for (int j = 0; j < 4; ++j) {
        int n = n0 + ty + j * 8;
        int k = k0 + tx;
        if (n < N && k < K) out[(size_t)n * ldo + k] = f2b(t[tx][ty + j * 8]);
    }
}

// ===================== misc small kernels =====================
__global__ __launch_bounds__(256) void f2b_kernel(const float* __restrict__ in, u16* __restrict__ out, int n)
{
    int i = blockIdx.x * 256 + threadIdx.x;
    if (i < n) out[i] = f2b(in[i]);
}

__global__ __launch_bounds__(256) void emb_kernel(const float* __restrict__ pos, u16* __restrict__ emb)
{
    int idx = blockIdx.x * 256 + threadIdx.x;
    int f = idx & 63;
    int rest = idx >> 6;
    int coord = rest % 42;
    int n = rest / 42;
    float t = pos[(size_t)n * 42 + coord];
    const double l0 = -6.643856189774724;
    const double step = 14.643856189774724 / 63.0;
    float freq = exp2f((float)(l0 + f * step));
    float r = t * freq;
    size_t o = (size_t)n * 5376 + (size_t)coord * 128 + 2 * f;
    emb[o]     = f2b(sinf(r));
    emb[o + 1] = f2b(cosf(r));
}

__global__ __launch_bounds__(256) void frames_kernel(const float* __restrict__ pos,
                                                     float* __restrict__ Rb, float* __restrict__ tb)
{
    int n = blockIdx.x * 256 + threadIdx.x;
    if (n >= NRES) return;
    const float* p = pos + (size_t)n * 42;
    float nx = p[0], ny = p[1], nz = p[2];
    float cax = p[3], cay = p[4], caz = p[5];
    float cx = p[6], cy = p[7], cz = p[8];
    float v1x = cx - cax, v1y = cy - cay, v1z = cz - caz;
    float i1 = rsqrtf(v1x * v1x + v1y * v1y + v1z * v1z + 1e-8f);
    float e1x = v1x * i1, e1y = v1y * i1, e1z = v1z * i1;
    float v2x = nx - cax, v2y = ny - cay, v2z = nz - caz;
    float d = e1x * v2x + e1y * v2y + e1z * v2z;
    float wx = v2x - d * e1x, wy = v2y - d * e1y, wz = v2z - d * e1z;
    float i2 = rsqrtf(wx * wx + wy * wy + wz * wz + 1e-8f);
    float e2x = wx * i2, e2y = wy * i2, e2z = wz * i2;
    float e3x = e1y * e2z - e1z * e2y;
    float e3y = e1z * e2x - e1x * e2z;
    float e3z = e1x * e2y - e1y * e2x;
    float* R = Rb + (size_t)n * 9;
    R[0] = e1x; R[1] = e2x; R[2] = e3x;
    R[3] = e1y; R[4] = e2y; R[5] = e3y;
    R[6] = e1z; R[7] = e2z; R[8] = e3z;
    tb[(size_t)n * 3 + 0] = cax;
    tb[(size_t)n * 3 + 1] = cay;
    tb[(size_t)n * 3 + 2] = caz;
}

__global__ __launch_bounds__(256) void condnorm_bf16(const float* __restrict__ xb,
                                                     const float* __restrict__ cs,
                                                     const float* __restrict__ cb,
                                                     u16* __restrict__ outb)
{
    int i = blockIdx.x, tid = threadIdx.x;
    size_t base = (size_t)i * 1024 + tid * 4;
    float4 xv = *reinterpret_cast<const float4*>(xb + base);
    float s = xv.x + xv.y + xv.z + xv.w;
    float q = xv.x * xv.x + xv.y * xv.y + xv.z * xv.z + xv.w * xv.w;
    __shared__ float r1[256], r2[256];
    r1[tid] = s; r2[tid] = q;
    __syncthreads();
    for (int st = 128; st > 0; st >>= 1) {
        if (tid < st) { r1[tid] += r1[tid + st]; r2[tid] += r2[tid + st]; }
        __syncthreads();
    }
    float mean = r1[0] * (1.f / 1024.f);
    float var = r2[0] * (1.f / 1024.f) - mean * mean;
    float rs = rsqrtf(var + 1e-5f);
    float4 sv = *reinterpret_cast<const float4*>(cs + base);
    float4 bv = *reinterpret_cast<const float4*>(cb + base);
    outb[base + 0] = f2b((1.f / (1.f + expf(-sv.x))) * (xv.x - mean) * rs + bv.x);
    outb[base + 1] = f2b((1.f / (1.f + expf(-sv.y))) * (xv.y - mean) * rs + bv.y);
    outb[base + 2] = f2b((1.f / (1.f + expf(-sv.z))) * (xv.z - mean) * rs + bv.z);
    outb[base + 3] = f2b((1.f / (1.f + expf(-sv.w))) * (xv.w - mean) * rs + bv.w);
}

__global__ __launch_bounds__(256) void bias_pack(const float* a, const float* b, const float* c,
                                                 const float* d, const float* e, const float* f,
                                                 float* out)
{
    int i = blockIdx.x * 256 + threadIdx.x;
    if (i >= 1024) return;
    out[i] = a[i]; out[1024 + i] = b[i]; out[2048 + i] = c[i];
    out[3072 + i] = d[i]; out[4096 + i] = e[i]; out[5120 + i] = f[i];
}

// full-width pack: writes c<64 from q/k and zeros c>=89 (cols 64..88 filled by build_pts)
__global__ __launch_bounds__(256) void pack_qk(const float* __restrict__ qb, const float* __restrict__ kb,
                                               u16* __restrict__ qe, u16* __restrict__ ke)
{
    int idx = blockIdx.x * 256 + threadIdx.x;   // < 16*1536*128
    int c = idx & 127;
    int t = idx >> 7;
    int n = t % NRES;
    int h = t / NRES;
    size_t o = (size_t)idx;
    if (c < 64) {
        size_t src = (size_t)n * 1024 + h * 64 + c;
        qe[o] = f2b(0.125f * qb[src]);
        ke[o] = f2b(kb[src]);
    } else if (c >= 89) {
        qe[o] = 0;
        ke[o] = 0;
    }
}

__global__ __launch_bounds__(256) void build_pts(
    const float* __restrict__ qp, const float* __restrict__ kp, const float* __restrict__ vp,
    const float* __restrict__ Rb, const float* __restrict__ tb, const float* __restrict__ gamma,
    u16* __restrict__ qe, u16* __restrict__ ke, float* __restrict__ vgt)
{
    int idx = blockIdx.x * 256 + threadIdx.x;
    if (idx >= NRES * NH) return;
    int n = idx >> 4, h = idx & 15;
    float R[9];
    #pragma unroll
    for (int a = 0; a < 9; ++a) R[a] = Rb[(size_t)n * 9 + a];
    float t0 = tb[(size_t)n * 3 + 0], t1 = tb[(size_t)n * 3 + 1], t2 = tb[(size_t)n * 3 + 2];
    float g = gamma[h];
    float sp = (g > 20.f) ? g : log1pf(expf(g));
    float ch = 0.5f * (1.f / 6.f) * sp;

    u16* qeh = qe + ((size_t)h * NRES + n) * 128;
    u16* keh = ke + ((size_t)h * NRES + n) * 128;
    size_t pbase = (size_t)n * 384 + h * 24;
    float kn = 0.f;
    #pragma unroll
    for (int p = 0; p < 8; ++p) {
        size_t o = pbase + p * 3;
        {
            float x = qp[o], y = qp[o + 1], z = qp[o + 2];
            float g0 = R[0] * x + R[1] * y + R[2] * z + t0;
            float g1 = R[3] * x + R[4] * y + R[5] * z + t1;
            float g2 = R[6] * x + R[7] * y + R[8] * z + t2;
            qeh[64 + p * 3 + 0] = f2b(2.f * ch * g0);
            qeh[64 + p * 3 + 1] = f2b(2.f * ch * g1);
            qeh[64 + p * 3 + 2] = f2b(2.f * ch * g2);
        }
        {
            float x = kp[o], y = kp[o + 1], z = kp[o + 2];
            float g0 = R[0] * x + R[1] * y + R[2] * z + t0;
            float g1 = R[3] * x + R[4] * y + R[5] * z + t1;
            float g2 = R[6] * x + R[7] * y + R[8] * z + t2;
            keh[64 + p * 3 + 0] = f2b(g0);
            keh[64 + p * 3 + 1] = f2b(g1);
            keh[64 + p * 3 + 2] = f2b(g2);
            kn += g0 * g0 + g1 * g1 + g2 * g2;
        }
        {
            float x = vp[o], y = vp[o + 1], z = vp[o + 2];
            vgt[o]     = R[0] * x + R[1] * y + R[2] * z + t0;
            vgt[o + 1] = R[3] * x + R[4] * y + R[5] * z + t1;
            vgt[o + 2] = R[6] * x + R[7] * y + R[8] * z + t2;
        }
    }
    qeh[88] = f2b(1.0f);
    keh[88] = f2b(-ch * kn);
}

__global__ __launch_bounds__(256) void finalize_kernel(const float* __restrict__ cat,
                                                       const float* __restrict__ Rb,
                                                       const float* __restrict__ tb,
                                                       u16* __restrict__ featB)
{
    int idx = blockIdx.x * 256 + threadIdx.x;
    if (idx >= NRES * NH) return;
    int n = idx >> 4, h = idx & 15;
    float R[9];
    #pragma unroll
    for (int a = 0; a < 9; ++a) R[a] = Rb[(size_t)n * 9 + a];
    float t0 = tb[(size_t)n * 3 + 0], t1 = tb[(size_t)n * 3 + 1], t2 = tb[(size_t)n * 3 + 2];
    const float* c = cat + ((size_t)h * NRES + n) * 88;
    u16* fb = featB + (size_t)n * 1536;
    #pragma unroll
    for (int k = 0; k < 64; ++k) fb[h * 64 + k] = f2b(c[k]);
    #pragma unroll
    for (int p = 0; p < 8; ++p) {
        float x = c[64 + p * 3 + 0] - t0;
        float y = c[64 + p * 3 + 1] - t1;
        float z = c[64 + p * 3 + 2] - t2;
        float a0 = R[0] * x + R[3] * y + R[6] * z;
        float a1 = R[1] * x + R[4] * y + R[7] * z;
        float a2 = R[2] * x + R[5] * y + R[8] * z;
        fb[1024 + h * 24 + p * 3 + 0] = f2b(a0);
        fb[1024 + h * 24 + p * 3 + 1] = f2b(a1);
        fb[1024 + h * 24 + p * 3 + 2] = f2b(a2);
        fb[1408 + h * 8 + p] = f2b(sqrtf(a0 * a0 + a1 * a1 + a2 * a2 + 1e-8f));
    }
}

// ========================= host =========================
extern "C" void kernel_launch(void* const* d_in, const int* in_sizes, int n_in,
                              void* d_out, int out_size, void* d_ws, size_t ws_size,
                              hipStream_t stream)
{
    const float* local_in = (const float*)d_in[0];
    const float* pos      = (const float*)d_in[1];
    const float* cond     = (const float*)d_in[2];
    const float* pb       = (const float*)d_in[4];
    const float* w_f1     = (const float*)d_in[5];
    const float* b_f1     = (const float*)d_in[6];
    const float* w_f2     = (const float*)d_in[7];
    const float* b_f2     = (const float*)d_in[8];
    const float* cn1_ws   = (const float*)d_in[9];
    const float* cn1_bs   = (const float*)d_in[10];
    const float* cn1_wb   = (const float*)d_in[11];
    const float* cn1_bb   = (const float*)d_in[12];
    const float* wq       = (const float*)d_in[13];
    const float* wk       = (const float*)d_in[14];
    const float* wv       = (const float*)d_in[15];
    const float* wqp      = (const float*)d_in[16];
    const float* wkp      = (const float*)d_in[17];
    const float* wvp      = (const float*)d_in[18];
    const float* gamma    = (const float*)d_in[19];
    const float* wo       = (const float*)d_in[20];
    const float* bo       = (const float*)d_in[21];
    const float* cn2_ws   = (const float*)d_in[22];
    const float* cn2_bs   = (const float*)d_in[23];
    const float* cn2_wb   = (const float*)d_in[24];
    const float* cn2_bb   = (const float*)d_in[25];
    const float* wg1      = (const float*)d_in[26];
    const float* bg1      = (const float*)d_in[27];
    const float* wg2      = (const float*)d_in[28];
    const float* bg2      = (const float*)d_in[29];
    const float* wg3      = (const float*)d_in[30];
    const float* bg3      = (const float*)d_in[31];
    const float* cn3_ws   = (const float*)d_in[32];
    const float* cn3_bs   = (const float*)d_in[33];
    const float* cn3_wb   = (const float*)d_in[34];
    const float* cn3_bb   = (const float*)d_in[35];
    const float* w_vel    = (const float*)d_in[36];

    float* out = (float*)d_out;
    float* ws  = (float*)d_ws;

    size_t off = 0;
    auto alloc = [&](size_t nf) -> float* { float* p = ws + off; off += (nf + 7) & ~7ull; return p; };

    const size_t NN1 = (size_t)NRES * 1024;
    float* Rb    = alloc(NRES * 9);
    float* tb    = alloc(NRES * 3);
    float* loc   = alloc(NN1);
    float* cs6   = alloc(6 * NN1);
    u16*   condB = (u16*)alloc(NN1 / 2);
    u16*   normB = (u16*)alloc(NN1 / 2);
    float* bias2 = alloc(6 * 1024);
    float* qb    = alloc(3 * NN1);
    float* kb    = qb + NN1;
    float* vb    = kb + NN1;
    float* qp    = alloc(3 * (size_t)NRES * 384);
    float* kp    = qp + NRES * 384;
    float* vp    = kp + NRES * 384;
    float* vgt   = alloc((size_t)NRES * 384);
    u16*   qeB   = (u16*)alloc((size_t)NH * NRES * 128 / 2);
    u16*   keB   = (u16*)alloc((size_t)NH * NRES * 128 / 2);
    u16*   vTB   = (u16*)alloc((size_t)NH * 96 * NRES / 2);
    float* cat   = alloc((size_t)NH * NRES * 88);
    u16*   featB = (u16*)alloc((size_t)NRES * 1536 / 2);
    u16*   g1sB  = (u16*)alloc((size_t)NRES * 2048 / 2);
    u16*   gmB   = (u16*)alloc((size_t)NRES * 2048 / 2);
    u16*   cnT9  = (u16*)alloc((size_t)9 * 1024 * 1024 / 2);
    u16*   ptsT  = (u16*)alloc((size_t)3 * 384 * 1024 / 2);
    u16*   wgT   = (u16*)alloc((size_t)2 * 2048 * 1024 / 2);
    u16*   wf1T  = (u16*)alloc((size_t)2048 * 5376 / 2);
    u16*   wf2T  = (u16*)alloc((size_t)1024 * 2048 / 2);
    u16*   woT   = (u16*)alloc((size_t)1024 * 1536 / 2);
    u16*   wg3T  = (u16*)alloc((size_t)1024 * 2048 / 2);
    u16*   wvT   = (u16*)alloc((size_t)42 * 1024 / 2 + 8);
    u16*   embB  = (u16*)alloc((size_t)NRES * 5376 / 2);
    u16*   hidB  = (u16*)alloc((size_t)NRES * 2048 / 2);
    float* pscr  = alloc((size_t)3 * NRES * 2048);          // split-K partials (37.7 MB)
    float* Opart = alloc((size_t)2 * NH * NRES * 96);       // 18.9 MB
    float* mlprt = alloc((size_t)2 * NH * NRES * 2);

    const float* nilf = nullptr;
    const u16*   nilb = nullptr;

    auto gemm = [&](int tnf, const u16* A, int lda, size_t zsA,
                    const u16* BT, int ldb, size_t zsB,
                    float* Cf, u16* Cb2, int ldc, size_t zsC,
                    const float* bias, size_t zsBias,
                    const float* resid, int ldr, size_t zsR,
                    const u16* mulb, int ldm,
                    int Nc, int Kd, int flags, int gz, int ksl) {
        int tn = tnf * 32;
        dim3 grid((Nc + tn - 1) / tn, NRES / 128, gz);
        if (tnf == 4)
            hipLaunchKernelGGL(gemm_t<4>, grid, dim3(256), 0, stream,
                               A, lda, zsA, BT, ldb, zsB, Cf, Cb2, ldc, zsC,
                               bias, zsBias, resid, ldr, zsR, mulb, ldm, Nc, Kd, flags, ksl);
        else
            hipLaunchKernelGGL(gemm_t<2>, grid, dim3(256), 0, stream,
                               A, lda, zsA, BT, ldb, zsB, Cf, Cb2, ldc, zsC,
                               bias, zsBias, resid, ldr, zsR, mulb, ldm, Nc, Kd, flags, ksl);
    };
    auto red = [&](const float* part, size_t slice, int nsl, float* Cf, u16* Cb2,
                   const float* bias, const float* resid, int ldr,
                   const u16* mulb, int ldm, int Nc, int flags) {
        hipLaunchKernelGGL(reduce_epi, dim3(1024), dim3(256), 0, stream,
                           part, slice, nsl, Cf, Cb2, bias, resid, ldr, mulb, ldm,
                           NRES, Nc, flags);
    };
    auto tpz = [&](TP9 tp, int ldi, int K, int N, u16* o, int ldo, size_t zso, int nsrc) {
        dim3 grid((N + 31) / 32, (K + 31) / 32, nsrc);
        hipLaunchKernelGGL(transpose_bz, grid, dim3(256), 0, stream, tp, ldi, (size_t)0, o, ldo, zso, K, N, nsrc);
    };
    auto tps = [&](const float* in, int ldi, size_t zsi, int K, int N, u16* o, int ldo, size_t zso, int gz) {
        dim3 grid((N + 31) / 32, (K + 31) / 32, gz);
        TP9 tp; tp.p[0] = in;
        hipLaunchKernelGGL(transpose_bz, grid, dim3(256), 0, stream, tp, ldi, zsi, o, ldo, zso, K, N, 1);
    };

    // ---- prologue ----
    hipLaunchKernelGGL(frames_kernel, dim3(6), dim3(256), 0, stream, pos, Rb, tb);
    hipLaunchKernelGGL(emb_kernel, dim3((NRES * 42 * 64) / 256), dim3(256), 0, stream, pos, embB);
    hipLaunchKernelGGL(f2b_kernel, dim3(6144), dim3(256), 0, stream, cond, condB, NRES * 1024);
    hipLaunchKernelGGL(bias_pack, dim3(4), dim3(256), 0, stream,
                       cn1_bs, cn1_bb, cn2_bs, cn2_bb, cn3_bs, cn3_bb, bias2);

    // ---- weight transposes ----
    {
        TP9 t9; t9.p[0]=cn1_ws; t9.p[1]=cn1_wb; t9.p[2]=cn2_ws; t9.p[3]=cn2_wb;
        t9.p[4]=cn3_ws; t9.p[5]=cn3_wb; t9.p[6]=wq; t9.p[7]=wk; t9.p[8]=wv;
        tpz(t9, 1024, 1024, 1024, cnT9, 1024, (size_t)1024 * 1024, 9);
    }
    {
        TP9 t3; t3.p[0]=wqp; t3.p[1]=wkp; t3.p[2]=wvp;
        tpz(t3, 384, 1024, 384, ptsT, 1024, (size_t)384 * 1024, 3);
    }
    {
        TP9 t2; t2.p[0]=wg1; t2.p[1]=wg2;
        tpz(t2, 2048, 1024, 2048, wgT, 1024, (size_t)2048 * 1024, 2);
    }
    tps(w_f1, 2048, 0, 5376, 2048, wf1T, 5376, 0, 1);
    tps(w_f2, 1024, 0, 2048, 1024, wf2T, 2048, 0, 1);
    tps(wo,   1024, 0, 1536, 1024, woT,  1536, 0, 1);
    tps(wg3,  1024, 0, 2048, 1024, wg3T, 2048, 0, 1);
    tps(w_vel,  42, 0, 1024,   42, wvT,  1024, 0, 1);

    // ---- all 6 cond GEMMs (z=6, TN=128, 576 blocks) ----
    gemm(4, condB, 1024, 0, cnT9, 1024, (size_t)1024 * 1024, cs6, nullptr, 1024, NN1,
         bias2, 1024, nilf, 0, 0, nilb, 0, 1024, 1024, F_BIAS, 6, 0);

    // ---- phase A: emb GEMM split-K=3 + reduce(silu->bf16) ----
    gemm(4, embB, 5376, 0, wf1T, 5376, 0, pscr, nullptr, 2048, (size_t)NRES * 2048,
         nilf, 0, nilf, 0, 0, nilb, 0, 2048, 5376, 0, 3, 1792);
    red(pscr, (size_t)NRES * 2048, 3, nullptr, hidB, b_f1, nilf, 0, nilb, 0,
        2048, F_BIAS | F_SILU | F_OUTBF);
    gemm(2, hidB, 2048, 0, wf2T, 2048, 0, pscr, nullptr, 1024, NN1,
         nilf, 0, nilf, 0, 0, nilb, 0, 1024, 2048, 0, 2, 1024);
    red(pscr, NN1, 2, loc, nullptr, b_f2, local_in, 1024, nilb, 0,
        1024, F_BIAS | F_RESID);

    // ---- cond_norm 1 ----
    hipLaunchKernelGGL(condnorm_bf16, dim3(NRES), dim3(256), 0, stream, loc, cs6, cs6 + NN1, normB);

    // ---- projections ----
    gemm(2, normB, 1024, 0, cnT9 + (size_t)6 * 1024 * 1024, 1024, (size_t)1024 * 1024,
         qb, nullptr, 1024, NN1, nilf, 0, nilf, 0, 0, nilb, 0, 1024, 1024, 0, 3, 0);
    gemm(2, normB, 1024, 0, ptsT, 1024, (size_t)384 * 1024, qp, nullptr, 384, (size_t)NRES * 384,
         nilf, 0, nilf, 0, 0, nilb, 0, 384, 1024, 0, 3, 0);

    // ---- attention operands ----
    hipMemsetAsync(vTB, 0, (size_t)NH * 96 * NRES * 2, stream);
    hipLaunchKernelGGL(pack_qk, dim3((NH * NRES * 128) / 256), dim3(256), 0, stream, qb, kb, qeB, keB);
    hipLaunchKernelGGL(build_pts, dim3(96), dim3(256), 0, stream,
                       qp, kp, vp, Rb, tb, gamma, qeB, keB, vgt);
    tps(vb, 1024, 64, NRES, 64, vTB, NRES, (size_t)96 * NRES, NH);
    tps(vgt, 384, 24, NRES, 24, vTB + (size_t)64 * NRES, NRES, (size_t)96 * NRES, NH);

    // ---- fused attention (split-KV) + combine ----
    hipLaunchKernelGGL(attn_kernel, dim3(NRES / 64, NH, 2), dim3(256), 0, stream,
                       qeB, keB, vTB, pb, Opart, mlprt);
    hipLaunchKernelGGL(combine_kernel, dim3((NH * NRES * 88 + 255) / 256), dim3(256), 0, stream,
                       Opart, mlprt, cat);
    hipLaunchKernelGGL(finalize_kernel, dim3(96), dim3(256), 0, stream, cat, Rb, tb, featB);

    // ---- local += feat @ wo + bo : split-K=2 ----
    gemm(2, featB, 1536, 0, woT, 1536, 0, pscr, nullptr, 1024, NN1,
         nilf, 0, nilf, 0, 0, nilb, 0, 1024, 1536, 0, 2, 768);
    red(pscr, NN1, 2, loc, nullptr, bo, loc, 1024, nilb, 0, 1024, F_BIAS | F_RESID);

    // ---- cond_norm 2 + gated MLP ----
    hipLaunchKernelGGL(condnorm_bf16, dim3(NRES), dim3(256), 0, stream, loc, cs6 + 2 * NN1, cs6 + 3 * NN1, normB);
    gemm(2, normB, 1024, 0, wgT, 1024, 0, nullptr, g1sB, 2048, 0,
         bg1, 0, nilf, 0, 0, nilb, 0, 2048, 1024, F_BIAS | F_SILU | F_OUTBF, 1, 0);
    gemm(2, normB, 1024, 0, wgT + (size_t)2048 * 1024, 1024, 0, nullptr, gmB, 2048, 0,
         bg2, 0, nilf, 0, 0, g1sB, 2048, 2048, 1024, F_BIAS | F_MUL | F_OUTBF, 1, 0);
    gemm(2, gmB, 2048, 0, wg3T, 2048, 0, pscr, nullptr, 1024, NN1,
         nilf, 0, nilf, 0, 0, nilb, 0, 1024, 2048, 0, 2, 1024);
    red(pscr, NN1, 2, out, nullptr, bg3, loc, 1024, nilb, 0, 1024, F_BIAS | F_RESID);

    // ---- cond_norm 3 + velocity (split-K=8) ----
    hipLaunchKernelGGL(condnorm_bf16, dim3(NRES), dim3(256), 0, stream, out, cs6 + 4 * NN1, cs6 + 5 * NN1, normB);
    gemm(2, normB, 1024, 0, wvT, 1024, 0, pscr, nullptr, 42, (size_t)NRES * 42,
         nilf, 0, nilf, 0, 0, nilb, 0, 42, 1024, 0, 8, 128);
    red(pscr, (size_t)NRES * 42, 8, out + (size_t)NRES * 1024, nullptr,
        nilf, nilf, 0, nilb, 0, 42, 0);
}

// Round 6
// 656.959 us; speedup vs baseline: 1.0706x; 1.0706x over previous
//
#include <hip/hip_runtime.h>
#include <hip/hip_bf16.h>
#include <math.h>

#define NRES 1536
#define NH 16
#define NNF 2359296ull    // NRES*NRES
#define LOG2E 1.44269504f

typedef unsigned short u16;
typedef __attribute__((ext_vector_type(8))) short short8;
typedef __attribute__((ext_vector_type(4))) float f32x4;

typedef const __attribute__((address_space(1))) void gvoid;
typedef __attribute__((address_space(3))) void lvoid;

__device__ __forceinline__ u16 f2b(float x){
    __hip_bfloat16 h = __float2bfloat16(x);
    return *reinterpret_cast<u16*>(&h);
}
__device__ __forceinline__ float b2f(u16 u){
    unsigned v = ((unsigned)u) << 16;
    return __uint_as_float(v);
}

// ===================== bf16 MFMA GEMM (templated tile-N, optional split-K) ==========
#define F_BIAS  1
#define F_SILU  2
#define F_MUL   4
#define F_RESID 8
#define F_OUTBF 16

template<int TNF>
__global__ __launch_bounds__(256) void gemm_t(
    const u16* __restrict__ A, int lda, size_t zsA,
    const u16* __restrict__ BT, int ldb, size_t zsB,
    float* __restrict__ Cf, u16* __restrict__ Cb, int ldc, size_t zsC,
    const float* __restrict__ bias, size_t zsBias,
    const float* __restrict__ resid, int ldr, size_t zsR,
    const u16* __restrict__ mulb, int ldm,
    int Ncols, int Kd, int flags, int ksl)
{
    constexpr int TN = TNF * 32;
    __shared__ u16 As[128 * 64];
    __shared__ u16 Bs[TN * 64];

    const int tid = threadIdx.x;
    const int l = tid & 63, w = tid >> 6;
    const int bz = blockIdx.z;
    const int bm = blockIdx.y * 128, bn = blockIdx.x * TN;

    A  += zsA * bz;
    BT += zsB * bz;

    const int kbeg = ksl ? bz * ksl : 0;
    const int kend = ksl ? kbeg + ksl : Kd;

    const int arow   = l >> 3;
    const int aslot  = l & 7;
    const int srcslt = aslot ^ arow;

    const u16* aBase[4];
    const u16* bBase[TN / 32];
    #pragma unroll
    for (int t = 0; t < 4; ++t) {
        int ra = bm + (w * 4 + t) * 8 + arow;
        aBase[t] = A + (size_t)ra * lda + srcslt * 8;
    }
    #pragma unroll
    for (int t = 0; t < TN / 32; ++t) {
        int rb = bn + (w * (TN / 32) + t) * 8 + arow;
        if (rb > Ncols - 1) rb = Ncols - 1;
        bBase[t] = BT + (size_t)rb * ldb + srcslt * 8;
    }

    const int wr = w >> 1, wc = w & 1;
    const int fr = l & 15;
    const int fq = l >> 4;

    f32x4 acc[4][TNF];
    #pragma unroll
    for (int i = 0; i < 4; ++i)
        #pragma unroll
        for (int j = 0; j < TNF; ++j) acc[i][j] = (f32x4){0.f, 0.f, 0.f, 0.f};

    for (int k0 = kbeg; k0 < kend; k0 += 64) {
        #pragma unroll
        for (int t = 0; t < 4; ++t)
            __builtin_amdgcn_global_load_lds((gvoid*)(aBase[t] + k0),
                (lvoid*)((char*)As + (w * 4 + t) * 1024), 16, 0, 0);
        #pragma unroll
        for (int t = 0; t < TN / 32; ++t)
            __builtin_amdgcn_global_load_lds((gvoid*)(bBase[t] + k0),
                (lvoid*)((char*)Bs + (w * (TN / 32) + t) * 1024), 16, 0, 0);
        __syncthreads();
        #pragma unroll
        for (int kk = 0; kk < 2; ++kk) {
            const int slotR = ((kk * 4) + fq) ^ (l & 7);
            short8 av[4], bv[TNF];
            #pragma unroll
            for (int m = 0; m < 4; ++m) {
                int r = wr * 64 + m * 16 + fr;
                av[m] = *(const short8*)((const char*)As + r * 128 + slotR * 16);
            }
            #pragma unroll
            for (int n = 0; n < TNF; ++n) {
                int r = wc * (TNF * 16) + n * 16 + fr;
                bv[n] = *(const short8*)((const char*)Bs + r * 128 + slotR * 16);
            }
            #pragma unroll
            for (int m = 0; m < 4; ++m)
                #pragma unroll
                for (int n = 0; n < TNF; ++n)
                    acc[m][n] = __builtin_amdgcn_mfma_f32_16x16x32_bf16(av[m], bv[n], acc[m][n], 0, 0, 0);
        }
        __syncthreads();
    }

    const float* residz = (flags & F_RESID) ? resid + zsR * bz : nullptr;
    const float* biasz  = (flags & F_BIAS)  ? bias + zsBias * bz : nullptr;
    float* cfz = Cf ? Cf + zsC * bz : nullptr;
    u16*   cbz = Cb ? Cb + zsC * bz : nullptr;

    #pragma unroll
    for (int m = 0; m < 4; ++m) {
        #pragma unroll
        for (int n = 0; n < TNF; ++n) {
            int gc = bn + wc * (TNF * 16) + n * 16 + fr;
            if (gc >= Ncols) continue;
            int gr0 = bm + wr * 64 + m * 16 + fq * 4;
            #pragma unroll
            for (int r = 0; r < 4; ++r) {
                int gr = gr0 + r;
                float v = acc[m][n][r];
                if (flags & F_BIAS)  v += biasz[gc];
                if (flags & F_SILU)  v = v / (1.f + expf(-v));
                if (flags & F_MUL)   v *= b2f(mulb[(size_t)gr * ldm + gc]);
                if (flags & F_RESID) v += residz[(size_t)gr * ldr + gc];
                if (flags & F_OUTBF) cbz[(size_t)gr * ldc + gc] = f2b(v);
                else                 cfz[(size_t)gr * ldc + gc] = v;
            }
        }
    }
}

// ===================== split-K reduce + fused epilogue =====================
__global__ __launch_bounds__(256) void reduce_epi(
    const float* __restrict__ part, size_t slice, int nsl,
    float* __restrict__ Cf, u16* __restrict__ Cb,
    const float* __restrict__ bias,
    const float* __restrict__ resid, int ldr,
    const u16* __restrict__ mulb, int ldm,
    int M, int Ncols, int flags)
{
    size_t total = (size_t)M * Ncols;
    for (size_t i = (size_t)blockIdx.x * 256 + threadIdx.x; i < total;
         i += (size_t)gridDim.x * 256) {
        int r = (int)(i / (unsigned)Ncols);
        int c = (int)(i - (size_t)r * Ncols);
        float v = 0.f;
        for (int s = 0; s < nsl; ++s) v += part[(size_t)s * slice + i];
        if (flags & F_BIAS)  v += bias[c];
        if (flags & F_SILU)  v = v / (1.f + expf(-v));
        if (flags & F_MUL)   v *= b2f(mulb[(size_t)r * ldm + c]);
        if (flags & F_RESID) v += resid[(size_t)r * ldr + c];
        if (flags & F_OUTBF) Cb[i] = f2b(v);
        else                 Cf[i] = v;
    }
}

// ===================== fused flash attention v3 =====================
// grid (24 q-tiles, 16 heads, 2 kv-halves), 256 threads = 4 waves.
// Wave-owns-rows layout: wave w computes S rows q0+w*16..+16 x all 64 KV cols.
// Softmax fully wave-local (no cross-wave reduction). ONE barrier per iteration.
// K/V double-buffered in LDS (64KB -> 2 blocks/CU); pb double-buffered in regs;
// stage(t+1)+pb(t+1) issued BEFORE compute(t) so the syncthreads vmcnt-drain
// lands after compute -> HBM latency hidden.
__global__ __launch_bounds__(256, 2) void attn_kernel(
    const u16* __restrict__ qe, const u16* __restrict__ ke,
    const u16* __restrict__ vt, const float* __restrict__ pb,
    float* __restrict__ Opart, float* __restrict__ mlpart)
{
    __shared__ u16 Ks[2][64 * 128];   // 2 x 16 KB, rows 256B, XOR-swizzled slots
    __shared__ u16 Vs[2][96 * 64];    // 2 x 12 KB, [channel][j], rows 128B
    __shared__ u16 Ps[64 * 64];       // 8 KB, wave-private 16-row strips

    const int tid = threadIdx.x;
    const int l = tid & 63, w = tid >> 6;
    const int h = blockIdx.y;
    const int q0 = blockIdx.x * 64;
    const int z = blockIdx.z;
    const int fr = l & 15, fq = l >> 4;

    const u16* keh = ke + (size_t)h * NRES * 128;
    const u16* vth = vt + (size_t)h * 96 * NRES;

    const int kr4 = l >> 4, ks16 = l & 15;   // K staging
    const int vr8 = l >> 3, vs8 = l & 7;     // V staging

    // ---- Q fragments in registers (wave w owns S-rows q0+w*16..+16) ----
    short8 qv[4];
    {
        const u16* qrow = qe + ((size_t)h * NRES + (q0 + w * 16 + fr)) * 128 + fq * 8;
        #pragma unroll
        for (int kk = 0; kk < 4; ++kk)
            qv[kk] = *(const short8*)(qrow + kk * 32);
    }

    float m_run[4], l_run[4];
    f32x4 oacc[6];
    #pragma unroll
    for (int r = 0; r < 4; ++r) { m_run[r] = -1e30f; l_run[r] = 0.f; }
    #pragma unroll
    for (int n = 0; n < 6; ++n) oacc[n] = (f32x4){0.f, 0.f, 0.f, 0.f};

    const int NIT = NRES / 128;   // 12 tiles of 64 per z-half
    const int jbase = z * (NRES / 2);
    int cur = 0;

    auto stage = [&](int buf, int j0) {
        #pragma unroll
        for (int t = 0; t < 4; ++t) {
            int row = w * 16 + t * 4 + kr4;
            int ss = ks16 ^ (row & 7);
            __builtin_amdgcn_global_load_lds(
                (gvoid*)(keh + (size_t)(j0 + row) * 128 + ss * 8),
                (lvoid*)((char*)Ks[buf] + (w * 16 + t * 4) * 256), 16, 0, 0);
        }
        #pragma unroll
        for (int t = 0; t < 3; ++t) {
            int row = w * 24 + t * 8 + vr8;
            int ss = vs8 ^ (row & 7);
            __builtin_amdgcn_global_load_lds(
                (gvoid*)(vth + (size_t)row * NRES + j0 + ss * 8),
                (lvoid*)((char*)Vs[buf] + (w * 24 + t * 8) * 128), 16, 0, 0);
        }
    };
    const float* pbrow = pb + ((size_t)h * NRES + (q0 + w * 16 + fq * 4)) * NRES + fr;

    f32x4 pbv[4], pbn[4] = {};
    stage(0, jbase);
    #pragma unroll
    for (int n = 0; n < 4; ++n)
        #pragma unroll
        for (int r = 0; r < 4; ++r)
            pbv[n][r] = pbrow[(size_t)r * NRES + jbase + n * 16];
    __syncthreads();

    for (int it = 0; it < NIT; ++it) {
        if (it + 1 < NIT) {
            int j1 = jbase + (it + 1) * 64;
            stage(cur ^ 1, j1);
            #pragma unroll
            for (int n = 0; n < 4; ++n)
                #pragma unroll
                for (int r = 0; r < 4; ++r)
                    pbn[n][r] = pbrow[(size_t)r * NRES + j1 + n * 16];
        }

        // ---- S = Q K^T + pb ----
        f32x4 sacc[4];
        #pragma unroll
        for (int n = 0; n < 4; ++n) sacc[n] = (f32x4){0.f, 0.f, 0.f, 0.f};
        #pragma unroll
        for (int kk = 0; kk < 4; ++kk) {
            #pragma unroll
            for (int n = 0; n < 4; ++n) {
                int row = n * 16 + fr;
                short8 bv = *(const short8*)((const char*)Ks[cur] + row * 256
                                             + (((kk * 4 + fq) ^ (fr & 7)) * 16));
                sacc[n] = __builtin_amdgcn_mfma_f32_16x16x32_bf16(qv[kk], bv, sacc[n], 0, 0, 0);
            }
        }
        #pragma unroll
        for (int n = 0; n < 4; ++n) sacc[n] += pbv[n];

        // ---- wave-local row max + rescale factor ----
        float alpha[4];
        #pragma unroll
        for (int r = 0; r < 4; ++r) {
            float v = fmaxf(fmaxf(sacc[0][r], sacc[1][r]), fmaxf(sacc[2][r], sacc[3][r]));
            v = fmaxf(v, __shfl_xor(v, 1, 64));
            v = fmaxf(v, __shfl_xor(v, 2, 64));
            v = fmaxf(v, __shfl_xor(v, 4, 64));
            v = fmaxf(v, __shfl_xor(v, 8, 64));
            float mn = fmaxf(m_run[r], v);
            alpha[r] = exp2f((m_run[r] - mn) * LOG2E);
            m_run[r] = mn;
        }

        // ---- P = exp(S-m) -> Ps (wave-private strip) + wave-local sums ----
        float psum[4] = {0.f, 0.f, 0.f, 0.f};
        #pragma unroll
        for (int n = 0; n < 4; ++n) {
            int col = n * 16 + fr;
            #pragma unroll
            for (int r = 0; r < 4; ++r) {
                float p = exp2f((sacc[n][r] - m_run[r]) * LOG2E);
                psum[r] += p;
                int rowf = w * 16 + fq * 4 + r;
                int byte = rowf * 128 + (((col >> 3) ^ (rowf & 7)) * 16) + (col & 7) * 2;
                *(u16*)((char*)Ps + byte) = f2b(p);
            }
        }
        #pragma unroll
        for (int r = 0; r < 4; ++r) {
            float v = psum[r];
            v += __shfl_xor(v, 1, 64);
            v += __shfl_xor(v, 2, 64);
            v += __shfl_xor(v, 4, 64);
            v += __shfl_xor(v, 8, 64);
            l_run[r] = l_run[r] * alpha[r] + v;
        }
        #pragma unroll
        for (int n = 0; n < 6; ++n)
            #pragma unroll
            for (int r = 0; r < 4; ++r)
                oacc[n][r] *= alpha[r];

        // ---- O += P V (same-wave Ps readback, lgkmcnt-ordered, no barrier) ----
        #pragma unroll
        for (int kk = 0; kk < 2; ++kk) {
            int prow = w * 16 + fr;
            short8 pa = *(const short8*)((const char*)Ps + prow * 128
                                         + (((kk * 4 + fq) ^ (prow & 7)) * 16));
            #pragma unroll
            for (int n = 0; n < 6; ++n) {
                int vrow = n * 16 + fr;
                short8 vv = *(const short8*)((const char*)Vs[cur] + vrow * 128
                                             + (((kk * 4 + fq) ^ (fr & 7)) * 16));
                oacc[n] = __builtin_amdgcn_mfma_f32_16x16x32_bf16(pa, vv, oacc[n], 0, 0, 0);
            }
        }

        __syncthreads();   // single barrier: drains next-tile staging AFTER compute
        cur ^= 1;
        #pragma unroll
        for (int n = 0; n < 4; ++n) pbv[n] = pbn[n];
    }

    // ---- epilogue: unnormalized O + (m,l) partials ----
    float* Oz = Opart + ((size_t)z * NH + h) * NRES * 96;
    #pragma unroll
    for (int n = 0; n < 6; ++n) {
        int c = n * 16 + fr;
        #pragma unroll
        for (int r = 0; r < 4; ++r) {
            int row = q0 + w * 16 + fq * 4 + r;
            Oz[(size_t)row * 96 + c] = oacc[n][r];
        }
    }
    if (fr == 0) {
        float* mlz = mlpart + ((size_t)z * NH + h) * NRES * 2;
        #pragma unroll
        for (int r = 0; r < 4; ++r) {
            int row = q0 + w * 16 + fq * 4 + r;
            mlz[row * 2 + 0] = m_run[r];
            mlz[row * 2 + 1] = l_run[r];
        }
    }
}

// ===================== split-KV combine -> cat =====================
__global__ __launch_bounds__(256) void combine_kernel(
    const float* __restrict__ Opart, const float* __restrict__ mlpart,
    float* __restrict__ cat)
{
    int idx = blockIdx.x * 256 + threadIdx.x;
    if (idx >= NH * NRES * 88) return;
    int c = idx % 88;
    int rh = idx / 88;
    size_t r0 = (size_t)rh;
    size_t r1 = (size_t)NH * NRES + r0;
    float m0 = mlpart[r0 * 2], l0 = mlpart[r0 * 2 + 1];
    float m1 = mlpart[r1 * 2], l1 = mlpart[r1 * 2 + 1];
    float mm = fmaxf(m0, m1);
    float w0 = exp2f((m0 - mm) * LOG2E);
    float w1 = exp2f((m1 - mm) * LOG2E);
    float ll = l0 * w0 + l1 * w1;
    cat[r0 * 88 + c] = (Opart[r0 * 96 + c] * w0 + Opart[r1 * 96 + c] * w1) / ll;
}

// ===================== batched transpose fp32 -> bf16 [N][K] =====================
struct TP9 { const float* p[9]; };

__global__ __launch_bounds__(256) void transpose_bz(
    TP9 tp, int ldi, size_t zsi,
    u16* __restrict__ out, int ldo, size_t zso, int K, int N, int nsrc)
{
    __shared__ float t[32][33];
    int z = blockIdx.z;
    const float* in = tp.p[(z < nsrc) ? z : 0] + zsi * ((z < nsrc) ? 0 : z);
    if (nsrc == 1) in = tp.p[0] + zsi * z;
    out += zso * z;
    int k0 = blockIdx.y * 32, n0 = blockIdx.x * 32;
    int tx = threadIdx.x & 31, ty = threadIdx.x >> 5;
    #pragma unroll
    for (int j = 0; j < 4; ++j) {
        int k = k0 + ty + j * 8;
        if (k < K && n0 + tx < N) t[ty + j * 8][tx] = in[(size_t)k * ldi + n0 + tx];
    }
    __syncthreads();
    #pragma unroll
    for (int j = 0; j < 4; ++j) {
        int n = n0 + ty + j * 8;
        int k = k0 + tx;
        if (n < N && k < K) out[(size_t)n * ldo + k] = f2b(t[tx][ty + j * 8]);
    }
}

// ===================== misc small kernels =====================
__global__ __launch_bounds__(256) void f2b_kernel(const float* __restrict__ in, u16* __restrict__ out, int n)
{
    int i = blockIdx.x * 256 + threadIdx.x;
    if (i < n) out[i] = f2b(in[i]);
}

__global__ __launch_bounds__(256) void emb_kernel(const float* __restrict__ pos, u16* __restrict__ emb)
{
    int idx = blockIdx.x * 256 + threadIdx.x;
    int f = idx & 63;
    int rest = idx >> 6;
    int coord = rest % 42;
    int n = rest / 42;
    float t = pos[(size_t)n * 42 + coord];
    const double l0 = -6.643856189774724;
    const double step = 14.643856189774724 / 63.0;
    float freq = exp2f((float)(l0 + f * step));
    float r = t * freq;
    size_t o = (size_t)n * 5376 + (size_t)coord * 128 + 2 * f;
    emb[o]     = f2b(sinf(r));
    emb[o + 1] = f2b(cosf(r));
}

__global__ __launch_bounds__(256) void frames_kernel(const float* __restrict__ pos,
                                                     float* __restrict__ Rb, float* __restrict__ tb)
{
    int n = blockIdx.x * 256 + threadIdx.x;
    if (n >= NRES) return;
    const float* p = pos + (size_t)n * 42;
    float nx = p[0], ny = p[1], nz = p[2];
    float cax = p[3], cay = p[4], caz = p[5];
    float cx = p[6], cy = p[7], cz = p[8];
    float v1x = cx - cax, v1y = cy - cay, v1z = cz - caz;
    float i1 = rsqrtf(v1x * v1x + v1y * v1y + v1z * v1z + 1e-8f);
    float e1x = v1x * i1, e1y = v1y * i1, e1z = v1z * i1;
    float v2x = nx - cax, v2y = ny - cay, v2z = nz - caz;
    float d = e1x * v2x + e1y * v2y + e1z * v2z;
    float wx = v2x - d * e1x, wy = v2y - d * e1y, wz = v2z - d * e1z;
    float i2 = rsqrtf(wx * wx + wy * wy + wz * wz + 1e-8f);
    float e2x = wx * i2, e2y = wy * i2, e2z = wz * i2;
    float e3x = e1y * e2z - e1z * e2y;
    float e3y = e1z * e2x - e1x * e2z;
    float e3z = e1x * e2y - e1y * e2x;
    float* R = Rb + (size_t)n * 9;
    R[0] = e1x; R[1] = e2x; R[2] = e3x;
    R[3] = e1y; R[4] = e2y; R[5] = e3y;
    R[6] = e1z; R[7] = e2z; R[8] = e3z;
    tb[(size_t)n * 3 + 0] = cax;
    tb[(size_t)n * 3 + 1] = cay;
    tb[(size_t)n * 3 + 2] = caz;
}

__global__ __launch_bounds__(256) void condnorm_bf16(const float* __restrict__ xb,
                                                     const float* __restrict__ cs,
                                                     const float* __restrict__ cb,
                                                     u16* __restrict__ outb)
{
    int i = blockIdx.x, tid = threadIdx.x;
    size_t base = (size_t)i * 1024 + tid * 4;
    float4 xv = *reinterpret_cast<const float4*>(xb + base);
    float s = xv.x + xv.y + xv.z + xv.w;
    float q = xv.x * xv.x + xv.y * xv.y + xv.z * xv.z + xv.w * xv.w;
    __shared__ float r1[256], r2[256];
    r1[tid] = s; r2[tid] = q;
    __syncthreads();
    for (int st = 128; st > 0; st >>= 1) {
        if (tid < st) { r1[tid] += r1[tid + st]; r2[tid] += r2[tid + st]; }
        __syncthreads();
    }
    float mean = r1[0] * (1.f / 1024.f);
    float var = r2[0] * (1.f / 1024.f) - mean * mean;
    float rs = rsqrtf(var + 1e-5f);
    float4 sv = *reinterpret_cast<const float4*>(cs + base);
    float4 bv = *reinterpret_cast<const float4*>(cb + base);
    outb[base + 0] = f2b((1.f / (1.f + expf(-sv.x))) * (xv.x - mean) * rs + bv.x);
    outb[base + 1] = f2b((1.f / (1.f + expf(-sv.y))) * (xv.y - mean) * rs + bv.y);
    outb[base + 2] = f2b((1.f / (1.f + expf(-sv.z))) * (xv.z - mean) * rs + bv.z);
    outb[base + 3] = f2b((1.f / (1.f + expf(-sv.w))) * (xv.w - mean) * rs + bv.w);
}

__global__ __launch_bounds__(256) void bias_pack(const float* a, const float* b, const float* c,
                                                 const float* d, const float* e, const float* f,
                                                 float* out)
{
    int i = blockIdx.x * 256 + threadIdx.x;
    if (i >= 1024) return;
    out[i] = a[i]; out[1024 + i] = b[i]; out[2048 + i] = c[i];
    out[3072 + i] = d[i]; out[4096 + i] = e[i]; out[5120 + i] = f[i];
}

// full-width pack: writes c<64 from q/k and zeros c>=89 (cols 64..88 filled by build_pts)
__global__ __launch_bounds__(256) void pack_qk(const float* __restrict__ qb, const float* __restrict__ kb,
                                               u16* __restrict__ qe, u16* __restrict__ ke)
{
    int idx = blockIdx.x * 256 + threadIdx.x;   // < 16*1536*128
    int c = idx & 127;
    int t = idx >> 7;
    int n = t % NRES;
    int h = t / NRES;
    size_t o = (size_t)idx;
    if (c < 64) {
        size_t src = (size_t)n * 1024 + h * 64 + c;
        qe[o] = f2b(0.125f * qb[src]);
        ke[o] = f2b(kb[src]);
    } else if (c >= 89) {
        qe[o] = 0;
        ke[o] = 0;
    }
}

__global__ __launch_bounds__(256) void build_pts(
    const float* __restrict__ qp, const float* __restrict__ kp, const float* __restrict__ vp,
    const float* __restrict__ Rb, const float* __restrict__ tb, const float* __restrict__ gamma,
    u16* __restrict__ qe, u16* __restrict__ ke, float* __restrict__ vgt)
{
    int idx = blockIdx.x * 256 + threadIdx.x;
    if (idx >= NRES * NH) return;
    int n = idx >> 4, h = idx & 15;
    float R[9];
    #pragma unroll
    for (int a = 0; a < 9; ++a) R[a] = Rb[(size_t)n * 9 + a];
    float t0 = tb[(size_t)n * 3 + 0], t1 = tb[(size_t)n * 3 + 1], t2 = tb[(size_t)n * 3 + 2];
    float g = gamma[h];
    float sp = (g > 20.f) ? g : log1pf(expf(g));
    float ch = 0.5f * (1.f / 6.f) * sp;

    u16* qeh = qe + ((size_t)h * NRES + n) * 128;
    u16* keh = ke + ((size_t)h * NRES + n) * 128;
    size_t pbase = (size_t)n * 384 + h * 24;
    float kn = 0.f;
    #pragma unroll
    for (int p = 0; p < 8; ++p) {
        size_t o = pbase + p * 3;
        {
            float x = qp[o], y = qp[o + 1], z = qp[o + 2];
            float g0 = R[0] * x + R[1] * y + R[2] * z + t0;
            float g1 = R[3] * x + R[4] * y + R[5] * z + t1;
            float g2 = R[6] * x + R[7] * y + R[8] * z + t2;
            qeh[64 + p * 3 + 0] = f2b(2.f * ch * g0);
            qeh[64 + p * 3 + 1] = f2b(2.f * ch * g1);
            qeh[64 + p * 3 + 2] = f2b(2.f * ch * g2);
        }
        {
            float x = kp[o], y = kp[o + 1], z = kp[o + 2];
            float g0 = R[0] * x + R[1] * y + R[2] * z + t0;
            float g1 = R[3] * x + R[4] * y + R[5] * z + t1;
            float g2 = R[6] * x + R[7] * y + R[8] * z + t2;
            keh[64 + p * 3 + 0] = f2b(g0);
            keh[64 + p * 3 + 1] = f2b(g1);
            keh[64 + p * 3 + 2] = f2b(g2);
            kn += g0 * g0 + g1 * g1 + g2 * g2;
        }
        {
            float x = vp[o], y = vp[o + 1], z = vp[o + 2];
            vgt[o]     = R[0] * x + R[1] * y + R[2] * z + t0;
            vgt[o + 1] = R[3] * x + R[4] * y + R[5] * z + t1;
            vgt[o + 2] = R[6] * x + R[7] * y + R[8] * z + t2;
        }
    }
    qeh[88] = f2b(1.0f);
    keh[88] = f2b(-ch * kn);
}

__global__ __launch_bounds__(256) void finalize_kernel(const float* __restrict__ cat,
                                                       const float* __restrict__ Rb,
                                                       const float* __restrict__ tb,
                                                       u16* __restrict__ featB)
{
    int idx = blockIdx.x * 256 + threadIdx.x;
    if (idx >= NRES * NH) return;
    int n = idx >> 4, h = idx & 15;
    float R[9];
    #pragma unroll
    for (int a = 0; a < 9; ++a) R[a] = Rb[(size_t)n * 9 + a];
    float t0 = tb[(size_t)n * 3 + 0], t1 = tb[(size_t)n * 3 + 1], t2 = tb[(size_t)n * 3 + 2];
    const float* c = cat + ((size_t)h * NRES + n) * 88;
    u16* fb = featB + (size_t)n * 1536;
    #pragma unroll
    for (int k = 0; k < 64; ++k) fb[h * 64 + k] = f2b(c[k]);
    #pragma unroll
    for (int p = 0; p < 8; ++p) {
        float x = c[64 + p * 3 + 0] - t0;
        float y = c[64 + p * 3 + 1] - t1;
        float z = c[64 + p * 3 + 2] - t2;
        float a0 = R[0] * x + R[3] * y + R[6] * z;
        float a1 = R[1] * x + R[4] * y + R[7] * z;
        float a2 = R[2] * x + R[5] * y + R[8] * z;
        fb[1024 + h * 24 + p * 3 + 0] = f2b(a0);
        fb[1024 + h * 24 + p * 3 + 1] = f2b(a1);
        fb[1024 + h * 24 + p * 3 + 2] = f2b(a2);
        fb[1408 + h * 8 + p] = f2b(sqrtf(a0 * a0 + a1 * a1 + a2 * a2 + 1e-8f));
    }
}

// ========================= host =========================
extern "C" void kernel_launch(void* const* d_in, const int* in_sizes, int n_in,
                              void* d_out, int out_size, void* d_ws, size_t ws_size,
                              hipStream_t stream)
{
    const float* local_in = (const float*)d_in[0];
    const float* pos      = (const float*)d_in[1];
    const float* cond     = (const float*)d_in[2];
    const float* pb       = (const float*)d_in[4];
    const float* w_f1     = (const float*)d_in[5];
    const float* b_f1     = (const float*)d_in[6];
    const float* w_f2     = (const float*)d_in[7];
    const float* b_f2     = (const float*)d_in[8];
    const float* cn1_ws   = (const float*)d_in[9];
    const float* cn1_bs   = (const float*)d_in[10];
    const float* cn1_wb   = (const float*)d_in[11];
    const float* cn1_bb   = (const float*)d_in[12];
    const float* wq       = (const float*)d_in[13];
    const float* wk       = (const float*)d_in[14];
    const float* wv       = (const float*)d_in[15];
    const float* wqp      = (const float*)d_in[16];
    const float* wkp      = (const float*)d_in[17];
    const float* wvp      = (const float*)d_in[18];
    const float* gamma    = (const float*)d_in[19];
    const float* wo       = (const float*)d_in[20];
    const float* bo       = (const float*)d_in[21];
    const float* cn2_ws   = (const float*)d_in[22];
    const float* cn2_bs   = (const float*)d_in[23];
    const float* cn2_wb   = (const float*)d_in[24];
    const float* cn2_bb   = (const float*)d_in[25];
    const float* wg1      = (const float*)d_in[26];
    const float* bg1      = (const float*)d_in[27];
    const float* wg2      = (const float*)d_in[28];
    const float* bg2      = (const float*)d_in[29];
    const float* wg3      = (const float*)d_in[30];
    const float* bg3      = (const float*)d_in[31];
    const float* cn3_ws   = (const float*)d_in[32];
    const float* cn3_bs   = (const float*)d_in[33];
    const float* cn3_wb   = (const float*)d_in[34];
    const float* cn3_bb   = (const float*)d_in[35];
    const float* w_vel    = (const float*)d_in[36];

    float* out = (float*)d_out;
    float* ws  = (float*)d_ws;

    size_t off = 0;
    auto alloc = [&](size_t nf) -> float* { float* p = ws + off; off += (nf + 7) & ~7ull; return p; };

    const size_t NN1 = (size_t)NRES * 1024;
    float* Rb    = alloc(NRES * 9);
    float* tb    = alloc(NRES * 3);
    float* loc   = alloc(NN1);
    float* cs6   = alloc(6 * NN1);
    u16*   condB = (u16*)alloc(NN1 / 2);
    u16*   normB = (u16*)alloc(NN1 / 2);
    float* bias2 = alloc(6 * 1024);
    float* qb    = alloc(3 * NN1);
    float* kb    = qb + NN1;
    float* vb    = kb + NN1;
    float* qp    = alloc(3 * (size_t)NRES * 384);
    float* kp    = qp + NRES * 384;
    float* vp    = kp + NRES * 384;
    float* vgt   = alloc((size_t)NRES * 384);
    u16*   qeB   = (u16*)alloc((size_t)NH * NRES * 128 / 2);
    u16*   keB   = (u16*)alloc((size_t)NH * NRES * 128 / 2);
    u16*   vTB   = (u16*)alloc((size_t)NH * 96 * NRES / 2);
    float* cat   = alloc((size_t)NH * NRES * 88);
    u16*   featB = (u16*)alloc((size_t)NRES * 1536 / 2);
    u16*   g1sB  = (u16*)alloc((size_t)NRES * 2048 / 2);
    u16*   gmB   = (u16*)alloc((size_t)NRES * 2048 / 2);
    u16*   cnT9  = (u16*)alloc((size_t)9 * 1024 * 1024 / 2);
    u16*   ptsT  = (u16*)alloc((size_t)3 * 384 * 1024 / 2);
    u16*   wgT   = (u16*)alloc((size_t)2 * 2048 * 1024 / 2);
    u16*   wf1T  = (u16*)alloc((size_t)2048 * 5376 / 2);
    u16*   wf2T  = (u16*)alloc((size_t)1024 * 2048 / 2);
    u16*   woT   = (u16*)alloc((size_t)1024 * 1536 / 2);
    u16*   wg3T  = (u16*)alloc((size_t)1024 * 2048 / 2);
    u16*   wvT   = (u16*)alloc((size_t)42 * 1024 / 2 + 8);
    u16*   embB  = (u16*)alloc((size_t)NRES * 5376 / 2);
    u16*   hidB  = (u16*)alloc((size_t)NRES * 2048 / 2);
    float* pscr  = alloc((size_t)3 * NRES * 2048);          // split-K partials
    float* Opart = alloc((size_t)2 * NH * NRES * 96);       // 18.9 MB
    float* mlprt = alloc((size_t)2 * NH * NRES * 2);

    const float* nilf = nullptr;
    const u16*   nilb = nullptr;

    auto gemm = [&](int tnf, const u16* A, int lda, size_t zsA,
                    const u16* BT, int ldb, size_t zsB,
                    float* Cf, u16* Cb2, int ldc, size_t zsC,
                    const float* bias, size_t zsBias,
                    const float* resid, int ldr, size_t zsR,
                    const u16* mulb, int ldm,
                    int Nc, int Kd, int flags, int gz, int ksl) {
        int tn = tnf * 32;
        dim3 grid((Nc + tn - 1) / tn, NRES / 128, gz);
        if (tnf == 4)
            hipLaunchKernelGGL(gemm_t<4>, grid, dim3(256), 0, stream,
                               A, lda, zsA, BT, ldb, zsB, Cf, Cb2, ldc, zsC,
                               bias, zsBias, resid, ldr, zsR, mulb, ldm, Nc, Kd, flags, ksl);
        else
            hipLaunchKernelGGL(gemm_t<2>, grid, dim3(256), 0, stream,
                               A, lda, zsA, BT, ldb, zsB, Cf, Cb2, ldc, zsC,
                               bias, zsBias, resid, ldr, zsR, mulb, ldm, Nc, Kd, flags, ksl);
    };
    auto red = [&](const float* part, size_t slice, int nsl, float* Cf, u16* Cb2,
                   const float* bias, const float* resid, int ldr,
                   const u16* mulb, int ldm, int Nc, int flags) {
        hipLaunchKernelGGL(reduce_epi, dim3(1024), dim3(256), 0, stream,
                           part, slice, nsl, Cf, Cb2, bias, resid, ldr, mulb, ldm,
                           NRES, Nc, flags);
    };
    auto tpz = [&](TP9 tp, int ldi, int K, int N, u16* o, int ldo, size_t zso, int nsrc) {
        dim3 grid((N + 31) / 32, (K + 31) / 32, nsrc);
        hipLaunchKernelGGL(transpose_bz, grid, dim3(256), 0, stream, tp, ldi, (size_t)0, o, ldo, zso, K, N, nsrc);
    };
    auto tps = [&](const float* in, int ldi, size_t zsi, int K, int N, u16* o, int ldo, size_t zso, int gz) {
        dim3 grid((N + 31) / 32, (K + 31) / 32, gz);
        TP9 tp; tp.p[0] = in;
        hipLaunchKernelGGL(transpose_bz, grid, dim3(256), 0, stream, tp, ldi, zsi, o, ldo, zso, K, N, 1);
    };

    // ---- prologue ----
    hipLaunchKernelGGL(frames_kernel, dim3(6), dim3(256), 0, stream, pos, Rb, tb);
    hipLaunchKernelGGL(emb_kernel, dim3((NRES * 42 * 64) / 256), dim3(256), 0, stream, pos, embB);
    hipLaunchKernelGGL(f2b_kernel, dim3(6144), dim3(256), 0, stream, cond, condB, NRES * 1024);
    hipLaunchKernelGGL(bias_pack, dim3(4), dim3(256), 0, stream,
                       cn1_bs, cn1_bb, cn2_bs, cn2_bb, cn3_bs, cn3_bb, bias2);

    // ---- weight transposes ----
    {
        TP9 t9; t9.p[0]=cn1_ws; t9.p[1]=cn1_wb; t9.p[2]=cn2_ws; t9.p[3]=cn2_wb;
        t9.p[4]=cn3_ws; t9.p[5]=cn3_wb; t9.p[6]=wq; t9.p[7]=wk; t9.p[8]=wv;
        tpz(t9, 1024, 1024, 1024, cnT9, 1024, (size_t)1024 * 1024, 9);
    }
    {
        TP9 t3; t3.p[0]=wqp; t3.p[1]=wkp; t3.p[2]=wvp;
        tpz(t3, 384, 1024, 384, ptsT, 1024, (size_t)384 * 1024, 3);
    }
    {
        TP9 t2; t2.p[0]=wg1; t2.p[1]=wg2;
        tpz(t2, 2048, 1024, 2048, wgT, 1024, (size_t)2048 * 1024, 2);
    }
    tps(w_f1, 2048, 0, 5376, 2048, wf1T, 5376, 0, 1);
    tps(w_f2, 1024, 0, 2048, 1024, wf2T, 2048, 0, 1);
    tps(wo,   1024, 0, 1536, 1024, woT,  1536, 0, 1);
    tps(wg3,  1024, 0, 2048, 1024, wg3T, 2048, 0, 1);
    tps(w_vel,  42, 0, 1024,   42, wvT,  1024, 0, 1);

    // ---- all 6 cond GEMMs (z=6) ----
    gemm(4, condB, 1024, 0, cnT9, 1024, (size_t)1024 * 1024, cs6, nullptr, 1024, NN1,
         bias2, 1024, nilf, 0, 0, nilb, 0, 1024, 1024, F_BIAS, 6, 0);

    // ---- phase A: emb GEMM split-K=3 + reduce(silu->bf16) ----
    gemm(4, embB, 5376, 0, wf1T, 5376, 0, pscr, nullptr, 2048, (size_t)NRES * 2048,
         nilf, 0, nilf, 0, 0, nilb, 0, 2048, 5376, 0, 3, 1792);
    red(pscr, (size_t)NRES * 2048, 3, nullptr, hidB, b_f1, nilf, 0, nilb, 0,
        2048, F_BIAS | F_SILU | F_OUTBF);
    gemm(2, hidB, 2048, 0, wf2T, 2048, 0, pscr, nullptr, 1024, NN1,
         nilf, 0, nilf, 0, 0, nilb, 0, 1024, 2048, 0, 2, 1024);
    red(pscr, NN1, 2, loc, nullptr, b_f2, local_in, 1024, nilb, 0,
        1024, F_BIAS | F_RESID);

    // ---- cond_norm 1 ----
    hipLaunchKernelGGL(condnorm_bf16, dim3(NRES), dim3(256), 0, stream, loc, cs6, cs6 + NN1, normB);

    // ---- projections ----
    gemm(2, normB, 1024, 0, cnT9 + (size_t)6 * 1024 * 1024, 1024, (size_t)1024 * 1024,
         qb, nullptr, 1024, NN1, nilf, 0, nilf, 0, 0, nilb, 0, 1024, 1024, 0, 3, 0);
    gemm(2, normB, 1024, 0, ptsT, 1024, (size_t)384 * 1024, qp, nullptr, 384, (size_t)NRES * 384,
         nilf, 0, nilf, 0, 0, nilb, 0, 384, 1024, 0, 3, 0);

    // ---- attention operands ----
    hipMemsetAsync(vTB, 0, (size_t)NH * 96 * NRES * 2, stream);
    hipLaunchKernelGGL(pack_qk, dim3((NH * NRES * 128) / 256), dim3(256), 0, stream, qb, kb, qeB, keB);
    hipLaunchKernelGGL(build_pts, dim3(96), dim3(256), 0, stream,
                       qp, kp, vp, Rb, tb, gamma, qeB, keB, vgt);
    tps(vb, 1024, 64, NRES, 64, vTB, NRES, (size_t)96 * NRES, NH);
    tps(vgt, 384, 24, NRES, 24, vTB + (size_t)64 * NRES, NRES, (size_t)96 * NRES, NH);

    // ---- fused attention (split-KV, pipelined) + combine ----
    hipLaunchKernelGGL(attn_kernel, dim3(NRES / 64, NH, 2), dim3(256), 0, stream,
                       qeB, keB, vTB, pb, Opart, mlprt);
    hipLaunchKernelGGL(combine_kernel, dim3((NH * NRES * 88 + 255) / 256), dim3(256), 0, stream,
                       Opart, mlprt, cat);
    hipLaunchKernelGGL(finalize_kernel, dim3(96), dim3(256), 0, stream, cat, Rb, tb, featB);

    // ---- local += feat @ wo + bo : split-K=2 ----
    gemm(2, featB, 1536, 0, woT, 1536, 0, pscr, nullptr, 1024, NN1,
         nilf, 0, nilf, 0, 0, nilb, 0, 1024, 1536, 0, 2, 768);
    red(pscr, NN1, 2, loc, nullptr, bo, loc, 1024, nilb, 0, 1024, F_BIAS | F_RESID);

    // ---- cond_norm 2 + gated MLP ----
    hipLaunchKernelGGL(condnorm_bf16, dim3(NRES), dim3(256), 0, stream, loc, cs6 + 2 * NN1, cs6 + 3 * NN1, normB);
    gemm(2, normB, 1024, 0, wgT, 1024, 0, nullptr, g1sB, 2048, 0,
         bg1, 0, nilf, 0, 0, nilb, 0, 2048, 1024, F_BIAS | F_SILU | F_OUTBF, 1, 0);
    gemm(2, normB, 1024, 0, wgT + (size_t)2048 * 1024, 1024, 0, nullptr, gmB, 2048, 0,
         bg2, 0, nilf, 0, 0, g1sB, 2048, 2048, 1024, F_BIAS | F_MUL | F_OUTBF, 1, 0);
    gemm(2, gmB, 2048, 0, wg3T, 2048, 0, pscr, nullptr, 1024, NN1,
         nilf, 0, nilf, 0, 0, nilb, 0, 1024, 2048, 0, 2, 1024);
    red(pscr, NN1, 2, out, nullptr, bg3, loc, 1024, nilb, 0, 1024, F_BIAS | F_RESID);

    // ---- cond_norm 3 + velocity (split-K=8) ----
    hipLaunchKernelGGL(condnorm_bf16, dim3(NRES), dim3(256), 0, stream, out, cs6 + 4 * NN1, cs6 + 5 * NN1, normB);
    gemm(2, normB, 1024, 0, wvT, 1024, 0, pscr, nullptr, 42, (size_t)NRES * 42,
         nilf, 0, nilf, 0, 0, nilb, 0, 42, 1024, 0, 8, 128);
    red(pscr, (size_t)NRES * 42, 8, out + (size_t)NRES * 1024, nullptr,
        nilf, nilf, 0, nilb, 0, 42, 0);
}

// Round 7
// 594.145 us; speedup vs baseline: 1.1837x; 1.1057x over previous
//
#include <hip/hip_runtime.h>
#include <hip/hip_bf16.h>
#include <math.h>

#define NRES 1536
#define NH 16
#define NNF 2359296ull    // NRES*NRES
#define LOG2E 1.44269504f

typedef unsigned short u16;
typedef __attribute__((ext_vector_type(8))) short short8;
typedef __attribute__((ext_vector_type(4))) float f32x4;

typedef const __attribute__((address_space(1))) void gvoid;
typedef __attribute__((address_space(3))) void lvoid;

__device__ __forceinline__ u16 f2b(float x){
    __hip_bfloat16 h = __float2bfloat16(x);
    return *reinterpret_cast<u16*>(&h);
}
__device__ __forceinline__ float b2f(u16 u){
    unsigned v = ((unsigned)u) << 16;
    return __uint_as_float(v);
}

// ===================== bf16 MFMA GEMM (templated tile-N, optional split-K) ==========
#define F_BIAS  1
#define F_SILU  2
#define F_MUL   4
#define F_RESID 8
#define F_OUTBF 16

template<int TNF>
__global__ __launch_bounds__(256) void gemm_t(
    const u16* __restrict__ A, int lda, size_t zsA,
    const u16* __restrict__ BT, int ldb, size_t zsB,
    float* __restrict__ Cf, u16* __restrict__ Cb, int ldc, size_t zsC,
    const float* __restrict__ bias, size_t zsBias,
    const float* __restrict__ resid, int ldr, size_t zsR,
    const u16* __restrict__ mulb, int ldm,
    int Ncols, int Kd, int flags, int ksl)
{
    constexpr int TN = TNF * 32;
    __shared__ u16 As[128 * 64];
    __shared__ u16 Bs[TN * 64];

    const int tid = threadIdx.x;
    const int l = tid & 63, w = tid >> 6;
    const int bz = blockIdx.z;
    const int bm = blockIdx.y * 128, bn = blockIdx.x * TN;

    A  += zsA * bz;
    BT += zsB * bz;

    const int kbeg = ksl ? bz * ksl : 0;
    const int kend = ksl ? kbeg + ksl : Kd;

    const int arow   = l >> 3;
    const int aslot  = l & 7;
    const int srcslt = aslot ^ arow;

    const u16* aBase[4];
    const u16* bBase[TN / 32];
    #pragma unroll
    for (int t = 0; t < 4; ++t) {
        int ra = bm + (w * 4 + t) * 8 + arow;
        aBase[t] = A + (size_t)ra * lda + srcslt * 8;
    }
    #pragma unroll
    for (int t = 0; t < TN / 32; ++t) {
        int rb = bn + (w * (TN / 32) + t) * 8 + arow;
        if (rb > Ncols - 1) rb = Ncols - 1;
        bBase[t] = BT + (size_t)rb * ldb + srcslt * 8;
    }

    const int wr = w >> 1, wc = w & 1;
    const int fr = l & 15;
    const int fq = l >> 4;

    f32x4 acc[4][TNF];
    #pragma unroll
    for (int i = 0; i < 4; ++i)
        #pragma unroll
        for (int j = 0; j < TNF; ++j) acc[i][j] = (f32x4){0.f, 0.f, 0.f, 0.f};

    for (int k0 = kbeg; k0 < kend; k0 += 64) {
        #pragma unroll
        for (int t = 0; t < 4; ++t)
            __builtin_amdgcn_global_load_lds((gvoid*)(aBase[t] + k0),
                (lvoid*)((char*)As + (w * 4 + t) * 1024), 16, 0, 0);
        #pragma unroll
        for (int t = 0; t < TN / 32; ++t)
            __builtin_amdgcn_global_load_lds((gvoid*)(bBase[t] + k0),
                (lvoid*)((char*)Bs + (w * (TN / 32) + t) * 1024), 16, 0, 0);
        __syncthreads();
        #pragma unroll
        for (int kk = 0; kk < 2; ++kk) {
            const int slotR = ((kk * 4) + fq) ^ (l & 7);
            short8 av[4], bv[TNF];
            #pragma unroll
            for (int m = 0; m < 4; ++m) {
                int r = wr * 64 + m * 16 + fr;
                av[m] = *(const short8*)((const char*)As + r * 128 + slotR * 16);
            }
            #pragma unroll
            for (int n = 0; n < TNF; ++n) {
                int r = wc * (TNF * 16) + n * 16 + fr;
                bv[n] = *(const short8*)((const char*)Bs + r * 128 + slotR * 16);
            }
            #pragma unroll
            for (int m = 0; m < 4; ++m)
                #pragma unroll
                for (int n = 0; n < TNF; ++n)
                    acc[m][n] = __builtin_amdgcn_mfma_f32_16x16x32_bf16(av[m], bv[n], acc[m][n], 0, 0, 0);
        }
        __syncthreads();
    }

    const float* residz = (flags & F_RESID) ? resid + zsR * bz : nullptr;
    const float* biasz  = (flags & F_BIAS)  ? bias + zsBias * bz : nullptr;
    float* cfz = Cf ? Cf + zsC * bz : nullptr;
    u16*   cbz = Cb ? Cb + zsC * bz : nullptr;

    #pragma unroll
    for (int m = 0; m < 4; ++m) {
        #pragma unroll
        for (int n = 0; n < TNF; ++n) {
            int gc = bn + wc * (TNF * 16) + n * 16 + fr;
            if (gc >= Ncols) continue;
            int gr0 = bm + wr * 64 + m * 16 + fq * 4;
            #pragma unroll
            for (int r = 0; r < 4; ++r) {
                int gr = gr0 + r;
                float v = acc[m][n][r];
                if (flags & F_BIAS)  v += biasz[gc];
                if (flags & F_SILU)  v = v / (1.f + expf(-v));
                if (flags & F_MUL)   v *= b2f(mulb[(size_t)gr * ldm + gc]);
                if (flags & F_RESID) v += residz[(size_t)gr * ldr + gc];
                if (flags & F_OUTBF) cbz[(size_t)gr * ldc + gc] = f2b(v);
                else                 cfz[(size_t)gr * ldc + gc] = v;
            }
        }
    }
}

// ===================== split-K reduce + fused epilogue =====================
__global__ __launch_bounds__(256) void reduce_epi(
    const float* __restrict__ part, size_t slice, int nsl,
    float* __restrict__ Cf, u16* __restrict__ Cb,
    const float* __restrict__ bias,
    const float* __restrict__ resid, int ldr,
    const u16* __restrict__ mulb, int ldm,
    int M, int Ncols, int flags)
{
    size_t total = (size_t)M * Ncols;
    for (size_t i = (size_t)blockIdx.x * 256 + threadIdx.x; i < total;
         i += (size_t)gridDim.x * 256) {
        int r = (int)(i / (unsigned)Ncols);
        int c = (int)(i - (size_t)r * Ncols);
        float v = 0.f;
        for (int s = 0; s < nsl; ++s) v += part[(size_t)s * slice + i];
        if (flags & F_BIAS)  v += bias[c];
        if (flags & F_SILU)  v = v / (1.f + expf(-v));
        if (flags & F_MUL)   v *= b2f(mulb[(size_t)r * ldm + c]);
        if (flags & F_RESID) v += resid[(size_t)r * ldr + c];
        if (flags & F_OUTBF) Cb[i] = f2b(v);
        else                 Cf[i] = v;
    }
}

// ===================== fused flash attention v3 (proven R6) =====================
__global__ __launch_bounds__(256, 2) void attn_kernel(
    const u16* __restrict__ qe, const u16* __restrict__ ke,
    const u16* __restrict__ vt, const float* __restrict__ pb,
    float* __restrict__ Opart, float* __restrict__ mlpart)
{
    __shared__ u16 Ks[2][64 * 128];
    __shared__ u16 Vs[2][96 * 64];
    __shared__ u16 Ps[64 * 64];

    const int tid = threadIdx.x;
    const int l = tid & 63, w = tid >> 6;
    const int h = blockIdx.y;
    const int q0 = blockIdx.x * 64;
    const int z = blockIdx.z;
    const int fr = l & 15, fq = l >> 4;

    const u16* keh = ke + (size_t)h * NRES * 128;
    const u16* vth = vt + (size_t)h * 96 * NRES;

    const int kr4 = l >> 4, ks16 = l & 15;
    const int vr8 = l >> 3, vs8 = l & 7;

    short8 qv[4];
    {
        const u16* qrow = qe + ((size_t)h * NRES + (q0 + w * 16 + fr)) * 128 + fq * 8;
        #pragma unroll
        for (int kk = 0; kk < 4; ++kk)
            qv[kk] = *(const short8*)(qrow + kk * 32);
    }

    float m_run[4], l_run[4];
    f32x4 oacc[6];
    #pragma unroll
    for (int r = 0; r < 4; ++r) { m_run[r] = -1e30f; l_run[r] = 0.f; }
    #pragma unroll
    for (int n = 0; n < 6; ++n) oacc[n] = (f32x4){0.f, 0.f, 0.f, 0.f};

    const int NIT = NRES / 128;
    const int jbase = z * (NRES / 2);
    int cur = 0;

    auto stage = [&](int buf, int j0) {
        #pragma unroll
        for (int t = 0; t < 4; ++t) {
            int row = w * 16 + t * 4 + kr4;
            int ss = ks16 ^ (row & 7);
            __builtin_amdgcn_global_load_lds(
                (gvoid*)(keh + (size_t)(j0 + row) * 128 + ss * 8),
                (lvoid*)((char*)Ks[buf] + (w * 16 + t * 4) * 256), 16, 0, 0);
        }
        #pragma unroll
        for (int t = 0; t < 3; ++t) {
            int row = w * 24 + t * 8 + vr8;
            int ss = vs8 ^ (row & 7);
            __builtin_amdgcn_global_load_lds(
                (gvoid*)(vth + (size_t)row * NRES + j0 + ss * 8),
                (lvoid*)((char*)Vs[buf] + (w * 24 + t * 8) * 128), 16, 0, 0);
        }
    };
    const float* pbrow = pb + ((size_t)h * NRES + (q0 + w * 16 + fq * 4)) * NRES + fr;

    f32x4 pbv[4], pbn[4] = {};
    stage(0, jbase);
    #pragma unroll
    for (int n = 0; n < 4; ++n)
        #pragma unroll
        for (int r = 0; r < 4; ++r)
            pbv[n][r] = pbrow[(size_t)r * NRES + jbase + n * 16];
    __syncthreads();

    for (int it = 0; it < NIT; ++it) {
        if (it + 1 < NIT) {
            int j1 = jbase + (it + 1) * 64;
            stage(cur ^ 1, j1);
            #pragma unroll
            for (int n = 0; n < 4; ++n)
                #pragma unroll
                for (int r = 0; r < 4; ++r)
                    pbn[n][r] = pbrow[(size_t)r * NRES + j1 + n * 16];
        }

        f32x4 sacc[4];
        #pragma unroll
        for (int n = 0; n < 4; ++n) sacc[n] = (f32x4){0.f, 0.f, 0.f, 0.f};
        #pragma unroll
        for (int kk = 0; kk < 4; ++kk) {
            #pragma unroll
            for (int n = 0; n < 4; ++n) {
                int row = n * 16 + fr;
                short8 bv = *(const short8*)((const char*)Ks[cur] + row * 256
                                             + (((kk * 4 + fq) ^ (fr & 7)) * 16));
                sacc[n] = __builtin_amdgcn_mfma_f32_16x16x32_bf16(qv[kk], bv, sacc[n], 0, 0, 0);
            }
        }
        #pragma unroll
        for (int n = 0; n < 4; ++n) sacc[n] += pbv[n];

        float alpha[4];
        #pragma unroll
        for (int r = 0; r < 4; ++r) {
            float v = fmaxf(fmaxf(sacc[0][r], sacc[1][r]), fmaxf(sacc[2][r], sacc[3][r]));
            v = fmaxf(v, __shfl_xor(v, 1, 64));
            v = fmaxf(v, __shfl_xor(v, 2, 64));
            v = fmaxf(v, __shfl_xor(v, 4, 64));
            v = fmaxf(v, __shfl_xor(v, 8, 64));
            float mn = fmaxf(m_run[r], v);
            alpha[r] = exp2f((m_run[r] - mn) * LOG2E);
            m_run[r] = mn;
        }

        float psum[4] = {0.f, 0.f, 0.f, 0.f};
        #pragma unroll
        for (int n = 0; n < 4; ++n) {
            int col = n * 16 + fr;
            #pragma unroll
            for (int r = 0; r < 4; ++r) {
                float p = exp2f((sacc[n][r] - m_run[r]) * LOG2E);
                psum[r] += p;
                int rowf = w * 16 + fq * 4 + r;
                int byte = rowf * 128 + (((col >> 3) ^ (rowf & 7)) * 16) + (col & 7) * 2;
                *(u16*)((char*)Ps + byte) = f2b(p);
            }
        }
        #pragma unroll
        for (int r = 0; r < 4; ++r) {
            float v = psum[r];
            v += __shfl_xor(v, 1, 64);
            v += __shfl_xor(v, 2, 64);
            v += __shfl_xor(v, 4, 64);
            v += __shfl_xor(v, 8, 64);
            l_run[r] = l_run[r] * alpha[r] + v;
        }
        #pragma unroll
        for (int n = 0; n < 6; ++n)
            #pragma unroll
            for (int r = 0; r < 4; ++r)
                oacc[n][r] *= alpha[r];

        #pragma unroll
        for (int kk = 0; kk < 2; ++kk) {
            int prow = w * 16 + fr;
            short8 pa = *(const short8*)((const char*)Ps + prow * 128
                                         + (((kk * 4 + fq) ^ (prow & 7)) * 16));
            #pragma unroll
            for (int n = 0; n < 6; ++n) {
                int vrow = n * 16 + fr;
                short8 vv = *(const short8*)((const char*)Vs[cur] + vrow * 128
                                             + (((kk * 4 + fq) ^ (fr & 7)) * 16));
                oacc[n] = __builtin_amdgcn_mfma_f32_16x16x32_bf16(pa, vv, oacc[n], 0, 0, 0);
            }
        }

        __syncthreads();
        cur ^= 1;
        #pragma unroll
        for (int n = 0; n < 4; ++n) pbv[n] = pbn[n];
    }

    float* Oz = Opart + ((size_t)z * NH + h) * NRES * 96;
    #pragma unroll
    for (int n = 0; n < 6; ++n) {
        int c = n * 16 + fr;
        #pragma unroll
        for (int r = 0; r < 4; ++r) {
            int row = q0 + w * 16 + fq * 4 + r;
            Oz[(size_t)row * 96 + c] = oacc[n][r];
        }
    }
    if (fr == 0) {
        float* mlz = mlpart + ((size_t)z * NH + h) * NRES * 2;
        #pragma unroll
        for (int r = 0; r < 4; ++r) {
            int row = q0 + w * 16 + fq * 4 + r;
            mlz[row * 2 + 0] = m_run[r];
            mlz[row * 2 + 1] = l_run[r];
        }
    }
}

// ===================== split-KV combine -> cat =====================
__global__ __launch_bounds__(256) void combine_kernel(
    const float* __restrict__ Opart, const float* __restrict__ mlpart,
    float* __restrict__ cat)
{
    int idx = blockIdx.x * 256 + threadIdx.x;
    if (idx >= NH * NRES * 88) return;
    int c = idx % 88;
    int rh = idx / 88;
    size_t r0 = (size_t)rh;
    size_t r1 = (size_t)NH * NRES + r0;
    float m0 = mlpart[r0 * 2], l0 = mlpart[r0 * 2 + 1];
    float m1 = mlpart[r1 * 2], l1 = mlpart[r1 * 2 + 1];
    float mm = fmaxf(m0, m1);
    float w0 = exp2f((m0 - mm) * LOG2E);
    float w1 = exp2f((m1 - mm) * LOG2E);
    float ll = l0 * w0 + l1 * w1;
    cat[r0 * 88 + c] = (Opart[r0 * 96 + c] * w0 + Opart[r1 * 96 + c] * w1) / ll;
}

// ===================== batched transpose fp32 -> bf16 [N][K] =====================
struct TP9 { const float* p[9]; };

__global__ __launch_bounds__(256) void transpose_bz(
    TP9 tp, int ldi, size_t zsi,
    u16* __restrict__ out, int ldo, size_t zso, int K, int N, int nsrc)
{
    __shared__ float t[32][33];
    int z = blockIdx.z;
    const float* in = tp.p[(z < nsrc) ? z : 0] + zsi * ((z < nsrc) ? 0 : z);
    if (nsrc == 1) in = tp.p[0] + zsi * z;
    out += zso * z;
    int k0 = blockIdx.y * 32, n0 = blockIdx.x * 32;
    int tx = threadIdx.x & 31, ty = threadIdx.x >> 5;
    #pragma unroll
    for (int j = 0; j < 4; ++j) {
        int k = k0 + ty + j * 8;
        if (k < K && n0 + tx < N) t[ty + j * 8][tx] = in[(size_t)k * ldi + n0 + tx];
    }
    __syncthreads();
    #pragma unroll
    for (int j = 0; j < 4; ++j) {
        int n = n0 + ty + j * 8;
        int k = k0 + tx;
        if (n < N && k < K) out[(size_t)n * ldo + k] = f2b(t[tx][ty + j * 8]);
    }
}

// ===================== misc small kernels =====================
__global__ __launch_bounds__(256) void f2b_kernel(const float* __restrict__ in, u16* __restrict__ out, int n)
{
    int i = blockIdx.x * 256 + threadIdx.x;
    if (i < n) out[i] = f2b(in[i]);
}

__global__ __launch_bounds__(256) void emb_kernel(const float* __restrict__ pos, u16* __restrict__ emb)
{
    int idx = blockIdx.x * 256 + threadIdx.x;
    int f = idx & 63;
    int rest = idx >> 6;
    int coord = rest % 42;
    int n = rest / 42;
    float t = pos[(size_t)n * 42 + coord];
    const double l0 = -6.643856189774724;
    const double step = 14.643856189774724 / 63.0;
    float freq = exp2f((float)(l0 + f * step));
    float r = t * freq;
    size_t o = (size_t)n * 5376 + (size_t)coord * 128 + 2 * f;
    emb[o]     = f2b(sinf(r));
    emb[o + 1] = f2b(cosf(r));
}

__global__ __launch_bounds__(256) void frames_kernel(const float* __restrict__ pos,
                                                     float* __restrict__ Rb, float* __restrict__ tb)
{
    int n = blockIdx.x * 256 + threadIdx.x;
    if (n >= NRES) return;
    const float* p = pos + (size_t)n * 42;
    float nx = p[0], ny = p[1], nz = p[2];
    float cax = p[3], cay = p[4], caz = p[5];
    float cx = p[6], cy = p[7], cz = p[8];
    float v1x = cx - cax, v1y = cy - cay, v1z = cz - caz;
    float i1 = rsqrtf(v1x * v1x + v1y * v1y + v1z * v1z + 1e-8f);
    float e1x = v1x * i1, e1y = v1y * i1, e1z = v1z * i1;
    float v2x = nx - cax, v2y = ny - cay, v2z = nz - caz;
    float d = e1x * v2x + e1y * v2y + e1z * v2z;
    float wx = v2x - d * e1x, wy = v2y - d * e1y, wz = v2z - d * e1z;
    float i2 = rsqrtf(wx * wx + wy * wy + wz * wz + 1e-8f);
    float e2x = wx * i2, e2y = wy * i2, e2z = wz * i2;
    float e3x = e1y * e2z - e1z * e2y;
    float e3y = e1z * e2x - e1x * e2z;
    float e3z = e1x * e2y - e1y * e2x;
    float* R = Rb + (size_t)n * 9;
    R[0] = e1x; R[1] = e2x; R[2] = e3x;
    R[3] = e1y; R[4] = e2y; R[5] = e3y;
    R[6] = e1z; R[7] = e2z; R[8] = e3z;
    tb[(size_t)n * 3 + 0] = cax;
    tb[(size_t)n * 3 + 1] = cay;
    tb[(size_t)n * 3 + 2] = caz;
}

__global__ __launch_bounds__(256) void condnorm_bf16(const float* __restrict__ xb,
                                                     const float* __restrict__ cs,
                                                     const float* __restrict__ cb,
                                                     u16* __restrict__ outb)
{
    int i = blockIdx.x, tid = threadIdx.x;
    size_t base = (size_t)i * 1024 + tid * 4;
    float4 xv = *reinterpret_cast<const float4*>(xb + base);
    float s = xv.x + xv.y + xv.z + xv.w;
    float q = xv.x * xv.x + xv.y * xv.y + xv.z * xv.z + xv.w * xv.w;
    __shared__ float r1[256], r2[256];
    r1[tid] = s; r2[tid] = q;
    __syncthreads();
    for (int st = 128; st > 0; st >>= 1) {
        if (tid < st) { r1[tid] += r1[tid + st]; r2[tid] += r2[tid + st]; }
        __syncthreads();
    }
    float mean = r1[0] * (1.f / 1024.f);
    float var = r2[0] * (1.f / 1024.f) - mean * mean;
    float rs = rsqrtf(var + 1e-5f);
    float4 sv = *reinterpret_cast<const float4*>(cs + base);
    float4 bv = *reinterpret_cast<const float4*>(cb + base);
    outb[base + 0] = f2b((1.f / (1.f + expf(-sv.x))) * (xv.x - mean) * rs + bv.x);
    outb[base + 1] = f2b((1.f / (1.f + expf(-sv.y))) * (xv.y - mean) * rs + bv.y);
    outb[base + 2] = f2b((1.f / (1.f + expf(-sv.z))) * (xv.z - mean) * rs + bv.z);
    outb[base + 3] = f2b((1.f / (1.f + expf(-sv.w))) * (xv.w - mean) * rs + bv.w);
}

__global__ __launch_bounds__(256) void bias_pack(const float* a, const float* b, const float* c,
                                                 const float* d, const float* e, const float* f,
                                                 float* out)
{
    int i = blockIdx.x * 256 + threadIdx.x;
    if (i >= 1024) return;
    out[i] = a[i]; out[1024 + i] = b[i]; out[2048 + i] = c[i];
    out[3072 + i] = d[i]; out[4096 + i] = e[i]; out[5120 + i] = f[i];
}

__global__ __launch_bounds__(256) void biasg_pack(const float* a, const float* b, float* out)
{
    int i = blockIdx.x * 256 + threadIdx.x;
    if (i >= 2048) return;
    out[i] = a[i]; out[2048 + i] = b[i];
}

// gm = silu(g1) * g2  (g1 = g12[0], g2 = g12[1], z-strided NRES*2048)
__global__ __launch_bounds__(256) void glu_kernel(const u16* __restrict__ g12, u16* __restrict__ gm)
{
    int i = blockIdx.x * 256 + threadIdx.x;
    if (i >= NRES * 2048) return;
    float a = b2f(g12[i]);
    float b = b2f(g12[(size_t)NRES * 2048 + i]);
    float s = a / (1.f + expf(-a));
    gm[i] = f2b(s * b);
}

// full-width pack: writes c<64 from q/k and zeros c>=89 (cols 64..88 filled by build_pts)
__global__ __launch_bounds__(256) void pack_qk(const float* __restrict__ qb, const float* __restrict__ kb,
                                               u16* __restrict__ qe, u16* __restrict__ ke)
{
    int idx = blockIdx.x * 256 + threadIdx.x;   // < 16*1536*128
    int c = idx & 127;
    int t = idx >> 7;
    int n = t % NRES;
    int h = t / NRES;
    size_t o = (size_t)idx;
    if (c < 64) {
        size_t src = (size_t)n * 1024 + h * 64 + c;
        qe[o] = f2b(0.125f * qb[src]);
        ke[o] = f2b(kb[src]);
    } else if (c >= 89) {
        qe[o] = 0;
        ke[o] = 0;
    }
}

__global__ __launch_bounds__(256) void build_pts(
    const float* __restrict__ qp, const float* __restrict__ kp, const float* __restrict__ vp,
    const float* __restrict__ Rb, const float* __restrict__ tb, const float* __restrict__ gamma,
    u16* __restrict__ qe, u16* __restrict__ ke, float* __restrict__ vgt)
{
    int idx = blockIdx.x * 256 + threadIdx.x;
    if (idx >= NRES * NH) return;
    int n = idx >> 4, h = idx & 15;
    float R[9];
    #pragma unroll
    for (int a = 0; a < 9; ++a) R[a] = Rb[(size_t)n * 9 + a];
    float t0 = tb[(size_t)n * 3 + 0], t1 = tb[(size_t)n * 3 + 1], t2 = tb[(size_t)n * 3 + 2];
    float g = gamma[h];
    float sp = (g > 20.f) ? g : log1pf(expf(g));
    float ch = 0.5f * (1.f / 6.f) * sp;

    u16* qeh = qe + ((size_t)h * NRES + n) * 128;
    u16* keh = ke + ((size_t)h * NRES + n) * 128;
    size_t pbase = (size_t)n * 384 + h * 24;
    float kn = 0.f;
    #pragma unroll
    for (int p = 0; p < 8; ++p) {
        size_t o = pbase + p * 3;
        {
            float x = qp[o], y = qp[o + 1], z = qp[o + 2];
            float g0 = R[0] * x + R[1] * y + R[2] * z + t0;
            float g1 = R[3] * x + R[4] * y + R[5] * z + t1;
            float g2 = R[6] * x + R[7] * y + R[8] * z + t2;
            qeh[64 + p * 3 + 0] = f2b(2.f * ch * g0);
            qeh[64 + p * 3 + 1] = f2b(2.f * ch * g1);
            qeh[64 + p * 3 + 2] = f2b(2.f * ch * g2);
        }
        {
            float x = kp[o], y = kp[o + 1], z = kp[o + 2];
            float g0 = R[0] * x + R[1] * y + R[2] * z + t0;
            float g1 = R[3] * x + R[4] * y + R[5] * z + t1;
            float g2 = R[6] * x + R[7] * y + R[8] * z + t2;
            keh[64 + p * 3 + 0] = f2b(g0);
            keh[64 + p * 3 + 1] = f2b(g1);
            keh[64 + p * 3 + 2] = f2b(g2);
            kn += g0 * g0 + g1 * g1 + g2 * g2;
        }
        {
            float x = vp[o], y = vp[o + 1], z = vp[o + 2];
            vgt[o]     = R[0] * x + R[1] * y + R[2] * z + t0;
            vgt[o + 1] = R[3] * x + R[4] * y + R[5] * z + t1;
            vgt[o + 2] = R[6] * x + R[7] * y + R[8] * z + t2;
        }
    }
    qeh[88] = f2b(1.0f);
    keh[88] = f2b(-ch * kn);
}

__global__ __launch_bounds__(256) void finalize_kernel(const float* __restrict__ cat,
                                                       const float* __restrict__ Rb,
                                                       const float* __restrict__ tb,
                                                       u16* __restrict__ featB)
{
    int idx = blockIdx.x * 256 + threadIdx.x;
    if (idx >= NRES * NH) return;
    int n = idx >> 4, h = idx & 15;
    float R[9];
    #pragma unroll
    for (int a = 0; a < 9; ++a) R[a] = Rb[(size_t)n * 9 + a];
    float t0 = tb[(size_t)n * 3 + 0], t1 = tb[(size_t)n * 3 + 1], t2 = tb[(size_t)n * 3 + 2];
    const float* c = cat + ((size_t)h * NRES + n) * 88;
    u16* fb = featB + (size_t)n * 1536;
    #pragma unroll
    for (int k = 0; k < 64; ++k) fb[h * 64 + k] = f2b(c[k]);
    #pragma unroll
    for (int p = 0; p < 8; ++p) {
        float x = c[64 + p * 3 + 0] - t0;
        float y = c[64 + p * 3 + 1] - t1;
        float z = c[64 + p * 3 + 2] - t2;
        float a0 = R[0] * x + R[3] * y + R[6] * z;
        float a1 = R[1] * x + R[4] * y + R[7] * z;
        float a2 = R[2] * x + R[5] * y + R[8] * z;
        fb[1024 + h * 24 + p * 3 + 0] = f2b(a0);
        fb[1024 + h * 24 + p * 3 + 1] = f2b(a1);
        fb[1024 + h * 24 + p * 3 + 2] = f2b(a2);
        fb[1408 + h * 8 + p] = f2b(sqrtf(a0 * a0 + a1 * a1 + a2 * a2 + 1e-8f));
    }
}

// ========================= host =========================
extern "C" void kernel_launch(void* const* d_in, const int* in_sizes, int n_in,
                              void* d_out, int out_size, void* d_ws, size_t ws_size,
                              hipStream_t stream)
{
    const float* local_in = (const float*)d_in[0];
    const float* pos      = (const float*)d_in[1];
    const float* cond     = (const float*)d_in[2];
    const float* pb       = (const float*)d_in[4];
    const float* w_f1     = (const float*)d_in[5];
    const float* b_f1     = (const float*)d_in[6];
    const float* w_f2     = (const float*)d_in[7];
    const float* b_f2     = (const float*)d_in[8];
    const float* cn1_ws   = (const float*)d_in[9];
    const float* cn1_bs   = (const float*)d_in[10];
    const float* cn1_wb   = (const float*)d_in[11];
    const float* cn1_bb   = (const float*)d_in[12];
    const float* wq       = (const float*)d_in[13];
    const float* wk       = (const float*)d_in[14];
    const float* wv       = (const float*)d_in[15];
    const float* wqp      = (const float*)d_in[16];
    const float* wkp      = (const float*)d_in[17];
    const float* wvp      = (const float*)d_in[18];
    const float* gamma    = (const float*)d_in[19];
    const float* wo       = (const float*)d_in[20];
    const float* bo       = (const float*)d_in[21];
    const float* cn2_ws   = (const float*)d_in[22];
    const float* cn2_bs   = (const float*)d_in[23];
    const float* cn2_wb   = (const float*)d_in[24];
    const float* cn2_bb   = (const float*)d_in[25];
    const float* wg1      = (const float*)d_in[26];
    const float* bg1      = (const float*)d_in[27];
    const float* wg2      = (const float*)d_in[28];
    const float* bg2      = (const float*)d_in[29];
    const float* wg3      = (const float*)d_in[30];
    const float* bg3      = (const float*)d_in[31];
    const float* cn3_ws   = (const float*)d_in[32];
    const float* cn3_bs   = (const float*)d_in[33];
    const float* cn3_wb   = (const float*)d_in[34];
    const float* cn3_bb   = (const float*)d_in[35];
    const float* w_vel    = (const float*)d_in[36];

    float* out = (float*)d_out;
    float* ws  = (float*)d_ws;

    size_t off = 0;
    auto alloc = [&](size_t nf) -> float* { float* p = ws + off; off += (nf + 7) & ~7ull; return p; };

    const size_t NN1 = (size_t)NRES * 1024;
    float* Rb    = alloc(NRES * 9);
    float* tb    = alloc(NRES * 3);
    float* loc   = alloc(NN1);
    float* cs6   = alloc(6 * NN1);
    u16*   condB = (u16*)alloc(NN1 / 2);
    u16*   normB = (u16*)alloc(NN1 / 2);
    float* bias2 = alloc(6 * 1024);
    float* biasg = alloc(2 * 2048);
    float* qb    = alloc(3 * NN1);
    float* kb    = qb + NN1;
    float* vb    = kb + NN1;
    float* qp    = alloc(3 * (size_t)NRES * 384);
    float* kp    = qp + NRES * 384;
    float* vp    = kp + NRES * 384;
    float* vgt   = alloc((size_t)NRES * 384);
    u16*   qeB   = (u16*)alloc((size_t)NH * NRES * 128 / 2);
    u16*   keB   = (u16*)alloc((size_t)NH * NRES * 128 / 2);
    u16*   vTB   = (u16*)alloc((size_t)NH * 96 * NRES / 2);
    float* cat   = alloc((size_t)NH * NRES * 88);
    u16*   featB = (u16*)alloc((size_t)NRES * 1536 / 2);
    u16*   g1sB  = (u16*)alloc((size_t)NRES * 2048 / 2);   // g12B z=0
    u16*   gmB   = (u16*)alloc((size_t)NRES * 2048 / 2);   // g12B z=1 (contiguous)
    u16*   cnT9  = (u16*)alloc((size_t)9 * 1024 * 1024 / 2);
    u16*   ptsT  = (u16*)alloc((size_t)3 * 384 * 1024 / 2);
    u16*   wgT   = (u16*)alloc((size_t)2 * 2048 * 1024 / 2);
    u16*   wf1T  = (u16*)alloc((size_t)2048 * 5376 / 2);
    u16*   wf2T  = (u16*)alloc((size_t)1024 * 2048 / 2);
    u16*   woT   = (u16*)alloc((size_t)1024 * 1536 / 2);
    u16*   wg3T  = (u16*)alloc((size_t)1024 * 2048 / 2);
    u16*   wvT   = (u16*)alloc((size_t)42 * 1024 / 2 + 8);
    u16*   embB  = (u16*)alloc((size_t)NRES * 5376 / 2);   // reused as gm output later
    u16*   hidB  = (u16*)alloc((size_t)NRES * 2048 / 2);
    float* pscr  = alloc((size_t)3 * NRES * 2048);          // split-K partials (fits 4*NN1)
    float* Opart = alloc((size_t)2 * NH * NRES * 96);
    float* mlprt = alloc((size_t)2 * NH * NRES * 2);

    const float* nilf = nullptr;
    const u16*   nilb = nullptr;

    auto gemm = [&](int tnf, const u16* A, int lda, size_t zsA,
                    const u16* BT, int ldb, size_t zsB,
                    float* Cf, u16* Cb2, int ldc, size_t zsC,
                    const float* bias, size_t zsBias,
                    const float* resid, int ldr, size_t zsR,
                    const u16* mulb, int ldm,
                    int Nc, int Kd, int flags, int gz, int ksl) {
        int tn = tnf * 32;
        dim3 grid((Nc + tn - 1) / tn, NRES / 128, gz);
        if (tnf == 4)
            hipLaunchKernelGGL(gemm_t<4>, grid, dim3(256), 0, stream,
                               A, lda, zsA, BT, ldb, zsB, Cf, Cb2, ldc, zsC,
                               bias, zsBias, resid, ldr, zsR, mulb, ldm, Nc, Kd, flags, ksl);
        else
            hipLaunchKernelGGL(gemm_t<2>, grid, dim3(256), 0, stream,
                               A, lda, zsA, BT, ldb, zsB, Cf, Cb2, ldc, zsC,
                               bias, zsBias, resid, ldr, zsR, mulb, ldm, Nc, Kd, flags, ksl);
    };
    auto red = [&](const float* part, size_t slice, int nsl, float* Cf, u16* Cb2,
                   const float* bias, const float* resid, int ldr,
                   const u16* mulb, int ldm, int Nc, int flags) {
        hipLaunchKernelGGL(reduce_epi, dim3(1024), dim3(256), 0, stream,
                           part, slice, nsl, Cf, Cb2, bias, resid, ldr, mulb, ldm,
                           NRES, Nc, flags);
    };
    auto tpz = [&](TP9 tp, int ldi, int K, int N, u16* o, int ldo, size_t zso, int nsrc) {
        dim3 grid((N + 31) / 32, (K + 31) / 32, nsrc);
        hipLaunchKernelGGL(transpose_bz, grid, dim3(256), 0, stream, tp, ldi, (size_t)0, o, ldo, zso, K, N, nsrc);
    };
    auto tps = [&](const float* in, int ldi, size_t zsi, int K, int N, u16* o, int ldo, size_t zso, int gz) {
        dim3 grid((N + 31) / 32, (K + 31) / 32, gz);
        TP9 tp; tp.p[0] = in;
        hipLaunchKernelGGL(transpose_bz, grid, dim3(256), 0, stream, tp, ldi, zsi, o, ldo, zso, K, N, 1);
    };

    // ---- prologue ----
    hipLaunchKernelGGL(frames_kernel, dim3(6), dim3(256), 0, stream, pos, Rb, tb);
    hipLaunchKernelGGL(emb_kernel, dim3((NRES * 42 * 64) / 256), dim3(256), 0, stream, pos, embB);
    hipLaunchKernelGGL(f2b_kernel, dim3(6144), dim3(256), 0, stream, cond, condB, NRES * 1024);
    hipLaunchKernelGGL(bias_pack, dim3(4), dim3(256), 0, stream,
                       cn1_bs, cn1_bb, cn2_bs, cn2_bb, cn3_bs, cn3_bb, bias2);
    hipLaunchKernelGGL(biasg_pack, dim3(8), dim3(256), 0, stream, bg1, bg2, biasg);

    // ---- weight transposes ----
    {
        TP9 t9; t9.p[0]=cn1_ws; t9.p[1]=cn1_wb; t9.p[2]=cn2_ws; t9.p[3]=cn2_wb;
        t9.p[4]=cn3_ws; t9.p[5]=cn3_wb; t9.p[6]=wq; t9.p[7]=wk; t9.p[8]=wv;
        tpz(t9, 1024, 1024, 1024, cnT9, 1024, (size_t)1024 * 1024, 9);
    }
    {
        TP9 t3; t3.p[0]=wqp; t3.p[1]=wkp; t3.p[2]=wvp;
        tpz(t3, 384, 1024, 384, ptsT, 1024, (size_t)384 * 1024, 3);
    }
    {
        TP9 t2; t2.p[0]=wg1; t2.p[1]=wg2;
        tpz(t2, 2048, 1024, 2048, wgT, 1024, (size_t)2048 * 1024, 2);
    }
    tps(w_f1, 2048, 0, 5376, 2048, wf1T, 5376, 0, 1);
    tps(w_f2, 1024, 0, 2048, 1024, wf2T, 2048, 0, 1);
    tps(wo,   1024, 0, 1536, 1024, woT,  1536, 0, 1);
    tps(wg3,  1024, 0, 2048, 1024, wg3T, 2048, 0, 1);
    tps(w_vel,  42, 0, 1024,   42, wvT,  1024, 0, 1);

    // ---- all 6 cond GEMMs (z=6, TN=64, 1152 blocks) ----
    gemm(2, condB, 1024, 0, cnT9, 1024, (size_t)1024 * 1024, cs6, nullptr, 1024, NN1,
         bias2, 1024, nilf, 0, 0, nilb, 0, 1024, 1024, F_BIAS, 6, 0);

    // ---- phase A: emb GEMM split-K=3, TN=64 (1152 blocks) + reduce(silu->bf16) ----
    gemm(2, embB, 5376, 0, wf1T, 5376, 0, pscr, nullptr, 2048, (size_t)NRES * 2048,
         nilf, 0, nilf, 0, 0, nilb, 0, 2048, 5376, 0, 3, 1792);
    red(pscr, (size_t)NRES * 2048, 3, nullptr, hidB, b_f1, nilf, 0, nilb, 0,
        2048, F_BIAS | F_SILU | F_OUTBF);
    // hid GEMM split-K=4 (768 blocks)
    gemm(2, hidB, 2048, 0, wf2T, 2048, 0, pscr, nullptr, 1024, NN1,
         nilf, 0, nilf, 0, 0, nilb, 0, 1024, 2048, 0, 4, 512);
    red(pscr, NN1, 4, loc, nullptr, b_f2, local_in, 1024, nilb, 0,
        1024, F_BIAS | F_RESID);

    // ---- cond_norm 1 ----
    hipLaunchKernelGGL(condnorm_bf16, dim3(NRES), dim3(256), 0, stream, loc, cs6, cs6 + NN1, normB);

    // ---- projections ----
    gemm(2, normB, 1024, 0, cnT9 + (size_t)6 * 1024 * 1024, 1024, (size_t)1024 * 1024,
         qb, nullptr, 1024, NN1, nilf, 0, nilf, 0, 0, nilb, 0, 1024, 1024, 0, 3, 0);
    gemm(2, normB, 1024, 0, ptsT, 1024, (size_t)384 * 1024, qp, nullptr, 384, (size_t)NRES * 384,
         nilf, 0, nilf, 0, 0, nilb, 0, 384, 1024, 0, 3, 0);

    // ---- attention operands ----
    hipMemsetAsync(vTB, 0, (size_t)NH * 96 * NRES * 2, stream);
    hipLaunchKernelGGL(pack_qk, dim3((NH * NRES * 128) / 256), dim3(256), 0, stream, qb, kb, qeB, keB);
    hipLaunchKernelGGL(build_pts, dim3(96), dim3(256), 0, stream,
                       qp, kp, vp, Rb, tb, gamma, qeB, keB, vgt);
    tps(vb, 1024, 64, NRES, 64, vTB, NRES, (size_t)96 * NRES, NH);
    tps(vgt, 384, 24, NRES, 24, vTB + (size_t)64 * NRES, NRES, (size_t)96 * NRES, NH);

    // ---- fused attention (split-KV, pipelined) + combine ----
    hipLaunchKernelGGL(attn_kernel, dim3(NRES / 64, NH, 2), dim3(256), 0, stream,
                       qeB, keB, vTB, pb, Opart, mlprt);
    hipLaunchKernelGGL(combine_kernel, dim3((NH * NRES * 88 + 255) / 256), dim3(256), 0, stream,
                       Opart, mlprt, cat);
    hipLaunchKernelGGL(finalize_kernel, dim3(96), dim3(256), 0, stream, cat, Rb, tb, featB);

    // ---- local += feat @ wo + bo : split-K=4 (768 blocks) ----
    gemm(2, featB, 1536, 0, woT, 1536, 0, pscr, nullptr, 1024, NN1,
         nilf, 0, nilf, 0, 0, nilb, 0, 1024, 1536, 0, 4, 384);
    red(pscr, NN1, 4, loc, nullptr, bo, loc, 1024, nilb, 0, 1024, F_BIAS | F_RESID);

    // ---- cond_norm 2 + gated MLP (wg1+wg2 fused z=2, then glu, then wg3 split-K=4) ----
    hipLaunchKernelGGL(condnorm_bf16, dim3(NRES), dim3(256), 0, stream, loc, cs6 + 2 * NN1, cs6 + 3 * NN1, normB);
    gemm(2, normB, 1024, 0, wgT, 1024, (size_t)2048 * 1024, nullptr, g1sB, 2048, (size_t)NRES * 2048,
         biasg, 2048, nilf, 0, 0, nilb, 0, 2048, 1024, F_BIAS | F_OUTBF, 2, 0);
    u16* gmO = embB;   // emb is dead; reuse as glu output
    hipLaunchKernelGGL(glu_kernel, dim3((NRES * 2048 + 255) / 256), dim3(256), 0, stream, g1sB, gmO);
    gemm(2, gmO, 2048, 0, wg3T, 2048, 0, pscr, nullptr, 1024, NN1,
         nilf, 0, nilf, 0, 0, nilb, 0, 1024, 2048, 0, 4, 512);
    red(pscr, NN1, 4, out, nullptr, bg3, loc, 1024, nilb, 0, 1024, F_BIAS | F_RESID);

    // ---- cond_norm 3 + velocity (split-K=8) ----
    hipLaunchKernelGGL(condnorm_bf16, dim3(NRES), dim3(256), 0, stream, out, cs6 + 4 * NN1, cs6 + 5 * NN1, normB);
    gemm(2, normB, 1024, 0, wvT, 1024, 0, pscr, nullptr, 42, (size_t)NRES * 42,
         nilf, 0, nilf, 0, 0, nilb, 0, 42, 1024, 0, 8, 128);
    red(pscr, (size_t)NRES * 42, 8, out + (size_t)NRES * 1024, nullptr,
        nilf, nilf, 0, nilb, 0, 42, 0);
}

// Round 8
// 529.043 us; speedup vs baseline: 1.3294x; 1.1231x over previous
//
#include <hip/hip_runtime.h>
#include <hip/hip_bf16.h>
#include <math.h>

#define NRES 1536
#define NH 16
#define NNF 2359296ull    // NRES*NRES
#define LOG2E 1.44269504f

typedef unsigned short u16;
typedef __attribute__((ext_vector_type(8))) short short8;
typedef __attribute__((ext_vector_type(4))) unsigned short u16x4;
typedef __attribute__((ext_vector_type(4))) float f32x4;

typedef const __attribute__((address_space(1))) void gvoid;
typedef __attribute__((address_space(3))) void lvoid;

__device__ __forceinline__ u16 f2b(float x){
    __hip_bfloat16 h = __float2bfloat16(x);
    return *reinterpret_cast<u16*>(&h);
}
__device__ __forceinline__ float b2f(u16 u){
    unsigned v = ((unsigned)u) << 16;
    return __uint_as_float(v);
}

// ===================== bf16 MFMA GEMM (templated tile-N, optional split-K) ==========
#define F_BIAS  1
#define F_SILU  2
#define F_RESID 8
#define F_OUTBF 16

template<int TNF>
__global__ __launch_bounds__(256) void gemm_t(
    const u16* __restrict__ A, int lda, size_t zsA,
    const u16* __restrict__ BT, int ldb, size_t zsB,
    float* __restrict__ Cf, u16* __restrict__ Cb, int ldc, size_t zsC,
    const float* __restrict__ bias, size_t zsBias,
    const float* __restrict__ resid, int ldr, size_t zsR,
    int Ncols, int Kd, int flags, int ksl)
{
    constexpr int TN = TNF * 32;
    __shared__ u16 As[128 * 64];
    __shared__ u16 Bs[TN * 64];

    const int tid = threadIdx.x;
    const int l = tid & 63, w = tid >> 6;
    const int bz = blockIdx.z;
    const int bm = blockIdx.y * 128, bn = blockIdx.x * TN;

    A  += zsA * bz;
    BT += zsB * bz;

    const int kbeg = ksl ? bz * ksl : 0;
    const int kend = ksl ? kbeg + ksl : Kd;

    const int arow   = l >> 3;
    const int aslot  = l & 7;
    const int srcslt = aslot ^ arow;

    const u16* aBase[4];
    const u16* bBase[TN / 32];
    #pragma unroll
    for (int t = 0; t < 4; ++t) {
        int ra = bm + (w * 4 + t) * 8 + arow;
        aBase[t] = A + (size_t)ra * lda + srcslt * 8;
    }
    #pragma unroll
    for (int t = 0; t < TN / 32; ++t) {
        int rb = bn + (w * (TN / 32) + t) * 8 + arow;
        if (rb > Ncols - 1) rb = Ncols - 1;
        bBase[t] = BT + (size_t)rb * ldb + srcslt * 8;
    }

    const int wr = w >> 1, wc = w & 1;
    const int fr = l & 15;
    const int fq = l >> 4;

    f32x4 acc[4][TNF];
    #pragma unroll
    for (int i = 0; i < 4; ++i)
        #pragma unroll
        for (int j = 0; j < TNF; ++j) acc[i][j] = (f32x4){0.f, 0.f, 0.f, 0.f};

    for (int k0 = kbeg; k0 < kend; k0 += 64) {
        #pragma unroll
        for (int t = 0; t < 4; ++t)
            __builtin_amdgcn_global_load_lds((gvoid*)(aBase[t] + k0),
                (lvoid*)((char*)As + (w * 4 + t) * 1024), 16, 0, 0);
        #pragma unroll
        for (int t = 0; t < TN / 32; ++t)
            __builtin_amdgcn_global_load_lds((gvoid*)(bBase[t] + k0),
                (lvoid*)((char*)Bs + (w * (TN / 32) + t) * 1024), 16, 0, 0);
        __syncthreads();
        #pragma unroll
        for (int kk = 0; kk < 2; ++kk) {
            const int slotR = ((kk * 4) + fq) ^ (l & 7);
            short8 av[4], bv[TNF];
            #pragma unroll
            for (int m = 0; m < 4; ++m) {
                int r = wr * 64 + m * 16 + fr;
                av[m] = *(const short8*)((const char*)As + r * 128 + slotR * 16);
            }
            #pragma unroll
            for (int n = 0; n < TNF; ++n) {
                int r = wc * (TNF * 16) + n * 16 + fr;
                bv[n] = *(const short8*)((const char*)Bs + r * 128 + slotR * 16);
            }
            #pragma unroll
            for (int m = 0; m < 4; ++m)
                #pragma unroll
                for (int n = 0; n < TNF; ++n)
                    acc[m][n] = __builtin_amdgcn_mfma_f32_16x16x32_bf16(av[m], bv[n], acc[m][n], 0, 0, 0);
        }
        __syncthreads();
    }

    const float* residz = (flags & F_RESID) ? resid + zsR * bz : nullptr;
    const float* biasz  = (flags & F_BIAS)  ? bias + zsBias * bz : nullptr;
    float* cfz = Cf ? Cf + zsC * bz : nullptr;
    u16*   cbz = Cb ? Cb + zsC * bz : nullptr;

    #pragma unroll
    for (int m = 0; m < 4; ++m) {
        #pragma unroll
        for (int n = 0; n < TNF; ++n) {
            int gc = bn + wc * (TNF * 16) + n * 16 + fr;
            if (gc >= Ncols) continue;
            int gr0 = bm + wr * 64 + m * 16 + fq * 4;
            #pragma unroll
            for (int r = 0; r < 4; ++r) {
                int gr = gr0 + r;
                float v = acc[m][n][r];
                if (flags & F_BIAS)  v += biasz[gc];
                if (flags & F_SILU)  v = v / (1.f + expf(-v));
                if (flags & F_RESID) v += residz[(size_t)gr * ldr + gc];
                if (flags & F_OUTBF) cbz[(size_t)gr * ldc + gc] = f2b(v);
                else                 cfz[(size_t)gr * ldc + gc] = v;
            }
        }
    }
}

// ===================== split-K reduce (bf16 partials) + fused epilogue ==========
__global__ __launch_bounds__(256) void reduce_epi(
    const u16* __restrict__ part, size_t slice, int nsl,
    float* __restrict__ Cf, u16* __restrict__ Cb,
    const float* __restrict__ bias,
    const float* __restrict__ resid, int ldr,
    int M, int Ncols, int flags)
{
    if ((Ncols & 7) == 0) {
        size_t total8 = (size_t)M * Ncols / 8;
        for (size_t i8 = (size_t)blockIdx.x * 256 + threadIdx.x; i8 < total8;
             i8 += (size_t)gridDim.x * 256) {
            size_t i0 = i8 * 8;
            int r = (int)(i0 / (unsigned)Ncols);
            int c0 = (int)(i0 - (size_t)r * Ncols);
            float v[8] = {0,0,0,0,0,0,0,0};
            for (int s = 0; s < nsl; ++s) {
                const u16x4* p = (const u16x4*)(part + (size_t)s * slice + i0);
                u16x4 a = p[0], b = p[1];
                v[0] += b2f(a.x); v[1] += b2f(a.y); v[2] += b2f(a.z); v[3] += b2f(a.w);
                v[4] += b2f(b.x); v[5] += b2f(b.y); v[6] += b2f(b.z); v[7] += b2f(b.w);
            }
            #pragma unroll
            for (int j = 0; j < 8; ++j) {
                if (flags & F_BIAS) v[j] += bias[c0 + j];
                if (flags & F_SILU) v[j] = v[j] / (1.f + expf(-v[j]));
            }
            if (flags & F_RESID) {
                const float4* rp = (const float4*)(resid + (size_t)r * ldr + c0);
                float4 r0 = rp[0], r1 = rp[1];
                v[0] += r0.x; v[1] += r0.y; v[2] += r0.z; v[3] += r0.w;
                v[4] += r1.x; v[5] += r1.y; v[6] += r1.z; v[7] += r1.w;
            }
            if (flags & F_OUTBF) {
                short8 o;
                #pragma unroll
                for (int j = 0; j < 8; ++j) o[j] = (short)f2b(v[j]);
                *(short8*)(Cb + i0) = o;
            } else {
                float4 o0 = {v[0], v[1], v[2], v[3]}, o1 = {v[4], v[5], v[6], v[7]};
                float4* cp = (float4*)(Cf + i0);
                cp[0] = o0; cp[1] = o1;
            }
        }
    } else {
        size_t total = (size_t)M * Ncols;
        for (size_t i = (size_t)blockIdx.x * 256 + threadIdx.x; i < total;
             i += (size_t)gridDim.x * 256) {
            float v = 0.f;
            for (int s = 0; s < nsl; ++s) v += b2f(part[(size_t)s * slice + i]);
            if (flags & F_OUTBF) Cb[i] = f2b(v);
            else                 Cf[i] = v;
        }
    }
}

// ===== fused split-K reduce -> local update -> cond LayerNorm -> bf16 =====
// block = row. v = Sum(partials) + bias + resid; locOut = v; normB = sig(cs)*LN(v)+cb
__global__ __launch_bounds__(256) void reduce_cn(
    const u16* __restrict__ part, size_t slice, int nsl,
    const float* __restrict__ bias, const float* __restrict__ resid,
    float* __restrict__ locOut,
    const u16* __restrict__ cs, const u16* __restrict__ cb,
    u16* __restrict__ normB)
{
    int row = blockIdx.x, tid = threadIdx.x;
    size_t base = (size_t)row * 1024 + tid * 4;
    float v[4];
    {
        float4 rv = *(const float4*)(resid + base);
        v[0] = rv.x; v[1] = rv.y; v[2] = rv.z; v[3] = rv.w;
    }
    for (int s = 0; s < nsl; ++s) {
        u16x4 p = *(const u16x4*)(part + (size_t)s * slice + base);
        v[0] += b2f(p.x); v[1] += b2f(p.y); v[2] += b2f(p.z); v[3] += b2f(p.w);
    }
    {
        float4 bv = *(const float4*)(bias + tid * 4);
        v[0] += bv.x; v[1] += bv.y; v[2] += bv.z; v[3] += bv.w;
    }
    *(float4*)(locOut + base) = (float4){v[0], v[1], v[2], v[3]};

    float s1 = v[0] + v[1] + v[2] + v[3];
    float s2 = v[0]*v[0] + v[1]*v[1] + v[2]*v[2] + v[3]*v[3];
    __shared__ float r1[256], r2[256];
    r1[tid] = s1; r2[tid] = s2;
    __syncthreads();
    for (int st = 128; st > 0; st >>= 1) {
        if (tid < st) { r1[tid] += r1[tid + st]; r2[tid] += r2[tid + st]; }
        __syncthreads();
    }
    float mean = r1[0] * (1.f / 1024.f);
    float var = r2[0] * (1.f / 1024.f) - mean * mean;
    float rs = rsqrtf(var + 1e-5f);
    u16x4 sv = *(const u16x4*)(cs + base);
    u16x4 bv = *(const u16x4*)(cb + base);
    u16x4 o;
    o.x = f2b((1.f / (1.f + expf(-b2f(sv.x)))) * (v[0] - mean) * rs + b2f(bv.x));
    o.y = f2b((1.f / (1.f + expf(-b2f(sv.y)))) * (v[1] - mean) * rs + b2f(bv.y));
    o.z = f2b((1.f / (1.f + expf(-b2f(sv.z)))) * (v[2] - mean) * rs + b2f(bv.z));
    o.w = f2b((1.f / (1.f + expf(-b2f(sv.w)))) * (v[3] - mean) * rs + b2f(bv.w));
    *(u16x4*)(normB + base) = o;
}

// ===================== fused flash attention v3 (proven R6/R7) =====================
__global__ __launch_bounds__(256, 2) void attn_kernel(
    const u16* __restrict__ qe, const u16* __restrict__ ke,
    const u16* __restrict__ vt, const float* __restrict__ pb,
    float* __restrict__ Opart, float* __restrict__ mlpart)
{
    __shared__ u16 Ks[2][64 * 128];
    __shared__ u16 Vs[2][96 * 64];
    __shared__ u16 Ps[64 * 64];

    const int tid = threadIdx.x;
    const int l = tid & 63, w = tid >> 6;
    const int h = blockIdx.y;
    const int q0 = blockIdx.x * 64;
    const int z = blockIdx.z;
    const int fr = l & 15, fq = l >> 4;

    const u16* keh = ke + (size_t)h * NRES * 128;
    const u16* vth = vt + (size_t)h * 96 * NRES;

    const int kr4 = l >> 4, ks16 = l & 15;
    const int vr8 = l >> 3, vs8 = l & 7;

    short8 qv[4];
    {
        const u16* qrow = qe + ((size_t)h * NRES + (q0 + w * 16 + fr)) * 128 + fq * 8;
        #pragma unroll
        for (int kk = 0; kk < 4; ++kk)
            qv[kk] = *(const short8*)(qrow + kk * 32);
    }

    float m_run[4], l_run[4];
    f32x4 oacc[6];
    #pragma unroll
    for (int r = 0; r < 4; ++r) { m_run[r] = -1e30f; l_run[r] = 0.f; }
    #pragma unroll
    for (int n = 0; n < 6; ++n) oacc[n] = (f32x4){0.f, 0.f, 0.f, 0.f};

    const int NIT = NRES / 128;
    const int jbase = z * (NRES / 2);
    int cur = 0;

    auto stage = [&](int buf, int j0) {
        #pragma unroll
        for (int t = 0; t < 4; ++t) {
            int row = w * 16 + t * 4 + kr4;
            int ss = ks16 ^ (row & 7);
            __builtin_amdgcn_global_load_lds(
                (gvoid*)(keh + (size_t)(j0 + row) * 128 + ss * 8),
                (lvoid*)((char*)Ks[buf] + (w * 16 + t * 4) * 256), 16, 0, 0);
        }
        #pragma unroll
        for (int t = 0; t < 3; ++t) {
            int row = w * 24 + t * 8 + vr8;
            int ss = vs8 ^ (row & 7);
            __builtin_amdgcn_global_load_lds(
                (gvoid*)(vth + (size_t)row * NRES + j0 + ss * 8),
                (lvoid*)((char*)Vs[buf] + (w * 24 + t * 8) * 128), 16, 0, 0);
        }
    };
    const float* pbrow = pb + ((size_t)h * NRES + (q0 + w * 16 + fq * 4)) * NRES + fr;

    f32x4 pbv[4], pbn[4] = {};
    stage(0, jbase);
    #pragma unroll
    for (int n = 0; n < 4; ++n)
        #pragma unroll
        for (int r = 0; r < 4; ++r)
            pbv[n][r] = pbrow[(size_t)r * NRES + jbase + n * 16];
    __syncthreads();

    for (int it = 0; it < NIT; ++it) {
        if (it + 1 < NIT) {
            int j1 = jbase + (it + 1) * 64;
            stage(cur ^ 1, j1);
            #pragma unroll
            for (int n = 0; n < 4; ++n)
                #pragma unroll
                for (int r = 0; r < 4; ++r)
                    pbn[n][r] = pbrow[(size_t)r * NRES + j1 + n * 16];
        }

        f32x4 sacc[4];
        #pragma unroll
        for (int n = 0; n < 4; ++n) sacc[n] = (f32x4){0.f, 0.f, 0.f, 0.f};
        #pragma unroll
        for (int kk = 0; kk < 4; ++kk) {
            #pragma unroll
            for (int n = 0; n < 4; ++n) {
                int row = n * 16 + fr;
                short8 bv = *(const short8*)((const char*)Ks[cur] + row * 256
                                             + (((kk * 4 + fq) ^ (fr & 7)) * 16));
                sacc[n] = __builtin_amdgcn_mfma_f32_16x16x32_bf16(qv[kk], bv, sacc[n], 0, 0, 0);
            }
        }
        #pragma unroll
        for (int n = 0; n < 4; ++n) sacc[n] += pbv[n];

        float alpha[4];
        #pragma unroll
        for (int r = 0; r < 4; ++r) {
            float v = fmaxf(fmaxf(sacc[0][r], sacc[1][r]), fmaxf(sacc[2][r], sacc[3][r]));
            v = fmaxf(v, __shfl_xor(v, 1, 64));
            v = fmaxf(v, __shfl_xor(v, 2, 64));
            v = fmaxf(v, __shfl_xor(v, 4, 64));
            v = fmaxf(v, __shfl_xor(v, 8, 64));
            float mn = fmaxf(m_run[r], v);
            alpha[r] = exp2f((m_run[r] - mn) * LOG2E);
            m_run[r] = mn;
        }

        float psum[4] = {0.f, 0.f, 0.f, 0.f};
        #pragma unroll
        for (int n = 0; n < 4; ++n) {
            int col = n * 16 + fr;
            #pragma unroll
            for (int r = 0; r < 4; ++r) {
                float p = exp2f((sacc[n][r] - m_run[r]) * LOG2E);
                psum[r] += p;
                int rowf = w * 16 + fq * 4 + r;
                int byte = rowf * 128 + (((col >> 3) ^ (rowf & 7)) * 16) + (col & 7) * 2;
                *(u16*)((char*)Ps + byte) = f2b(p);
            }
        }
        #pragma unroll
        for (int r = 0; r < 4; ++r) {
            float v = psum[r];
            v += __shfl_xor(v, 1, 64);
            v += __shfl_xor(v, 2, 64);
            v += __shfl_xor(v, 4, 64);
            v += __shfl_xor(v, 8, 64);
            l_run[r] = l_run[r] * alpha[r] + v;
        }
        #pragma unroll
        for (int n = 0; n < 6; ++n)
            #pragma unroll
            for (int r = 0; r < 4; ++r)
                oacc[n][r] *= alpha[r];

        #pragma unroll
        for (int kk = 0; kk < 2; ++kk) {
            int prow = w * 16 + fr;
            short8 pa = *(const short8*)((const char*)Ps + prow * 128
                                         + (((kk * 4 + fq) ^ (prow & 7)) * 16));
            #pragma unroll
            for (int n = 0; n < 6; ++n) {
                int vrow = n * 16 + fr;
                short8 vv = *(const short8*)((const char*)Vs[cur] + vrow * 128
                                             + (((kk * 4 + fq) ^ (fr & 7)) * 16));
                oacc[n] = __builtin_amdgcn_mfma_f32_16x16x32_bf16(pa, vv, oacc[n], 0, 0, 0);
            }
        }

        __syncthreads();
        cur ^= 1;
        #pragma unroll
        for (int n = 0; n < 4; ++n) pbv[n] = pbn[n];
    }

    float* Oz = Opart + ((size_t)z * NH + h) * NRES * 96;
    #pragma unroll
    for (int n = 0; n < 6; ++n) {
        int c = n * 16 + fr;
        #pragma unroll
        for (int r = 0; r < 4; ++r) {
            int row = q0 + w * 16 + fq * 4 + r;
            Oz[(size_t)row * 96 + c] = oacc[n][r];
        }
    }
    if (fr == 0) {
        float* mlz = mlpart + ((size_t)z * NH + h) * NRES * 2;
        #pragma unroll
        for (int r = 0; r < 4; ++r) {
            int row = q0 + w * 16 + fq * 4 + r;
            mlz[row * 2 + 0] = m_run[r];
            mlz[row * 2 + 1] = l_run[r];
        }
    }
}

// ===================== split-KV combine -> cat =====================
__global__ __launch_bounds__(256) void combine_kernel(
    const float* __restrict__ Opart, const float* __restrict__ mlpart,
    float* __restrict__ cat)
{
    int idx = blockIdx.x * 256 + threadIdx.x;
    if (idx >= NH * NRES * 88) return;
    int c = idx % 88;
    int rh = idx / 88;
    size_t r0 = (size_t)rh;
    size_t r1 = (size_t)NH * NRES + r0;
    float m0 = mlpart[r0 * 2], l0 = mlpart[r0 * 2 + 1];
    float m1 = mlpart[r1 * 2], l1 = mlpart[r1 * 2 + 1];
    float mm = fmaxf(m0, m1);
    float w0 = exp2f((m0 - mm) * LOG2E);
    float w1 = exp2f((m1 - mm) * LOG2E);
    float ll = l0 * w0 + l1 * w1;
    cat[r0 * 88 + c] = (Opart[r0 * 96 + c] * w0 + Opart[r1 * 96 + c] * w1) / ll;
}

// ===================== batched transpose fp32 -> bf16 [N][K] =====================
struct TP9 { const float* p[9]; };

__global__ __launch_bounds__(256) void transpose_bz(
    TP9 tp, int ldi, size_t zsi,
    u16* __restrict__ out, int ldo, size_t zso, int K, int N, int nsrc)
{
    __shared__ float t[32][33];
    int z = blockIdx.z;
    const float* in = tp.p[(z < nsrc) ? z : 0] + zsi * ((z < nsrc) ? 0 : z);
    if (nsrc == 1) in = tp.p[0] + zsi * z;
    out += zso * z;
    int k0 = blockIdx.y * 32, n0 = blockIdx.x * 32;
    int tx = threadIdx.x & 31, ty = threadIdx.x >> 5;
    #pragma unroll
    for (int j = 0; j < 4; ++j) {
        int k = k0 + ty + j * 8;
        if (k < K && n0 + tx < N) t[ty + j * 8][tx] = in[(size_t)k * ldi + n0 + tx];
    }
    __syncthreads();
    #pragma unroll
    for (int j = 0; j < 4; ++j) {
        int n = n0 + ty + j * 8;
        int k = k0 + tx;
        if (n < N && k < K) out[(size_t)n * ldo + k] = f2b(t[tx][ty + j * 8]);
    }
}

// ===================== misc small kernels =====================
__global__ __launch_bounds__(256) void f2b8_kernel(const float* __restrict__ in, u16* __restrict__ out, int n8)
{
    int i = blockIdx.x * 256 + threadIdx.x;
    if (i >= n8) return;
    size_t i0 = (size_t)i * 8;
    const float4* p = (const float4*)(in + i0);
    float4 a = p[0], b = p[1];
    short8 o;
    o[0]=(short)f2b(a.x); o[1]=(short)f2b(a.y); o[2]=(short)f2b(a.z); o[3]=(short)f2b(a.w);
    o[4]=(short)f2b(b.x); o[5]=(short)f2b(b.y); o[6]=(short)f2b(b.z); o[7]=(short)f2b(b.w);
    *(short8*)(out + i0) = o;
}

__global__ __launch_bounds__(256) void emb_kernel(const float* __restrict__ pos, u16* __restrict__ emb)
{
    int idx = blockIdx.x * 256 + threadIdx.x;
    int f = idx & 63;
    int rest = idx >> 6;
    int coord = rest % 42;
    int n = rest / 42;
    float t = pos[(size_t)n * 42 + coord];
    const double l0 = -6.643856189774724;
    const double step = 14.643856189774724 / 63.0;
    float freq = exp2f((float)(l0 + f * step));
    float r = t * freq;
    size_t o = (size_t)n * 5376 + (size_t)coord * 128 + 2 * f;
    emb[o]     = f2b(sinf(r));
    emb[o + 1] = f2b(cosf(r));
}

__global__ __launch_bounds__(256) void frames_kernel(const float* __restrict__ pos,
                                                     float* __restrict__ Rb, float* __restrict__ tb)
{
    int n = blockIdx.x * 256 + threadIdx.x;
    if (n >= NRES) return;
    const float* p = pos + (size_t)n * 42;
    float nx = p[0], ny = p[1], nz = p[2];
    float cax = p[3], cay = p[4], caz = p[5];
    float cx = p[6], cy = p[7], cz = p[8];
    float v1x = cx - cax, v1y = cy - cay, v1z = cz - caz;
    float i1 = rsqrtf(v1x * v1x + v1y * v1y + v1z * v1z + 1e-8f);
    float e1x = v1x * i1, e1y = v1y * i1, e1z = v1z * i1;
    float v2x = nx - cax, v2y = ny - cay, v2z = nz - caz;
    float d = e1x * v2x + e1y * v2y + e1z * v2z;
    float wx = v2x - d * e1x, wy = v2y - d * e1y, wz = v2z - d * e1z;
    float i2 = rsqrtf(wx * wx + wy * wy + wz * wz + 1e-8f);
    float e2x = wx * i2, e2y = wy * i2, e2z = wz * i2;
    float e3x = e1y * e2z - e1z * e2y;
    float e3y = e1z * e2x - e1x * e2z;
    float e3z = e1x * e2y - e1y * e2x;
    float* R = Rb + (size_t)n * 9;
    R[0] = e1x; R[1] = e2x; R[2] = e3x;
    R[3] = e1y; R[4] = e2y; R[5] = e3y;
    R[6] = e1z; R[7] = e2z; R[8] = e3z;
    tb[(size_t)n * 3 + 0] = cax;
    tb[(size_t)n * 3 + 1] = cay;
    tb[(size_t)n * 3 + 2] = caz;
}

__global__ __launch_bounds__(256) void bias_pack(const float* a, const float* b, const float* c,
                                                 const float* d, const float* e, const float* f,
                                                 float* out)
{
    int i = blockIdx.x * 256 + threadIdx.x;
    if (i >= 1024) return;
    out[i] = a[i]; out[1024 + i] = b[i]; out[2048 + i] = c[i];
    out[3072 + i] = d[i]; out[4096 + i] = e[i]; out[5120 + i] = f[i];
}

__global__ __launch_bounds__(256) void biasg_pack(const float* a, const float* b, float* out)
{
    int i = blockIdx.x * 256 + threadIdx.x;
    if (i >= 2048) return;
    out[i] = a[i]; out[2048 + i] = b[i];
}

// gm = silu(g1) * g2, 8-wide
__global__ __launch_bounds__(256) void glu_kernel(const u16* __restrict__ g12, u16* __restrict__ gm)
{
    int i = blockIdx.x * 256 + threadIdx.x;
    if (i >= NRES * 2048 / 8) return;
    size_t i0 = (size_t)i * 8;
    short8 a8 = *(const short8*)(g12 + i0);
    short8 b8 = *(const short8*)(g12 + (size_t)NRES * 2048 + i0);
    short8 o;
    #pragma unroll
    for (int j = 0; j < 8; ++j) {
        float a = b2f((u16)a8[j]);
        float b = b2f((u16)b8[j]);
        float s = a / (1.f + expf(-a));
        o[j] = (short)f2b(s * b);
    }
    *(short8*)(gm + i0) = o;
}

// vectorized pack: qe/ke [h][n][128]; g<8 data, g==11 zeros 88..95, g>=12 zeros
__global__ __launch_bounds__(256) void pack_qk(const float* __restrict__ qb, const float* __restrict__ kb,
                                               u16* __restrict__ qe, u16* __restrict__ ke)
{
    int idx = blockIdx.x * 256 + threadIdx.x;   // < NH*NRES*16
    if (idx >= NH * NRES * 16) return;
    int g = idx & 15;
    int t = idx >> 4;
    int n = t % NRES;
    int h = t / NRES;
    size_t o = ((size_t)h * NRES + n) * 128 + g * 8;
    if (g < 8) {
        const float* qs = qb + (size_t)n * 1024 + h * 64 + g * 8;
        const float* ks = kb + (size_t)n * 1024 + h * 64 + g * 8;
        const float4* q4 = (const float4*)qs;
        const float4* k4 = (const float4*)ks;
        float4 qa = q4[0], qb2 = q4[1], ka = k4[0], kb2 = k4[1];
        short8 oq, ok;
        oq[0]=(short)f2b(0.125f*qa.x); oq[1]=(short)f2b(0.125f*qa.y);
        oq[2]=(short)f2b(0.125f*qa.z); oq[3]=(short)f2b(0.125f*qa.w);
        oq[4]=(short)f2b(0.125f*qb2.x); oq[5]=(short)f2b(0.125f*qb2.y);
        oq[6]=(short)f2b(0.125f*qb2.z); oq[7]=(short)f2b(0.125f*qb2.w);
        ok[0]=(short)f2b(ka.x); ok[1]=(short)f2b(ka.y); ok[2]=(short)f2b(ka.z); ok[3]=(short)f2b(ka.w);
        ok[4]=(short)f2b(kb2.x); ok[5]=(short)f2b(kb2.y); ok[6]=(short)f2b(kb2.z); ok[7]=(short)f2b(kb2.w);
        *(short8*)(qe + o) = oq;
        *(short8*)(ke + o) = ok;
    } else if (g >= 11) {
        short8 zz = {};
        *(short8*)(qe + o) = zz;
        *(short8*)(ke + o) = zz;
    }
}

__global__ __launch_bounds__(256) void build_pts(
    const float* __restrict__ qp, const float* __restrict__ kp, const float* __restrict__ vp,
    const float* __restrict__ Rb, const float* __restrict__ tb, const float* __restrict__ gamma,
    u16* __restrict__ qe, u16* __restrict__ ke, float* __restrict__ vgt)
{
    int idx = blockIdx.x * 256 + threadIdx.x;
    if (idx >= NRES * NH) return;
    int n = idx >> 4, h = idx & 15;
    float R[9];
    #pragma unroll
    for (int a = 0; a < 9; ++a) R[a] = Rb[(size_t)n * 9 + a];
    float t0 = tb[(size_t)n * 3 + 0], t1 = tb[(size_t)n * 3 + 1], t2 = tb[(size_t)n * 3 + 2];
    float g = gamma[h];
    float sp = (g > 20.f) ? g : log1pf(expf(g));
    float ch = 0.5f * (1.f / 6.f) * sp;

    u16* qeh = qe + ((size_t)h * NRES + n) * 128;
    u16* keh = ke + ((size_t)h * NRES + n) * 128;
    size_t pbase = (size_t)n * 384 + h * 24;
    float kn = 0.f;
    #pragma unroll
    for (int p = 0; p < 8; ++p) {
        size_t o = pbase + p * 3;
        {
            float x = qp[o], y = qp[o + 1], z = qp[o + 2];
            float g0 = R[0] * x + R[1] * y + R[2] * z + t0;
            float g1 = R[3] * x + R[4] * y + R[5] * z + t1;
            float g2 = R[6] * x + R[7] * y + R[8] * z + t2;
            qeh[64 + p * 3 + 0] = f2b(2.f * ch * g0);
            qeh[64 + p * 3 + 1] = f2b(2.f * ch * g1);
            qeh[64 + p * 3 + 2] = f2b(2.f * ch * g2);
        }
        {
            float x = kp[o], y = kp[o + 1], z = kp[o + 2];
            float g0 = R[0] * x + R[1] * y + R[2] * z + t0;
            float g1 = R[3] * x + R[4] * y + R[5] * z + t1;
            float g2 = R[6] * x + R[7] * y + R[8] * z + t2;
            keh[64 + p * 3 + 0] = f2b(g0);
            keh[64 + p * 3 + 1] = f2b(g1);
            keh[64 + p * 3 + 2] = f2b(g2);
            kn += g0 * g0 + g1 * g1 + g2 * g2;
        }
        {
            float x = vp[o], y = vp[o + 1], z = vp[o + 2];
            vgt[o]     = R[0] * x + R[1] * y + R[2] * z + t0;
            vgt[o + 1] = R[3] * x + R[4] * y + R[5] * z + t1;
            vgt[o + 2] = R[6] * x + R[7] * y + R[8] * z + t2;
        }
    }
    qeh[88] = f2b(1.0f);
    keh[88] = f2b(-ch * kn);
}

__global__ __launch_bounds__(256) void finalize_kernel(const float* __restrict__ cat,
                                                       const float* __restrict__ Rb,
                                                       const float* __restrict__ tb,
                                                       u16* __restrict__ featB)
{
    int idx = blockIdx.x * 256 + threadIdx.x;
    if (idx >= NRES * NH) return;
    int n = idx >> 4, h = idx & 15;
    float R[9];
    #pragma unroll
    for (int a = 0; a < 9; ++a) R[a] = Rb[(size_t)n * 9 + a];
    float t0 = tb[(size_t)n * 3 + 0], t1 = tb[(size_t)n * 3 + 1], t2 = tb[(size_t)n * 3 + 2];
    const float* c = cat + ((size_t)h * NRES + n) * 88;
    u16* fb = featB + (size_t)n * 1536;
    #pragma unroll
    for (int k = 0; k < 64; ++k) fb[h * 64 + k] = f2b(c[k]);
    #pragma unroll
    for (int p = 0; p < 8; ++p) {
        float x = c[64 + p * 3 + 0] - t0;
        float y = c[64 + p * 3 + 1] - t1;
        float z = c[64 + p * 3 + 2] - t2;
        float a0 = R[0] * x + R[3] * y + R[6] * z;
        float a1 = R[1] * x + R[4] * y + R[7] * z;
        float a2 = R[2] * x + R[5] * y + R[8] * z;
        fb[1024 + h * 24 + p * 3 + 0] = f2b(a0);
        fb[1024 + h * 24 + p * 3 + 1] = f2b(a1);
        fb[1024 + h * 24 + p * 3 + 2] = f2b(a2);
        fb[1408 + h * 8 + p] = f2b(sqrtf(a0 * a0 + a1 * a1 + a2 * a2 + 1e-8f));
    }
}

// ========================= host =========================
extern "C" void kernel_launch(void* const* d_in, const int* in_sizes, int n_in,
                              void* d_out, int out_size, void* d_ws, size_t ws_size,
                              hipStream_t stream)
{
    const float* local_in = (const float*)d_in[0];
    const float* pos      = (const float*)d_in[1];
    const float* cond     = (const float*)d_in[2];
    const float* pb       = (const float*)d_in[4];
    const float* w_f1     = (const float*)d_in[5];
    const float* b_f1     = (const float*)d_in[6];
    const float* w_f2     = (const float*)d_in[7];
    const float* b_f2     = (const float*)d_in[8];
    const float* cn1_ws   = (const float*)d_in[9];
    const float* cn1_bs   = (const float*)d_in[10];
    const float* cn1_wb   = (const float*)d_in[11];
    const float* cn1_bb   = (const float*)d_in[12];
    const float* wq       = (const float*)d_in[13];
    const float* wk       = (const float*)d_in[14];
    const float* wv       = (const float*)d_in[15];
    const float* wqp      = (const float*)d_in[16];
    const float* wkp      = (const float*)d_in[17];
    const float* wvp      = (const float*)d_in[18];
    const float* gamma    = (const float*)d_in[19];
    const float* wo       = (const float*)d_in[20];
    const float* bo       = (const float*)d_in[21];
    const float* cn2_ws   = (const float*)d_in[22];
    const float* cn2_bs   = (const float*)d_in[23];
    const float* cn2_wb   = (const float*)d_in[24];
    const float* cn2_bb   = (const float*)d_in[25];
    const float* wg1      = (const float*)d_in[26];
    const float* bg1      = (const float*)d_in[27];
    const float* wg2      = (const float*)d_in[28];
    const float* bg2      = (const float*)d_in[29];
    const float* wg3      = (const float*)d_in[30];
    const float* bg3      = (const float*)d_in[31];
    const float* cn3_ws   = (const float*)d_in[32];
    const float* cn3_bs   = (const float*)d_in[33];
    const float* cn3_wb   = (const float*)d_in[34];
    const float* cn3_bb   = (const float*)d_in[35];
    const float* w_vel    = (const float*)d_in[36];

    float* out = (float*)d_out;
    float* ws  = (float*)d_ws;

    size_t off = 0;
    auto alloc = [&](size_t nf) -> float* { float* p = ws + off; off += (nf + 7) & ~7ull; return p; };

    const size_t NN1 = (size_t)NRES * 1024;
    float* Rb    = alloc(NRES * 9);
    float* tb    = alloc(NRES * 3);
    float* loc   = alloc(NN1);
    u16*   cs6b  = (u16*)alloc(6 * NN1 / 2);                 // bf16 cond scales/biases
    u16*   condB = (u16*)alloc(NN1 / 2);
    u16*   normB = (u16*)alloc(NN1 / 2);
    float* bias2 = alloc(6 * 1024);
    float* biasg = alloc(2 * 2048);
    float* qb    = alloc(3 * NN1);
    float* kb    = qb + NN1;
    float* vb    = kb + NN1;
    float* qp    = alloc(3 * (size_t)NRES * 384);
    float* kp    = qp + NRES * 384;
    float* vp    = kp + NRES * 384;
    float* vgt   = alloc((size_t)NRES * 384);
    u16*   qeB   = (u16*)alloc((size_t)NH * NRES * 128 / 2);
    u16*   keB   = (u16*)alloc((size_t)NH * NRES * 128 / 2);
    u16*   vTB   = (u16*)alloc((size_t)NH * 96 * NRES / 2);
    float* cat   = alloc((size_t)NH * NRES * 88);
    u16*   featB = (u16*)alloc((size_t)NRES * 1536 / 2);
    u16*   g1sB  = (u16*)alloc((size_t)NRES * 2048 / 2);   // g12B z=0
    u16*   gmB   = (u16*)alloc((size_t)NRES * 2048 / 2);   // g12B z=1 (contiguous)
    u16*   cnT9  = (u16*)alloc((size_t)9 * 1024 * 1024 / 2);
    u16*   ptsT  = (u16*)alloc((size_t)3 * 384 * 1024 / 2);
    u16*   wgT   = (u16*)alloc((size_t)2 * 2048 * 1024 / 2);
    u16*   wf1T  = (u16*)alloc((size_t)2048 * 5376 / 2);
    u16*   wf2T  = (u16*)alloc((size_t)1024 * 2048 / 2);
    u16*   woT   = (u16*)alloc((size_t)1024 * 1536 / 2);
    u16*   wg3T  = (u16*)alloc((size_t)1024 * 2048 / 2);
    u16*   wvT   = (u16*)alloc((size_t)42 * 1024 / 2 + 8);
    u16*   embB  = (u16*)alloc((size_t)NRES * 5376 / 2);   // reused as gm output later
    u16*   hidB  = (u16*)alloc((size_t)NRES * 2048 / 2);
    u16*   pscr  = (u16*)alloc((size_t)2 * NRES * 2048 * 4 / 2); // bf16 partials (up to 8 slices of NN1 / 4 of NRESx2048)
    float* Opart = alloc((size_t)2 * NH * NRES * 96);
    float* mlprt = alloc((size_t)2 * NH * NRES * 2);

    const float* nilf = nullptr;

    auto gemm = [&](int tnf, const u16* A, int lda, size_t zsA,
                    const u16* BT, int ldb, size_t zsB,
                    float* Cf, u16* Cb2, int ldc, size_t zsC,
                    const float* bias, size_t zsBias,
                    const float* resid, int ldr, size_t zsR,
                    int Nc, int Kd, int flags, int gz, int ksl) {
        int tn = tnf * 32;
        dim3 grid((Nc + tn - 1) / tn, NRES / 128, gz);
        if (tnf == 4)
            hipLaunchKernelGGL(gemm_t<4>, grid, dim3(256), 0, stream,
                               A, lda, zsA, BT, ldb, zsB, Cf, Cb2, ldc, zsC,
                               bias, zsBias, resid, ldr, zsR, Nc, Kd, flags, ksl);
        else
            hipLaunchKernelGGL(gemm_t<2>, grid, dim3(256), 0, stream,
                               A, lda, zsA, BT, ldb, zsB, Cf, Cb2, ldc, zsC,
                               bias, zsBias, resid, ldr, zsR, Nc, Kd, flags, ksl);
    };
    auto red = [&](const u16* part, size_t slice, int nsl, float* Cf, u16* Cb2,
                   const float* bias, const float* resid, int ldr, int Nc, int flags) {
        hipLaunchKernelGGL(reduce_epi, dim3(1024), dim3(256), 0, stream,
                           part, slice, nsl, Cf, Cb2, bias, resid, ldr, NRES, Nc, flags);
    };
    auto redcn = [&](const u16* part, size_t slice, int nsl,
                     const float* bias, const float* resid, float* locOut, int cnIdx) {
        hipLaunchKernelGGL(reduce_cn, dim3(NRES), dim3(256), 0, stream,
                           part, slice, nsl, bias, resid, locOut,
                           cs6b + (size_t)(2 * cnIdx) * NN1,
                           cs6b + (size_t)(2 * cnIdx + 1) * NN1, normB);
    };
    auto tpz = [&](TP9 tp, int ldi, int K, int N, u16* o, int ldo, size_t zso, int nsrc) {
        dim3 grid((N + 31) / 32, (K + 31) / 32, nsrc);
        hipLaunchKernelGGL(transpose_bz, grid, dim3(256), 0, stream, tp, ldi, (size_t)0, o, ldo, zso, K, N, nsrc);
    };
    auto tps = [&](const float* in, int ldi, size_t zsi, int K, int N, u16* o, int ldo, size_t zso, int gz) {
        dim3 grid((N + 31) / 32, (K + 31) / 32, gz);
        TP9 tp; tp.p[0] = in;
        hipLaunchKernelGGL(transpose_bz, grid, dim3(256), 0, stream, tp, ldi, zsi, o, ldo, zso, K, N, 1);
    };

    // ---- prologue ----
    hipLaunchKernelGGL(frames_kernel, dim3(6), dim3(256), 0, stream, pos, Rb, tb);
    hipLaunchKernelGGL(emb_kernel, dim3((NRES * 42 * 64) / 256), dim3(256), 0, stream, pos, embB);
    hipLaunchKernelGGL(f2b8_kernel, dim3(768), dim3(256), 0, stream, cond, condB, NRES * 1024 / 8);
    hipLaunchKernelGGL(bias_pack, dim3(4), dim3(256), 0, stream,
                       cn1_bs, cn1_bb, cn2_bs, cn2_bb, cn3_bs, cn3_bb, bias2);
    hipLaunchKernelGGL(biasg_pack, dim3(8), dim3(256), 0, stream, bg1, bg2, biasg);

    // ---- weight transposes ----
    {
        TP9 t9; t9.p[0]=cn1_ws; t9.p[1]=cn1_wb; t9.p[2]=cn2_ws; t9.p[3]=cn2_wb;
        t9.p[4]=cn3_ws; t9.p[5]=cn3_wb; t9.p[6]=wq; t9.p[7]=wk; t9.p[8]=wv;
        tpz(t9, 1024, 1024, 1024, cnT9, 1024, (size_t)1024 * 1024, 9);
    }
    {
        TP9 t3; t3.p[0]=wqp; t3.p[1]=wkp; t3.p[2]=wvp;
        tpz(t3, 384, 1024, 384, ptsT, 1024, (size_t)384 * 1024, 3);
    }
    {
        TP9 t2; t2.p[0]=wg1; t2.p[1]=wg2;
        tpz(t2, 2048, 1024, 2048, wgT, 1024, (size_t)2048 * 1024, 2);
    }
    tps(w_f1, 2048, 0, 5376, 2048, wf1T, 5376, 0, 1);
    tps(w_f2, 1024, 0, 2048, 1024, wf2T, 2048, 0, 1);
    tps(wo,   1024, 0, 1536, 1024, woT,  1536, 0, 1);
    tps(wg3,  1024, 0, 2048, 1024, wg3T, 2048, 0, 1);
    tps(w_vel,  42, 0, 1024,   42, wvT,  1024, 0, 1);

    // ---- all 6 cond GEMMs (z=6, TN=64, bf16 out) ----
    gemm(2, condB, 1024, 0, cnT9, 1024, (size_t)1024 * 1024, nullptr, cs6b, 1024, NN1,
         bias2, 1024, nilf, 0, 0, 1024, 1024, F_BIAS | F_OUTBF, 6, 0);

    // ---- phase A: emb GEMM split-K=4 (1536 blocks), bf16 partials + reduce(silu->bf16) ----
    gemm(2, embB, 5376, 0, wf1T, 5376, 0, nullptr, pscr, 2048, (size_t)NRES * 2048,
         nilf, 0, nilf, 0, 0, 2048, 5376, F_OUTBF, 4, 1344);
    red(pscr, (size_t)NRES * 2048, 4, nullptr, hidB, b_f1, nilf, 0,
        2048, F_BIAS | F_SILU | F_OUTBF);
    // hid GEMM split-K=4 + fused reduce+condnorm1 -> loc, normB
    gemm(2, hidB, 2048, 0, wf2T, 2048, 0, nullptr, pscr, 1024, NN1,
         nilf, 0, nilf, 0, 0, 1024, 2048, F_OUTBF, 4, 512);
    redcn(pscr, NN1, 4, b_f2, local_in, loc, 0);

    // ---- projections ----
    gemm(2, normB, 1024, 0, cnT9 + (size_t)6 * 1024 * 1024, 1024, (size_t)1024 * 1024,
         qb, nullptr, 1024, NN1, nilf, 0, nilf, 0, 0, 1024, 1024, 0, 3, 0);
    gemm(2, normB, 1024, 0, ptsT, 1024, (size_t)384 * 1024, qp, nullptr, 384, (size_t)NRES * 384,
         nilf, 0, nilf, 0, 0, 384, 1024, 0, 3, 0);

    // ---- attention operands ----
    hipMemsetAsync(vTB, 0, (size_t)NH * 96 * NRES * 2, stream);
    hipLaunchKernelGGL(pack_qk, dim3((NH * NRES * 16 + 255) / 256), dim3(256), 0, stream, qb, kb, qeB, keB);
    hipLaunchKernelGGL(build_pts, dim3(96), dim3(256), 0, stream,
                       qp, kp, vp, Rb, tb, gamma, qeB, keB, vgt);
    tps(vb, 1024, 64, NRES, 64, vTB, NRES, (size_t)96 * NRES, NH);
    tps(vgt, 384, 24, NRES, 24, vTB + (size_t)64 * NRES, NRES, (size_t)96 * NRES, NH);

    // ---- fused attention (split-KV, pipelined) + combine ----
    hipLaunchKernelGGL(attn_kernel, dim3(NRES / 64, NH, 2), dim3(256), 0, stream,
                       qeB, keB, vTB, pb, Opart, mlprt);
    hipLaunchKernelGGL(combine_kernel, dim3((NH * NRES * 88 + 255) / 256), dim3(256), 0, stream,
                       Opart, mlprt, cat);
    hipLaunchKernelGGL(finalize_kernel, dim3(96), dim3(256), 0, stream, cat, Rb, tb, featB);

    // ---- local += feat @ wo + bo : split-K=4, fused reduce+condnorm2 ----
    gemm(2, featB, 1536, 0, woT, 1536, 0, nullptr, pscr, 1024, NN1,
         nilf, 0, nilf, 0, 0, 1024, 1536, F_OUTBF, 4, 384);
    redcn(pscr, NN1, 4, bo, loc, loc, 1);

    // ---- gated MLP: wg1+wg2 fused z=2, glu, wg3 split-K=4 + fused reduce+condnorm3 ----
    gemm(2, normB, 1024, 0, wgT, 1024, (size_t)2048 * 1024, nullptr, g1sB, 2048, (size_t)NRES * 2048,
         biasg, 2048, nilf, 0, 0, 2048, 1024, F_BIAS | F_OUTBF, 2, 0);
    u16* gmO = embB;   // emb dead; reuse as glu output
    hipLaunchKernelGGL(glu_kernel, dim3((NRES * 2048 / 8 + 255) / 256), dim3(256), 0, stream, g1sB, gmO);
    gemm(2, gmO, 2048, 0, wg3T, 2048, 0, nullptr, pscr, 1024, NN1,
         nilf, 0, nilf, 0, 0, 1024, 2048, F_OUTBF, 4, 512);
    redcn(pscr, NN1, 4, bg3, loc, out, 2);

    // ---- velocity (split-K=8, bf16 partials) ----
    gemm(2, normB, 1024, 0, wvT, 1024, 0, nullptr, pscr, 42, (size_t)NRES * 42,
         nilf, 0, nilf, 0, 0, 42, 1024, F_OUTBF, 8, 128);
    red(pscr, (size_t)NRES * 42, 8, out + (size_t)NRES * 1024, nullptr,
        nilf, nilf, 0, 42, 0);
}

// Round 9
// 510.072 us; speedup vs baseline: 1.3789x; 1.0372x over previous
//
#include <hip/hip_runtime.h>
#include <hip/hip_bf16.h>
#include <math.h>

#define NRES 1536
#define NH 16
#define NNF 2359296ull    // NRES*NRES
#define LOG2E 1.44269504f
#define KVS 4             // split-KV ways

typedef unsigned short u16;
typedef __attribute__((ext_vector_type(8))) short short8;
typedef __attribute__((ext_vector_type(4))) unsigned short u16x4;
typedef __attribute__((ext_vector_type(4))) float f32x4;

typedef const __attribute__((address_space(1))) void gvoid;
typedef __attribute__((address_space(3))) void lvoid;

__device__ __forceinline__ u16 f2b(float x){
    __hip_bfloat16 h = __float2bfloat16(x);
    return *reinterpret_cast<u16*>(&h);
}
__device__ __forceinline__ float b2f(u16 u){
    unsigned v = ((unsigned)u) << 16;
    return __uint_as_float(v);
}

// ===================== bf16 MFMA GEMM (templated tile-N, optional split-K) ==========
#define F_BIAS  1
#define F_SILU  2
#define F_RESID 8
#define F_OUTBF 16

template<int TNF>
__global__ __launch_bounds__(256) void gemm_t(
    const u16* __restrict__ A, int lda, size_t zsA,
    const u16* __restrict__ BT, int ldb, size_t zsB,
    float* __restrict__ Cf, u16* __restrict__ Cb, int ldc, size_t zsC,
    const float* __restrict__ bias, size_t zsBias,
    const float* __restrict__ resid, int ldr, size_t zsR,
    int Ncols, int Kd, int flags, int ksl)
{
    constexpr int TN = TNF * 32;
    __shared__ u16 As[128 * 64];
    __shared__ u16 Bs[TN * 64];

    // ---- XCD-bijective block swizzle (T1): contiguous runs per XCD for L2 reuse ----
    unsigned gx = gridDim.x, gy = gridDim.y;
    unsigned nb = gx * gy * gridDim.z;
    unsigned bid = (blockIdx.z * gy + blockIdx.y) * gx + blockIdx.x;
    if ((nb & 7u) == 0u) bid = (bid & 7u) * (nb >> 3) + (bid >> 3);
    const int bxi = bid % gx;
    const int byi = (bid / gx) % gy;
    const int bz  = bid / (gx * gy);

    const int tid = threadIdx.x;
    const int l = tid & 63, w = tid >> 6;
    const int bm = byi * 128, bn = bxi * TN;

    A  += zsA * bz;
    BT += zsB * bz;

    const int kbeg = ksl ? bz * ksl : 0;
    const int kend = ksl ? kbeg + ksl : Kd;

    const int arow   = l >> 3;
    const int aslot  = l & 7;
    const int srcslt = aslot ^ arow;

    const u16* aBase[4];
    const u16* bBase[TN / 32];
    #pragma unroll
    for (int t = 0; t < 4; ++t) {
        int ra = bm + (w * 4 + t) * 8 + arow;
        aBase[t] = A + (size_t)ra * lda + srcslt * 8;
    }
    #pragma unroll
    for (int t = 0; t < TN / 32; ++t) {
        int rb = bn + (w * (TN / 32) + t) * 8 + arow;
        if (rb > Ncols - 1) rb = Ncols - 1;
        bBase[t] = BT + (size_t)rb * ldb + srcslt * 8;
    }

    const int wr = w >> 1, wc = w & 1;
    const int fr = l & 15;
    const int fq = l >> 4;

    f32x4 acc[4][TNF];
    #pragma unroll
    for (int i = 0; i < 4; ++i)
        #pragma unroll
        for (int j = 0; j < TNF; ++j) acc[i][j] = (f32x4){0.f, 0.f, 0.f, 0.f};

    for (int k0 = kbeg; k0 < kend; k0 += 64) {
        #pragma unroll
        for (int t = 0; t < 4; ++t)
            __builtin_amdgcn_global_load_lds((gvoid*)(aBase[t] + k0),
                (lvoid*)((char*)As + (w * 4 + t) * 1024), 16, 0, 0);
        #pragma unroll
        for (int t = 0; t < TN / 32; ++t)
            __builtin_amdgcn_global_load_lds((gvoid*)(bBase[t] + k0),
                (lvoid*)((char*)Bs + (w * (TN / 32) + t) * 1024), 16, 0, 0);
        __syncthreads();
        #pragma unroll
        for (int kk = 0; kk < 2; ++kk) {
            const int slotR = ((kk * 4) + fq) ^ (l & 7);
            short8 av[4], bv[TNF];
            #pragma unroll
            for (int m = 0; m < 4; ++m) {
                int r = wr * 64 + m * 16 + fr;
                av[m] = *(const short8*)((const char*)As + r * 128 + slotR * 16);
            }
            #pragma unroll
            for (int n = 0; n < TNF; ++n) {
                int r = wc * (TNF * 16) + n * 16 + fr;
                bv[n] = *(const short8*)((const char*)Bs + r * 128 + slotR * 16);
            }
            #pragma unroll
            for (int m = 0; m < 4; ++m)
                #pragma unroll
                for (int n = 0; n < TNF; ++n)
                    acc[m][n] = __builtin_amdgcn_mfma_f32_16x16x32_bf16(av[m], bv[n], acc[m][n], 0, 0, 0);
        }
        __syncthreads();
    }

    const float* residz = (flags & F_RESID) ? resid + zsR * bz : nullptr;
    const float* biasz  = (flags & F_BIAS)  ? bias + zsBias * bz : nullptr;
    float* cfz = Cf ? Cf + zsC * bz : nullptr;
    u16*   cbz = Cb ? Cb + zsC * bz : nullptr;

    #pragma unroll
    for (int m = 0; m < 4; ++m) {
        #pragma unroll
        for (int n = 0; n < TNF; ++n) {
            int gc = bn + wc * (TNF * 16) + n * 16 + fr;
            if (gc >= Ncols) continue;
            int gr0 = bm + wr * 64 + m * 16 + fq * 4;
            #pragma unroll
            for (int r = 0; r < 4; ++r) {
                int gr = gr0 + r;
                float v = acc[m][n][r];
                if (flags & F_BIAS)  v += biasz[gc];
                if (flags & F_SILU)  v = v / (1.f + expf(-v));
                if (flags & F_RESID) v += residz[(size_t)gr * ldr + gc];
                if (flags & F_OUTBF) cbz[(size_t)gr * ldc + gc] = f2b(v);
                else                 cfz[(size_t)gr * ldc + gc] = v;
            }
        }
    }
}

// ===================== split-K reduce (bf16 partials) + fused epilogue ==========
__global__ __launch_bounds__(256) void reduce_epi(
    const u16* __restrict__ part, size_t slice, int nsl,
    float* __restrict__ Cf, u16* __restrict__ Cb,
    const float* __restrict__ bias,
    const float* __restrict__ resid, int ldr,
    int M, int Ncols, int flags)
{
    if ((Ncols & 7) == 0) {
        size_t total8 = (size_t)M * Ncols / 8;
        for (size_t i8 = (size_t)blockIdx.x * 256 + threadIdx.x; i8 < total8;
             i8 += (size_t)gridDim.x * 256) {
            size_t i0 = i8 * 8;
            int r = (int)(i0 / (unsigned)Ncols);
            int c0 = (int)(i0 - (size_t)r * Ncols);
            float v[8] = {0,0,0,0,0,0,0,0};
            for (int s = 0; s < nsl; ++s) {
                const u16x4* p = (const u16x4*)(part + (size_t)s * slice + i0);
                u16x4 a = p[0], b = p[1];
                v[0] += b2f(a.x); v[1] += b2f(a.y); v[2] += b2f(a.z); v[3] += b2f(a.w);
                v[4] += b2f(b.x); v[5] += b2f(b.y); v[6] += b2f(b.z); v[7] += b2f(b.w);
            }
            #pragma unroll
            for (int j = 0; j < 8; ++j) {
                if (flags & F_BIAS) v[j] += bias[c0 + j];
                if (flags & F_SILU) v[j] = v[j] / (1.f + expf(-v[j]));
            }
            if (flags & F_RESID) {
                const float4* rp = (const float4*)(resid + (size_t)r * ldr + c0);
                float4 r0 = rp[0], r1 = rp[1];
                v[0] += r0.x; v[1] += r0.y; v[2] += r0.z; v[3] += r0.w;
                v[4] += r1.x; v[5] += r1.y; v[6] += r1.z; v[7] += r1.w;
            }
            if (flags & F_OUTBF) {
                short8 o;
                #pragma unroll
                for (int j = 0; j < 8; ++j) o[j] = (short)f2b(v[j]);
                *(short8*)(Cb + i0) = o;
            } else {
                float4 o0 = {v[0], v[1], v[2], v[3]}, o1 = {v[4], v[5], v[6], v[7]};
                float4* cp = (float4*)(Cf + i0);
                cp[0] = o0; cp[1] = o1;
            }
        }
    } else {
        size_t total = (size_t)M * Ncols;
        for (size_t i = (size_t)blockIdx.x * 256 + threadIdx.x; i < total;
             i += (size_t)gridDim.x * 256) {
            float v = 0.f;
            for (int s = 0; s < nsl; ++s) v += b2f(part[(size_t)s * slice + i]);
            if (flags & F_OUTBF) Cb[i] = f2b(v);
            else                 Cf[i] = v;
        }
    }
}

// ===== fused split-K reduce -> local update -> cond LayerNorm -> bf16 =====
__global__ __launch_bounds__(256) void reduce_cn(
    const u16* __restrict__ part, size_t slice, int nsl,
    const float* __restrict__ bias, const float* __restrict__ resid,
    float* __restrict__ locOut,
    const u16* __restrict__ cs, const u16* __restrict__ cb,
    u16* __restrict__ normB)
{
    int row = blockIdx.x, tid = threadIdx.x;
    size_t base = (size_t)row * 1024 + tid * 4;
    float v[4];
    {
        float4 rv = *(const float4*)(resid + base);
        v[0] = rv.x; v[1] = rv.y; v[2] = rv.z; v[3] = rv.w;
    }
    for (int s = 0; s < nsl; ++s) {
        u16x4 p = *(const u16x4*)(part + (size_t)s * slice + base);
        v[0] += b2f(p.x); v[1] += b2f(p.y); v[2] += b2f(p.z); v[3] += b2f(p.w);
    }
    {
        float4 bv = *(const float4*)(bias + tid * 4);
        v[0] += bv.x; v[1] += bv.y; v[2] += bv.z; v[3] += bv.w;
    }
    *(float4*)(locOut + base) = (float4){v[0], v[1], v[2], v[3]};

    float s1 = v[0] + v[1] + v[2] + v[3];
    float s2 = v[0]*v[0] + v[1]*v[1] + v[2]*v[2] + v[3]*v[3];
    __shared__ float r1[256], r2[256];
    r1[tid] = s1; r2[tid] = s2;
    __syncthreads();
    for (int st = 128; st > 0; st >>= 1) {
        if (tid < st) { r1[tid] += r1[tid + st]; r2[tid] += r2[tid + st]; }
        __syncthreads();
    }
    float mean = r1[0] * (1.f / 1024.f);
    float var = r2[0] * (1.f / 1024.f) - mean * mean;
    float rs = rsqrtf(var + 1e-5f);
    u16x4 sv = *(const u16x4*)(cs + base);
    u16x4 bv = *(const u16x4*)(cb + base);
    u16x4 o;
    o.x = f2b((1.f / (1.f + expf(-b2f(sv.x)))) * (v[0] - mean) * rs + b2f(bv.x));
    o.y = f2b((1.f / (1.f + expf(-b2f(sv.y)))) * (v[1] - mean) * rs + b2f(bv.y));
    o.z = f2b((1.f / (1.f + expf(-b2f(sv.z)))) * (v[2] - mean) * rs + b2f(bv.z));
    o.w = f2b((1.f / (1.f + expf(-b2f(sv.w)))) * (v[3] - mean) * rs + b2f(bv.w));
    *(u16x4*)(normB + base) = o;
}

// ===================== fused flash attention v4 (split-KV=4, bf16 O partials) ========
__global__ __launch_bounds__(256, 2) void attn_kernel(
    const u16* __restrict__ qe, const u16* __restrict__ ke,
    const u16* __restrict__ vt, const float* __restrict__ pb,
    u16* __restrict__ Opart, float* __restrict__ mlpart)
{
    __shared__ u16 Ks[2][64 * 128];
    __shared__ u16 Vs[2][96 * 64];
    __shared__ u16 Ps[64 * 64];

    const int tid = threadIdx.x;
    const int l = tid & 63, w = tid >> 6;
    const int h = blockIdx.y;
    const int q0 = blockIdx.x * 64;
    const int z = blockIdx.z;
    const int fr = l & 15, fq = l >> 4;

    const u16* keh = ke + (size_t)h * NRES * 128;
    const u16* vth = vt + (size_t)h * 96 * NRES;

    const int kr4 = l >> 4, ks16 = l & 15;
    const int vr8 = l >> 3, vs8 = l & 7;

    short8 qv[4];
    {
        const u16* qrow = qe + ((size_t)h * NRES + (q0 + w * 16 + fr)) * 128 + fq * 8;
        #pragma unroll
        for (int kk = 0; kk < 4; ++kk)
            qv[kk] = *(const short8*)(qrow + kk * 32);
    }

    float m_run[4], l_run[4];
    f32x4 oacc[6];
    #pragma unroll
    for (int r = 0; r < 4; ++r) { m_run[r] = -1e30f; l_run[r] = 0.f; }
    #pragma unroll
    for (int n = 0; n < 6; ++n) oacc[n] = (f32x4){0.f, 0.f, 0.f, 0.f};

    const int NIT = NRES / 64 / KVS;       // 6
    const int jbase = z * (NRES / KVS);    // z*384
    int cur = 0;

    auto stage = [&](int buf, int j0) {
        #pragma unroll
        for (int t = 0; t < 4; ++t) {
            int row = w * 16 + t * 4 + kr4;
            int ss = ks16 ^ (row & 7);
            __builtin_amdgcn_global_load_lds(
                (gvoid*)(keh + (size_t)(j0 + row) * 128 + ss * 8),
                (lvoid*)((char*)Ks[buf] + (w * 16 + t * 4) * 256), 16, 0, 0);
        }
        #pragma unroll
        for (int t = 0; t < 3; ++t) {
            int row = w * 24 + t * 8 + vr8;
            int ss = vs8 ^ (row & 7);
            __builtin_amdgcn_global_load_lds(
                (gvoid*)(vth + (size_t)row * NRES + j0 + ss * 8),
                (lvoid*)((char*)Vs[buf] + (w * 24 + t * 8) * 128), 16, 0, 0);
        }
    };
    const float* pbrow = pb + ((size_t)h * NRES + (q0 + w * 16 + fq * 4)) * NRES + fr;

    f32x4 pbv[4], pbn[4] = {};
    stage(0, jbase);
    #pragma unroll
    for (int n = 0; n < 4; ++n)
        #pragma unroll
        for (int r = 0; r < 4; ++r)
            pbv[n][r] = pbrow[(size_t)r * NRES + jbase + n * 16];
    __syncthreads();

    for (int it = 0; it < NIT; ++it) {
        if (it + 1 < NIT) {
            int j1 = jbase + (it + 1) * 64;
            stage(cur ^ 1, j1);
            #pragma unroll
            for (int n = 0; n < 4; ++n)
                #pragma unroll
                for (int r = 0; r < 4; ++r)
                    pbn[n][r] = pbrow[(size_t)r * NRES + j1 + n * 16];
        }

        f32x4 sacc[4];
        #pragma unroll
        for (int n = 0; n < 4; ++n) sacc[n] = (f32x4){0.f, 0.f, 0.f, 0.f};
        #pragma unroll
        for (int kk = 0; kk < 4; ++kk) {
            #pragma unroll
            for (int n = 0; n < 4; ++n) {
                int row = n * 16 + fr;
                short8 bv = *(const short8*)((const char*)Ks[cur] + row * 256
                                             + (((kk * 4 + fq) ^ (fr & 7)) * 16));
                sacc[n] = __builtin_amdgcn_mfma_f32_16x16x32_bf16(qv[kk], bv, sacc[n], 0, 0, 0);
            }
        }
        #pragma unroll
        for (int n = 0; n < 4; ++n) sacc[n] += pbv[n];

        float alpha[4];
        #pragma unroll
        for (int r = 0; r < 4; ++r) {
            float v = fmaxf(fmaxf(sacc[0][r], sacc[1][r]), fmaxf(sacc[2][r], sacc[3][r]));
            v = fmaxf(v, __shfl_xor(v, 1, 64));
            v = fmaxf(v, __shfl_xor(v, 2, 64));
            v = fmaxf(v, __shfl_xor(v, 4, 64));
            v = fmaxf(v, __shfl_xor(v, 8, 64));
            float mn = fmaxf(m_run[r], v);
            alpha[r] = exp2f((m_run[r] - mn) * LOG2E);
            m_run[r] = mn;
        }

        float psum[4] = {0.f, 0.f, 0.f, 0.f};
        #pragma unroll
        for (int n = 0; n < 4; ++n) {
            int col = n * 16 + fr;
            #pragma unroll
            for (int r = 0; r < 4; ++r) {
                float p = exp2f((sacc[n][r] - m_run[r]) * LOG2E);
                psum[r] += p;
                int rowf = w * 16 + fq * 4 + r;
                int byte = rowf * 128 + (((col >> 3) ^ (rowf & 7)) * 16) + (col & 7) * 2;
                *(u16*)((char*)Ps + byte) = f2b(p);
            }
        }
        #pragma unroll
        for (int r = 0; r < 4; ++r) {
            float v = psum[r];
            v += __shfl_xor(v, 1, 64);
            v += __shfl_xor(v, 2, 64);
            v += __shfl_xor(v, 4, 64);
            v += __shfl_xor(v, 8, 64);
            l_run[r] = l_run[r] * alpha[r] + v;
        }
        #pragma unroll
        for (int n = 0; n < 6; ++n)
            #pragma unroll
            for (int r = 0; r < 4; ++r)
                oacc[n][r] *= alpha[r];

        #pragma unroll
        for (int kk = 0; kk < 2; ++kk) {
            int prow = w * 16 + fr;
            short8 pa = *(const short8*)((const char*)Ps + prow * 128
                                         + (((kk * 4 + fq) ^ (prow & 7)) * 16));
            #pragma unroll
            for (int n = 0; n < 6; ++n) {
                int vrow = n * 16 + fr;
                short8 vv = *(const short8*)((const char*)Vs[cur] + vrow * 128
                                             + (((kk * 4 + fq) ^ (fr & 7)) * 16));
                oacc[n] = __builtin_amdgcn_mfma_f32_16x16x32_bf16(pa, vv, oacc[n], 0, 0, 0);
            }
        }

        __syncthreads();
        cur ^= 1;
        #pragma unroll
        for (int n = 0; n < 4; ++n) pbv[n] = pbn[n];
    }

    u16* Oz = Opart + ((size_t)z * NH + h) * NRES * 96;
    #pragma unroll
    for (int n = 0; n < 6; ++n) {
        int c = n * 16 + fr;
        #pragma unroll
        for (int r = 0; r < 4; ++r) {
            int row = q0 + w * 16 + fq * 4 + r;
            Oz[(size_t)row * 96 + c] = f2b(oacc[n][r]);
        }
    }
    if (fr == 0) {
        float* mlz = mlpart + ((size_t)z * NH + h) * NRES * 2;
        #pragma unroll
        for (int r = 0; r < 4; ++r) {
            int row = q0 + w * 16 + fq * 4 + r;
            mlz[row * 2 + 0] = m_run[r];
            mlz[row * 2 + 1] = l_run[r];
        }
    }
}

// ===================== split-KV combine (KVS-way, bf16 O) -> cat =====================
__global__ __launch_bounds__(256) void combine_kernel(
    const u16* __restrict__ Opart, const float* __restrict__ mlpart,
    float* __restrict__ cat)
{
    int idx = blockIdx.x * 256 + threadIdx.x;
    if (idx >= NH * NRES * 88) return;
    int c = idx % 88;
    int rh = idx / 88;
    float m[KVS], lv[KVS];
    float mm = -1e30f;
    #pragma unroll
    for (int s = 0; s < KVS; ++s) {
        size_t rr = (size_t)s * NH * NRES + rh;
        m[s] = mlpart[rr * 2];
        lv[s] = mlpart[rr * 2 + 1];
        mm = fmaxf(mm, m[s]);
    }
    float ll = 0.f, ov = 0.f;
    #pragma unroll
    for (int s = 0; s < KVS; ++s) {
        float wgt = exp2f((m[s] - mm) * LOG2E);
        ll += lv[s] * wgt;
        ov += b2f(Opart[((size_t)s * NH * NRES + rh) * 96 + c]) * wgt;
    }
    cat[(size_t)rh * 88 + c] = ov / ll;
}

// ===================== batched transpose fp32 -> bf16 [N][K] =====================
struct TP9 { const float* p[9]; };

__global__ __launch_bounds__(256) void transpose_bz(
    TP9 tp, int ldi, size_t zsi,
    u16* __restrict__ out, int ldo, size_t zso, int K, int N, int nsrc)
{
    __shared__ float t[32][33];
    int z = blockIdx.z;
    const float* in = tp.p[(z < nsrc) ? z : 0] + zsi * ((z < nsrc) ? 0 : z);
    if (nsrc == 1) in = tp.p[0] + zsi * z;
    out += zso * z;
    int k0 = blockIdx.y * 32, n0 = blockIdx.x * 32;
    int tx = threadIdx.x & 31, ty = threadIdx.x >> 5;
    #pragma unroll
    for (int j = 0; j < 4; ++j) {
        int k = k0 + ty + j * 8;
        if (k < K && n0 + tx < N) t[ty + j * 8][tx] = in[(size_t)k * ldi + n0 + tx];
    }
    __syncthreads();
    #pragma unroll
    for (int j = 0; j < 4; ++j) {
        int n = n0 + ty + j * 8;
        int k = k0 + tx;
        if (n < N && k < K) out[(size_t)n * ldo + k] = f2b(t[tx][ty + j * 8]);
    }
}

// ===================== misc small kernels =====================
__global__ __launch_bounds__(256) void f2b8_kernel(const float* __restrict__ in, u16* __restrict__ out, int n8)
{
    int i = blockIdx.x * 256 + threadIdx.x;
    if (i >= n8) return;
    size_t i0 = (size_t)i * 8;
    const float4* p = (const float4*)(in + i0);
    float4 a = p[0], b = p[1];
    short8 o;
    o[0]=(short)f2b(a.x); o[1]=(short)f2b(a.y); o[2]=(short)f2b(a.z); o[3]=(short)f2b(a.w);
    o[4]=(short)f2b(b.x); o[5]=(short)f2b(b.y); o[6]=(short)f2b(b.z); o[7]=(short)f2b(b.w);
    *(short8*)(out + i0) = o;
}

__global__ __launch_bounds__(256) void emb_kernel(const float* __restrict__ pos, u16* __restrict__ emb)
{
    int idx = blockIdx.x * 256 + threadIdx.x;
    int f = idx & 63;
    int rest = idx >> 6;
    int coord = rest % 42;
    int n = rest / 42;
    float t = pos[(size_t)n * 42 + coord];
    const double l0 = -6.643856189774724;
    const double step = 14.643856189774724 / 63.0;
    float freq = exp2f((float)(l0 + f * step));
    float r = t * freq;
    size_t o = (size_t)n * 5376 + (size_t)coord * 128 + 2 * f;
    emb[o]     = f2b(sinf(r));
    emb[o + 1] = f2b(cosf(r));
}

__global__ __launch_bounds__(256) void frames_kernel(const float* __restrict__ pos,
                                                     float* __restrict__ Rb, float* __restrict__ tb)
{
    int n = blockIdx.x * 256 + threadIdx.x;
    if (n >= NRES) return;
    const float* p = pos + (size_t)n * 42;
    float nx = p[0], ny = p[1], nz = p[2];
    float cax = p[3], cay = p[4], caz = p[5];
    float cx = p[6], cy = p[7], cz = p[8];
    float v1x = cx - cax, v1y = cy - cay, v1z = cz - caz;
    float i1 = rsqrtf(v1x * v1x + v1y * v1y + v1z * v1z + 1e-8f);
    float e1x = v1x * i1, e1y = v1y * i1, e1z = v1z * i1;
    float v2x = nx - cax, v2y = ny - cay, v2z = nz - caz;
    float d = e1x * v2x + e1y * v2y + e1z * v2z;
    float wx = v2x - d * e1x, wy = v2y - d * e1y, wz = v2z - d * e1z;
    float i2 = rsqrtf(wx * wx + wy * wy + wz * wz + 1e-8f);
    float e2x = wx * i2, e2y = wy * i2, e2z = wz * i2;
    float e3x = e1y * e2z - e1z * e2y;
    float e3y = e1z * e2x - e1x * e2z;
    float e3z = e1x * e2y - e1y * e2x;
    float* R = Rb + (size_t)n * 9;
    R[0] = e1x; R[1] = e2x; R[2] = e3x;
    R[3] = e1y; R[4] = e2y; R[5] = e3y;
    R[6] = e1z; R[7] = e2z; R[8] = e3z;
    tb[(size_t)n * 3 + 0] = cax;
    tb[(size_t)n * 3 + 1] = cay;
    tb[(size_t)n * 3 + 2] = caz;
}

__global__ __launch_bounds__(256) void bias_pack(const float* a, const float* b, const float* c,
                                                 const float* d, const float* e, const float* f,
                                                 float* out)
{
    int i = blockIdx.x * 256 + threadIdx.x;
    if (i >= 1024) return;
    out[i] = a[i]; out[1024 + i] = b[i]; out[2048 + i] = c[i];
    out[3072 + i] = d[i]; out[4096 + i] = e[i]; out[5120 + i] = f[i];
}

__global__ __launch_bounds__(256) void biasg_pack(const float* a, const float* b, float* out)
{
    int i = blockIdx.x * 256 + threadIdx.x;
    if (i >= 2048) return;
    out[i] = a[i]; out[2048 + i] = b[i];
}

// gm = silu(g1) * g2, 8-wide
__global__ __launch_bounds__(256) void glu_kernel(const u16* __restrict__ g12, u16* __restrict__ gm)
{
    int i = blockIdx.x * 256 + threadIdx.x;
    if (i >= NRES * 2048 / 8) return;
    size_t i0 = (size_t)i * 8;
    short8 a8 = *(const short8*)(g12 + i0);
    short8 b8 = *(const short8*)(g12 + (size_t)NRES * 2048 + i0);
    short8 o;
    #pragma unroll
    for (int j = 0; j < 8; ++j) {
        float a = b2f((u16)a8[j]);
        float b = b2f((u16)b8[j]);
        float s = a / (1.f + expf(-a));
        o[j] = (short)f2b(s * b);
    }
    *(short8*)(gm + i0) = o;
}

// vectorized pack: qe/ke [h][n][128]; g<8 data, g==11 zeros 88..95, g>=12 zeros
__global__ __launch_bounds__(256) void pack_qk(const float* __restrict__ qb, const float* __restrict__ kb,
                                               u16* __restrict__ qe, u16* __restrict__ ke)
{
    int idx = blockIdx.x * 256 + threadIdx.x;
    if (idx >= NH * NRES * 16) return;
    int g = idx & 15;
    int t = idx >> 4;
    int n = t % NRES;
    int h = t / NRES;
    size_t o = ((size_t)h * NRES + n) * 128 + g * 8;
    if (g < 8) {
        const float4* q4 = (const float4*)(qb + (size_t)n * 1024 + h * 64 + g * 8);
        const float4* k4 = (const float4*)(kb + (size_t)n * 1024 + h * 64 + g * 8);
        float4 qa = q4[0], qb2 = q4[1], ka = k4[0], kb2 = k4[1];
        short8 oq, ok;
        oq[0]=(short)f2b(0.125f*qa.x); oq[1]=(short)f2b(0.125f*qa.y);
        oq[2]=(short)f2b(0.125f*qa.z); oq[3]=(short)f2b(0.125f*qa.w);
        oq[4]=(short)f2b(0.125f*qb2.x); oq[5]=(short)f2b(0.125f*qb2.y);
        oq[6]=(short)f2b(0.125f*qb2.z); oq[7]=(short)f2b(0.125f*qb2.w);
        ok[0]=(short)f2b(ka.x); ok[1]=(short)f2b(ka.y); ok[2]=(short)f2b(ka.z); ok[3]=(short)f2b(ka.w);
        ok[4]=(short)f2b(kb2.x); ok[5]=(short)f2b(kb2.y); ok[6]=(short)f2b(kb2.z); ok[7]=(short)f2b(kb2.w);
        *(short8*)(qe + o) = oq;
        *(short8*)(ke + o) = ok;
    } else if (g >= 11) {
        short8 zz = {};
        *(short8*)(qe + o) = zz;
        *(short8*)(ke + o) = zz;
    }
}

__global__ __launch_bounds__(256) void build_pts(
    const float* __restrict__ qp, const float* __restrict__ kp, const float* __restrict__ vp,
    const float* __restrict__ Rb, const float* __restrict__ tb, const float* __restrict__ gamma,
    u16* __restrict__ qe, u16* __restrict__ ke, float* __restrict__ vgt)
{
    int idx = blockIdx.x * 256 + threadIdx.x;
    if (idx >= NRES * NH) return;
    int n = idx >> 4, h = idx & 15;
    float R[9];
    #pragma unroll
    for (int a = 0; a < 9; ++a) R[a] = Rb[(size_t)n * 9 + a];
    float t0 = tb[(size_t)n * 3 + 0], t1 = tb[(size_t)n * 3 + 1], t2 = tb[(size_t)n * 3 + 2];
    float g = gamma[h];
    float sp = (g > 20.f) ? g : log1pf(expf(g));
    float ch = 0.5f * (1.f / 6.f) * sp;

    u16* qeh = qe + ((size_t)h * NRES + n) * 128;
    u16* keh = ke + ((size_t)h * NRES + n) * 128;
    size_t pbase = (size_t)n * 384 + h * 24;
    float kn = 0.f;
    #pragma unroll
    for (int p = 0; p < 8; ++p) {
        size_t o = pbase + p * 3;
        {
            float x = qp[o], y = qp[o + 1], z = qp[o + 2];
            float g0 = R[0] * x + R[1] * y + R[2] * z + t0;
            float g1 = R[3] * x + R[4] * y + R[5] * z + t1;
            float g2 = R[6] * x + R[7] * y + R[8] * z + t2;
            qeh[64 + p * 3 + 0] = f2b(2.f * ch * g0);
            qeh[64 + p * 3 + 1] = f2b(2.f * ch * g1);
            qeh[64 + p * 3 + 2] = f2b(2.f * ch * g2);
        }
        {
            float x = kp[o], y = kp[o + 1], z = kp[o + 2];
            float g0 = R[0] * x + R[1] * y + R[2] * z + t0;
            float g1 = R[3] * x + R[4] * y + R[5] * z + t1;
            float g2 = R[6] * x + R[7] * y + R[8] * z + t2;
            keh[64 + p * 3 + 0] = f2b(g0);
            keh[64 + p * 3 + 1] = f2b(g1);
            keh[64 + p * 3 + 2] = f2b(g2);
            kn += g0 * g0 + g1 * g1 + g2 * g2;
        }
        {
            float x = vp[o], y = vp[o + 1], z = vp[o + 2];
            vgt[o]     = R[0] * x + R[1] * y + R[2] * z + t0;
            vgt[o + 1] = R[3] * x + R[4] * y + R[5] * z + t1;
            vgt[o + 2] = R[6] * x + R[7] * y + R[8] * z + t2;
        }
    }
    qeh[88] = f2b(1.0f);
    keh[88] = f2b(-ch * kn);
}

__global__ __launch_bounds__(256) void finalize_kernel(const float* __restrict__ cat,
                                                       const float* __restrict__ Rb,
                                                       const float* __restrict__ tb,
                                                       u16* __restrict__ featB)
{
    int idx = blockIdx.x * 256 + threadIdx.x;
    if (idx >= NRES * NH) return;
    int n = idx >> 4, h = idx & 15;
    float R[9];
    #pragma unroll
    for (int a = 0; a < 9; ++a) R[a] = Rb[(size_t)n * 9 + a];
    float t0 = tb[(size_t)n * 3 + 0], t1 = tb[(size_t)n * 3 + 1], t2 = tb[(size_t)n * 3 + 2];
    const float* c = cat + ((size_t)h * NRES + n) * 88;
    u16* fb = featB + (size_t)n * 1536;
    #pragma unroll
    for (int k = 0; k < 64; ++k) fb[h * 64 + k] = f2b(c[k]);
    #pragma unroll
    for (int p = 0; p < 8; ++p) {
        float x = c[64 + p * 3 + 0] - t0;
        float y = c[64 + p * 3 + 1] - t1;
        float z = c[64 + p * 3 + 2] - t2;
        float a0 = R[0] * x + R[3] * y + R[6] * z;
        float a1 = R[1] * x + R[4] * y + R[7] * z;
        float a2 = R[2] * x + R[5] * y + R[8] * z;
        fb[1024 + h * 24 + p * 3 + 0] = f2b(a0);
        fb[1024 + h * 24 + p * 3 + 1] = f2b(a1);
        fb[1024 + h * 24 + p * 3 + 2] = f2b(a2);
        fb[1408 + h * 8 + p] = f2b(sqrtf(a0 * a0 + a1 * a1 + a2 * a2 + 1e-8f));
    }
}

// ========================= host =========================
extern "C" void kernel_launch(void* const* d_in, const int* in_sizes, int n_in,
                              void* d_out, int out_size, void* d_ws, size_t ws_size,
                              hipStream_t stream)
{
    const float* local_in = (const float*)d_in[0];
    const float* pos      = (const float*)d_in[1];
    const float* cond     = (const float*)d_in[2];
    const float* pb       = (const float*)d_in[4];
    const float* w_f1     = (const float*)d_in[5];
    const float* b_f1     = (const float*)d_in[6];
    const float* w_f2     = (const float*)d_in[7];
    const float* b_f2     = (const float*)d_in[8];
    const float* cn1_ws   = (const float*)d_in[9];
    const float* cn1_bs   = (const float*)d_in[10];
    const float* cn1_wb   = (const float*)d_in[11];
    const float* cn1_bb   = (const float*)d_in[12];
    const float* wq       = (const float*)d_in[13];
    const float* wk       = (const float*)d_in[14];
    const float* wv       = (const float*)d_in[15];
    const float* wqp      = (const float*)d_in[16];
    const float* wkp      = (const float*)d_in[17];
    const float* wvp      = (const float*)d_in[18];
    const float* gamma    = (const float*)d_in[19];
    const float* wo       = (const float*)d_in[20];
    const float* bo       = (const float*)d_in[21];
    const float* cn2_ws   = (const float*)d_in[22];
    const float* cn2_bs   = (const float*)d_in[23];
    const float* cn2_wb   = (const float*)d_in[24];
    const float* cn2_bb   = (const float*)d_in[25];
    const float* wg1      = (const float*)d_in[26];
    const float* bg1      = (const float*)d_in[27];
    const float* wg2      = (const float*)d_in[28];
    const float* bg2      = (const float*)d_in[29];
    const float* wg3      = (const float*)d_in[30];
    const float* bg3      = (const float*)d_in[31];
    const float* cn3_ws   = (const float*)d_in[32];
    const float* cn3_bs   = (const float*)d_in[33];
    const float* cn3_wb   = (const float*)d_in[34];
    const float* cn3_bb   = (const float*)d_in[35];
    const float* w_vel    = (const float*)d_in[36];

    float* out = (float*)d_out;
    float* ws  = (float*)d_ws;

    size_t off = 0;
    auto alloc = [&](size_t nf) -> float* { float* p = ws + off; off += (nf + 7) & ~7ull; return p; };

    const size_t NN1 = (size_t)NRES * 1024;
    float* Rb    = alloc(NRES * 9);
    float* tb    = alloc(NRES * 3);
    float* loc   = alloc(NN1);
    u16*   cs6b  = (u16*)alloc(6 * NN1 / 2);
    u16*   condB = (u16*)alloc(NN1 / 2);
    u16*   normB = (u16*)alloc(NN1 / 2);
    float* bias2 = alloc(6 * 1024);
    float* biasg = alloc(2 * 2048);
    float* qb    = alloc(3 * NN1);
    float* kb    = qb + NN1;
    float* vb    = kb + NN1;
    float* qp    = alloc(3 * (size_t)NRES * 384);
    float* kp    = qp + NRES * 384;
    float* vp    = kp + NRES * 384;
    float* vgt   = alloc((size_t)NRES * 384);
    u16*   qeB   = (u16*)alloc((size_t)NH * NRES * 128 / 2);
    u16*   keB   = (u16*)alloc((size_t)NH * NRES * 128 / 2);
    u16*   vTB   = (u16*)alloc((size_t)NH * 96 * NRES / 2);
    float* cat   = alloc((size_t)NH * NRES * 88);
    u16*   featB = (u16*)alloc((size_t)NRES * 1536 / 2);
    u16*   g1sB  = (u16*)alloc((size_t)NRES * 2048 / 2);
    u16*   gmB   = (u16*)alloc((size_t)NRES * 2048 / 2);
    u16*   cnT9  = (u16*)alloc((size_t)9 * 1024 * 1024 / 2);
    u16*   ptsT  = (u16*)alloc((size_t)3 * 384 * 1024 / 2);
    u16*   wgT   = (u16*)alloc((size_t)2 * 2048 * 1024 / 2);
    u16*   wf1T  = (u16*)alloc((size_t)2048 * 5376 / 2);
    u16*   wf2T  = (u16*)alloc((size_t)1024 * 2048 / 2);
    u16*   woT   = (u16*)alloc((size_t)1024 * 1536 / 2);
    u16*   wg3T  = (u16*)alloc((size_t)1024 * 2048 / 2);
    u16*   wvT   = (u16*)alloc((size_t)42 * 1024 / 2 + 8);
    u16*   embB  = (u16*)alloc((size_t)NRES * 5376 / 2);
    u16*   hidB  = (u16*)alloc((size_t)NRES * 2048 / 2);
    u16*   pscr  = (u16*)alloc((size_t)2 * NRES * 2048 * 4 / 2);
    u16*   Opart = (u16*)alloc((size_t)KVS * NH * NRES * 96 / 2);
    float* mlprt = alloc((size_t)KVS * NH * NRES * 2);

    const float* nilf = nullptr;

    auto gemm = [&](int tnf, const u16* A, int lda, size_t zsA,
                    const u16* BT, int ldb, size_t zsB,
                    float* Cf, u16* Cb2, int ldc, size_t zsC,
                    const float* bias, size_t zsBias,
                    const float* resid, int ldr, size_t zsR,
                    int Nc, int Kd, int flags, int gz, int ksl) {
        int tn = tnf * 32;
        dim3 grid((Nc + tn - 1) / tn, NRES / 128, gz);
        if (tnf == 4)
            hipLaunchKernelGGL(gemm_t<4>, grid, dim3(256), 0, stream,
                               A, lda, zsA, BT, ldb, zsB, Cf, Cb2, ldc, zsC,
                               bias, zsBias, resid, ldr, zsR, Nc, Kd, flags, ksl);
        else
            hipLaunchKernelGGL(gemm_t<2>, grid, dim3(256), 0, stream,
                               A, lda, zsA, BT, ldb, zsB, Cf, Cb2, ldc, zsC,
                               bias, zsBias, resid, ldr, zsR, Nc, Kd, flags, ksl);
    };
    auto red = [&](const u16* part, size_t slice, int nsl, float* Cf, u16* Cb2,
                   const float* bias, const float* resid, int ldr, int Nc, int flags) {
        hipLaunchKernelGGL(reduce_epi, dim3(1024), dim3(256), 0, stream,
                           part, slice, nsl, Cf, Cb2, bias, resid, ldr, NRES, Nc, flags);
    };
    auto redcn = [&](const u16* part, size_t slice, int nsl,
                     const float* bias, const float* resid, float* locOut, int cnIdx) {
        hipLaunchKernelGGL(reduce_cn, dim3(NRES), dim3(256), 0, stream,
                           part, slice, nsl, bias, resid, locOut,
                           cs6b + (size_t)(2 * cnIdx) * NN1,
                           cs6b + (size_t)(2 * cnIdx + 1) * NN1, normB);
    };
    auto tpz = [&](TP9 tp, int ldi, int K, int N, u16* o, int ldo, size_t zso, int nsrc) {
        dim3 grid((N + 31) / 32, (K + 31) / 32, nsrc);
        hipLaunchKernelGGL(transpose_bz, grid, dim3(256), 0, stream, tp, ldi, (size_t)0, o, ldo, zso, K, N, nsrc);
    };
    auto tps = [&](const float* in, int ldi, size_t zsi, int K, int N, u16* o, int ldo, size_t zso, int gz) {
        dim3 grid((N + 31) / 32, (K + 31) / 32, gz);
        TP9 tp; tp.p[0] = in;
        hipLaunchKernelGGL(transpose_bz, grid, dim3(256), 0, stream, tp, ldi, zsi, o, ldo, zso, K, N, 1);
    };

    // ---- prologue ----
    hipLaunchKernelGGL(frames_kernel, dim3(6), dim3(256), 0, stream, pos, Rb, tb);
    hipLaunchKernelGGL(emb_kernel, dim3((NRES * 42 * 64) / 256), dim3(256), 0, stream, pos, embB);
    hipLaunchKernelGGL(f2b8_kernel, dim3(768), dim3(256), 0, stream, cond, condB, NRES * 1024 / 8);
    hipLaunchKernelGGL(bias_pack, dim3(4), dim3(256), 0, stream,
                       cn1_bs, cn1_bb, cn2_bs, cn2_bb, cn3_bs, cn3_bb, bias2);
    hipLaunchKernelGGL(biasg_pack, dim3(8), dim3(256), 0, stream, bg1, bg2, biasg);

    // ---- weight transposes ----
    {
        TP9 t9; t9.p[0]=cn1_ws; t9.p[1]=cn1_wb; t9.p[2]=cn2_ws; t9.p[3]=cn2_wb;
        t9.p[4]=cn3_ws; t9.p[5]=cn3_wb; t9.p[6]=wq; t9.p[7]=wk; t9.p[8]=wv;
        tpz(t9, 1024, 1024, 1024, cnT9, 1024, (size_t)1024 * 1024, 9);
    }
    {
        TP9 t3; t3.p[0]=wqp; t3.p[1]=wkp; t3.p[2]=wvp;
        tpz(t3, 384, 1024, 384, ptsT, 1024, (size_t)384 * 1024, 3);
    }
    {
        TP9 t2; t2.p[0]=wg1; t2.p[1]=wg2;
        tpz(t2, 2048, 1024, 2048, wgT, 1024, (size_t)2048 * 1024, 2);
    }
    tps(w_f1, 2048, 0, 5376, 2048, wf1T, 5376, 0, 1);
    tps(w_f2, 1024, 0, 2048, 1024, wf2T, 2048, 0, 1);
    tps(wo,   1024, 0, 1536, 1024, woT,  1536, 0, 1);
    tps(wg3,  1024, 0, 2048, 1024, wg3T, 2048, 0, 1);
    tps(w_vel,  42, 0, 1024,   42, wvT,  1024, 0, 1);

    // ---- all 6 cond GEMMs (z=6, TN=64, bf16 out) ----
    gemm(2, condB, 1024, 0, cnT9, 1024, (size_t)1024 * 1024, nullptr, cs6b, 1024, NN1,
         bias2, 1024, nilf, 0, 0, 1024, 1024, F_BIAS | F_OUTBF, 6, 0);

    // ---- phase A: emb GEMM split-K=4, bf16 partials + reduce(silu->bf16) ----
    gemm(2, embB, 5376, 0, wf1T, 5376, 0, nullptr, pscr, 2048, (size_t)NRES * 2048,
         nilf, 0, nilf, 0, 0, 2048, 5376, F_OUTBF, 4, 1344);
    red(pscr, (size_t)NRES * 2048, 4, nullptr, hidB, b_f1, nilf, 0,
        2048, F_BIAS | F_SILU | F_OUTBF);
    gemm(2, hidB, 2048, 0, wf2T, 2048, 0, nullptr, pscr, 1024, NN1,
         nilf, 0, nilf, 0, 0, 1024, 2048, F_OUTBF, 4, 512);
    redcn(pscr, NN1, 4, b_f2, local_in, loc, 0);

    // ---- projections ----
    gemm(2, normB, 1024, 0, cnT9 + (size_t)6 * 1024 * 1024, 1024, (size_t)1024 * 1024,
         qb, nullptr, 1024, NN1, nilf, 0, nilf, 0, 0, 1024, 1024, 0, 3, 0);
    gemm(2, normB, 1024, 0, ptsT, 1024, (size_t)384 * 1024, qp, nullptr, 384, (size_t)NRES * 384,
         nilf, 0, nilf, 0, 0, 384, 1024, 0, 3, 0);

    // ---- attention operands ----
    hipMemsetAsync(vTB, 0, (size_t)NH * 96 * NRES * 2, stream);
    hipLaunchKernelGGL(pack_qk, dim3((NH * NRES * 16 + 255) / 256), dim3(256), 0, stream, qb, kb, qeB, keB);
    hipLaunchKernelGGL(build_pts, dim3(96), dim3(256), 0, stream,
                       qp, kp, vp, Rb, tb, gamma, qeB, keB, vgt);
    tps(vb, 1024, 64, NRES, 64, vTB, NRES, (size_t)96 * NRES, NH);
    tps(vgt, 384, 24, NRES, 24, vTB + (size_t)64 * NRES, NRES, (size_t)96 * NRES, NH);

    // ---- fused attention (split-KV=4) + combine ----
    hipLaunchKernelGGL(attn_kernel, dim3(NRES / 64, NH, KVS), dim3(256), 0, stream,
                       qeB, keB, vTB, pb, Opart, mlprt);
    hipLaunchKernelGGL(combine_kernel, dim3((NH * NRES * 88 + 255) / 256), dim3(256), 0, stream,
                       Opart, mlprt, cat);
    hipLaunchKernelGGL(finalize_kernel, dim3(96), dim3(256), 0, stream, cat, Rb, tb, featB);

    // ---- local += feat @ wo + bo : split-K=4, fused reduce+condnorm2 ----
    gemm(2, featB, 1536, 0, woT, 1536, 0, nullptr, pscr, 1024, NN1,
         nilf, 0, nilf, 0, 0, 1024, 1536, F_OUTBF, 4, 384);
    redcn(pscr, NN1, 4, bo, loc, loc, 1);

    // ---- gated MLP ----
    gemm(2, normB, 1024, 0, wgT, 1024, (size_t)2048 * 1024, nullptr, g1sB, 2048, (size_t)NRES * 2048,
         biasg, 2048, nilf, 0, 0, 2048, 1024, F_BIAS | F_OUTBF, 2, 0);
    u16* gmO = embB;
    hipLaunchKernelGGL(glu_kernel, dim3((NRES * 2048 / 8 + 255) / 256), dim3(256), 0, stream, g1sB, gmO);
    gemm(2, gmO, 2048, 0, wg3T, 2048, 0, nullptr, pscr, 1024, NN1,
         nilf, 0, nilf, 0, 0, 1024, 2048, F_OUTBF, 4, 512);
    redcn(pscr, NN1, 4, bg3, loc, out, 2);

    // ---- velocity (split-K=8, bf16 partials) ----
    gemm(2, normB, 1024, 0, wvT, 1024, 0, nullptr, pscr, 42, (size_t)NRES * 42,
         nilf, 0, nilf, 0, 0, 42, 1024, F_OUTBF, 8, 128);
    red(pscr, (size_t)NRES * 42, 8, out + (size_t)NRES * 1024, nullptr,
        nilf, nilf, 0, 42, 0);
}

// Round 10
// 507.687 us; speedup vs baseline: 1.3853x; 1.0047x over previous
//
#include <hip/hip_runtime.h>
#include <hip/hip_bf16.h>
#include <math.h>

#define NRES 1536
#define NH 16
#define NNF 2359296ull    // NRES*NRES
#define LOG2E 1.44269504f
#define KVS 4             // split-KV ways

typedef unsigned short u16;
typedef __attribute__((ext_vector_type(8))) short short8;
typedef __attribute__((ext_vector_type(4))) unsigned short u16x4;
typedef __attribute__((ext_vector_type(4))) float f32x4;

typedef const __attribute__((address_space(1))) void gvoid;
typedef __attribute__((address_space(3))) void lvoid;

__device__ __forceinline__ u16 f2b(float x){
    __hip_bfloat16 h = __float2bfloat16(x);
    return *reinterpret_cast<u16*>(&h);
}
__device__ __forceinline__ float b2f(u16 u){
    unsigned v = ((unsigned)u) << 16;
    return __uint_as_float(v);
}

// ===================== bf16 MFMA GEMM v2: double-buffered, 1 barrier/K-step ==========
#define F_BIAS  1
#define F_SILU  2
#define F_RESID 8
#define F_OUTBF 16

template<int TNF>
__global__ __launch_bounds__(256) void gemm_t(
    const u16* __restrict__ A, int lda, size_t zsA,
    const u16* __restrict__ BT, int ldb, size_t zsB,
    float* __restrict__ Cf, u16* __restrict__ Cb, int ldc, size_t zsC,
    const float* __restrict__ bias, size_t zsBias,
    const float* __restrict__ resid, int ldr, size_t zsR,
    int Ncols, int Kd, int flags, int ksl)
{
    constexpr int TN = TNF * 32;
    __shared__ u16 As[2][128 * 64];
    __shared__ u16 Bs[2][TN * 64];

    // ---- XCD-bijective block swizzle (T1) ----
    unsigned gx = gridDim.x, gy = gridDim.y;
    unsigned nb = gx * gy * gridDim.z;
    unsigned bid = (blockIdx.z * gy + blockIdx.y) * gx + blockIdx.x;
    if ((nb & 7u) == 0u) bid = (bid & 7u) * (nb >> 3) + (bid >> 3);
    const int bxi = bid % gx;
    const int byi = (bid / gx) % gy;
    const int bz  = bid / (gx * gy);

    const int tid = threadIdx.x;
    const int l = tid & 63, w = tid >> 6;
    const int bm = byi * 128, bn = bxi * TN;

    A  += zsA * bz;
    BT += zsB * bz;

    const int kbeg = ksl ? bz * ksl : 0;
    const int kend = ksl ? kbeg + ksl : Kd;
    const int nk = (kend - kbeg) >> 6;

    const int arow   = l >> 3;
    const int aslot  = l & 7;
    const int srcslt = aslot ^ arow;

    const u16* aBase[4];
    const u16* bBase[TN / 32];
    #pragma unroll
    for (int t = 0; t < 4; ++t) {
        int ra = bm + (w * 4 + t) * 8 + arow;
        aBase[t] = A + (size_t)ra * lda + srcslt * 8;
    }
    #pragma unroll
    for (int t = 0; t < TN / 32; ++t) {
        int rb = bn + (w * (TN / 32) + t) * 8 + arow;
        if (rb > Ncols - 1) rb = Ncols - 1;
        bBase[t] = BT + (size_t)rb * ldb + srcslt * 8;
    }

    const int wr = w >> 1, wc = w & 1;
    const int fr = l & 15;
    const int fq = l >> 4;

    f32x4 acc[4][TNF];
    #pragma unroll
    for (int i = 0; i < 4; ++i)
        #pragma unroll
        for (int j = 0; j < TNF; ++j) acc[i][j] = (f32x4){0.f, 0.f, 0.f, 0.f};

    auto stage = [&](int buf, int k0) {
        #pragma unroll
        for (int t = 0; t < 4; ++t)
            __builtin_amdgcn_global_load_lds((gvoid*)(aBase[t] + k0),
                (lvoid*)((char*)As[buf] + (w * 4 + t) * 1024), 16, 0, 0);
        #pragma unroll
        for (int t = 0; t < TN / 32; ++t)
            __builtin_amdgcn_global_load_lds((gvoid*)(bBase[t] + k0),
                (lvoid*)((char*)Bs[buf] + (w * (TN / 32) + t) * 1024), 16, 0, 0);
    };

    stage(0, kbeg);
    __syncthreads();
    int cur = 0;

    for (int it = 0; it < nk; ++it) {
        if (it + 1 < nk) stage(cur ^ 1, kbeg + (it + 1) * 64);
        #pragma unroll
        for (int kk = 0; kk < 2; ++kk) {
            const int slotR = ((kk * 4) + fq) ^ (l & 7);
            short8 av[4], bv[TNF];
            #pragma unroll
            for (int m = 0; m < 4; ++m) {
                int r = wr * 64 + m * 16 + fr;
                av[m] = *(const short8*)((const char*)As[cur] + r * 128 + slotR * 16);
            }
            #pragma unroll
            for (int n = 0; n < TNF; ++n) {
                int r = wc * (TNF * 16) + n * 16 + fr;
                bv[n] = *(const short8*)((const char*)Bs[cur] + r * 128 + slotR * 16);
            }
            #pragma unroll
            for (int m = 0; m < 4; ++m)
                #pragma unroll
                for (int n = 0; n < TNF; ++n)
                    acc[m][n] = __builtin_amdgcn_mfma_f32_16x16x32_bf16(av[m], bv[n], acc[m][n], 0, 0, 0);
        }
        __syncthreads();   // single barrier: drains next-tile staging AFTER compute
        cur ^= 1;
    }

    const float* residz = (flags & F_RESID) ? resid + zsR * bz : nullptr;
    const float* biasz  = (flags & F_BIAS)  ? bias + zsBias * bz : nullptr;
    float* cfz = Cf ? Cf + zsC * bz : nullptr;
    u16*   cbz = Cb ? Cb + zsC * bz : nullptr;

    #pragma unroll
    for (int m = 0; m < 4; ++m) {
        #pragma unroll
        for (int n = 0; n < TNF; ++n) {
            int gc = bn + wc * (TNF * 16) + n * 16 + fr;
            if (gc >= Ncols) continue;
            int gr0 = bm + wr * 64 + m * 16 + fq * 4;
            #pragma unroll
            for (int r = 0; r < 4; ++r) {
                int gr = gr0 + r;
                float v = acc[m][n][r];
                if (flags & F_BIAS)  v += biasz[gc];
                if (flags & F_SILU)  v = v / (1.f + expf(-v));
                if (flags & F_RESID) v += residz[(size_t)gr * ldr + gc];
                if (flags & F_OUTBF) cbz[(size_t)gr * ldc + gc] = f2b(v);
                else                 cfz[(size_t)gr * ldc + gc] = v;
            }
        }
    }
}

// ===================== split-K reduce (bf16 partials) + fused epilogue ==========
__global__ __launch_bounds__(256) void reduce_epi(
    const u16* __restrict__ part, size_t slice, int nsl,
    float* __restrict__ Cf, u16* __restrict__ Cb,
    const float* __restrict__ bias,
    const float* __restrict__ resid, int ldr,
    int M, int Ncols, int flags)
{
    if ((Ncols & 7) == 0) {
        size_t total8 = (size_t)M * Ncols / 8;
        for (size_t i8 = (size_t)blockIdx.x * 256 + threadIdx.x; i8 < total8;
             i8 += (size_t)gridDim.x * 256) {
            size_t i0 = i8 * 8;
            int r = (int)(i0 / (unsigned)Ncols);
            int c0 = (int)(i0 - (size_t)r * Ncols);
            float v[8] = {0,0,0,0,0,0,0,0};
            for (int s = 0; s < nsl; ++s) {
                const u16x4* p = (const u16x4*)(part + (size_t)s * slice + i0);
                u16x4 a = p[0], b = p[1];
                v[0] += b2f(a.x); v[1] += b2f(a.y); v[2] += b2f(a.z); v[3] += b2f(a.w);
                v[4] += b2f(b.x); v[5] += b2f(b.y); v[6] += b2f(b.z); v[7] += b2f(b.w);
            }
            #pragma unroll
            for (int j = 0; j < 8; ++j) {
                if (flags & F_BIAS) v[j] += bias[c0 + j];
                if (flags & F_SILU) v[j] = v[j] / (1.f + expf(-v[j]));
            }
            if (flags & F_RESID) {
                const float4* rp = (const float4*)(resid + (size_t)r * ldr + c0);
                float4 r0 = rp[0], r1 = rp[1];
                v[0] += r0.x; v[1] += r0.y; v[2] += r0.z; v[3] += r0.w;
                v[4] += r1.x; v[5] += r1.y; v[6] += r1.z; v[7] += r1.w;
            }
            if (flags & F_OUTBF) {
                short8 o;
                #pragma unroll
                for (int j = 0; j < 8; ++j) o[j] = (short)f2b(v[j]);
                *(short8*)(Cb + i0) = o;
            } else {
                float4 o0 = {v[0], v[1], v[2], v[3]}, o1 = {v[4], v[5], v[6], v[7]};
                float4* cp = (float4*)(Cf + i0);
                cp[0] = o0; cp[1] = o1;
            }
        }
    } else {
        size_t total = (size_t)M * Ncols;
        for (size_t i = (size_t)blockIdx.x * 256 + threadIdx.x; i < total;
             i += (size_t)gridDim.x * 256) {
            float v = 0.f;
            for (int s = 0; s < nsl; ++s) v += b2f(part[(size_t)s * slice + i]);
            if (flags & F_OUTBF) Cb[i] = f2b(v);
            else                 Cf[i] = v;
        }
    }
}

// ===== fused split-K reduce -> local update -> cond LayerNorm -> bf16 =====
__global__ __launch_bounds__(256) void reduce_cn(
    const u16* __restrict__ part, size_t slice, int nsl,
    const float* __restrict__ bias, const float* __restrict__ resid,
    float* __restrict__ locOut,
    const u16* __restrict__ cs, const u16* __restrict__ cb,
    u16* __restrict__ normB)
{
    int row = blockIdx.x, tid = threadIdx.x;
    size_t base = (size_t)row * 1024 + tid * 4;
    float v[4];
    {
        float4 rv = *(const float4*)(resid + base);
        v[0] = rv.x; v[1] = rv.y; v[2] = rv.z; v[3] = rv.w;
    }
    for (int s = 0; s < nsl; ++s) {
        u16x4 p = *(const u16x4*)(part + (size_t)s * slice + base);
        v[0] += b2f(p.x); v[1] += b2f(p.y); v[2] += b2f(p.z); v[3] += b2f(p.w);
    }
    {
        float4 bv = *(const float4*)(bias + tid * 4);
        v[0] += bv.x; v[1] += bv.y; v[2] += bv.z; v[3] += bv.w;
    }
    *(float4*)(locOut + base) = (float4){v[0], v[1], v[2], v[3]};

    float s1 = v[0] + v[1] + v[2] + v[3];
    float s2 = v[0]*v[0] + v[1]*v[1] + v[2]*v[2] + v[3]*v[3];
    __shared__ float r1[256], r2[256];
    r1[tid] = s1; r2[tid] = s2;
    __syncthreads();
    for (int st = 128; st > 0; st >>= 1) {
        if (tid < st) { r1[tid] += r1[tid + st]; r2[tid] += r2[tid + st]; }
        __syncthreads();
    }
    float mean = r1[0] * (1.f / 1024.f);
    float var = r2[0] * (1.f / 1024.f) - mean * mean;
    float rs = rsqrtf(var + 1e-5f);
    u16x4 sv = *(const u16x4*)(cs + base);
    u16x4 bv = *(const u16x4*)(cb + base);
    u16x4 o;
    o.x = f2b((1.f / (1.f + expf(-b2f(sv.x)))) * (v[0] - mean) * rs + b2f(bv.x));
    o.y = f2b((1.f / (1.f + expf(-b2f(sv.y)))) * (v[1] - mean) * rs + b2f(bv.y));
    o.z = f2b((1.f / (1.f + expf(-b2f(sv.z)))) * (v[2] - mean) * rs + b2f(bv.z));
    o.w = f2b((1.f / (1.f + expf(-b2f(sv.w)))) * (v[3] - mean) * rs + b2f(bv.w));
    *(u16x4*)(normB + base) = o;
}

// ===================== fused flash attention v4 (split-KV=4, bf16 O partials) ========
__global__ __launch_bounds__(256, 2) void attn_kernel(
    const u16* __restrict__ qe, const u16* __restrict__ ke,
    const u16* __restrict__ vt, const float* __restrict__ pb,
    u16* __restrict__ Opart, float* __restrict__ mlpart)
{
    __shared__ u16 Ks[2][64 * 128];
    __shared__ u16 Vs[2][96 * 64];
    __shared__ u16 Ps[64 * 64];

    const int tid = threadIdx.x;
    const int l = tid & 63, w = tid >> 6;
    const int h = blockIdx.y;
    const int q0 = blockIdx.x * 64;
    const int z = blockIdx.z;
    const int fr = l & 15, fq = l >> 4;

    const u16* keh = ke + (size_t)h * NRES * 128;
    const u16* vth = vt + (size_t)h * 96 * NRES;

    const int kr4 = l >> 4, ks16 = l & 15;
    const int vr8 = l >> 3, vs8 = l & 7;

    short8 qv[4];
    {
        const u16* qrow = qe + ((size_t)h * NRES + (q0 + w * 16 + fr)) * 128 + fq * 8;
        #pragma unroll
        for (int kk = 0; kk < 4; ++kk)
            qv[kk] = *(const short8*)(qrow + kk * 32);
    }

    float m_run[4], l_run[4];
    f32x4 oacc[6];
    #pragma unroll
    for (int r = 0; r < 4; ++r) { m_run[r] = -1e30f; l_run[r] = 0.f; }
    #pragma unroll
    for (int n = 0; n < 6; ++n) oacc[n] = (f32x4){0.f, 0.f, 0.f, 0.f};

    const int NIT = NRES / 64 / KVS;
    const int jbase = z * (NRES / KVS);
    int cur = 0;

    auto stage = [&](int buf, int j0) {
        #pragma unroll
        for (int t = 0; t < 4; ++t) {
            int row = w * 16 + t * 4 + kr4;
            int ss = ks16 ^ (row & 7);
            __builtin_amdgcn_global_load_lds(
                (gvoid*)(keh + (size_t)(j0 + row) * 128 + ss * 8),
                (lvoid*)((char*)Ks[buf] + (w * 16 + t * 4) * 256), 16, 0, 0);
        }
        #pragma unroll
        for (int t = 0; t < 3; ++t) {
            int row = w * 24 + t * 8 + vr8;
            int ss = vs8 ^ (row & 7);
            __builtin_amdgcn_global_load_lds(
                (gvoid*)(vth + (size_t)row * NRES + j0 + ss * 8),
                (lvoid*)((char*)Vs[buf] + (w * 24 + t * 8) * 128), 16, 0, 0);
        }
    };
    const float* pbrow = pb + ((size_t)h * NRES + (q0 + w * 16 + fq * 4)) * NRES + fr;

    f32x4 pbv[4], pbn[4] = {};
    stage(0, jbase);
    #pragma unroll
    for (int n = 0; n < 4; ++n)
        #pragma unroll
        for (int r = 0; r < 4; ++r)
            pbv[n][r] = pbrow[(size_t)r * NRES + jbase + n * 16];
    __syncthreads();

    for (int it = 0; it < NIT; ++it) {
        if (it + 1 < NIT) {
            int j1 = jbase + (it + 1) * 64;
            stage(cur ^ 1, j1);
            #pragma unroll
            for (int n = 0; n < 4; ++n)
                #pragma unroll
                for (int r = 0; r < 4; ++r)
                    pbn[n][r] = pbrow[(size_t)r * NRES + j1 + n * 16];
        }

        f32x4 sacc[4];
        #pragma unroll
        for (int n = 0; n < 4; ++n) sacc[n] = (f32x4){0.f, 0.f, 0.f, 0.f};
        #pragma unroll
        for (int kk = 0; kk < 4; ++kk) {
            #pragma unroll
            for (int n = 0; n < 4; ++n) {
                int row = n * 16 + fr;
                short8 bv = *(const short8*)((const char*)Ks[cur] + row * 256
                                             + (((kk * 4 + fq) ^ (fr & 7)) * 16));
                sacc[n] = __builtin_amdgcn_mfma_f32_16x16x32_bf16(qv[kk], bv, sacc[n], 0, 0, 0);
            }
        }
        #pragma unroll
        for (int n = 0; n < 4; ++n) sacc[n] += pbv[n];

        float alpha[4];
        #pragma unroll
        for (int r = 0; r < 4; ++r) {
            float v = fmaxf(fmaxf(sacc[0][r], sacc[1][r]), fmaxf(sacc[2][r], sacc[3][r]));
            v = fmaxf(v, __shfl_xor(v, 1, 64));
            v = fmaxf(v, __shfl_xor(v, 2, 64));
            v = fmaxf(v, __shfl_xor(v, 4, 64));
            v = fmaxf(v, __shfl_xor(v, 8, 64));
            float mn = fmaxf(m_run[r], v);
            alpha[r] = exp2f((m_run[r] - mn) * LOG2E);
            m_run[r] = mn;
        }

        float psum[4] = {0.f, 0.f, 0.f, 0.f};
        #pragma unroll
        for (int n = 0; n < 4; ++n) {
            int col = n * 16 + fr;
            #pragma unroll
            for (int r = 0; r < 4; ++r) {
                float p = exp2f((sacc[n][r] - m_run[r]) * LOG2E);
                psum[r] += p;
                int rowf = w * 16 + fq * 4 + r;
                int byte = rowf * 128 + (((col >> 3) ^ (rowf & 7)) * 16) + (col & 7) * 2;
                *(u16*)((char*)Ps + byte) = f2b(p);
            }
        }
        #pragma unroll
        for (int r = 0; r < 4; ++r) {
            float v = psum[r];
            v += __shfl_xor(v, 1, 64);
            v += __shfl_xor(v, 2, 64);
            v += __shfl_xor(v, 4, 64);
            v += __shfl_xor(v, 8, 64);
            l_run[r] = l_run[r] * alpha[r] + v;
        }
        #pragma unroll
        for (int n = 0; n < 6; ++n)
            #pragma unroll
            for (int r = 0; r < 4; ++r)
                oacc[n][r] *= alpha[r];

        #pragma unroll
        for (int kk = 0; kk < 2; ++kk) {
            int prow = w * 16 + fr;
            short8 pa = *(const short8*)((const char*)Ps + prow * 128
                                         + (((kk * 4 + fq) ^ (prow & 7)) * 16));
            #pragma unroll
            for (int n = 0; n < 6; ++n) {
                int vrow = n * 16 + fr;
                short8 vv = *(const short8*)((const char*)Vs[cur] + vrow * 128
                                             + (((kk * 4 + fq) ^ (fr & 7)) * 16));
                oacc[n] = __builtin_amdgcn_mfma_f32_16x16x32_bf16(pa, vv, oacc[n], 0, 0, 0);
            }
        }

        __syncthreads();
        cur ^= 1;
        #pragma unroll
        for (int n = 0; n < 4; ++n) pbv[n] = pbn[n];
    }

    u16* Oz = Opart + ((size_t)z * NH + h) * NRES * 96;
    #pragma unroll
    for (int n = 0; n < 6; ++n) {
        int c = n * 16 + fr;
        #pragma unroll
        for (int r = 0; r < 4; ++r) {
            int row = q0 + w * 16 + fq * 4 + r;
            Oz[(size_t)row * 96 + c] = f2b(oacc[n][r]);
        }
    }
    if (fr == 0) {
        float* mlz = mlpart + ((size_t)z * NH + h) * NRES * 2;
        #pragma unroll
        for (int r = 0; r < 4; ++r) {
            int row = q0 + w * 16 + fq * 4 + r;
            mlz[row * 2 + 0] = m_run[r];
            mlz[row * 2 + 1] = l_run[r];
        }
    }
}

// ===================== split-KV combine (KVS-way, bf16 O) -> cat =====================
__global__ __launch_bounds__(256) void combine_kernel(
    const u16* __restrict__ Opart, const float* __restrict__ mlpart,
    float* __restrict__ cat)
{
    int idx = blockIdx.x * 256 + threadIdx.x;
    if (idx >= NH * NRES * 88) return;
    int c = idx % 88;
    int rh = idx / 88;
    float m[KVS], lv[KVS];
    float mm = -1e30f;
    #pragma unroll
    for (int s = 0; s < KVS; ++s) {
        size_t rr = (size_t)s * NH * NRES + rh;
        m[s] = mlpart[rr * 2];
        lv[s] = mlpart[rr * 2 + 1];
        mm = fmaxf(mm, m[s]);
    }
    float ll = 0.f, ov = 0.f;
    #pragma unroll
    for (int s = 0; s < KVS; ++s) {
        float wgt = exp2f((m[s] - mm) * LOG2E);
        ll += lv[s] * wgt;
        ov += b2f(Opart[((size_t)s * NH * NRES + rh) * 96 + c]) * wgt;
    }
    cat[(size_t)rh * 88 + c] = ov / ll;
}

// ===================== batched transpose fp32 -> bf16 [N][K] =====================
struct TP9 { const float* p[9]; };

__global__ __launch_bounds__(256) void transpose_bz(
    TP9 tp, int ldi, size_t zsi,
    u16* __restrict__ out, int ldo, size_t zso, int K, int N, int nsrc)
{
    __shared__ float t[32][33];
    int z = blockIdx.z;
    const float* in = tp.p[(z < nsrc) ? z : 0] + zsi * ((z < nsrc) ? 0 : z);
    if (nsrc == 1) in = tp.p[0] + zsi * z;
    out += zso * z;
    int k0 = blockIdx.y * 32, n0 = blockIdx.x * 32;
    int tx = threadIdx.x & 31, ty = threadIdx.x >> 5;
    #pragma unroll
    for (int j = 0; j < 4; ++j) {
        int k = k0 + ty + j * 8;
        if (k < K && n0 + tx < N) t[ty + j * 8][tx] = in[(size_t)k * ldi + n0 + tx];
    }
    __syncthreads();
    #pragma unroll
    for (int j = 0; j < 4; ++j) {
        int n = n0 + ty + j * 8;
        int k = k0 + tx;
        if (n < N && k < K) out[(size_t)n * ldo + k] = f2b(t[tx][ty + j * 8]);
    }
}

// ===================== misc small kernels =====================
__global__ __launch_bounds__(256) void f2b8_kernel(const float* __restrict__ in, u16* __restrict__ out, int n8)
{
    int i = blockIdx.x * 256 + threadIdx.x;
    if (i >= n8) return;
    size_t i0 = (size_t)i * 8;
    const float4* p = (const float4*)(in + i0);
    float4 a = p[0], b = p[1];
    short8 o;
    o[0]=(short)f2b(a.x); o[1]=(short)f2b(a.y); o[2]=(short)f2b(a.z); o[3]=(short)f2b(a.w);
    o[4]=(short)f2b(b.x); o[5]=(short)f2b(b.y); o[6]=(short)f2b(b.z); o[7]=(short)f2b(b.w);
    *(short8*)(out + i0) = o;
}

__global__ __launch_bounds__(256) void emb_kernel(const float* __restrict__ pos, u16* __restrict__ emb)
{
    int idx = blockIdx.x * 256 + threadIdx.x;
    int f = idx & 63;
    int rest = idx >> 6;
    int coord = rest % 42;
    int n = rest / 42;
    float t = pos[(size_t)n * 42 + coord];
    const double l0 = -6.643856189774724;
    const double step = 14.643856189774724 / 63.0;
    float freq = exp2f((float)(l0 + f * step));
    float r = t * freq;
    size_t o = (size_t)n * 5376 + (size_t)coord * 128 + 2 * f;
    emb[o]     = f2b(sinf(r));
    emb[o + 1] = f2b(cosf(r));
}

__global__ __launch_bounds__(256) void frames_kernel(const float* __restrict__ pos,
                                                     float* __restrict__ Rb, float* __restrict__ tb)
{
    int n = blockIdx.x * 256 + threadIdx.x;
    if (n >= NRES) return;
    const float* p = pos + (size_t)n * 42;
    float nx = p[0], ny = p[1], nz = p[2];
    float cax = p[3], cay = p[4], caz = p[5];
    float cx = p[6], cy = p[7], cz = p[8];
    float v1x = cx - cax, v1y = cy - cay, v1z = cz - caz;
    float i1 = rsqrtf(v1x * v1x + v1y * v1y + v1z * v1z + 1e-8f);
    float e1x = v1x * i1, e1y = v1y * i1, e1z = v1z * i1;
    float v2x = nx - cax, v2y = ny - cay, v2z = nz - caz;
    float d = e1x * v2x + e1y * v2y + e1z * v2z;
    float wx = v2x - d * e1x, wy = v2y - d * e1y, wz = v2z - d * e1z;
    float i2 = rsqrtf(wx * wx + wy * wy + wz * wz + 1e-8f);
    float e2x = wx * i2, e2y = wy * i2, e2z = wz * i2;
    float e3x = e1y * e2z - e1z * e2y;
    float e3y = e1z * e2x - e1x * e2z;
    float e3z = e1x * e2y - e1y * e2x;
    float* R = Rb + (size_t)n * 9;
    R[0] = e1x; R[1] = e2x; R[2] = e3x;
    R[3] = e1y; R[4] = e2y; R[5] = e3y;
    R[6] = e1z; R[7] = e2z; R[8] = e3z;
    tb[(size_t)n * 3 + 0] = cax;
    tb[(size_t)n * 3 + 1] = cay;
    tb[(size_t)n * 3 + 2] = caz;
}

__global__ __launch_bounds__(256) void bias_pack(const float* a, const float* b, const float* c,
                                                 const float* d, const float* e, const float* f,
                                                 float* out)
{
    int i = blockIdx.x * 256 + threadIdx.x;
    if (i >= 1024) return;
    out[i] = a[i]; out[1024 + i] = b[i]; out[2048 + i] = c[i];
    out[3072 + i] = d[i]; out[4096 + i] = e[i]; out[5120 + i] = f[i];
}

__global__ __launch_bounds__(256) void biasg_pack(const float* a, const float* b, float* out)
{
    int i = blockIdx.x * 256 + threadIdx.x;
    if (i >= 2048) return;
    out[i] = a[i]; out[2048 + i] = b[i];
}

// gm = silu(g1) * g2, 8-wide
__global__ __launch_bounds__(256) void glu_kernel(const u16* __restrict__ g12, u16* __restrict__ gm)
{
    int i = blockIdx.x * 256 + threadIdx.x;
    if (i >= NRES * 2048 / 8) return;
    size_t i0 = (size_t)i * 8;
    short8 a8 = *(const short8*)(g12 + i0);
    short8 b8 = *(const short8*)(g12 + (size_t)NRES * 2048 + i0);
    short8 o;
    #pragma unroll
    for (int j = 0; j < 8; ++j) {
        float a = b2f((u16)a8[j]);
        float b = b2f((u16)b8[j]);
        float s = a / (1.f + expf(-a));
        o[j] = (short)f2b(s * b);
    }
    *(short8*)(gm + i0) = o;
}

// vectorized pack: qe/ke [h][n][128]; g<8 data, g==11 zeros 88..95, g>=12 zeros
__global__ __launch_bounds__(256) void pack_qk(const float* __restrict__ qb, const float* __restrict__ kb,
                                               u16* __restrict__ qe, u16* __restrict__ ke)
{
    int idx = blockIdx.x * 256 + threadIdx.x;
    if (idx >= NH * NRES * 16) return;
    int g = idx & 15;
    int t = idx >> 4;
    int n = t % NRES;
    int h = t / NRES;
    size_t o = ((size_t)h * NRES + n) * 128 + g * 8;
    if (g < 8) {
        const float4* q4 = (const float4*)(qb + (size_t)n * 1024 + h * 64 + g * 8);
        const float4* k4 = (const float4*)(kb + (size_t)n * 1024 + h * 64 + g * 8);
        float4 qa = q4[0], qb2 = q4[1], ka = k4[0], kb2 = k4[1];
        short8 oq, ok;
        oq[0]=(short)f2b(0.125f*qa.x); oq[1]=(short)f2b(0.125f*qa.y);
        oq[2]=(short)f2b(0.125f*qa.z); oq[3]=(short)f2b(0.125f*qa.w);
        oq[4]=(short)f2b(0.125f*qb2.x); oq[5]=(short)f2b(0.125f*qb2.y);
        oq[6]=(short)f2b(0.125f*qb2.z); oq[7]=(short)f2b(0.125f*qb2.w);
        ok[0]=(short)f2b(ka.x); ok[1]=(short)f2b(ka.y); ok[2]=(short)f2b(ka.z); ok[3]=(short)f2b(ka.w);
        ok[4]=(short)f2b(kb2.x); ok[5]=(short)f2b(kb2.y); ok[6]=(short)f2b(kb2.z); ok[7]=(short)f2b(kb2.w);
        *(short8*)(qe + o) = oq;
        *(short8*)(ke + o) = ok;
    } else if (g >= 11) {
        short8 zz = {};
        *(short8*)(qe + o) = zz;
        *(short8*)(ke + o) = zz;
    }
}

__global__ __launch_bounds__(256) void build_pts(
    const float* __restrict__ qp, const float* __restrict__ kp, const float* __restrict__ vp,
    const float* __restrict__ Rb, const float* __restrict__ tb, const float* __restrict__ gamma,
    u16* __restrict__ qe, u16* __restrict__ ke, float* __restrict__ vgt)
{
    int idx = blockIdx.x * 256 + threadIdx.x;
    if (idx >= NRES * NH) return;
    int n = idx >> 4, h = idx & 15;
    float R[9];
    #pragma unroll
    for (int a = 0; a < 9; ++a) R[a] = Rb[(size_t)n * 9 + a];
    float t0 = tb[(size_t)n * 3 + 0], t1 = tb[(size_t)n * 3 + 1], t2 = tb[(size_t)n * 3 + 2];
    float g = gamma[h];
    float sp = (g > 20.f) ? g : log1pf(expf(g));
    float ch = 0.5f * (1.f / 6.f) * sp;

    u16* qeh = qe + ((size_t)h * NRES + n) * 128;
    u16* keh = ke + ((size_t)h * NRES + n) * 128;
    size_t pbase = (size_t)n * 384 + h * 24;
    float kn = 0.f;
    #pragma unroll
    for (int p = 0; p < 8; ++p) {
        size_t o = pbase + p * 3;
        {
            float x = qp[o], y = qp[o + 1], z = qp[o + 2];
            float g0 = R[0] * x + R[1] * y + R[2] * z + t0;
            float g1 = R[3] * x + R[4] * y + R[5] * z + t1;
            float g2 = R[6] * x + R[7] * y + R[8] * z + t2;
            qeh[64 + p * 3 + 0] = f2b(2.f * ch * g0);
            qeh[64 + p * 3 + 1] = f2b(2.f * ch * g1);
            qeh[64 + p * 3 + 2] = f2b(2.f * ch * g2);
        }
        {
            float x = kp[o], y = kp[o + 1], z = kp[o + 2];
            float g0 = R[0] * x + R[1] * y + R[2] * z + t0;
            float g1 = R[3] * x + R[4] * y + R[5] * z + t1;
            float g2 = R[6] * x + R[7] * y + R[8] * z + t2;
            keh[64 + p * 3 + 0] = f2b(g0);
            keh[64 + p * 3 + 1] = f2b(g1);
            keh[64 + p * 3 + 2] = f2b(g2);
            kn += g0 * g0 + g1 * g1 + g2 * g2;
        }
        {
            float x = vp[o], y = vp[o + 1], z = vp[o + 2];
            vgt[o]     = R[0] * x + R[1] * y + R[2] * z + t0;
            vgt[o + 1] = R[3] * x + R[4] * y + R[5] * z + t1;
            vgt[o + 2] = R[6] * x + R[7] * y + R[8] * z + t2;
        }
    }
    qeh[88] = f2b(1.0f);
    keh[88] = f2b(-ch * kn);
}

__global__ __launch_bounds__(256) void finalize_kernel(const float* __restrict__ cat,
                                                       const float* __restrict__ Rb,
                                                       const float* __restrict__ tb,
                                                       u16* __restrict__ featB)
{
    int idx = blockIdx.x * 256 + threadIdx.x;
    if (idx >= NRES * NH) return;
    int n = idx >> 4, h = idx & 15;
    float R[9];
    #pragma unroll
    for (int a = 0; a < 9; ++a) R[a] = Rb[(size_t)n * 9 + a];
    float t0 = tb[(size_t)n * 3 + 0], t1 = tb[(size_t)n * 3 + 1], t2 = tb[(size_t)n * 3 + 2];
    const float* c = cat + ((size_t)h * NRES + n) * 88;
    u16* fb = featB + (size_t)n * 1536;
    #pragma unroll
    for (int k = 0; k < 64; ++k) fb[h * 64 + k] = f2b(c[k]);
    #pragma unroll
    for (int p = 0; p < 8; ++p) {
        float x = c[64 + p * 3 + 0] - t0;
        float y = c[64 + p * 3 + 1] - t1;
        float z = c[64 + p * 3 + 2] - t2;
        float a0 = R[0] * x + R[3] * y + R[6] * z;
        float a1 = R[1] * x + R[4] * y + R[7] * z;
        float a2 = R[2] * x + R[5] * y + R[8] * z;
        fb[1024 + h * 24 + p * 3 + 0] = f2b(a0);
        fb[1024 + h * 24 + p * 3 + 1] = f2b(a1);
        fb[1024 + h * 24 + p * 3 + 2] = f2b(a2);
        fb[1408 + h * 8 + p] = f2b(sqrtf(a0 * a0 + a1 * a1 + a2 * a2 + 1e-8f));
    }
}

// ========================= host =========================
extern "C" void kernel_launch(void* const* d_in, const int* in_sizes, int n_in,
                              void* d_out, int out_size, void* d_ws, size_t ws_size,
                              hipStream_t stream)
{
    const float* local_in = (const float*)d_in[0];
    const float* pos      = (const float*)d_in[1];
    const float* cond     = (const float*)d_in[2];
    const float* pb       = (const float*)d_in[4];
    const float* w_f1     = (const float*)d_in[5];
    const float* b_f1     = (const float*)d_in[6];
    const float* w_f2     = (const float*)d_in[7];
    const float* b_f2     = (const float*)d_in[8];
    const float* cn1_ws   = (const float*)d_in[9];
    const float* cn1_bs   = (const float*)d_in[10];
    const float* cn1_wb   = (const float*)d_in[11];
    const float* cn1_bb   = (const float*)d_in[12];
    const float* wq       = (const float*)d_in[13];
    const float* wk       = (const float*)d_in[14];
    const float* wv       = (const float*)d_in[15];
    const float* wqp      = (const float*)d_in[16];
    const float* wkp      = (const float*)d_in[17];
    const float* wvp      = (const float*)d_in[18];
    const float* gamma    = (const float*)d_in[19];
    const float* wo       = (const float*)d_in[20];
    const float* bo       = (const float*)d_in[21];
    const float* cn2_ws   = (const float*)d_in[22];
    const float* cn2_bs   = (const float*)d_in[23];
    const float* cn2_wb   = (const float*)d_in[24];
    const float* cn2_bb   = (const float*)d_in[25];
    const float* wg1      = (const float*)d_in[26];
    const float* bg1      = (const float*)d_in[27];
    const float* wg2      = (const float*)d_in[28];
    const float* bg2      = (const float*)d_in[29];
    const float* wg3      = (const float*)d_in[30];
    const float* bg3      = (const float*)d_in[31];
    const float* cn3_ws   = (const float*)d_in[32];
    const float* cn3_bs   = (const float*)d_in[33];
    const float* cn3_wb   = (const float*)d_in[34];
    const float* cn3_bb   = (const float*)d_in[35];
    const float* w_vel    = (const float*)d_in[36];

    float* out = (float*)d_out;
    float* ws  = (float*)d_ws;

    size_t off = 0;
    auto alloc = [&](size_t nf) -> float* { float* p = ws + off; off += (nf + 7) & ~7ull; return p; };

    const size_t NN1 = (size_t)NRES * 1024;
    float* Rb    = alloc(NRES * 9);
    float* tb    = alloc(NRES * 3);
    float* loc   = alloc(NN1);
    u16*   cs6b  = (u16*)alloc(6 * NN1 / 2);
    u16*   condB = (u16*)alloc(NN1 / 2);
    u16*   normB = (u16*)alloc(NN1 / 2);
    float* bias2 = alloc(6 * 1024);
    float* biasg = alloc(2 * 2048);
    float* qb    = alloc(3 * NN1);
    float* kb    = qb + NN1;
    float* vb    = kb + NN1;
    float* qp    = alloc(3 * (size_t)NRES * 384);
    float* kp    = qp + NRES * 384;
    float* vp    = kp + NRES * 384;
    float* vgt   = alloc((size_t)NRES * 384);
    u16*   qeB   = (u16*)alloc((size_t)NH * NRES * 128 / 2);
    u16*   keB   = (u16*)alloc((size_t)NH * NRES * 128 / 2);
    u16*   vTB   = (u16*)alloc((size_t)NH * 96 * NRES / 2);
    float* cat   = alloc((size_t)NH * NRES * 88);
    u16*   featB = (u16*)alloc((size_t)NRES * 1536 / 2);
    u16*   g1sB  = (u16*)alloc((size_t)NRES * 2048 / 2);
    u16*   gmB   = (u16*)alloc((size_t)NRES * 2048 / 2);
    u16*   cnT9  = (u16*)alloc((size_t)9 * 1024 * 1024 / 2);
    u16*   ptsT  = (u16*)alloc((size_t)3 * 384 * 1024 / 2);
    u16*   wgT   = (u16*)alloc((size_t)2 * 2048 * 1024 / 2);
    u16*   wf1T  = (u16*)alloc((size_t)2048 * 5376 / 2);
    u16*   wf2T  = (u16*)alloc((size_t)1024 * 2048 / 2);
    u16*   woT   = (u16*)alloc((size_t)1024 * 1536 / 2);
    u16*   wg3T  = (u16*)alloc((size_t)1024 * 2048 / 2);
    u16*   wvT   = (u16*)alloc((size_t)42 * 1024 / 2 + 8);
    u16*   embB  = (u16*)alloc((size_t)NRES * 5376 / 2);
    u16*   hidB  = (u16*)alloc((size_t)NRES * 2048 / 2);
    u16*   pscr  = (u16*)alloc((size_t)2 * NRES * 2048 * 4 / 2);
    u16*   Opart = (u16*)alloc((size_t)KVS * NH * NRES * 96 / 2);
    float* mlprt = alloc((size_t)KVS * NH * NRES * 2);

    const float* nilf = nullptr;

    auto gemm = [&](int tnf, const u16* A, int lda, size_t zsA,
                    const u16* BT, int ldb, size_t zsB,
                    float* Cf, u16* Cb2, int ldc, size_t zsC,
                    const float* bias, size_t zsBias,
                    const float* resid, int ldr, size_t zsR,
                    int Nc, int Kd, int flags, int gz, int ksl) {
        int tn = tnf * 32;
        dim3 grid((Nc + tn - 1) / tn, NRES / 128, gz);
        if (tnf == 4)
            hipLaunchKernelGGL(gemm_t<4>, grid, dim3(256), 0, stream,
                               A, lda, zsA, BT, ldb, zsB, Cf, Cb2, ldc, zsC,
                               bias, zsBias, resid, ldr, zsR, Nc, Kd, flags, ksl);
        else
            hipLaunchKernelGGL(gemm_t<2>, grid, dim3(256), 0, stream,
                               A, lda, zsA, BT, ldb, zsB, Cf, Cb2, ldc, zsC,
                               bias, zsBias, resid, ldr, zsR, Nc, Kd, flags, ksl);
    };
    auto red = [&](const u16* part, size_t slice, int nsl, float* Cf, u16* Cb2,
                   const float* bias, const float* resid, int ldr, int Nc, int flags) {
        hipLaunchKernelGGL(reduce_epi, dim3(1024), dim3(256), 0, stream,
                           part, slice, nsl, Cf, Cb2, bias, resid, ldr, NRES, Nc, flags);
    };
    auto redcn = [&](const u16* part, size_t slice, int nsl,
                     const float* bias, const float* resid, float* locOut, int cnIdx) {
        hipLaunchKernelGGL(reduce_cn, dim3(NRES), dim3(256), 0, stream,
                           part, slice, nsl, bias, resid, locOut,
                           cs6b + (size_t)(2 * cnIdx) * NN1,
                           cs6b + (size_t)(2 * cnIdx + 1) * NN1, normB);
    };
    auto tpz = [&](TP9 tp, int ldi, int K, int N, u16* o, int ldo, size_t zso, int nsrc) {
        dim3 grid((N + 31) / 32, (K + 31) / 32, nsrc);
        hipLaunchKernelGGL(transpose_bz, grid, dim3(256), 0, stream, tp, ldi, (size_t)0, o, ldo, zso, K, N, nsrc);
    };
    auto tps = [&](const float* in, int ldi, size_t zsi, int K, int N, u16* o, int ldo, size_t zso, int gz) {
        dim3 grid((N + 31) / 32, (K + 31) / 32, gz);
        TP9 tp; tp.p[0] = in;
        hipLaunchKernelGGL(transpose_bz, grid, dim3(256), 0, stream, tp, ldi, zsi, o, ldo, zso, K, N, 1);
    };

    // ---- prologue ----
    hipLaunchKernelGGL(frames_kernel, dim3(6), dim3(256), 0, stream, pos, Rb, tb);
    hipLaunchKernelGGL(emb_kernel, dim3((NRES * 42 * 64) / 256), dim3(256), 0, stream, pos, embB);
    hipLaunchKernelGGL(f2b8_kernel, dim3(768), dim3(256), 0, stream, cond, condB, NRES * 1024 / 8);
    hipLaunchKernelGGL(bias_pack, dim3(4), dim3(256), 0, stream,
                       cn1_bs, cn1_bb, cn2_bs, cn2_bb, cn3_bs, cn3_bb, bias2);
    hipLaunchKernelGGL(biasg_pack, dim3(8), dim3(256), 0, stream, bg1, bg2, biasg);

    // ---- weight transposes ----
    {
        TP9 t9; t9.p[0]=cn1_ws; t9.p[1]=cn1_wb; t9.p[2]=cn2_ws; t9.p[3]=cn2_wb;
        t9.p[4]=cn3_ws; t9.p[5]=cn3_wb; t9.p[6]=wq; t9.p[7]=wk; t9.p[8]=wv;
        tpz(t9, 1024, 1024, 1024, cnT9, 1024, (size_t)1024 * 1024, 9);
    }
    {
        TP9 t3; t3.p[0]=wqp; t3.p[1]=wkp; t3.p[2]=wvp;
        tpz(t3, 384, 1024, 384, ptsT, 1024, (size_t)384 * 1024, 3);
    }
    {
        TP9 t2; t2.p[0]=wg1; t2.p[1]=wg2;
        tpz(t2, 2048, 1024, 2048, wgT, 1024, (size_t)2048 * 1024, 2);
    }
    tps(w_f1, 2048, 0, 5376, 2048, wf1T, 5376, 0, 1);
    tps(w_f2, 1024, 0, 2048, 1024, wf2T, 2048, 0, 1);
    tps(wo,   1024, 0, 1536, 1024, woT,  1536, 0, 1);
    tps(wg3,  1024, 0, 2048, 1024, wg3T, 2048, 0, 1);
    tps(w_vel,  42, 0, 1024,   42, wvT,  1024, 0, 1);

    // ---- all 6 cond GEMMs (z=6, TN=64, bf16 out) ----
    gemm(2, condB, 1024, 0, cnT9, 1024, (size_t)1024 * 1024, nullptr, cs6b, 1024, NN1,
         bias2, 1024, nilf, 0, 0, 1024, 1024, F_BIAS | F_OUTBF, 6, 0);

    // ---- phase A: emb GEMM split-K=4, bf16 partials + reduce(silu->bf16) ----
    gemm(2, embB, 5376, 0, wf1T, 5376, 0, nullptr, pscr, 2048, (size_t)NRES * 2048,
         nilf, 0, nilf, 0, 0, 2048, 5376, F_OUTBF, 4, 1344);
    red(pscr, (size_t)NRES * 2048, 4, nullptr, hidB, b_f1, nilf, 0,
        2048, F_BIAS | F_SILU | F_OUTBF);
    gemm(2, hidB, 2048, 0, wf2T, 2048, 0, nullptr, pscr, 1024, NN1,
         nilf, 0, nilf, 0, 0, 1024, 2048, F_OUTBF, 4, 512);
    redcn(pscr, NN1, 4, b_f2, local_in, loc, 0);

    // ---- projections ----
    gemm(2, normB, 1024, 0, cnT9 + (size_t)6 * 1024 * 1024, 1024, (size_t)1024 * 1024,
         qb, nullptr, 1024, NN1, nilf, 0, nilf, 0, 0, 1024, 1024, 0, 3, 0);
    gemm(2, normB, 1024, 0, ptsT, 1024, (size_t)384 * 1024, qp, nullptr, 384, (size_t)NRES * 384,
         nilf, 0, nilf, 0, 0, 384, 1024, 0, 3, 0);

    // ---- attention operands ----
    hipMemsetAsync(vTB, 0, (size_t)NH * 96 * NRES * 2, stream);
    hipLaunchKernelGGL(pack_qk, dim3((NH * NRES * 16 + 255) / 256), dim3(256), 0, stream, qb, kb, qeB, keB);
    hipLaunchKernelGGL(build_pts, dim3(96), dim3(256), 0, stream,
                       qp, kp, vp, Rb, tb, gamma, qeB, keB, vgt);
    tps(vb, 1024, 64, NRES, 64, vTB, NRES, (size_t)96 * NRES, NH);
    tps(vgt, 384, 24, NRES, 24, vTB + (size_t)64 * NRES, NRES, (size_t)96 * NRES, NH);

    // ---- fused attention (split-KV=4) + combine ----
    hipLaunchKernelGGL(attn_kernel, dim3(NRES / 64, NH, KVS), dim3(256), 0, stream,
                       qeB, keB, vTB, pb, Opart, mlprt);
    hipLaunchKernelGGL(combine_kernel, dim3((NH * NRES * 88 + 255) / 256), dim3(256), 0, stream,
                       Opart, mlprt, cat);
    hipLaunchKernelGGL(finalize_kernel, dim3(96), dim3(256), 0, stream, cat, Rb, tb, featB);

    // ---- local += feat @ wo + bo : split-K=4, fused reduce+condnorm2 ----
    gemm(2, featB, 1536, 0, woT, 1536, 0, nullptr, pscr, 1024, NN1,
         nilf, 0, nilf, 0, 0, 1024, 1536, F_OUTBF, 4, 384);
    redcn(pscr, NN1, 4, bo, loc, loc, 1);

    // ---- gated MLP ----
    gemm(2, normB, 1024, 0, wgT, 1024, (size_t)2048 * 1024, nullptr, g1sB, 2048, (size_t)NRES * 2048,
         biasg, 2048, nilf, 0, 0, 2048, 1024, F_BIAS | F_OUTBF, 2, 0);
    u16* gmO = embB;
    hipLaunchKernelGGL(glu_kernel, dim3((NRES * 2048 / 8 + 255) / 256), dim3(256), 0, stream, g1sB, gmO);
    gemm(2, gmO, 2048, 0, wg3T, 2048, 0, nullptr, pscr, 1024, NN1,
         nilf, 0, nilf, 0, 0, 1024, 2048, F_OUTBF, 4, 512);
    redcn(pscr, NN1, 4, bg3, loc, out, 2);

    // ---- velocity (split-K=8, bf16 partials) ----
    gemm(2, normB, 1024, 0, wvT, 1024, 0, nullptr, pscr, 42, (size_t)NRES * 42,
         nilf, 0, nilf, 0, 0, 42, 1024, F_OUTBF, 8, 128);
    red(pscr, (size_t)NRES * 42, 8, out + (size_t)NRES * 1024, nullptr,
        nilf, nilf, 0, 42, 0);
}

// Round 11
// 487.344 us; speedup vs baseline: 1.4432x; 1.0417x over previous
//
#include <hip/hip_runtime.h>
#include <hip/hip_bf16.h>
#include <math.h>

#define NRES 1536
#define NH 16
#define NNF 2359296ull    // NRES*NRES
#define LOG2E 1.44269504f
#define KVS 4             // split-KV ways
#define LDQ 4224          // merged projection C leading dim

typedef unsigned short u16;
typedef __attribute__((ext_vector_type(8))) short short8;
typedef __attribute__((ext_vector_type(4))) unsigned short u16x4;
typedef __attribute__((ext_vector_type(4))) float f32x4;

typedef const __attribute__((address_space(1))) void gvoid;
typedef __attribute__((address_space(3))) void lvoid;

__device__ __forceinline__ u16 f2b(float x){
    __hip_bfloat16 h = __float2bfloat16(x);
    return *reinterpret_cast<u16*>(&h);
}
__device__ __forceinline__ float b2f(u16 u){
    unsigned v = ((unsigned)u) << 16;
    return __uint_as_float(v);
}

// ===================== bf16 MFMA GEMM (dbuf, 1 barrier/K-step, XCD swizzle) ==========
#define F_BIAS  1
#define F_SILU  2
#define F_RESID 8
#define F_OUTBF 16

template<int TNF>
__global__ __launch_bounds__(256) void gemm_t(
    const u16* __restrict__ A, int lda, size_t zsA,
    const u16* __restrict__ BT, int ldb, size_t zsB,
    float* __restrict__ Cf, u16* __restrict__ Cb, int ldc, size_t zsC,
    const float* __restrict__ bias, size_t zsBias,
    const float* __restrict__ resid, int ldr, size_t zsR,
    int Ncols, int Kd, int flags, int ksl)
{
    constexpr int TN = TNF * 32;
    __shared__ u16 As[2][128 * 64];
    __shared__ u16 Bs[2][TN * 64];

    unsigned gx = gridDim.x, gy = gridDim.y;
    unsigned nb = gx * gy * gridDim.z;
    unsigned bid = (blockIdx.z * gy + blockIdx.y) * gx + blockIdx.x;
    if ((nb & 7u) == 0u) bid = (bid & 7u) * (nb >> 3) + (bid >> 3);
    const int bxi = bid % gx;
    const int byi = (bid / gx) % gy;
    const int bz  = bid / (gx * gy);

    const int tid = threadIdx.x;
    const int l = tid & 63, w = tid >> 6;
    const int bm = byi * 128, bn = bxi * TN;

    A  += zsA * bz;
    BT += zsB * bz;

    const int kbeg = ksl ? bz * ksl : 0;
    const int kend = ksl ? kbeg + ksl : Kd;
    const int nk = (kend - kbeg) >> 6;

    const int arow   = l >> 3;
    const int aslot  = l & 7;
    const int srcslt = aslot ^ arow;

    const u16* aBase[4];
    const u16* bBase[TN / 32];
    #pragma unroll
    for (int t = 0; t < 4; ++t) {
        int ra = bm + (w * 4 + t) * 8 + arow;
        aBase[t] = A + (size_t)ra * lda + srcslt * 8;
    }
    #pragma unroll
    for (int t = 0; t < TN / 32; ++t) {
        int rb = bn + (w * (TN / 32) + t) * 8 + arow;
        if (rb > Ncols - 1) rb = Ncols - 1;
        bBase[t] = BT + (size_t)rb * ldb + srcslt * 8;
    }

    const int wr = w >> 1, wc = w & 1;
    const int fr = l & 15;
    const int fq = l >> 4;

    f32x4 acc[4][TNF];
    #pragma unroll
    for (int i = 0; i < 4; ++i)
        #pragma unroll
        for (int j = 0; j < TNF; ++j) acc[i][j] = (f32x4){0.f, 0.f, 0.f, 0.f};

    auto stage = [&](int buf, int k0) {
        #pragma unroll
        for (int t = 0; t < 4; ++t)
            __builtin_amdgcn_global_load_lds((gvoid*)(aBase[t] + k0),
                (lvoid*)((char*)As[buf] + (w * 4 + t) * 1024), 16, 0, 0);
        #pragma unroll
        for (int t = 0; t < TN / 32; ++t)
            __builtin_amdgcn_global_load_lds((gvoid*)(bBase[t] + k0),
                (lvoid*)((char*)Bs[buf] + (w * (TN / 32) + t) * 1024), 16, 0, 0);
    };

    stage(0, kbeg);
    __syncthreads();
    int cur = 0;

    for (int it = 0; it < nk; ++it) {
        if (it + 1 < nk) stage(cur ^ 1, kbeg + (it + 1) * 64);
        #pragma unroll
        for (int kk = 0; kk < 2; ++kk) {
            const int slotR = ((kk * 4) + fq) ^ (l & 7);
            short8 av[4], bv[TNF];
            #pragma unroll
            for (int m = 0; m < 4; ++m) {
                int r = wr * 64 + m * 16 + fr;
                av[m] = *(const short8*)((const char*)As[cur] + r * 128 + slotR * 16);
            }
            #pragma unroll
            for (int n = 0; n < TNF; ++n) {
                int r = wc * (TNF * 16) + n * 16 + fr;
                bv[n] = *(const short8*)((const char*)Bs[cur] + r * 128 + slotR * 16);
            }
            #pragma unroll
            for (int m = 0; m < 4; ++m)
                #pragma unroll
                for (int n = 0; n < TNF; ++n)
                    acc[m][n] = __builtin_amdgcn_mfma_f32_16x16x32_bf16(av[m], bv[n], acc[m][n], 0, 0, 0);
        }
        __syncthreads();
        cur ^= 1;
    }

    const float* residz = (flags & F_RESID) ? resid + zsR * bz : nullptr;
    const float* biasz  = (flags & F_BIAS)  ? bias + zsBias * bz : nullptr;
    float* cfz = Cf ? Cf + zsC * bz : nullptr;
    u16*   cbz = Cb ? Cb + zsC * bz : nullptr;

    #pragma unroll
    for (int m = 0; m < 4; ++m) {
        #pragma unroll
        for (int n = 0; n < TNF; ++n) {
            int gc = bn + wc * (TNF * 16) + n * 16 + fr;
            if (gc >= Ncols) continue;
            int gr0 = bm + wr * 64 + m * 16 + fq * 4;
            #pragma unroll
            for (int r = 0; r < 4; ++r) {
                int gr = gr0 + r;
                float v = acc[m][n][r];
                if (flags & F_BIAS)  v += biasz[gc];
                if (flags & F_SILU)  v = v / (1.f + expf(-v));
                if (flags & F_RESID) v += residz[(size_t)gr * ldr + gc];
                if (flags & F_OUTBF) cbz[(size_t)gr * ldc + gc] = f2b(v);
                else                 cfz[(size_t)gr * ldc + gc] = v;
            }
        }
    }
}

// ===================== split-K reduce (bf16 partials) + fused epilogue ==========
__global__ __launch_bounds__(256) void reduce_epi(
    const u16* __restrict__ part, size_t slice, int nsl,
    float* __restrict__ Cf, u16* __restrict__ Cb,
    const float* __restrict__ bias,
    const float* __restrict__ resid, int ldr,
    int M, int Ncols, int flags)
{
    if ((Ncols & 7) == 0) {
        size_t total8 = (size_t)M * Ncols / 8;
        for (size_t i8 = (size_t)blockIdx.x * 256 + threadIdx.x; i8 < total8;
             i8 += (size_t)gridDim.x * 256) {
            size_t i0 = i8 * 8;
            int r = (int)(i0 / (unsigned)Ncols);
            int c0 = (int)(i0 - (size_t)r * Ncols);
            float v[8] = {0,0,0,0,0,0,0,0};
            for (int s = 0; s < nsl; ++s) {
                const u16x4* p = (const u16x4*)(part + (size_t)s * slice + i0);
                u16x4 a = p[0], b = p[1];
                v[0] += b2f(a.x); v[1] += b2f(a.y); v[2] += b2f(a.z); v[3] += b2f(a.w);
                v[4] += b2f(b.x); v[5] += b2f(b.y); v[6] += b2f(b.z); v[7] += b2f(b.w);
            }
            #pragma unroll
            for (int j = 0; j < 8; ++j) {
                if (flags & F_BIAS) v[j] += bias[c0 + j];
                if (flags & F_SILU) v[j] = v[j] / (1.f + expf(-v[j]));
            }
            if (flags & F_RESID) {
                const float4* rp = (const float4*)(resid + (size_t)r * ldr + c0);
                float4 r0 = rp[0], r1 = rp[1];
                v[0] += r0.x; v[1] += r0.y; v[2] += r0.z; v[3] += r0.w;
                v[4] += r1.x; v[5] += r1.y; v[6] += r1.z; v[7] += r1.w;
            }
            if (flags & F_OUTBF) {
                short8 o;
                #pragma unroll
                for (int j = 0; j < 8; ++j) o[j] = (short)f2b(v[j]);
                *(short8*)(Cb + i0) = o;
            } else {
                float4 o0 = {v[0], v[1], v[2], v[3]}, o1 = {v[4], v[5], v[6], v[7]};
                float4* cp = (float4*)(Cf + i0);
                cp[0] = o0; cp[1] = o1;
            }
        }
    } else {
        size_t total = (size_t)M * Ncols;
        for (size_t i = (size_t)blockIdx.x * 256 + threadIdx.x; i < total;
             i += (size_t)gridDim.x * 256) {
            float v = 0.f;
            for (int s = 0; s < nsl; ++s) v += b2f(part[(size_t)s * slice + i]);
            if (flags & F_OUTBF) Cb[i] = f2b(v);
            else                 Cf[i] = v;
        }
    }
}

// ===== fused split-K reduce -> local update -> cond LayerNorm -> bf16 =====
__global__ __launch_bounds__(256) void reduce_cn(
    const u16* __restrict__ part, size_t slice, int nsl,
    const float* __restrict__ bias, const float* __restrict__ resid,
    float* __restrict__ locOut,
    const u16* __restrict__ cs, const u16* __restrict__ cb,
    u16* __restrict__ normB)
{
    int row = blockIdx.x, tid = threadIdx.x;
    size_t base = (size_t)row * 1024 + tid * 4;
    float v[4];
    {
        float4 rv = *(const float4*)(resid + base);
        v[0] = rv.x; v[1] = rv.y; v[2] = rv.z; v[3] = rv.w;
    }
    for (int s = 0; s < nsl; ++s) {
        u16x4 p = *(const u16x4*)(part + (size_t)s * slice + base);
        v[0] += b2f(p.x); v[1] += b2f(p.y); v[2] += b2f(p.z); v[3] += b2f(p.w);
    }
    {
        float4 bv = *(const float4*)(bias + tid * 4);
        v[0] += bv.x; v[1] += bv.y; v[2] += bv.z; v[3] += bv.w;
    }
    *(float4*)(locOut + base) = (float4){v[0], v[1], v[2], v[3]};

    float s1 = v[0] + v[1] + v[2] + v[3];
    float s2 = v[0]*v[0] + v[1]*v[1] + v[2]*v[2] + v[3]*v[3];
    __shared__ float r1[256], r2[256];
    r1[tid] = s1; r2[tid] = s2;
    __syncthreads();
    for (int st = 128; st > 0; st >>= 1) {
        if (tid < st) { r1[tid] += r1[tid + st]; r2[tid] += r2[tid + st]; }
        __syncthreads();
    }
    float mean = r1[0] * (1.f / 1024.f);
    float var = r2[0] * (1.f / 1024.f) - mean * mean;
    float rs = rsqrtf(var + 1e-5f);
    u16x4 sv = *(const u16x4*)(cs + base);
    u16x4 bv = *(const u16x4*)(cb + base);
    u16x4 o;
    o.x = f2b((1.f / (1.f + expf(-b2f(sv.x)))) * (v[0] - mean) * rs + b2f(bv.x));
    o.y = f2b((1.f / (1.f + expf(-b2f(sv.y)))) * (v[1] - mean) * rs + b2f(bv.y));
    o.z = f2b((1.f / (1.f + expf(-b2f(sv.z)))) * (v[2] - mean) * rs + b2f(bv.z));
    o.w = f2b((1.f / (1.f + expf(-b2f(sv.w)))) * (v[3] - mean) * rs + b2f(bv.w));
    *(u16x4*)(normB + base) = o;
}

// ===================== fused flash attention (split-KV=4, bf16 O partials) ========
__global__ __launch_bounds__(256, 2) void attn_kernel(
    const u16* __restrict__ qe, const u16* __restrict__ ke,
    const u16* __restrict__ vt, const float* __restrict__ pb,
    u16* __restrict__ Opart, float* __restrict__ mlpart)
{
    __shared__ u16 Ks[2][64 * 128];
    __shared__ u16 Vs[2][96 * 64];
    __shared__ u16 Ps[64 * 64];

    const int tid = threadIdx.x;
    const int l = tid & 63, w = tid >> 6;
    const int h = blockIdx.y;
    const int q0 = blockIdx.x * 64;
    const int z = blockIdx.z;
    const int fr = l & 15, fq = l >> 4;

    const u16* keh = ke + (size_t)h * NRES * 128;
    const u16* vth = vt + (size_t)h * 96 * NRES;

    const int kr4 = l >> 4, ks16 = l & 15;
    const int vr8 = l >> 3, vs8 = l & 7;

    short8 qv[4];
    {
        const u16* qrow = qe + ((size_t)h * NRES + (q0 + w * 16 + fr)) * 128 + fq * 8;
        #pragma unroll
        for (int kk = 0; kk < 4; ++kk)
            qv[kk] = *(const short8*)(qrow + kk * 32);
    }

    float m_run[4], l_run[4];
    f32x4 oacc[6];
    #pragma unroll
    for (int r = 0; r < 4; ++r) { m_run[r] = -1e30f; l_run[r] = 0.f; }
    #pragma unroll
    for (int n = 0; n < 6; ++n) oacc[n] = (f32x4){0.f, 0.f, 0.f, 0.f};

    const int NIT = NRES / 64 / KVS;
    const int jbase = z * (NRES / KVS);
    int cur = 0;

    auto stage = [&](int buf, int j0) {
        #pragma unroll
        for (int t = 0; t < 4; ++t) {
            int row = w * 16 + t * 4 + kr4;
            int ss = ks16 ^ (row & 7);
            __builtin_amdgcn_global_load_lds(
                (gvoid*)(keh + (size_t)(j0 + row) * 128 + ss * 8),
                (lvoid*)((char*)Ks[buf] + (w * 16 + t * 4) * 256), 16, 0, 0);
        }
        #pragma unroll
        for (int t = 0; t < 3; ++t) {
            int row = w * 24 + t * 8 + vr8;
            int ss = vs8 ^ (row & 7);
            __builtin_amdgcn_global_load_lds(
                (gvoid*)(vth + (size_t)row * NRES + j0 + ss * 8),
                (lvoid*)((char*)Vs[buf] + (w * 24 + t * 8) * 128), 16, 0, 0);
        }
    };
    const float* pbrow = pb + ((size_t)h * NRES + (q0 + w * 16 + fq * 4)) * NRES + fr;

    f32x4 pbv[4], pbn[4] = {};
    stage(0, jbase);
    #pragma unroll
    for (int n = 0; n < 4; ++n)
        #pragma unroll
        for (int r = 0; r < 4; ++r)
            pbv[n][r] = pbrow[(size_t)r * NRES + jbase + n * 16];
    __syncthreads();

    for (int it = 0; it < NIT; ++it) {
        if (it + 1 < NIT) {
            int j1 = jbase + (it + 1) * 64;
            stage(cur ^ 1, j1);
            #pragma unroll
            for (int n = 0; n < 4; ++n)
                #pragma unroll
                for (int r = 0; r < 4; ++r)
                    pbn[n][r] = pbrow[(size_t)r * NRES + j1 + n * 16];
        }

        f32x4 sacc[4];
        #pragma unroll
        for (int n = 0; n < 4; ++n) sacc[n] = (f32x4){0.f, 0.f, 0.f, 0.f};
        #pragma unroll
        for (int kk = 0; kk < 4; ++kk) {
            #pragma unroll
            for (int n = 0; n < 4; ++n) {
                int row = n * 16 + fr;
                short8 bv = *(const short8*)((const char*)Ks[cur] + row * 256
                                             + (((kk * 4 + fq) ^ (fr & 7)) * 16));
                sacc[n] = __builtin_amdgcn_mfma_f32_16x16x32_bf16(qv[kk], bv, sacc[n], 0, 0, 0);
            }
        }
        #pragma unroll
        for (int n = 0; n < 4; ++n) sacc[n] += pbv[n];

        float alpha[4];
        #pragma unroll
        for (int r = 0; r < 4; ++r) {
            float v = fmaxf(fmaxf(sacc[0][r], sacc[1][r]), fmaxf(sacc[2][r], sacc[3][r]));
            v = fmaxf(v, __shfl_xor(v, 1, 64));
            v = fmaxf(v, __shfl_xor(v, 2, 64));
            v = fmaxf(v, __shfl_xor(v, 4, 64));
            v = fmaxf(v, __shfl_xor(v, 8, 64));
            float mn = fmaxf(m_run[r], v);
            alpha[r] = exp2f((m_run[r] - mn) * LOG2E);
            m_run[r] = mn;
        }

        float psum[4] = {0.f, 0.f, 0.f, 0.f};
        #pragma unroll
        for (int n = 0; n < 4; ++n) {
            int col = n * 16 + fr;
            #pragma unroll
            for (int r = 0; r < 4; ++r) {
                float p = exp2f((sacc[n][r] - m_run[r]) * LOG2E);
                psum[r] += p;
                int rowf = w * 16 + fq * 4 + r;
                int byte = rowf * 128 + (((col >> 3) ^ (rowf & 7)) * 16) + (col & 7) * 2;
                *(u16*)((char*)Ps + byte) = f2b(p);
            }
        }
        #pragma unroll
        for (int r = 0; r < 4; ++r) {
            float v = psum[r];
            v += __shfl_xor(v, 1, 64);
            v += __shfl_xor(v, 2, 64);
            v += __shfl_xor(v, 4, 64);
            v += __shfl_xor(v, 8, 64);
            l_run[r] = l_run[r] * alpha[r] + v;
        }
        #pragma unroll
        for (int n = 0; n < 6; ++n)
            #pragma unroll
            for (int r = 0; r < 4; ++r)
                oacc[n][r] *= alpha[r];

        #pragma unroll
        for (int kk = 0; kk < 2; ++kk) {
            int prow = w * 16 + fr;
            short8 pa = *(const short8*)((const char*)Ps + prow * 128
                                         + (((kk * 4 + fq) ^ (prow & 7)) * 16));
            #pragma unroll
            for (int n = 0; n < 6; ++n) {
                int vrow = n * 16 + fr;
                short8 vv = *(const short8*)((const char*)Vs[cur] + vrow * 128
                                             + (((kk * 4 + fq) ^ (fr & 7)) * 16));
                oacc[n] = __builtin_amdgcn_mfma_f32_16x16x32_bf16(pa, vv, oacc[n], 0, 0, 0);
            }
        }

        __syncthreads();
        cur ^= 1;
        #pragma unroll
        for (int n = 0; n < 4; ++n) pbv[n] = pbn[n];
    }

    u16* Oz = Opart + ((size_t)z * NH + h) * NRES * 96;
    #pragma unroll
    for (int n = 0; n < 6; ++n) {
        int c = n * 16 + fr;
        #pragma unroll
        for (int r = 0; r < 4; ++r) {
            int row = q0 + w * 16 + fq * 4 + r;
            Oz[(size_t)row * 96 + c] = f2b(oacc[n][r]);
        }
    }
    if (fr == 0) {
        float* mlz = mlpart + ((size_t)z * NH + h) * NRES * 2;
        #pragma unroll
        for (int r = 0; r < 4; ++r) {
            int row = q0 + w * 16 + fq * 4 + r;
            mlz[row * 2 + 0] = m_run[r];
            mlz[row * 2 + 1] = l_run[r];
        }
    }
}

// ========== fused combine(split-KV) + finalize -> featB (cat eliminated) ==========
__global__ __launch_bounds__(256) void combine_fin(
    const u16* __restrict__ Opart, const float* __restrict__ mlpart,
    const float* __restrict__ Rb, const float* __restrict__ tb,
    u16* __restrict__ featB)
{
    int idx = blockIdx.x * 256 + threadIdx.x;
    if (idx >= NRES * NH) return;
    int n = idx >> 4, h = idx & 15;

    float m[KVS], lv[KVS], wgt[KVS];
    float mm = -1e30f;
    #pragma unroll
    for (int s = 0; s < KVS; ++s) {
        size_t rr = ((size_t)s * NH + h) * NRES + n;
        m[s] = mlpart[rr * 2];
        lv[s] = mlpart[rr * 2 + 1];
        mm = fmaxf(mm, m[s]);
    }
    float ll = 0.f;
    #pragma unroll
    for (int s = 0; s < KVS; ++s) {
        wgt[s] = exp2f((m[s] - mm) * LOG2E);
        ll += lv[s] * wgt[s];
    }
    float inv = 1.f / ll;
    const u16* op[KVS];
    #pragma unroll
    for (int s = 0; s < KVS; ++s)
        op[s] = Opart + (((size_t)s * NH + h) * NRES + n) * 96;

    u16* fb = featB + (size_t)n * 1536;
    #pragma unroll
    for (int k = 0; k < 64; ++k) {
        float v = 0.f;
        #pragma unroll
        for (int s = 0; s < KVS; ++s) v += b2f(op[s][k]) * wgt[s];
        fb[h * 64 + k] = f2b(v * inv);
    }

    float R[9];
    #pragma unroll
    for (int a = 0; a < 9; ++a) R[a] = Rb[(size_t)n * 9 + a];
    float t0 = tb[(size_t)n * 3 + 0], t1 = tb[(size_t)n * 3 + 1], t2 = tb[(size_t)n * 3 + 2];
    #pragma unroll
    for (int p = 0; p < 8; ++p) {
        float d[3];
        #pragma unroll
        for (int dd = 0; dd < 3; ++dd) {
            int c = 64 + p * 3 + dd;
            float v = 0.f;
            #pragma unroll
            for (int s = 0; s < KVS; ++s) v += b2f(op[s][c]) * wgt[s];
            d[dd] = v * inv;
        }
        float x = d[0] - t0, y = d[1] - t1, z = d[2] - t2;
        float a0 = R[0] * x + R[3] * y + R[6] * z;
        float a1 = R[1] * x + R[4] * y + R[7] * z;
        float a2 = R[2] * x + R[5] * y + R[8] * z;
        fb[1024 + h * 24 + p * 3 + 0] = f2b(a0);
        fb[1024 + h * 24 + p * 3 + 1] = f2b(a1);
        fb[1024 + h * 24 + p * 3 + 2] = f2b(a2);
        fb[1408 + h * 8 + p] = f2b(sqrtf(a0 * a0 + a1 * a1 + a2 * a2 + 1e-8f));
    }
}

// ===================== batched transpose fp32 -> bf16 [N][K] =====================
struct TP9 { const float* p[9]; };

__global__ __launch_bounds__(256) void transpose_bz(
    TP9 tp, int ldi, size_t zsi,
    u16* __restrict__ out, int ldo, size_t zso, int K, int N, int nsrc)
{
    __shared__ float t[32][33];
    int z = blockIdx.z;
    const float* in = tp.p[(z < nsrc) ? z : 0] + zsi * ((z < nsrc) ? 0 : z);
    if (nsrc == 1) in = tp.p[0] + zsi * z;
    out += zso * z;
    int k0 = blockIdx.y * 32, n0 = blockIdx.x * 32;
    int tx = threadIdx.x & 31, ty = threadIdx.x >> 5;
    #pragma unroll
    for (int j = 0; j < 4; ++j) {
        int k = k0 + ty + j * 8;
        if (k < K && n0 + tx < N) t[ty + j * 8][tx] = in[(size_t)k * ldi + n0 + tx];
    }
    __syncthreads();
    #pragma unroll
    for (int j = 0; j < 4; ++j) {
        int n = n0 + ty + j * 8;
        int k = k0 + tx;
        if (n < N && k < K) out[(size_t)n * ldo + k] = f2b(t[tx][ty + j * 8]);
    }
}

// ===== vT pack: vt[h][96][NRES] from qkc (v cols) + vgt; zero rows 88..95 =====
__global__ __launch_bounds__(256) void vt_pack(
    const float* __restrict__ qkc, const float* __restrict__ vgt,
    u16* __restrict__ vt)
{
    __shared__ float t[32][33];
    int h = blockIdx.z, grp = blockIdx.y, n0 = blockIdx.x * 32;
    int tx = threadIdx.x & 31, ty = threadIdx.x >> 5;
    #pragma unroll
    for (int j = 0; j < 4; ++j) {
        int n = n0 + ty + j * 8;
        int c = grp * 32 + tx;
        float v = 0.f;
        if (c < 64) v = qkc[(size_t)n * LDQ + 2048 + h * 64 + c];
        else if (c < 88) v = vgt[(size_t)n * 384 + h * 24 + (c - 64)];
        t[ty + j * 8][tx] = v;
    }
    __syncthreads();
    #pragma unroll
    for (int j = 0; j < 4; ++j) {
        int r = grp * 32 + ty + j * 8;
        vt[((size_t)h * 96 + r) * NRES + n0 + tx] = f2b(t[tx][ty + j * 8]);
    }
}

// ===================== merged prologue =====================
// blocks: [0,16128) emb | [16128,16896) cond->bf16 | [16896,16902) frames
//         [16902,16906) bias_pack | [16906,16914) biasg_pack
__global__ __launch_bounds__(256) void prologue_kernel(
    const float* __restrict__ pos, const float* __restrict__ cond,
    const float* __restrict__ cn1_bs, const float* __restrict__ cn1_bb,
    const float* __restrict__ cn2_bs, const float* __restrict__ cn2_bb,
    const float* __restrict__ cn3_bs, const float* __restrict__ cn3_bb,
    const float* __restrict__ bg1, const float* __restrict__ bg2,
    float* __restrict__ Rb, float* __restrict__ tb,
    u16* __restrict__ emb, u16* __restrict__ condB,
    float* __restrict__ bias2, float* __restrict__ biasg)
{
    int b = blockIdx.x, tid = threadIdx.x;
    if (b < 16128) {
        int idx = b * 256 + tid;
        int f = idx & 63;
        int rest = idx >> 6;
        int coord = rest % 42;
        int n = rest / 42;
        float t = pos[(size_t)n * 42 + coord];
        const double l0 = -6.643856189774724;
        const double step = 14.643856189774724 / 63.0;
        float freq = exp2f((float)(l0 + f * step));
        float r = t * freq;
        size_t o = (size_t)n * 5376 + (size_t)coord * 128 + 2 * f;
        emb[o]     = f2b(sinf(r));
        emb[o + 1] = f2b(cosf(r));
    } else if (b < 16896) {
        int i = (b - 16128) * 256 + tid;
        size_t i0 = (size_t)i * 8;
        const float4* p = (const float4*)(cond + i0);
        float4 a = p[0], bb = p[1];
        short8 o;
        o[0]=(short)f2b(a.x); o[1]=(short)f2b(a.y); o[2]=(short)f2b(a.z); o[3]=(short)f2b(a.w);
        o[4]=(short)f2b(bb.x); o[5]=(short)f2b(bb.y); o[6]=(short)f2b(bb.z); o[7]=(short)f2b(bb.w);
        *(short8*)(condB + i0) = o;
    } else if (b < 16902) {
        int n = (b - 16896) * 256 + tid;
        if (n >= NRES) return;
        const float* p = pos + (size_t)n * 42;
        float nx = p[0], ny = p[1], nz = p[2];
        float cax = p[3], cay = p[4], caz = p[5];
        float cx = p[6], cy = p[7], cz = p[8];
        float v1x = cx - cax, v1y = cy - cay, v1z = cz - caz;
        float i1 = rsqrtf(v1x * v1x + v1y * v1y + v1z * v1z + 1e-8f);
        float e1x = v1x * i1, e1y = v1y * i1, e1z = v1z * i1;
        float v2x = nx - cax, v2y = ny - cay, v2z = nz - caz;
        float d = e1x * v2x + e1y * v2y + e1z * v2z;
        float wx = v2x - d * e1x, wy = v2y - d * e1y, wz = v2z - d * e1z;
        float i2 = rsqrtf(wx * wx + wy * wy + wz * wz + 1e-8f);
        float e2x = wx * i2, e2y = wy * i2, e2z = wz * i2;
        float e3x = e1y * e2z - e1z * e2y;
        float e3y = e1z * e2x - e1x * e2z;
        float e3z = e1x * e2y - e1y * e2x;
        float* R = Rb + (size_t)n * 9;
        R[0] = e1x; R[1] = e2x; R[2] = e3x;
        R[3] = e1y; R[4] = e2y; R[5] = e3y;
        R[6] = e1z; R[7] = e2z; R[8] = e3z;
        tb[(size_t)n * 3 + 0] = cax;
        tb[(size_t)n * 3 + 1] = cay;
        tb[(size_t)n * 3 + 2] = caz;
    } else if (b < 16906) {
        int i = (b - 16902) * 256 + tid;
        if (i >= 1024) return;
        bias2[i] = cn1_bs[i]; bias2[1024 + i] = cn1_bb[i]; bias2[2048 + i] = cn2_bs[i];
        bias2[3072 + i] = cn2_bb[i]; bias2[4096 + i] = cn3_bs[i]; bias2[5120 + i] = cn3_bb[i];
    } else {
        int i = (b - 16906) * 256 + tid;
        if (i >= 2048) return;
        biasg[i] = bg1[i]; biasg[2048 + i] = bg2[i];
    }
}

// ===== merged pack: qe/ke cols 0..63 + zeros (blocks<1536), points cols 64..88 =====
__global__ __launch_bounds__(256) void pack_attn(
    const float* __restrict__ qkc,
    const float* __restrict__ Rb, const float* __restrict__ tb,
    const float* __restrict__ gamma,
    u16* __restrict__ qe, u16* __restrict__ ke, float* __restrict__ vgt)
{
    int b = blockIdx.x;
    if (b < 1536) {
        int idx = b * 256 + threadIdx.x;
        int g = idx & 15;
        int t = idx >> 4;
        int n = t % NRES;
        int h = t / NRES;
        size_t o = ((size_t)h * NRES + n) * 128 + g * 8;
        if (g < 8) {
            const float4* q4 = (const float4*)(qkc + (size_t)n * LDQ + h * 64 + g * 8);
            const float4* k4 = (const float4*)(qkc + (size_t)n * LDQ + 1024 + h * 64 + g * 8);
            float4 qa = q4[0], qb2 = q4[1], ka = k4[0], kb2 = k4[1];
            short8 oq, ok;
            oq[0]=(short)f2b(0.125f*qa.x); oq[1]=(short)f2b(0.125f*qa.y);
            oq[2]=(short)f2b(0.125f*qa.z); oq[3]=(short)f2b(0.125f*qa.w);
            oq[4]=(short)f2b(0.125f*qb2.x); oq[5]=(short)f2b(0.125f*qb2.y);
            oq[6]=(short)f2b(0.125f*qb2.z); oq[7]=(short)f2b(0.125f*qb2.w);
            ok[0]=(short)f2b(ka.x); ok[1]=(short)f2b(ka.y); ok[2]=(short)f2b(ka.z); ok[3]=(short)f2b(ka.w);
            ok[4]=(short)f2b(kb2.x); ok[5]=(short)f2b(kb2.y); ok[6]=(short)f2b(kb2.z); ok[7]=(short)f2b(kb2.w);
            *(short8*)(qe + o) = oq;
            *(short8*)(ke + o) = ok;
        } else if (g >= 11) {
            short8 zz = {};
            *(short8*)(qe + o) = zz;
            *(short8*)(ke + o) = zz;
        }
        return;
    }
    int idx = (b - 1536) * 256 + threadIdx.x;
    if (idx >= NRES * NH) return;
    int n = idx >> 4, h = idx & 15;
    float R[9];
    #pragma unroll
    for (int a = 0; a < 9; ++a) R[a] = Rb[(size_t)n * 9 + a];
    float t0 = tb[(size_t)n * 3 + 0], t1 = tb[(size_t)n * 3 + 1], t2 = tb[(size_t)n * 3 + 2];
    float g = gamma[h];
    float sp = (g > 20.f) ? g : log1pf(expf(g));
    float ch = 0.5f * (1.f / 6.f) * sp;

    u16* qeh = qe + ((size_t)h * NRES + n) * 128;
    u16* keh = ke + ((size_t)h * NRES + n) * 128;
    const float* qp = qkc + (size_t)n * LDQ + 3072 + h * 24;
    const float* kp = qkc + (size_t)n * LDQ + 3456 + h * 24;
    const float* vp = qkc + (size_t)n * LDQ + 3840 + h * 24;
    float kn = 0.f;
    #pragma unroll
    for (int p = 0; p < 8; ++p) {
        {
            float x = qp[p*3], y = qp[p*3+1], z = qp[p*3+2];
            float g0 = R[0] * x + R[1] * y + R[2] * z + t0;
            float g1 = R[3] * x + R[4] * y + R[5] * z + t1;
            float g2 = R[6] * x + R[7] * y + R[8] * z + t2;
            qeh[64 + p * 3 + 0] = f2b(2.f * ch * g0);
            qeh[64 + p * 3 + 1] = f2b(2.f * ch * g1);
            qeh[64 + p * 3 + 2] = f2b(2.f * ch * g2);
        }
        {
            float x = kp[p*3], y = kp[p*3+1], z = kp[p*3+2];
            float g0 = R[0] * x + R[1] * y + R[2] * z + t0;
            float g1 = R[3] * x + R[4] * y + R[5] * z + t1;
            float g2 = R[6] * x + R[7] * y + R[8] * z + t2;
            keh[64 + p * 3 + 0] = f2b(g0);
            keh[64 + p * 3 + 1] = f2b(g1);
            keh[64 + p * 3 + 2] = f2b(g2);
            kn += g0 * g0 + g1 * g1 + g2 * g2;
        }
        {
            float x = vp[p*3], y = vp[p*3+1], z = vp[p*3+2];
            vgt[(size_t)n * 384 + h * 24 + p * 3 + 0] = R[0] * x + R[1] * y + R[2] * z + t0;
            vgt[(size_t)n * 384 + h * 24 + p * 3 + 1] = R[3] * x + R[4] * y + R[5] * z + t1;
            vgt[(size_t)n * 384 + h * 24 + p * 3 + 2] = R[6] * x + R[7] * y + R[8] * z + t2;
        }
    }
    qeh[88] = f2b(1.0f);
    keh[88] = f2b(-ch * kn);
}

// gm = silu(g1) * g2, 8-wide
__global__ __launch_bounds__(256) void glu_kernel(const u16* __restrict__ g12, u16* __restrict__ gm)
{
    int i = blockIdx.x * 256 + threadIdx.x;
    if (i >= NRES * 2048 / 8) return;
    size_t i0 = (size_t)i * 8;
    short8 a8 = *(const short8*)(g12 + i0);
    short8 b8 = *(const short8*)(g12 + (size_t)NRES * 2048 + i0);
    short8 o;
    #pragma unroll
    for (int j = 0; j < 8; ++j) {
        float a = b2f((u16)a8[j]);
        float b = b2f((u16)b8[j]);
        float s = a / (1.f + expf(-a));
        o[j] = (short)f2b(s * b);
    }
    *(short8*)(gm + i0) = o;
}

// ========================= host =========================
extern "C" void kernel_launch(void* const* d_in, const int* in_sizes, int n_in,
                              void* d_out, int out_size, void* d_ws, size_t ws_size,
                              hipStream_t stream)
{
    const float* local_in = (const float*)d_in[0];
    const float* pos      = (const float*)d_in[1];
    const float* cond     = (const float*)d_in[2];
    const float* pb       = (const float*)d_in[4];
    const float* w_f1     = (const float*)d_in[5];
    const float* b_f1     = (const float*)d_in[6];
    const float* w_f2     = (const float*)d_in[7];
    const float* b_f2     = (const float*)d_in[8];
    const float* cn1_ws   = (const float*)d_in[9];
    const float* cn1_bs   = (const float*)d_in[10];
    const float* cn1_wb   = (const float*)d_in[11];
    const float* cn1_bb   = (const float*)d_in[12];
    const float* wq       = (const float*)d_in[13];
    const float* wk       = (const float*)d_in[14];
    const float* wv       = (const float*)d_in[15];
    const float* wqp      = (const float*)d_in[16];
    const float* wkp      = (const float*)d_in[17];
    const float* wvp      = (const float*)d_in[18];
    const float* gamma    = (const float*)d_in[19];
    const float* wo       = (const float*)d_in[20];
    const float* bo       = (const float*)d_in[21];
    const float* cn2_ws   = (const float*)d_in[22];
    const float* cn2_bs   = (const float*)d_in[23];
    const float* cn2_wb   = (const float*)d_in[24];
    const float* cn2_bb   = (const float*)d_in[25];
    const float* wg1      = (const float*)d_in[26];
    const float* bg1      = (const float*)d_in[27];
    const float* wg2      = (const float*)d_in[28];
    const float* bg2      = (const float*)d_in[29];
    const float* wg3      = (const float*)d_in[30];
    const float* bg3      = (const float*)d_in[31];
    const float* cn3_ws   = (const float*)d_in[32];
    const float* cn3_bs   = (const float*)d_in[33];
    const float* cn3_wb   = (const float*)d_in[34];
    const float* cn3_bb   = (const float*)d_in[35];
    const float* w_vel    = (const float*)d_in[36];

    float* out = (float*)d_out;
    float* ws  = (float*)d_ws;

    size_t off = 0;
    auto alloc = [&](size_t nf) -> float* { float* p = ws + off; off += (nf + 7) & ~7ull; return p; };

    const size_t NN1 = (size_t)NRES * 1024;
    float* Rb    = alloc(NRES * 9);
    float* tb    = alloc(NRES * 3);
    float* loc   = alloc(NN1);
    u16*   cs6b  = (u16*)alloc(6 * NN1 / 2);
    u16*   condB = (u16*)alloc(NN1 / 2);
    u16*   normB = (u16*)alloc(NN1 / 2);
    float* bias2 = alloc(6 * 1024);
    float* biasg = alloc(2 * 2048);
    float* qkc   = alloc((size_t)NRES * LDQ);               // merged projection out (26 MB)
    float* vgt   = alloc((size_t)NRES * 384);
    u16*   qeB   = (u16*)alloc((size_t)NH * NRES * 128 / 2);
    u16*   keB   = (u16*)alloc((size_t)NH * NRES * 128 / 2);
    u16*   vTB   = (u16*)alloc((size_t)NH * 96 * NRES / 2);
    u16*   featB = (u16*)alloc((size_t)NRES * 1536 / 2);
    u16*   g1sB  = (u16*)alloc((size_t)NRES * 2048 / 2);
    u16*   gmB   = (u16*)alloc((size_t)NRES * 2048 / 2);
    u16*   cnT9  = (u16*)alloc((size_t)9 * 1024 * 1024 / 2);  // cn x6, wq, wk, wv
    u16*   ptsT  = (u16*)alloc((size_t)3 * 384 * 1024 / 2);   // contiguous after cnT9!
    u16*   wgT   = (u16*)alloc((size_t)2 * 2048 * 1024 / 2);
    u16*   wf1T  = (u16*)alloc((size_t)2048 * 5376 / 2);
    u16*   wf2T  = (u16*)alloc((size_t)1024 * 2048 / 2);
    u16*   woT   = (u16*)alloc((size_t)1024 * 1536 / 2);
    u16*   wg3T  = (u16*)alloc((size_t)1024 * 2048 / 2);
    u16*   wvT   = (u16*)alloc((size_t)42 * 1024 / 2 + 8);
    u16*   embB  = (u16*)alloc((size_t)NRES * 5376 / 2);
    u16*   hidB  = (u16*)alloc((size_t)NRES * 2048 / 2);
    u16*   pscr  = (u16*)alloc((size_t)2 * NRES * 2048 * 4 / 2);
    u16*   Opart = (u16*)alloc((size_t)KVS * NH * NRES * 96 / 2);
    float* mlprt = alloc((size_t)KVS * NH * NRES * 2);

    const float* nilf = nullptr;

    auto gemm = [&](int tnf, const u16* A, int lda, size_t zsA,
                    const u16* BT, int ldb, size_t zsB,
                    float* Cf, u16* Cb2, int ldc, size_t zsC,
                    const float* bias, size_t zsBias,
                    const float* resid, int ldr, size_t zsR,
                    int Nc, int Kd, int flags, int gz, int ksl) {
        int tn = tnf * 32;
        dim3 grid((Nc + tn - 1) / tn, NRES / 128, gz);
        if (tnf == 4)
            hipLaunchKernelGGL(gemm_t<4>, grid, dim3(256), 0, stream,
                               A, lda, zsA, BT, ldb, zsB, Cf, Cb2, ldc, zsC,
                               bias, zsBias, resid, ldr, zsR, Nc, Kd, flags, ksl);
        else
            hipLaunchKernelGGL(gemm_t<2>, grid, dim3(256), 0, stream,
                               A, lda, zsA, BT, ldb, zsB, Cf, Cb2, ldc, zsC,
                               bias, zsBias, resid, ldr, zsR, Nc, Kd, flags, ksl);
    };
    auto red = [&](const u16* part, size_t slice, int nsl, float* Cf, u16* Cb2,
                   const float* bias, const float* resid, int ldr, int Nc, int flags) {
        hipLaunchKernelGGL(reduce_epi, dim3(1024), dim3(256), 0, stream,
                           part, slice, nsl, Cf, Cb2, bias, resid, ldr, NRES, Nc, flags);
    };
    auto redcn = [&](const u16* part, size_t slice, int nsl,
                     const float* bias, const float* resid, float* locOut, int cnIdx) {
        hipLaunchKernelGGL(reduce_cn, dim3(NRES), dim3(256), 0, stream,
                           part, slice, nsl, bias, resid, locOut,
                           cs6b + (size_t)(2 * cnIdx) * NN1,
                           cs6b + (size_t)(2 * cnIdx + 1) * NN1, normB);
    };
    auto tpz = [&](TP9 tp, int ldi, int K, int N, u16* o, int ldo, size_t zso, int nsrc) {
        dim3 grid((N + 31) / 32, (K + 31) / 32, nsrc);
        hipLaunchKernelGGL(transpose_bz, grid, dim3(256), 0, stream, tp, ldi, (size_t)0, o, ldo, zso, K, N, nsrc);
    };
    auto tps = [&](const float* in, int ldi, size_t zsi, int K, int N, u16* o, int ldo, size_t zso, int gz) {
        dim3 grid((N + 31) / 32, (K + 31) / 32, gz);
        TP9 tp; tp.p[0] = in;
        hipLaunchKernelGGL(transpose_bz, grid, dim3(256), 0, stream, tp, ldi, zsi, o, ldo, zso, K, N, 1);
    };

    // ---- merged prologue (frames + emb + cond cast + bias packs) ----
    hipLaunchKernelGGL(prologue_kernel, dim3(16914), dim3(256), 0, stream,
                       pos, cond, cn1_bs, cn1_bb, cn2_bs, cn2_bb, cn3_bs, cn3_bb,
                       bg1, bg2, Rb, tb, embB, condB, bias2, biasg);

    // ---- weight transposes ----
    {
        TP9 t9; t9.p[0]=cn1_ws; t9.p[1]=cn1_wb; t9.p[2]=cn2_ws; t9.p[3]=cn2_wb;
        t9.p[4]=cn3_ws; t9.p[5]=cn3_wb; t9.p[6]=wq; t9.p[7]=wk; t9.p[8]=wv;
        tpz(t9, 1024, 1024, 1024, cnT9, 1024, (size_t)1024 * 1024, 9);
    }
    {
        TP9 t3; t3.p[0]=wqp; t3.p[1]=wkp; t3.p[2]=wvp;
        tpz(t3, 384, 1024, 384, ptsT, 1024, (size_t)384 * 1024, 3);
    }
    {
        TP9 t2; t2.p[0]=wg1; t2.p[1]=wg2;
        tpz(t2, 2048, 1024, 2048, wgT, 1024, (size_t)2048 * 1024, 2);
    }
    tps(w_f1, 2048, 0, 5376, 2048, wf1T, 5376, 0, 1);
    tps(w_f2, 1024, 0, 2048, 1024, wf2T, 2048, 0, 1);
    tps(wo,   1024, 0, 1536, 1024, woT,  1536, 0, 1);
    tps(wg3,  1024, 0, 2048, 1024, wg3T, 2048, 0, 1);
    tps(w_vel,  42, 0, 1024,   42, wvT,  1024, 0, 1);

    // ---- all 6 cond GEMMs (z=6, TN=64, bf16 out) ----
    gemm(2, condB, 1024, 0, cnT9, 1024, (size_t)1024 * 1024, nullptr, cs6b, 1024, NN1,
         bias2, 1024, nilf, 0, 0, 1024, 1024, F_BIAS | F_OUTBF, 6, 0);

    // ---- phase A: emb GEMM split-K=4, bf16 partials + reduce(silu->bf16) ----
    gemm(2, embB, 5376, 0, wf1T, 5376, 0, nullptr, pscr, 2048, (size_t)NRES * 2048,
         nilf, 0, nilf, 0, 0, 2048, 5376, F_OUTBF, 4, 1344);
    red(pscr, (size_t)NRES * 2048, 4, nullptr, hidB, b_f1, nilf, 0,
        2048, F_BIAS | F_SILU | F_OUTBF);
    gemm(2, hidB, 2048, 0, wf2T, 2048, 0, nullptr, pscr, 1024, NN1,
         nilf, 0, nilf, 0, 0, 1024, 2048, F_OUTBF, 4, 512);
    redcn(pscr, NN1, 4, b_f2, local_in, loc, 0);

    // ---- merged projections: [wq|wk|wv|wqp|wkp|wvp] -> qkc[1536][4224] (one launch) ----
    gemm(2, normB, 1024, 0, cnT9 + (size_t)6 * 1024 * 1024, 1024, 0,
         qkc, nullptr, LDQ, 0, nilf, 0, nilf, 0, 0, LDQ, 1024, 0, 1, 0);

    // ---- attention operands (merged pack + vT pack) ----
    hipLaunchKernelGGL(pack_attn, dim3(1536 + 96), dim3(256), 0, stream,
                       qkc, Rb, tb, gamma, qeB, keB, vgt);
    hipLaunchKernelGGL(vt_pack, dim3(NRES / 32, 3, NH), dim3(256), 0, stream,
                       qkc, vgt, vTB);

    // ---- fused attention (split-KV=4) + merged combine+finalize ----
    hipLaunchKernelGGL(attn_kernel, dim3(NRES / 64, NH, KVS), dim3(256), 0, stream,
                       qeB, keB, vTB, pb, Opart, mlprt);
    hipLaunchKernelGGL(combine_fin, dim3(96), dim3(256), 0, stream,
                       Opart, mlprt, Rb, tb, featB);

    // ---- local += feat @ wo + bo : split-K=4, fused reduce+condnorm2 ----
    gemm(2, featB, 1536, 0, woT, 1536, 0, nullptr, pscr, 1024, NN1,
         nilf, 0, nilf, 0, 0, 1024, 1536, F_OUTBF, 4, 384);
    redcn(pscr, NN1, 4, bo, loc, loc, 1);

    // ---- gated MLP ----
    gemm(2, normB, 1024, 0, wgT, 1024, (size_t)2048 * 1024, nullptr, g1sB, 2048, (size_t)NRES * 2048,
         biasg, 2048, nilf, 0, 0, 2048, 1024, F_BIAS | F_OUTBF, 2, 0);
    u16* gmO = embB;
    hipLaunchKernelGGL(glu_kernel, dim3((NRES * 2048 / 8 + 255) / 256), dim3(256), 0, stream, g1sB, gmO);
    gemm(2, gmO, 2048, 0, wg3T, 2048, 0, nullptr, pscr, 1024, NN1,
         nilf, 0, nilf, 0, 0, 1024, 2048, F_OUTBF, 4, 512);
    redcn(pscr, NN1, 4, bg3, loc, out, 2);

    // ---- velocity (split-K=8, bf16 partials) ----
    gemm(2, normB, 1024, 0, wvT, 1024, 0, nullptr, pscr, 42, (size_t)NRES * 42,
         nilf, 0, nilf, 0, 0, 42, 1024, F_OUTBF, 8, 128);
    red(pscr, (size_t)NRES * 42, 8, out + (size_t)NRES * 1024, nullptr,
        nilf, nilf, 0, 42, 0);
}

// Round 12
// 476.844 us; speedup vs baseline: 1.4749x; 1.0220x over previous
//
#include <hip/hip_runtime.h>
#include <hip/hip_bf16.h>
#include <math.h>

#define NRES 1536
#define NH 16
#define NNF 2359296ull    // NRES*NRES
#define LOG2E 1.44269504f
#define KVS 4             // split-KV ways
#define LDQ 4224          // merged projection C leading dim

typedef unsigned short u16;
typedef __attribute__((ext_vector_type(8))) short short8;
typedef __attribute__((ext_vector_type(4))) unsigned short u16x4;
typedef __attribute__((ext_vector_type(4))) float f32x4;

typedef const __attribute__((address_space(1))) void gvoid;
typedef __attribute__((address_space(3))) void lvoid;

__device__ __forceinline__ u16 f2b(float x){
    __hip_bfloat16 h = __float2bfloat16(x);
    return *reinterpret_cast<u16*>(&h);
}
__device__ __forceinline__ float b2f(u16 u){
    unsigned v = ((unsigned)u) << 16;
    return __uint_as_float(v);
}

// ===================== bf16 MFMA GEMM (dbuf, 1 barrier/K-step, XCD swizzle) ==========
#define F_BIAS  1
#define F_SILU  2
#define F_RESID 8
#define F_OUTBF 16

template<int TNF>
__global__ __launch_bounds__(256) void gemm_t(
    const u16* __restrict__ A, int lda, size_t zsA,
    const u16* __restrict__ BT, int ldb, size_t zsB,
    float* __restrict__ Cf, u16* __restrict__ Cb, int ldc, size_t zsC,
    const float* __restrict__ bias, size_t zsBias,
    const float* __restrict__ resid, int ldr, size_t zsR,
    int Ncols, int Kd, int flags, int ksl)
{
    constexpr int TN = TNF * 32;
    __shared__ u16 As[2][128 * 64];
    __shared__ u16 Bs[2][TN * 64];

    unsigned gx = gridDim.x, gy = gridDim.y;
    unsigned nb = gx * gy * gridDim.z;
    unsigned bid = (blockIdx.z * gy + blockIdx.y) * gx + blockIdx.x;
    if ((nb & 7u) == 0u) bid = (bid & 7u) * (nb >> 3) + (bid >> 3);
    const int bxi = bid % gx;
    const int byi = (bid / gx) % gy;
    const int bz  = bid / (gx * gy);

    const int tid = threadIdx.x;
    const int l = tid & 63, w = tid >> 6;
    const int bm = byi * 128, bn = bxi * TN;

    A  += zsA * bz;
    BT += zsB * bz;

    const int kbeg = ksl ? bz * ksl : 0;
    const int kend = ksl ? kbeg + ksl : Kd;
    const int nk = (kend - kbeg) >> 6;

    const int arow   = l >> 3;
    const int aslot  = l & 7;
    const int srcslt = aslot ^ arow;

    const u16* aBase[4];
    const u16* bBase[TN / 32];
    #pragma unroll
    for (int t = 0; t < 4; ++t) {
        int ra = bm + (w * 4 + t) * 8 + arow;
        aBase[t] = A + (size_t)ra * lda + srcslt * 8;
    }
    #pragma unroll
    for (int t = 0; t < TN / 32; ++t) {
        int rb = bn + (w * (TN / 32) + t) * 8 + arow;
        if (rb > Ncols - 1) rb = Ncols - 1;
        bBase[t] = BT + (size_t)rb * ldb + srcslt * 8;
    }

    const int wr = w >> 1, wc = w & 1;
    const int fr = l & 15;
    const int fq = l >> 4;

    f32x4 acc[4][TNF];
    #pragma unroll
    for (int i = 0; i < 4; ++i)
        #pragma unroll
        for (int j = 0; j < TNF; ++j) acc[i][j] = (f32x4){0.f, 0.f, 0.f, 0.f};

    auto stage = [&](int buf, int k0) {
        #pragma unroll
        for (int t = 0; t < 4; ++t)
            __builtin_amdgcn_global_load_lds((gvoid*)(aBase[t] + k0),
                (lvoid*)((char*)As[buf] + (w * 4 + t) * 1024), 16, 0, 0);
        #pragma unroll
        for (int t = 0; t < TN / 32; ++t)
            __builtin_amdgcn_global_load_lds((gvoid*)(bBase[t] + k0),
                (lvoid*)((char*)Bs[buf] + (w * (TN / 32) + t) * 1024), 16, 0, 0);
    };

    stage(0, kbeg);
    __syncthreads();
    int cur = 0;

    for (int it = 0; it < nk; ++it) {
        if (it + 1 < nk) stage(cur ^ 1, kbeg + (it + 1) * 64);
        #pragma unroll
        for (int kk = 0; kk < 2; ++kk) {
            const int slotR = ((kk * 4) + fq) ^ (l & 7);
            short8 av[4], bv[TNF];
            #pragma unroll
            for (int m = 0; m < 4; ++m) {
                int r = wr * 64 + m * 16 + fr;
                av[m] = *(const short8*)((const char*)As[cur] + r * 128 + slotR * 16);
            }
            #pragma unroll
            for (int n = 0; n < TNF; ++n) {
                int r = wc * (TNF * 16) + n * 16 + fr;
                bv[n] = *(const short8*)((const char*)Bs[cur] + r * 128 + slotR * 16);
            }
            #pragma unroll
            for (int m = 0; m < 4; ++m)
                #pragma unroll
                for (int n = 0; n < TNF; ++n)
                    acc[m][n] = __builtin_amdgcn_mfma_f32_16x16x32_bf16(av[m], bv[n], acc[m][n], 0, 0, 0);
        }
        __syncthreads();
        cur ^= 1;
    }

    const float* residz = (flags & F_RESID) ? resid + zsR * bz : nullptr;
    const float* biasz  = (flags & F_BIAS)  ? bias + zsBias * bz : nullptr;
    float* cfz = Cf ? Cf + zsC * bz : nullptr;
    u16*   cbz = Cb ? Cb + zsC * bz : nullptr;

    #pragma unroll
    for (int m = 0; m < 4; ++m) {
        #pragma unroll
        for (int n = 0; n < TNF; ++n) {
            int gc = bn + wc * (TNF * 16) + n * 16 + fr;
            if (gc >= Ncols) continue;
            int gr0 = bm + wr * 64 + m * 16 + fq * 4;
            #pragma unroll
            for (int r = 0; r < 4; ++r) {
                int gr = gr0 + r;
                float v = acc[m][n][r];
                if (flags & F_BIAS)  v += biasz[gc];
                if (flags & F_SILU)  v = v / (1.f + expf(-v));
                if (flags & F_RESID) v += residz[(size_t)gr * ldr + gc];
                if (flags & F_OUTBF) cbz[(size_t)gr * ldc + gc] = f2b(v);
                else                 cfz[(size_t)gr * ldc + gc] = v;
            }
        }
    }
}

// ===================== split-K reduce (bf16 partials) + fused epilogue ==========
__global__ __launch_bounds__(256) void reduce_epi(
    const u16* __restrict__ part, size_t slice, int nsl,
    float* __restrict__ Cf, u16* __restrict__ Cb,
    const float* __restrict__ bias,
    const float* __restrict__ resid, int ldr,
    int M, int Ncols, int flags)
{
    if ((Ncols & 7) == 0) {
        size_t total8 = (size_t)M * Ncols / 8;
        for (size_t i8 = (size_t)blockIdx.x * 256 + threadIdx.x; i8 < total8;
             i8 += (size_t)gridDim.x * 256) {
            size_t i0 = i8 * 8;
            int r = (int)(i0 / (unsigned)Ncols);
            int c0 = (int)(i0 - (size_t)r * Ncols);
            float v[8] = {0,0,0,0,0,0,0,0};
            for (int s = 0; s < nsl; ++s) {
                const u16x4* p = (const u16x4*)(part + (size_t)s * slice + i0);
                u16x4 a = p[0], b = p[1];
                v[0] += b2f(a.x); v[1] += b2f(a.y); v[2] += b2f(a.z); v[3] += b2f(a.w);
                v[4] += b2f(b.x); v[5] += b2f(b.y); v[6] += b2f(b.z); v[7] += b2f(b.w);
            }
            #pragma unroll
            for (int j = 0; j < 8; ++j) {
                if (flags & F_BIAS) v[j] += bias[c0 + j];
                if (flags & F_SILU) v[j] = v[j] / (1.f + expf(-v[j]));
            }
            if (flags & F_RESID) {
                const float4* rp = (const float4*)(resid + (size_t)r * ldr + c0);
                float4 r0 = rp[0], r1 = rp[1];
                v[0] += r0.x; v[1] += r0.y; v[2] += r0.z; v[3] += r0.w;
                v[4] += r1.x; v[5] += r1.y; v[6] += r1.z; v[7] += r1.w;
            }
            if (flags & F_OUTBF) {
                short8 o;
                #pragma unroll
                for (int j = 0; j < 8; ++j) o[j] = (short)f2b(v[j]);
                *(short8*)(Cb + i0) = o;
            } else {
                float4 o0 = {v[0], v[1], v[2], v[3]}, o1 = {v[4], v[5], v[6], v[7]};
                float4* cp = (float4*)(Cf + i0);
                cp[0] = o0; cp[1] = o1;
            }
        }
    } else {
        size_t total = (size_t)M * Ncols;
        for (size_t i = (size_t)blockIdx.x * 256 + threadIdx.x; i < total;
             i += (size_t)gridDim.x * 256) {
            float v = 0.f;
            for (int s = 0; s < nsl; ++s) v += b2f(part[(size_t)s * slice + i]);
            if (flags & F_OUTBF) Cb[i] = f2b(v);
            else                 Cf[i] = v;
        }
    }
}

// ===== fused split-K reduce -> local update -> cond LayerNorm -> bf16 =====
__global__ __launch_bounds__(256) void reduce_cn(
    const u16* __restrict__ part, size_t slice, int nsl,
    const float* __restrict__ bias, const float* __restrict__ resid,
    float* __restrict__ locOut,
    const u16* __restrict__ cs, const u16* __restrict__ cb,
    u16* __restrict__ normB)
{
    int row = blockIdx.x, tid = threadIdx.x;
    size_t base = (size_t)row * 1024 + tid * 4;
    float v[4];
    {
        float4 rv = *(const float4*)(resid + base);
        v[0] = rv.x; v[1] = rv.y; v[2] = rv.z; v[3] = rv.w;
    }
    for (int s = 0; s < nsl; ++s) {
        u16x4 p = *(const u16x4*)(part + (size_t)s * slice + base);
        v[0] += b2f(p.x); v[1] += b2f(p.y); v[2] += b2f(p.z); v[3] += b2f(p.w);
    }
    {
        float4 bv = *(const float4*)(bias + tid * 4);
        v[0] += bv.x; v[1] += bv.y; v[2] += bv.z; v[3] += bv.w;
    }
    *(float4*)(locOut + base) = (float4){v[0], v[1], v[2], v[3]};

    float s1 = v[0] + v[1] + v[2] + v[3];
    float s2 = v[0]*v[0] + v[1]*v[1] + v[2]*v[2] + v[3]*v[3];
    __shared__ float r1[256], r2[256];
    r1[tid] = s1; r2[tid] = s2;
    __syncthreads();
    for (int st = 128; st > 0; st >>= 1) {
        if (tid < st) { r1[tid] += r1[tid + st]; r2[tid] += r2[tid + st]; }
        __syncthreads();
    }
    float mean = r1[0] * (1.f / 1024.f);
    float var = r2[0] * (1.f / 1024.f) - mean * mean;
    float rs = rsqrtf(var + 1e-5f);
    u16x4 sv = *(const u16x4*)(cs + base);
    u16x4 bv = *(const u16x4*)(cb + base);
    u16x4 o;
    o.x = f2b((1.f / (1.f + expf(-b2f(sv.x)))) * (v[0] - mean) * rs + b2f(bv.x));
    o.y = f2b((1.f / (1.f + expf(-b2f(sv.y)))) * (v[1] - mean) * rs + b2f(bv.y));
    o.z = f2b((1.f / (1.f + expf(-b2f(sv.z)))) * (v[2] - mean) * rs + b2f(bv.z));
    o.w = f2b((1.f / (1.f + expf(-b2f(sv.w)))) * (v[3] - mean) * rs + b2f(bv.w));
    *(u16x4*)(normB + base) = o;
}

// ========== fused flash attention (split-KV=4, XCD-chunked swizzle, setprio) ==========
__global__ __launch_bounds__(256, 2) void attn_kernel(
    const u16* __restrict__ qe, const u16* __restrict__ ke,
    const u16* __restrict__ vt, const float* __restrict__ pb,
    u16* __restrict__ Opart, float* __restrict__ mlpart)
{
    __shared__ u16 Ks[2][64 * 128];
    __shared__ u16 Vs[2][96 * 64];
    __shared__ u16 Ps[64 * 64];

    // XCD-chunked bijective swizzle: 192 contiguous logical blocks per XCD
    // -> each XCD covers 8 complete (h,z) K/V tiles (1.4 MB, L2-resident)
    unsigned gx = gridDim.x, gy = gridDim.y;
    unsigned nb = gx * gy * gridDim.z;          // 1536, %8==0
    unsigned bid = (blockIdx.z * gy + blockIdx.y) * gx + blockIdx.x;
    bid = (bid & 7u) * (nb >> 3) + (bid >> 3);
    const int qx = bid % gx;
    const int h  = (bid / gx) % gy;
    const int z  = bid / (gx * gy);

    const int tid = threadIdx.x;
    const int l = tid & 63, w = tid >> 6;
    const int q0 = qx * 64;
    const int fr = l & 15, fq = l >> 4;

    const u16* keh = ke + (size_t)h * NRES * 128;
    const u16* vth = vt + (size_t)h * 96 * NRES;

    const int kr4 = l >> 4, ks16 = l & 15;
    const int vr8 = l >> 3, vs8 = l & 7;

    short8 qv[4];
    {
        const u16* qrow = qe + ((size_t)h * NRES + (q0 + w * 16 + fr)) * 128 + fq * 8;
        #pragma unroll
        for (int kk = 0; kk < 4; ++kk)
            qv[kk] = *(const short8*)(qrow + kk * 32);
    }

    float m_run[4], l_run[4];
    f32x4 oacc[6];
    #pragma unroll
    for (int r = 0; r < 4; ++r) { m_run[r] = -1e30f; l_run[r] = 0.f; }
    #pragma unroll
    for (int n = 0; n < 6; ++n) oacc[n] = (f32x4){0.f, 0.f, 0.f, 0.f};

    const int NIT = NRES / 64 / KVS;
    const int jbase = z * (NRES / KVS);
    int cur = 0;

    auto stage = [&](int buf, int j0) {
        #pragma unroll
        for (int t = 0; t < 4; ++t) {
            int row = w * 16 + t * 4 + kr4;
            int ss = ks16 ^ (row & 7);
            __builtin_amdgcn_global_load_lds(
                (gvoid*)(keh + (size_t)(j0 + row) * 128 + ss * 8),
                (lvoid*)((char*)Ks[buf] + (w * 16 + t * 4) * 256), 16, 0, 0);
        }
        #pragma unroll
        for (int t = 0; t < 3; ++t) {
            int row = w * 24 + t * 8 + vr8;
            int ss = vs8 ^ (row & 7);
            __builtin_amdgcn_global_load_lds(
                (gvoid*)(vth + (size_t)row * NRES + j0 + ss * 8),
                (lvoid*)((char*)Vs[buf] + (w * 24 + t * 8) * 128), 16, 0, 0);
        }
    };
    const float* pbrow = pb + ((size_t)h * NRES + (q0 + w * 16 + fq * 4)) * NRES + fr;

    f32x4 pbv[4], pbn[4] = {};
    stage(0, jbase);
    #pragma unroll
    for (int n = 0; n < 4; ++n)
        #pragma unroll
        for (int r = 0; r < 4; ++r)
            pbv[n][r] = pbrow[(size_t)r * NRES + jbase + n * 16];
    __syncthreads();

    for (int it = 0; it < NIT; ++it) {
        if (it + 1 < NIT) {
            int j1 = jbase + (it + 1) * 64;
            stage(cur ^ 1, j1);
            #pragma unroll
            for (int n = 0; n < 4; ++n)
                #pragma unroll
                for (int r = 0; r < 4; ++r)
                    pbn[n][r] = pbrow[(size_t)r * NRES + j1 + n * 16];
        }

        f32x4 sacc[4];
        #pragma unroll
        for (int n = 0; n < 4; ++n) sacc[n] = (f32x4){0.f, 0.f, 0.f, 0.f};
        __builtin_amdgcn_s_setprio(1);
        #pragma unroll
        for (int kk = 0; kk < 4; ++kk) {
            #pragma unroll
            for (int n = 0; n < 4; ++n) {
                int row = n * 16 + fr;
                short8 bv = *(const short8*)((const char*)Ks[cur] + row * 256
                                             + (((kk * 4 + fq) ^ (fr & 7)) * 16));
                sacc[n] = __builtin_amdgcn_mfma_f32_16x16x32_bf16(qv[kk], bv, sacc[n], 0, 0, 0);
            }
        }
        __builtin_amdgcn_s_setprio(0);
        #pragma unroll
        for (int n = 0; n < 4; ++n) sacc[n] += pbv[n];

        float alpha[4];
        #pragma unroll
        for (int r = 0; r < 4; ++r) {
            float v = fmaxf(fmaxf(sacc[0][r], sacc[1][r]), fmaxf(sacc[2][r], sacc[3][r]));
            v = fmaxf(v, __shfl_xor(v, 1, 64));
            v = fmaxf(v, __shfl_xor(v, 2, 64));
            v = fmaxf(v, __shfl_xor(v, 4, 64));
            v = fmaxf(v, __shfl_xor(v, 8, 64));
            float mn = fmaxf(m_run[r], v);
            alpha[r] = exp2f((m_run[r] - mn) * LOG2E);
            m_run[r] = mn;
        }

        float psum[4] = {0.f, 0.f, 0.f, 0.f};
        #pragma unroll
        for (int n = 0; n < 4; ++n) {
            int col = n * 16 + fr;
            #pragma unroll
            for (int r = 0; r < 4; ++r) {
                float p = exp2f((sacc[n][r] - m_run[r]) * LOG2E);
                psum[r] += p;
                int rowf = w * 16 + fq * 4 + r;
                int byte = rowf * 128 + (((col >> 3) ^ (rowf & 7)) * 16) + (col & 7) * 2;
                *(u16*)((char*)Ps + byte) = f2b(p);
            }
        }
        #pragma unroll
        for (int r = 0; r < 4; ++r) {
            float v = psum[r];
            v += __shfl_xor(v, 1, 64);
            v += __shfl_xor(v, 2, 64);
            v += __shfl_xor(v, 4, 64);
            v += __shfl_xor(v, 8, 64);
            l_run[r] = l_run[r] * alpha[r] + v;
        }
        #pragma unroll
        for (int n = 0; n < 6; ++n)
            #pragma unroll
            for (int r = 0; r < 4; ++r)
                oacc[n][r] *= alpha[r];

        __builtin_amdgcn_s_setprio(1);
        #pragma unroll
        for (int kk = 0; kk < 2; ++kk) {
            int prow = w * 16 + fr;
            short8 pa = *(const short8*)((const char*)Ps + prow * 128
                                         + (((kk * 4 + fq) ^ (prow & 7)) * 16));
            #pragma unroll
            for (int n = 0; n < 6; ++n) {
                int vrow = n * 16 + fr;
                short8 vv = *(const short8*)((const char*)Vs[cur] + vrow * 128
                                             + (((kk * 4 + fq) ^ (fr & 7)) * 16));
                oacc[n] = __builtin_amdgcn_mfma_f32_16x16x32_bf16(pa, vv, oacc[n], 0, 0, 0);
            }
        }
        __builtin_amdgcn_s_setprio(0);

        __syncthreads();
        cur ^= 1;
        #pragma unroll
        for (int n = 0; n < 4; ++n) pbv[n] = pbn[n];
    }

    u16* Oz = Opart + ((size_t)z * NH + h) * NRES * 96;
    #pragma unroll
    for (int n = 0; n < 6; ++n) {
        int c = n * 16 + fr;
        #pragma unroll
        for (int r = 0; r < 4; ++r) {
            int row = q0 + w * 16 + fq * 4 + r;
            Oz[(size_t)row * 96 + c] = f2b(oacc[n][r]);
        }
    }
    if (fr == 0) {
        float* mlz = mlpart + ((size_t)z * NH + h) * NRES * 2;
        #pragma unroll
        for (int r = 0; r < 4; ++r) {
            int row = q0 + w * 16 + fq * 4 + r;
            mlz[row * 2 + 0] = m_run[r];
            mlz[row * 2 + 1] = l_run[r];
        }
    }
}

// ========== fused combine(split-KV) + finalize -> featB ==========
__global__ __launch_bounds__(256) void combine_fin(
    const u16* __restrict__ Opart, const float* __restrict__ mlpart,
    const float* __restrict__ Rb, const float* __restrict__ tb,
    u16* __restrict__ featB)
{
    int idx = blockIdx.x * 256 + threadIdx.x;
    if (idx >= NRES * NH) return;
    int n = idx >> 4, h = idx & 15;

    float m[KVS], lv[KVS], wgt[KVS];
    float mm = -1e30f;
    #pragma unroll
    for (int s = 0; s < KVS; ++s) {
        size_t rr = ((size_t)s * NH + h) * NRES + n;
        m[s] = mlpart[rr * 2];
        lv[s] = mlpart[rr * 2 + 1];
        mm = fmaxf(mm, m[s]);
    }
    float ll = 0.f;
    #pragma unroll
    for (int s = 0; s < KVS; ++s) {
        wgt[s] = exp2f((m[s] - mm) * LOG2E);
        ll += lv[s] * wgt[s];
    }
    float inv = 1.f / ll;
    const u16* op[KVS];
    #pragma unroll
    for (int s = 0; s < KVS; ++s)
        op[s] = Opart + (((size_t)s * NH + h) * NRES + n) * 96;

    u16* fb = featB + (size_t)n * 1536;
    #pragma unroll
    for (int k = 0; k < 64; ++k) {
        float v = 0.f;
        #pragma unroll
        for (int s = 0; s < KVS; ++s) v += b2f(op[s][k]) * wgt[s];
        fb[h * 64 + k] = f2b(v * inv);
    }

    float R[9];
    #pragma unroll
    for (int a = 0; a < 9; ++a) R[a] = Rb[(size_t)n * 9 + a];
    float t0 = tb[(size_t)n * 3 + 0], t1 = tb[(size_t)n * 3 + 1], t2 = tb[(size_t)n * 3 + 2];
    #pragma unroll
    for (int p = 0; p < 8; ++p) {
        float d[3];
        #pragma unroll
        for (int dd = 0; dd < 3; ++dd) {
            int c = 64 + p * 3 + dd;
            float v = 0.f;
            #pragma unroll
            for (int s = 0; s < KVS; ++s) v += b2f(op[s][c]) * wgt[s];
            d[dd] = v * inv;
        }
        float x = d[0] - t0, y = d[1] - t1, z = d[2] - t2;
        float a0 = R[0] * x + R[3] * y + R[6] * z;
        float a1 = R[1] * x + R[4] * y + R[7] * z;
        float a2 = R[2] * x + R[5] * y + R[8] * z;
        fb[1024 + h * 24 + p * 3 + 0] = f2b(a0);
        fb[1024 + h * 24 + p * 3 + 1] = f2b(a1);
        fb[1024 + h * 24 + p * 3 + 2] = f2b(a2);
        fb[1408 + h * 8 + p] = f2b(sqrtf(a0 * a0 + a1 * a1 + a2 * a2 + 1e-8f));
    }
}

// ===================== batched transpose fp32 -> bf16 [N][K] =====================
struct TP9 { const float* p[9]; };

__global__ __launch_bounds__(256) void transpose_bz(
    TP9 tp, int ldi, size_t zsi,
    u16* __restrict__ out, int ldo, size_t zso, int K, int N, int nsrc)
{
    __shared__ float t[32][33];
    int z = blockIdx.z;
    const float* in = tp.p[(z < nsrc) ? z : 0] + zsi * ((z < nsrc) ? 0 : z);
    if (nsrc == 1) in = tp.p[0] + zsi * z;
    out += zso * z;
    int k0 = blockIdx.y * 32, n0 = blockIdx.x * 32;
    int tx = threadIdx.x & 31, ty = threadIdx.x >> 5;
    #pragma unroll
    for (int j = 0; j < 4; ++j) {
        int k = k0 + ty + j * 8;
        if (k < K && n0 + tx < N) t[ty + j * 8][tx] = in[(size_t)k * ldi + n0 + tx];
    }
    __syncthreads();
    #pragma unroll
    for (int j = 0; j < 4; ++j) {
        int n = n0 + ty + j * 8;
        int k = k0 + tx;
        if (n < N && k < K) out[(size_t)n * ldo + k] = f2b(t[tx][ty + j * 8]);
    }
}

// ===== vT pack: vt[h][96][NRES] from qkc (v cols) + vgt; zero rows 88..95 =====
__global__ __launch_bounds__(256) void vt_pack(
    const float* __restrict__ qkc, const float* __restrict__ vgt,
    u16* __restrict__ vt)
{
    __shared__ float t[32][33];
    int h = blockIdx.z, grp = blockIdx.y, n0 = blockIdx.x * 32;
    int tx = threadIdx.x & 31, ty = threadIdx.x >> 5;
    #pragma unroll
    for (int j = 0; j < 4; ++j) {
        int n = n0 + ty + j * 8;
        int c = grp * 32 + tx;
        float v = 0.f;
        if (c < 64) v = qkc[(size_t)n * LDQ + 2048 + h * 64 + c];
        else if (c < 88) v = vgt[(size_t)n * 384 + h * 24 + (c - 64)];
        t[ty + j * 8][tx] = v;
    }
    __syncthreads();
    #pragma unroll
    for (int j = 0; j < 4; ++j) {
        int r = grp * 32 + ty + j * 8;
        vt[((size_t)h * 96 + r) * NRES + n0 + tx] = f2b(t[tx][ty + j * 8]);
    }
}

// ===================== merged prologue =====================
__global__ __launch_bounds__(256) void prologue_kernel(
    const float* __restrict__ pos, const float* __restrict__ cond,
    const float* __restrict__ cn1_bs, const float* __restrict__ cn1_bb,
    const float* __restrict__ cn2_bs, const float* __restrict__ cn2_bb,
    const float* __restrict__ cn3_bs, const float* __restrict__ cn3_bb,
    const float* __restrict__ bg1, const float* __restrict__ bg2,
    float* __restrict__ Rb, float* __restrict__ tb,
    u16* __restrict__ emb, u16* __restrict__ condB,
    float* __restrict__ bias2, float* __restrict__ biasg)
{
    int b = blockIdx.x, tid = threadIdx.x;
    if (b < 16128) {
        int idx = b * 256 + tid;
        int f = idx & 63;
        int rest = idx >> 6;
        int coord = rest % 42;
        int n = rest / 42;
        float t = pos[(size_t)n * 42 + coord];
        const double l0 = -6.643856189774724;
        const double step = 14.643856189774724 / 63.0;
        float freq = exp2f((float)(l0 + f * step));
        float r = t * freq;
        size_t o = (size_t)n * 5376 + (size_t)coord * 128 + 2 * f;
        emb[o]     = f2b(sinf(r));
        emb[o + 1] = f2b(cosf(r));
    } else if (b < 16896) {
        int i = (b - 16128) * 256 + tid;
        size_t i0 = (size_t)i * 8;
        const float4* p = (const float4*)(cond + i0);
        float4 a = p[0], bb = p[1];
        short8 o;
        o[0]=(short)f2b(a.x); o[1]=(short)f2b(a.y); o[2]=(short)f2b(a.z); o[3]=(short)f2b(a.w);
        o[4]=(short)f2b(bb.x); o[5]=(short)f2b(bb.y); o[6]=(short)f2b(bb.z); o[7]=(short)f2b(bb.w);
        *(short8*)(condB + i0) = o;
    } else if (b < 16902) {
        int n = (b - 16896) * 256 + tid;
        if (n >= NRES) return;
        const float* p = pos + (size_t)n * 42;
        float nx = p[0], ny = p[1], nz = p[2];
        float cax = p[3], cay = p[4], caz = p[5];
        float cx = p[6], cy = p[7], cz = p[8];
        float v1x = cx - cax, v1y = cy - cay, v1z = cz - caz;
        float i1 = rsqrtf(v1x * v1x + v1y * v1y + v1z * v1z + 1e-8f);
        float e1x = v1x * i1, e1y = v1y * i1, e1z = v1z * i1;
        float v2x = nx - cax, v2y = ny - cay, v2z = nz - caz;
        float d = e1x * v2x + e1y * v2y + e1z * v2z;
        float wx = v2x - d * e1x, wy = v2y - d * e1y, wz = v2z - d * e1z;
        float i2 = rsqrtf(wx * wx + wy * wy + wz * wz + 1e-8f);
        float e2x = wx * i2, e2y = wy * i2, e2z = wz * i2;
        float e3x = e1y * e2z - e1z * e2y;
        float e3y = e1z * e2x - e1x * e2z;
        float e3z = e1x * e2y - e1y * e2x;
        float* R = Rb + (size_t)n * 9;
        R[0] = e1x; R[1] = e2x; R[2] = e3x;
        R[3] = e1y; R[4] = e2y; R[5] = e3y;
        R[6] = e1z; R[7] = e2z; R[8] = e3z;
        tb[(size_t)n * 3 + 0] = cax;
        tb[(size_t)n * 3 + 1] = cay;
        tb[(size_t)n * 3 + 2] = caz;
    } else if (b < 16906) {
        int i = (b - 16902) * 256 + tid;
        if (i >= 1024) return;
        bias2[i] = cn1_bs[i]; bias2[1024 + i] = cn1_bb[i]; bias2[2048 + i] = cn2_bs[i];
        bias2[3072 + i] = cn2_bb[i]; bias2[4096 + i] = cn3_bs[i]; bias2[5120 + i] = cn3_bb[i];
    } else {
        int i = (b - 16906) * 256 + tid;
        if (i >= 2048) return;
        biasg[i] = bg1[i]; biasg[2048 + i] = bg2[i];
    }
}

// ===== merged pack: qe/ke cols 0..63 + zeros (blocks<1536), points cols 64..88 =====
__global__ __launch_bounds__(256) void pack_attn(
    const float* __restrict__ qkc,
    const float* __restrict__ Rb, const float* __restrict__ tb,
    const float* __restrict__ gamma,
    u16* __restrict__ qe, u16* __restrict__ ke, float* __restrict__ vgt)
{
    int b = blockIdx.x;
    if (b < 1536) {
        int idx = b * 256 + threadIdx.x;
        int g = idx & 15;
        int t = idx >> 4;
        int n = t % NRES;
        int h = t / NRES;
        size_t o = ((size_t)h * NRES + n) * 128 + g * 8;
        if (g < 8) {
            const float4* q4 = (const float4*)(qkc + (size_t)n * LDQ + h * 64 + g * 8);
            const float4* k4 = (const float4*)(qkc + (size_t)n * LDQ + 1024 + h * 64 + g * 8);
            float4 qa = q4[0], qb2 = q4[1], ka = k4[0], kb2 = k4[1];
            short8 oq, ok;
            oq[0]=(short)f2b(0.125f*qa.x); oq[1]=(short)f2b(0.125f*qa.y);
            oq[2]=(short)f2b(0.125f*qa.z); oq[3]=(short)f2b(0.125f*qa.w);
            oq[4]=(short)f2b(0.125f*qb2.x); oq[5]=(short)f2b(0.125f*qb2.y);
            oq[6]=(short)f2b(0.125f*qb2.z); oq[7]=(short)f2b(0.125f*qb2.w);
            ok[0]=(short)f2b(ka.x); ok[1]=(short)f2b(ka.y); ok[2]=(short)f2b(ka.z); ok[3]=(short)f2b(ka.w);
            ok[4]=(short)f2b(kb2.x); ok[5]=(short)f2b(kb2.y); ok[6]=(short)f2b(kb2.z); ok[7]=(short)f2b(kb2.w);
            *(short8*)(qe + o) = oq;
            *(short8*)(ke + o) = ok;
        } else if (g >= 11) {
            short8 zz = {};
            *(short8*)(qe + o) = zz;
            *(short8*)(ke + o) = zz;
        }
        return;
    }
    int idx = (b - 1536) * 256 + threadIdx.x;
    if (idx >= NRES * NH) return;
    int n = idx >> 4, h = idx & 15;
    float R[9];
    #pragma unroll
    for (int a = 0; a < 9; ++a) R[a] = Rb[(size_t)n * 9 + a];
    float t0 = tb[(size_t)n * 3 + 0], t1 = tb[(size_t)n * 3 + 1], t2 = tb[(size_t)n * 3 + 2];
    float g = gamma[h];
    float sp = (g > 20.f) ? g : log1pf(expf(g));
    float ch = 0.5f * (1.f / 6.f) * sp;

    u16* qeh = qe + ((size_t)h * NRES + n) * 128;
    u16* keh = ke + ((size_t)h * NRES + n) * 128;
    const float* qp = qkc + (size_t)n * LDQ + 3072 + h * 24;
    const float* kp = qkc + (size_t)n * LDQ + 3456 + h * 24;
    const float* vp = qkc + (size_t)n * LDQ + 3840 + h * 24;
    float kn = 0.f;
    #pragma unroll
    for (int p = 0; p < 8; ++p) {
        {
            float x = qp[p*3], y = qp[p*3+1], z = qp[p*3+2];
            float g0 = R[0] * x + R[1] * y + R[2] * z + t0;
            float g1 = R[3] * x + R[4] * y + R[5] * z + t1;
            float g2 = R[6] * x + R[7] * y + R[8] * z + t2;
            qeh[64 + p * 3 + 0] = f2b(2.f * ch * g0);
            qeh[64 + p * 3 + 1] = f2b(2.f * ch * g1);
            qeh[64 + p * 3 + 2] = f2b(2.f * ch * g2);
        }
        {
            float x = kp[p*3], y = kp[p*3+1], z = kp[p*3+2];
            float g0 = R[0] * x + R[1] * y + R[2] * z + t0;
            float g1 = R[3] * x + R[4] * y + R[5] * z + t1;
            float g2 = R[6] * x + R[7] * y + R[8] * z + t2;
            keh[64 + p * 3 + 0] = f2b(g0);
            keh[64 + p * 3 + 1] = f2b(g1);
            keh[64 + p * 3 + 2] = f2b(g2);
            kn += g0 * g0 + g1 * g1 + g2 * g2;
        }
        {
            float x = vp[p*3], y = vp[p*3+1], z = vp[p*3+2];
            vgt[(size_t)n * 384 + h * 24 + p * 3 + 0] = R[0] * x + R[1] * y + R[2] * z + t0;
            vgt[(size_t)n * 384 + h * 24 + p * 3 + 1] = R[3] * x + R[4] * y + R[5] * z + t1;
            vgt[(size_t)n * 384 + h * 24 + p * 3 + 2] = R[6] * x + R[7] * y + R[8] * z + t2;
        }
    }
    qeh[88] = f2b(1.0f);
    keh[88] = f2b(-ch * kn);
}

// gm = silu(g1) * g2, 8-wide
__global__ __launch_bounds__(256) void glu_kernel(const u16* __restrict__ g12, u16* __restrict__ gm)
{
    int i = blockIdx.x * 256 + threadIdx.x;
    if (i >= NRES * 2048 / 8) return;
    size_t i0 = (size_t)i * 8;
    short8 a8 = *(const short8*)(g12 + i0);
    short8 b8 = *(const short8*)(g12 + (size_t)NRES * 2048 + i0);
    short8 o;
    #pragma unroll
    for (int j = 0; j < 8; ++j) {
        float a = b2f((u16)a8[j]);
        float b = b2f((u16)b8[j]);
        float s = a / (1.f + expf(-a));
        o[j] = (short)f2b(s * b);
    }
    *(short8*)(gm + i0) = o;
}

// ========================= host =========================
extern "C" void kernel_launch(void* const* d_in, const int* in_sizes, int n_in,
                              void* d_out, int out_size, void* d_ws, size_t ws_size,
                              hipStream_t stream)
{
    const float* local_in = (const float*)d_in[0];
    const float* pos      = (const float*)d_in[1];
    const float* cond     = (const float*)d_in[2];
    const float* pb       = (const float*)d_in[4];
    const float* w_f1     = (const float*)d_in[5];
    const float* b_f1     = (const float*)d_in[6];
    const float* w_f2     = (const float*)d_in[7];
    const float* b_f2     = (const float*)d_in[8];
    const float* cn1_ws   = (const float*)d_in[9];
    const float* cn1_bs   = (const float*)d_in[10];
    const float* cn1_wb   = (const float*)d_in[11];
    const float* cn1_bb   = (const float*)d_in[12];
    const float* wq       = (const float*)d_in[13];
    const float* wk       = (const float*)d_in[14];
    const float* wv       = (const float*)d_in[15];
    const float* wqp      = (const float*)d_in[16];
    const float* wkp      = (const float*)d_in[17];
    const float* wvp      = (const float*)d_in[18];
    const float* gamma    = (const float*)d_in[19];
    const float* wo       = (const float*)d_in[20];
    const float* bo       = (const float*)d_in[21];
    const float* cn2_ws   = (const float*)d_in[22];
    const float* cn2_bs   = (const float*)d_in[23];
    const float* cn2_wb   = (const float*)d_in[24];
    const float* cn2_bb   = (const float*)d_in[25];
    const float* wg1      = (const float*)d_in[26];
    const float* bg1      = (const float*)d_in[27];
    const float* wg2      = (const float*)d_in[28];
    const float* bg2      = (const float*)d_in[29];
    const float* wg3      = (const float*)d_in[30];
    const float* bg3      = (const float*)d_in[31];
    const float* cn3_ws   = (const float*)d_in[32];
    const float* cn3_bs   = (const float*)d_in[33];
    const float* cn3_wb   = (const float*)d_in[34];
    const float* cn3_bb   = (const float*)d_in[35];
    const float* w_vel    = (const float*)d_in[36];

    float* out = (float*)d_out;
    float* ws  = (float*)d_ws;

    size_t off = 0;
    auto alloc = [&](size_t nf) -> float* { float* p = ws + off; off += (nf + 7) & ~7ull; return p; };

    const size_t NN1 = (size_t)NRES * 1024;
    float* Rb    = alloc(NRES * 9);
    float* tb    = alloc(NRES * 3);
    float* loc   = alloc(NN1);
    u16*   cs6b  = (u16*)alloc(6 * NN1 / 2);
    u16*   condB = (u16*)alloc(NN1 / 2);
    u16*   normB = (u16*)alloc(NN1 / 2);
    float* bias2 = alloc(6 * 1024);
    float* biasg = alloc(2 * 2048);
    float* qkc   = alloc((size_t)NRES * LDQ);
    float* vgt   = alloc((size_t)NRES * 384);
    u16*   qeB   = (u16*)alloc((size_t)NH * NRES * 128 / 2);
    u16*   keB   = (u16*)alloc((size_t)NH * NRES * 128 / 2);
    u16*   vTB   = (u16*)alloc((size_t)NH * 96 * NRES / 2);
    u16*   featB = (u16*)alloc((size_t)NRES * 1536 / 2);
    u16*   g1sB  = (u16*)alloc((size_t)NRES * 2048 / 2);
    u16*   gmB   = (u16*)alloc((size_t)NRES * 2048 / 2);
    u16*   cnT9  = (u16*)alloc((size_t)9 * 1024 * 1024 / 2);
    u16*   ptsT  = (u16*)alloc((size_t)3 * 384 * 1024 / 2);
    u16*   wgT   = (u16*)alloc((size_t)2 * 2048 * 1024 / 2);
    u16*   wf1T  = (u16*)alloc((size_t)2048 * 5376 / 2);
    u16*   wf2T  = (u16*)alloc((size_t)1024 * 2048 / 2);
    u16*   woT   = (u16*)alloc((size_t)1024 * 1536 / 2);
    u16*   wg3T  = (u16*)alloc((size_t)1024 * 2048 / 2);
    u16*   wvT   = (u16*)alloc((size_t)42 * 1024 / 2 + 8);
    u16*   embB  = (u16*)alloc((size_t)NRES * 5376 / 2);
    u16*   hidB  = (u16*)alloc((size_t)NRES * 2048 / 2);
    u16*   pscr  = (u16*)alloc((size_t)2 * NRES * 2048 * 4 / 2);
    u16*   Opart = (u16*)alloc((size_t)KVS * NH * NRES * 96 / 2);
    float* mlprt = alloc((size_t)KVS * NH * NRES * 2);

    const float* nilf = nullptr;

    auto gemm = [&](int tnf, const u16* A, int lda, size_t zsA,
                    const u16* BT, int ldb, size_t zsB,
                    float* Cf, u16* Cb2, int ldc, size_t zsC,
                    const float* bias, size_t zsBias,
                    const float* resid, int ldr, size_t zsR,
                    int Nc, int Kd, int flags, int gz, int ksl) {
        int tn = tnf * 32;
        dim3 grid((Nc + tn - 1) / tn, NRES / 128, gz);
        if (tnf == 4)
            hipLaunchKernelGGL(gemm_t<4>, grid, dim3(256), 0, stream,
                               A, lda, zsA, BT, ldb, zsB, Cf, Cb2, ldc, zsC,
                               bias, zsBias, resid, ldr, zsR, Nc, Kd, flags, ksl);
        else
            hipLaunchKernelGGL(gemm_t<2>, grid, dim3(256), 0, stream,
                               A, lda, zsA, BT, ldb, zsB, Cf, Cb2, ldc, zsC,
                               bias, zsBias, resid, ldr, zsR, Nc, Kd, flags, ksl);
    };
    auto red = [&](const u16* part, size_t slice, int nsl, float* Cf, u16* Cb2,
                   const float* bias, const float* resid, int ldr, int Nc, int flags) {
        hipLaunchKernelGGL(reduce_epi, dim3(1024), dim3(256), 0, stream,
                           part, slice, nsl, Cf, Cb2, bias, resid, ldr, NRES, Nc, flags);
    };
    auto redcn = [&](const u16* part, size_t slice, int nsl,
                     const float* bias, const float* resid, float* locOut, int cnIdx) {
        hipLaunchKernelGGL(reduce_cn, dim3(NRES), dim3(256), 0, stream,
                           part, slice, nsl, bias, resid, locOut,
                           cs6b + (size_t)(2 * cnIdx) * NN1,
                           cs6b + (size_t)(2 * cnIdx + 1) * NN1, normB);
    };
    auto tpz = [&](TP9 tp, int ldi, int K, int N, u16* o, int ldo, size_t zso, int nsrc) {
        dim3 grid((N + 31) / 32, (K + 31) / 32, nsrc);
        hipLaunchKernelGGL(transpose_bz, grid, dim3(256), 0, stream, tp, ldi, (size_t)0, o, ldo, zso, K, N, nsrc);
    };
    auto tps = [&](const float* in, int ldi, size_t zsi, int K, int N, u16* o, int ldo, size_t zso, int gz) {
        dim3 grid((N + 31) / 32, (K + 31) / 32, gz);
        TP9 tp; tp.p[0] = in;
        hipLaunchKernelGGL(transpose_bz, grid, dim3(256), 0, stream, tp, ldi, zsi, o, ldo, zso, K, N, 1);
    };

    // ---- merged prologue ----
    hipLaunchKernelGGL(prologue_kernel, dim3(16914), dim3(256), 0, stream,
                       pos, cond, cn1_bs, cn1_bb, cn2_bs, cn2_bb, cn3_bs, cn3_bb,
                       bg1, bg2, Rb, tb, embB, condB, bias2, biasg);

    // ---- weight transposes ----
    {
        TP9 t9; t9.p[0]=cn1_ws; t9.p[1]=cn1_wb; t9.p[2]=cn2_ws; t9.p[3]=cn2_wb;
        t9.p[4]=cn3_ws; t9.p[5]=cn3_wb; t9.p[6]=wq; t9.p[7]=wk; t9.p[8]=wv;
        tpz(t9, 1024, 1024, 1024, cnT9, 1024, (size_t)1024 * 1024, 9);
    }
    {
        TP9 t3; t3.p[0]=wqp; t3.p[1]=wkp; t3.p[2]=wvp;
        tpz(t3, 384, 1024, 384, ptsT, 1024, (size_t)384 * 1024, 3);
    }
    {
        TP9 t2; t2.p[0]=wg1; t2.p[1]=wg2;
        tpz(t2, 2048, 1024, 2048, wgT, 1024, (size_t)2048 * 1024, 2);
    }
    tps(w_f1, 2048, 0, 5376, 2048, wf1T, 5376, 0, 1);
    tps(w_f2, 1024, 0, 2048, 1024, wf2T, 2048, 0, 1);
    tps(wo,   1024, 0, 1536, 1024, woT,  1536, 0, 1);
    tps(wg3,  1024, 0, 2048, 1024, wg3T, 2048, 0, 1);
    tps(w_vel,  42, 0, 1024,   42, wvT,  1024, 0, 1);

    // ---- all 6 cond GEMMs (z=6, TN=64, bf16 out) ----
    gemm(2, condB, 1024, 0, cnT9, 1024, (size_t)1024 * 1024, nullptr, cs6b, 1024, NN1,
         bias2, 1024, nilf, 0, 0, 1024, 1024, F_BIAS | F_OUTBF, 6, 0);

    // ---- phase A: emb GEMM split-K=4, bf16 partials + reduce(silu->bf16) ----
    gemm(2, embB, 5376, 0, wf1T, 5376, 0, nullptr, pscr, 2048, (size_t)NRES * 2048,
         nilf, 0, nilf, 0, 0, 2048, 5376, F_OUTBF, 4, 1344);
    red(pscr, (size_t)NRES * 2048, 4, nullptr, hidB, b_f1, nilf, 0,
        2048, F_BIAS | F_SILU | F_OUTBF);
    gemm(2, hidB, 2048, 0, wf2T, 2048, 0, nullptr, pscr, 1024, NN1,
         nilf, 0, nilf, 0, 0, 1024, 2048, F_OUTBF, 4, 512);
    redcn(pscr, NN1, 4, b_f2, local_in, loc, 0);

    // ---- merged projections ----
    gemm(2, normB, 1024, 0, cnT9 + (size_t)6 * 1024 * 1024, 1024, 0,
         qkc, nullptr, LDQ, 0, nilf, 0, nilf, 0, 0, LDQ, 1024, 0, 1, 0);

    // ---- attention operands ----
    hipLaunchKernelGGL(pack_attn, dim3(1536 + 96), dim3(256), 0, stream,
                       qkc, Rb, tb, gamma, qeB, keB, vgt);
    hipLaunchKernelGGL(vt_pack, dim3(NRES / 32, 3, NH), dim3(256), 0, stream,
                       qkc, vgt, vTB);

    // ---- fused attention (split-KV=4, XCD-chunked) + merged combine+finalize ----
    hipLaunchKernelGGL(attn_kernel, dim3(NRES / 64, NH, KVS), dim3(256), 0, stream,
                       qeB, keB, vTB, pb, Opart, mlprt);
    hipLaunchKernelGGL(combine_fin, dim3(96), dim3(256), 0, stream,
                       Opart, mlprt, Rb, tb, featB);

    // ---- local += feat @ wo + bo : split-K=4, fused reduce+condnorm2 ----
    gemm(2, featB, 1536, 0, woT, 1536, 0, nullptr, pscr, 1024, NN1,
         nilf, 0, nilf, 0, 0, 1024, 1536, F_OUTBF, 4, 384);
    redcn(pscr, NN1, 4, bo, loc, loc, 1);

    // ---- gated MLP ----
    gemm(2, normB, 1024, 0, wgT, 1024, (size_t)2048 * 1024, nullptr, g1sB, 2048, (size_t)NRES * 2048,
         biasg, 2048, nilf, 0, 0, 2048, 1024, F_BIAS | F_OUTBF, 2, 0);
    u16* gmO = embB;
    hipLaunchKernelGGL(glu_kernel, dim3((NRES * 2048 / 8 + 255) / 256), dim3(256), 0, stream, g1sB, gmO);
    gemm(2, gmO, 2048, 0, wg3T, 2048, 0, nullptr, pscr, 1024, NN1,
         nilf, 0, nilf, 0, 0, 1024, 2048, F_OUTBF, 4, 512);
    redcn(pscr, NN1, 4, bg3, loc, out, 2);

    // ---- velocity (split-K=8, bf16 partials) ----
    gemm(2, normB, 1024, 0, wvT, 1024, 0, nullptr, pscr, 42, (size_t)NRES * 42,
         nilf, 0, nilf, 0, 0, 42, 1024, F_OUTBF, 8, 128);
    red(pscr, (size_t)NRES * 42, 8, out + (size_t)NRES * 1024, nullptr,
        nilf, nilf, 0, 42, 0);
}

// Round 13
// 464.685 us; speedup vs baseline: 1.5135x; 1.0262x over previous
//
#include <hip/hip_runtime.h>
#include <hip/hip_bf16.h>
#include <math.h>

#define NRES 1536
#define NH 16
#define NNF 2359296ull    // NRES*NRES
#define LOG2E 1.44269504f
#define KVS 4             // split-KV ways
#define LDQ 4224          // merged projection C leading dim
#define NTPJ 19           // transpose jobs

typedef unsigned short u16;
typedef __attribute__((ext_vector_type(8))) short short8;
typedef __attribute__((ext_vector_type(4))) unsigned short u16x4;
typedef __attribute__((ext_vector_type(4))) float f32x4;

typedef const __attribute__((address_space(1))) void gvoid;
typedef __attribute__((address_space(3))) void lvoid;

__device__ __forceinline__ u16 f2b(float x){
    __hip_bfloat16 h = __float2bfloat16(x);
    return *reinterpret_cast<u16*>(&h);
}
__device__ __forceinline__ float b2f(u16 u){
    unsigned v = ((unsigned)u) << 16;
    return __uint_as_float(v);
}

// ===================== bf16 MFMA GEMM (dbuf, 1 barrier/K-step, XCD swizzle) ==========
#define F_BIAS  1
#define F_SILU  2
#define F_RESID 8
#define F_OUTBF 16

template<int TNF>
__global__ __launch_bounds__(256) void gemm_t(
    const u16* __restrict__ A, int lda, size_t zsA,
    const u16* __restrict__ BT, int ldb, size_t zsB,
    float* __restrict__ Cf, u16* __restrict__ Cb, int ldc, size_t zsC,
    const float* __restrict__ bias, size_t zsBias,
    const float* __restrict__ resid, int ldr, size_t zsR,
    int Ncols, int Kd, int flags, int ksl)
{
    constexpr int TN = TNF * 32;
    __shared__ u16 As[2][128 * 64];
    __shared__ u16 Bs[2][TN * 64];

    unsigned gx = gridDim.x, gy = gridDim.y;
    unsigned nb = gx * gy * gridDim.z;
    unsigned bid = (blockIdx.z * gy + blockIdx.y) * gx + blockIdx.x;
    if ((nb & 7u) == 0u) bid = (bid & 7u) * (nb >> 3) + (bid >> 3);
    const int bxi = bid % gx;
    const int byi = (bid / gx) % gy;
    const int bz  = bid / (gx * gy);

    const int tid = threadIdx.x;
    const int l = tid & 63, w = tid >> 6;
    const int bm = byi * 128, bn = bxi * TN;

    A  += zsA * bz;
    BT += zsB * bz;

    const int kbeg = ksl ? bz * ksl : 0;
    const int kend = ksl ? kbeg + ksl : Kd;
    const int nk = (kend - kbeg) >> 6;

    const int arow   = l >> 3;
    const int aslot  = l & 7;
    const int srcslt = aslot ^ arow;

    const u16* aBase[4];
    const u16* bBase[TN / 32];
    #pragma unroll
    for (int t = 0; t < 4; ++t) {
        int ra = bm + (w * 4 + t) * 8 + arow;
        aBase[t] = A + (size_t)ra * lda + srcslt * 8;
    }
    #pragma unroll
    for (int t = 0; t < TN / 32; ++t) {
        int rb = bn + (w * (TN / 32) + t) * 8 + arow;
        if (rb > Ncols - 1) rb = Ncols - 1;
        bBase[t] = BT + (size_t)rb * ldb + srcslt * 8;
    }

    const int wr = w >> 1, wc = w & 1;
    const int fr = l & 15;
    const int fq = l >> 4;

    f32x4 acc[4][TNF];
    #pragma unroll
    for (int i = 0; i < 4; ++i)
        #pragma unroll
        for (int j = 0; j < TNF; ++j) acc[i][j] = (f32x4){0.f, 0.f, 0.f, 0.f};

    auto stage = [&](int buf, int k0) {
        #pragma unroll
        for (int t = 0; t < 4; ++t)
            __builtin_amdgcn_global_load_lds((gvoid*)(aBase[t] + k0),
                (lvoid*)((char*)As[buf] + (w * 4 + t) * 1024), 16, 0, 0);
        #pragma unroll
        for (int t = 0; t < TN / 32; ++t)
            __builtin_amdgcn_global_load_lds((gvoid*)(bBase[t] + k0),
                (lvoid*)((char*)Bs[buf] + (w * (TN / 32) + t) * 1024), 16, 0, 0);
    };

    stage(0, kbeg);
    __syncthreads();
    int cur = 0;

    for (int it = 0; it < nk; ++it) {
        if (it + 1 < nk) stage(cur ^ 1, kbeg + (it + 1) * 64);
        #pragma unroll
        for (int kk = 0; kk < 2; ++kk) {
            const int slotR = ((kk * 4) + fq) ^ (l & 7);
            short8 av[4], bv[TNF];
            #pragma unroll
            for (int m = 0; m < 4; ++m) {
                int r = wr * 64 + m * 16 + fr;
                av[m] = *(const short8*)((const char*)As[cur] + r * 128 + slotR * 16);
            }
            #pragma unroll
            for (int n = 0; n < TNF; ++n) {
                int r = wc * (TNF * 16) + n * 16 + fr;
                bv[n] = *(const short8*)((const char*)Bs[cur] + r * 128 + slotR * 16);
            }
            #pragma unroll
            for (int m = 0; m < 4; ++m)
                #pragma unroll
                for (int n = 0; n < TNF; ++n)
                    acc[m][n] = __builtin_amdgcn_mfma_f32_16x16x32_bf16(av[m], bv[n], acc[m][n], 0, 0, 0);
        }
        __syncthreads();
        cur ^= 1;
    }

    const float* residz = (flags & F_RESID) ? resid + zsR * bz : nullptr;
    const float* biasz  = (flags & F_BIAS)  ? bias + zsBias * bz : nullptr;
    float* cfz = Cf ? Cf + zsC * bz : nullptr;
    u16*   cbz = Cb ? Cb + zsC * bz : nullptr;

    #pragma unroll
    for (int m = 0; m < 4; ++m) {
        #pragma unroll
        for (int n = 0; n < TNF; ++n) {
            int gc = bn + wc * (TNF * 16) + n * 16 + fr;
            if (gc >= Ncols) continue;
            int gr0 = bm + wr * 64 + m * 16 + fq * 4;
            #pragma unroll
            for (int r = 0; r < 4; ++r) {
                int gr = gr0 + r;
                float v = acc[m][n][r];
                if (flags & F_BIAS)  v += biasz[gc];
                if (flags & F_SILU)  v = v / (1.f + expf(-v));
                if (flags & F_RESID) v += residz[(size_t)gr * ldr + gc];
                if (flags & F_OUTBF) cbz[(size_t)gr * ldc + gc] = f2b(v);
                else                 cfz[(size_t)gr * ldc + gc] = v;
            }
        }
    }
}

// ===================== split-K reduce (bf16 partials) + fused epilogue ==========
__global__ __launch_bounds__(256) void reduce_epi(
    const u16* __restrict__ part, size_t slice, int nsl,
    float* __restrict__ Cf, u16* __restrict__ Cb,
    const float* __restrict__ bias,
    const float* __restrict__ resid, int ldr,
    int M, int Ncols, int flags)
{
    if ((Ncols & 7) == 0) {
        size_t total8 = (size_t)M * Ncols / 8;
        for (size_t i8 = (size_t)blockIdx.x * 256 + threadIdx.x; i8 < total8;
             i8 += (size_t)gridDim.x * 256) {
            size_t i0 = i8 * 8;
            int r = (int)(i0 / (unsigned)Ncols);
            int c0 = (int)(i0 - (size_t)r * Ncols);
            float v[8] = {0,0,0,0,0,0,0,0};
            for (int s = 0; s < nsl; ++s) {
                const u16x4* p = (const u16x4*)(part + (size_t)s * slice + i0);
                u16x4 a = p[0], b = p[1];
                v[0] += b2f(a.x); v[1] += b2f(a.y); v[2] += b2f(a.z); v[3] += b2f(a.w);
                v[4] += b2f(b.x); v[5] += b2f(b.y); v[6] += b2f(b.z); v[7] += b2f(b.w);
            }
            #pragma unroll
            for (int j = 0; j < 8; ++j) {
                if (flags & F_BIAS) v[j] += bias[c0 + j];
                if (flags & F_SILU) v[j] = v[j] / (1.f + expf(-v[j]));
            }
            if (flags & F_RESID) {
                const float4* rp = (const float4*)(resid + (size_t)r * ldr + c0);
                float4 r0 = rp[0], r1 = rp[1];
                v[0] += r0.x; v[1] += r0.y; v[2] += r0.z; v[3] += r0.w;
                v[4] += r1.x; v[5] += r1.y; v[6] += r1.z; v[7] += r1.w;
            }
            if (flags & F_OUTBF) {
                short8 o;
                #pragma unroll
                for (int j = 0; j < 8; ++j) o[j] = (short)f2b(v[j]);
                *(short8*)(Cb + i0) = o;
            } else {
                float4 o0 = {v[0], v[1], v[2], v[3]}, o1 = {v[4], v[5], v[6], v[7]};
                float4* cp = (float4*)(Cf + i0);
                cp[0] = o0; cp[1] = o1;
            }
        }
    } else {
        size_t total = (size_t)M * Ncols;
        for (size_t i = (size_t)blockIdx.x * 256 + threadIdx.x; i < total;
             i += (size_t)gridDim.x * 256) {
            float v = 0.f;
            for (int s = 0; s < nsl; ++s) v += b2f(part[(size_t)s * slice + i]);
            if (flags & F_OUTBF) Cb[i] = f2b(v);
            else                 Cf[i] = v;
        }
    }
}

// ===== fused split-K reduce -> local update -> cond LayerNorm -> bf16 =====
__global__ __launch_bounds__(256) void reduce_cn(
    const u16* __restrict__ part, size_t slice, int nsl,
    const float* __restrict__ bias, const float* __restrict__ resid,
    float* __restrict__ locOut,
    const u16* __restrict__ cs, const u16* __restrict__ cb,
    u16* __restrict__ normB)
{
    int row = blockIdx.x, tid = threadIdx.x;
    size_t base = (size_t)row * 1024 + tid * 4;
    float v[4];
    {
        float4 rv = *(const float4*)(resid + base);
        v[0] = rv.x; v[1] = rv.y; v[2] = rv.z; v[3] = rv.w;
    }
    for (int s = 0; s < nsl; ++s) {
        u16x4 p = *(const u16x4*)(part + (size_t)s * slice + base);
        v[0] += b2f(p.x); v[1] += b2f(p.y); v[2] += b2f(p.z); v[3] += b2f(p.w);
    }
    {
        float4 bv = *(const float4*)(bias + tid * 4);
        v[0] += bv.x; v[1] += bv.y; v[2] += bv.z; v[3] += bv.w;
    }
    *(float4*)(locOut + base) = (float4){v[0], v[1], v[2], v[3]};

    float s1 = v[0] + v[1] + v[2] + v[3];
    float s2 = v[0]*v[0] + v[1]*v[1] + v[2]*v[2] + v[3]*v[3];
    __shared__ float r1[256], r2[256];
    r1[tid] = s1; r2[tid] = s2;
    __syncthreads();
    for (int st = 128; st > 0; st >>= 1) {
        if (tid < st) { r1[tid] += r1[tid + st]; r2[tid] += r2[tid + st]; }
        __syncthreads();
    }
    float mean = r1[0] * (1.f / 1024.f);
    float var = r2[0] * (1.f / 1024.f) - mean * mean;
    float rs = rsqrtf(var + 1e-5f);
    u16x4 sv = *(const u16x4*)(cs + base);
    u16x4 bv = *(const u16x4*)(cb + base);
    u16x4 o;
    o.x = f2b((1.f / (1.f + expf(-b2f(sv.x)))) * (v[0] - mean) * rs + b2f(bv.x));
    o.y = f2b((1.f / (1.f + expf(-b2f(sv.y)))) * (v[1] - mean) * rs + b2f(bv.y));
    o.z = f2b((1.f / (1.f + expf(-b2f(sv.z)))) * (v[2] - mean) * rs + b2f(bv.z));
    o.w = f2b((1.f / (1.f + expf(-b2f(sv.w)))) * (v[3] - mean) * rs + b2f(bv.w));
    *(u16x4*)(normB + base) = o;
}

// ========== fused flash attention (split-KV=4, XCD-chunked swizzle, setprio) ==========
__global__ __launch_bounds__(256, 2) void attn_kernel(
    const u16* __restrict__ qe, const u16* __restrict__ ke,
    const u16* __restrict__ vt, const float* __restrict__ pb,
    u16* __restrict__ Opart, float* __restrict__ mlpart)
{
    __shared__ u16 Ks[2][64 * 128];
    __shared__ u16 Vs[2][96 * 64];
    __shared__ u16 Ps[64 * 64];

    unsigned gx = gridDim.x, gy = gridDim.y;
    unsigned nb = gx * gy * gridDim.z;          // 1536, %8==0
    unsigned bid = (blockIdx.z * gy + blockIdx.y) * gx + blockIdx.x;
    bid = (bid & 7u) * (nb >> 3) + (bid >> 3);
    const int qx = bid % gx;
    const int h  = (bid / gx) % gy;
    const int z  = bid / (gx * gy);

    const int tid = threadIdx.x;
    const int l = tid & 63, w = tid >> 6;
    const int q0 = qx * 64;
    const int fr = l & 15, fq = l >> 4;

    const u16* keh = ke + (size_t)h * NRES * 128;
    const u16* vth = vt + (size_t)h * 96 * NRES;

    const int kr4 = l >> 4, ks16 = l & 15;
    const int vr8 = l >> 3, vs8 = l & 7;

    short8 qv[4];
    {
        const u16* qrow = qe + ((size_t)h * NRES + (q0 + w * 16 + fr)) * 128 + fq * 8;
        #pragma unroll
        for (int kk = 0; kk < 4; ++kk)
            qv[kk] = *(const short8*)(qrow + kk * 32);
    }

    float m_run[4], l_run[4];
    f32x4 oacc[6];
    #pragma unroll
    for (int r = 0; r < 4; ++r) { m_run[r] = -1e30f; l_run[r] = 0.f; }
    #pragma unroll
    for (int n = 0; n < 6; ++n) oacc[n] = (f32x4){0.f, 0.f, 0.f, 0.f};

    const int NIT = NRES / 64 / KVS;
    const int jbase = z * (NRES / KVS);
    int cur = 0;

    auto stage = [&](int buf, int j0) {
        #pragma unroll
        for (int t = 0; t < 4; ++t) {
            int row = w * 16 + t * 4 + kr4;
            int ss = ks16 ^ (row & 7);
            __builtin_amdgcn_global_load_lds(
                (gvoid*)(keh + (size_t)(j0 + row) * 128 + ss * 8),
                (lvoid*)((char*)Ks[buf] + (w * 16 + t * 4) * 256), 16, 0, 0);
        }
        #pragma unroll
        for (int t = 0; t < 3; ++t) {
            int row = w * 24 + t * 8 + vr8;
            int ss = vs8 ^ (row & 7);
            __builtin_amdgcn_global_load_lds(
                (gvoid*)(vth + (size_t)row * NRES + j0 + ss * 8),
                (lvoid*)((char*)Vs[buf] + (w * 24 + t * 8) * 128), 16, 0, 0);
        }
    };
    const float* pbrow = pb + ((size_t)h * NRES + (q0 + w * 16 + fq * 4)) * NRES + fr;

    f32x4 pbv[4], pbn[4] = {};
    stage(0, jbase);
    #pragma unroll
    for (int n = 0; n < 4; ++n)
        #pragma unroll
        for (int r = 0; r < 4; ++r)
            pbv[n][r] = pbrow[(size_t)r * NRES + jbase + n * 16];
    __syncthreads();

    for (int it = 0; it < NIT; ++it) {
        if (it + 1 < NIT) {
            int j1 = jbase + (it + 1) * 64;
            stage(cur ^ 1, j1);
            #pragma unroll
            for (int n = 0; n < 4; ++n)
                #pragma unroll
                for (int r = 0; r < 4; ++r)
                    pbn[n][r] = pbrow[(size_t)r * NRES + j1 + n * 16];
        }

        f32x4 sacc[4];
        #pragma unroll
        for (int n = 0; n < 4; ++n) sacc[n] = (f32x4){0.f, 0.f, 0.f, 0.f};
        __builtin_amdgcn_s_setprio(1);
        #pragma unroll
        for (int kk = 0; kk < 4; ++kk) {
            #pragma unroll
            for (int n = 0; n < 4; ++n) {
                int row = n * 16 + fr;
                short8 bv = *(const short8*)((const char*)Ks[cur] + row * 256
                                             + (((kk * 4 + fq) ^ (fr & 7)) * 16));
                sacc[n] = __builtin_amdgcn_mfma_f32_16x16x32_bf16(qv[kk], bv, sacc[n], 0, 0, 0);
            }
        }
        __builtin_amdgcn_s_setprio(0);
        #pragma unroll
        for (int n = 0; n < 4; ++n) sacc[n] += pbv[n];

        float alpha[4];
        #pragma unroll
        for (int r = 0; r < 4; ++r) {
            float v = fmaxf(fmaxf(sacc[0][r], sacc[1][r]), fmaxf(sacc[2][r], sacc[3][r]));
            v = fmaxf(v, __shfl_xor(v, 1, 64));
            v = fmaxf(v, __shfl_xor(v, 2, 64));
            v = fmaxf(v, __shfl_xor(v, 4, 64));
            v = fmaxf(v, __shfl_xor(v, 8, 64));
            float mn = fmaxf(m_run[r], v);
            alpha[r] = exp2f((m_run[r] - mn) * LOG2E);
            m_run[r] = mn;
        }

        float psum[4] = {0.f, 0.f, 0.f, 0.f};
        #pragma unroll
        for (int n = 0; n < 4; ++n) {
            int col = n * 16 + fr;
            #pragma unroll
            for (int r = 0; r < 4; ++r) {
                float p = exp2f((sacc[n][r] - m_run[r]) * LOG2E);
                psum[r] += p;
                int rowf = w * 16 + fq * 4 + r;
                int byte = rowf * 128 + (((col >> 3) ^ (rowf & 7)) * 16) + (col & 7) * 2;
                *(u16*)((char*)Ps + byte) = f2b(p);
            }
        }
        #pragma unroll
        for (int r = 0; r < 4; ++r) {
            float v = psum[r];
            v += __shfl_xor(v, 1, 64);
            v += __shfl_xor(v, 2, 64);
            v += __shfl_xor(v, 4, 64);
            v += __shfl_xor(v, 8, 64);
            l_run[r] = l_run[r] * alpha[r] + v;
        }
        #pragma unroll
        for (int n = 0; n < 6; ++n)
            #pragma unroll
            for (int r = 0; r < 4; ++r)
                oacc[n][r] *= alpha[r];

        __builtin_amdgcn_s_setprio(1);
        #pragma unroll
        for (int kk = 0; kk < 2; ++kk) {
            int prow = w * 16 + fr;
            short8 pa = *(const short8*)((const char*)Ps + prow * 128
                                         + (((kk * 4 + fq) ^ (prow & 7)) * 16));
            #pragma unroll
            for (int n = 0; n < 6; ++n) {
                int vrow = n * 16 + fr;
                short8 vv = *(const short8*)((const char*)Vs[cur] + vrow * 128
                                             + (((kk * 4 + fq) ^ (fr & 7)) * 16));
                oacc[n] = __builtin_amdgcn_mfma_f32_16x16x32_bf16(pa, vv, oacc[n], 0, 0, 0);
            }
        }
        __builtin_amdgcn_s_setprio(0);

        __syncthreads();
        cur ^= 1;
        #pragma unroll
        for (int n = 0; n < 4; ++n) pbv[n] = pbn[n];
    }

    u16* Oz = Opart + ((size_t)z * NH + h) * NRES * 96;
    #pragma unroll
    for (int n = 0; n < 6; ++n) {
        int c = n * 16 + fr;
        #pragma unroll
        for (int r = 0; r < 4; ++r) {
            int row = q0 + w * 16 + fq * 4 + r;
            Oz[(size_t)row * 96 + c] = f2b(oacc[n][r]);
        }
    }
    if (fr == 0) {
        float* mlz = mlpart + ((size_t)z * NH + h) * NRES * 2;
        #pragma unroll
        for (int r = 0; r < 4; ++r) {
            int row = q0 + w * 16 + fq * 4 + r;
            mlz[row * 2 + 0] = m_run[r];
            mlz[row * 2 + 1] = l_run[r];
        }
    }
}

// ========== fused combine(split-KV) + finalize -> featB ==========
__global__ __launch_bounds__(256) void combine_fin(
    const u16* __restrict__ Opart, const float* __restrict__ mlpart,
    const float* __restrict__ Rb, const float* __restrict__ tb,
    u16* __restrict__ featB)
{
    int idx = blockIdx.x * 256 + threadIdx.x;
    if (idx >= NRES * NH) return;
    int n = idx >> 4, h = idx & 15;

    float m[KVS], lv[KVS], wgt[KVS];
    float mm = -1e30f;
    #pragma unroll
    for (int s = 0; s < KVS; ++s) {
        size_t rr = ((size_t)s * NH + h) * NRES + n;
        m[s] = mlpart[rr * 2];
        lv[s] = mlpart[rr * 2 + 1];
        mm = fmaxf(mm, m[s]);
    }
    float ll = 0.f;
    #pragma unroll
    for (int s = 0; s < KVS; ++s) {
        wgt[s] = exp2f((m[s] - mm) * LOG2E);
        ll += lv[s] * wgt[s];
    }
    float inv = 1.f / ll;
    const u16* op[KVS];
    #pragma unroll
    for (int s = 0; s < KVS; ++s)
        op[s] = Opart + (((size_t)s * NH + h) * NRES + n) * 96;

    u16* fb = featB + (size_t)n * 1536;
    #pragma unroll
    for (int k = 0; k < 64; ++k) {
        float v = 0.f;
        #pragma unroll
        for (int s = 0; s < KVS; ++s) v += b2f(op[s][k]) * wgt[s];
        fb[h * 64 + k] = f2b(v * inv);
    }

    float R[9];
    #pragma unroll
    for (int a = 0; a < 9; ++a) R[a] = Rb[(size_t)n * 9 + a];
    float t0 = tb[(size_t)n * 3 + 0], t1 = tb[(size_t)n * 3 + 1], t2 = tb[(size_t)n * 3 + 2];
    #pragma unroll
    for (int p = 0; p < 8; ++p) {
        float d[3];
        #pragma unroll
        for (int dd = 0; dd < 3; ++dd) {
            int c = 64 + p * 3 + dd;
            float v = 0.f;
            #pragma unroll
            for (int s = 0; s < KVS; ++s) v += b2f(op[s][c]) * wgt[s];
            d[dd] = v * inv;
        }
        float x = d[0] - t0, y = d[1] - t1, z = d[2] - t2;
        float a0 = R[0] * x + R[3] * y + R[6] * z;
        float a1 = R[1] * x + R[4] * y + R[7] * z;
        float a2 = R[2] * x + R[5] * y + R[8] * z;
        fb[1024 + h * 24 + p * 3 + 0] = f2b(a0);
        fb[1024 + h * 24 + p * 3 + 1] = f2b(a1);
        fb[1024 + h * 24 + p * 3 + 2] = f2b(a2);
        fb[1408 + h * 8 + p] = f2b(sqrtf(a0 * a0 + a1 * a1 + a2 * a2 + 1e-8f));
    }
}

// ===================== mega transpose: all weight transposes in ONE launch ==========
struct TpMega {
    const float* src[NTPJ];
    u16* dst[NTPJ];
    int ldi[NTPJ], ldo[NTPJ], K[NTPJ], N[NTPJ];
    int bx[NTPJ], start[NTPJ];
};

__global__ __launch_bounds__(256) void transpose_mega(TpMega J)
{
    __shared__ float t[32][33];
    int b = blockIdx.x;
    int j = NTPJ - 1;
    while (J.start[j] > b) --j;
    int lb = b - J.start[j];
    int bxn = J.bx[j];
    int n0 = (lb % bxn) * 32;
    int k0 = (lb / bxn) * 32;
    const float* in = J.src[j];
    u16* out = J.dst[j];
    int ldi = J.ldi[j], ldo = J.ldo[j], Kk = J.K[j], Nn = J.N[j];
    int tx = threadIdx.x & 31, ty = threadIdx.x >> 5;
    #pragma unroll
    for (int jj = 0; jj < 4; ++jj) {
        int k = k0 + ty + jj * 8;
        if (k < Kk && n0 + tx < Nn) t[ty + jj * 8][tx] = in[(size_t)k * ldi + n0 + tx];
    }
    __syncthreads();
    #pragma unroll
    for (int jj = 0; jj < 4; ++jj) {
        int n = n0 + ty + jj * 8;
        int k = k0 + tx;
        if (n < Nn && k < Kk) out[(size_t)n * ldo + k] = f2b(t[tx][ty + jj * 8]);
    }
}

// ===== vT pack: vt[h][96][NRES] from qkc (v cols) + vgt; zero rows 88..95 =====
__global__ __launch_bounds__(256) void vt_pack(
    const float* __restrict__ qkc, const float* __restrict__ vgt,
    u16* __restrict__ vt)
{
    __shared__ float t[32][33];
    int h = blockIdx.z, grp = blockIdx.y, n0 = blockIdx.x * 32;
    int tx = threadIdx.x & 31, ty = threadIdx.x >> 5;
    #pragma unroll
    for (int j = 0; j < 4; ++j) {
        int n = n0 + ty + j * 8;
        int c = grp * 32 + tx;
        float v = 0.f;
        if (c < 64) v = qkc[(size_t)n * LDQ + 2048 + h * 64 + c];
        else if (c < 88) v = vgt[(size_t)n * 384 + h * 24 + (c - 64)];
        t[ty + j * 8][tx] = v;
    }
    __syncthreads();
    #pragma unroll
    for (int j = 0; j < 4; ++j) {
        int r = grp * 32 + ty + j * 8;
        vt[((size_t)h * 96 + r) * NRES + n0 + tx] = f2b(t[tx][ty + j * 8]);
    }
}

// ===================== merged prologue =====================
__global__ __launch_bounds__(256) void prologue_kernel(
    const float* __restrict__ pos, const float* __restrict__ cond,
    const float* __restrict__ cn1_bs, const float* __restrict__ cn1_bb,
    const float* __restrict__ cn2_bs, const float* __restrict__ cn2_bb,
    const float* __restrict__ cn3_bs, const float* __restrict__ cn3_bb,
    const float* __restrict__ bg1, const float* __restrict__ bg2,
    float* __restrict__ Rb, float* __restrict__ tb,
    u16* __restrict__ emb, u16* __restrict__ condB,
    float* __restrict__ bias2, float* __restrict__ biasg)
{
    int b = blockIdx.x, tid = threadIdx.x;
    if (b < 16128) {
        int idx = b * 256 + tid;
        int f = idx & 63;
        int rest = idx >> 6;
        int coord = rest % 42;
        int n = rest / 42;
        float t = pos[(size_t)n * 42 + coord];
        const double l0 = -6.643856189774724;
        const double step = 14.643856189774724 / 63.0;
        float freq = exp2f((float)(l0 + f * step));
        float r = t * freq;
        size_t o = (size_t)n * 5376 + (size_t)coord * 128 + 2 * f;
        emb[o]     = f2b(sinf(r));
        emb[o + 1] = f2b(cosf(r));
    } else if (b < 16896) {
        int i = (b - 16128) * 256 + tid;
        size_t i0 = (size_t)i * 8;
        const float4* p = (const float4*)(cond + i0);
        float4 a = p[0], bb = p[1];
        short8 o;
        o[0]=(short)f2b(a.x); o[1]=(short)f2b(a.y); o[2]=(short)f2b(a.z); o[3]=(short)f2b(a.w);
        o[4]=(short)f2b(bb.x); o[5]=(short)f2b(bb.y); o[6]=(short)f2b(bb.z); o[7]=(short)f2b(bb.w);
        *(short8*)(condB + i0) = o;
    } else if (b < 16902) {
        int n = (b - 16896) * 256 + tid;
        if (n >= NRES) return;
        const float* p = pos + (size_t)n * 42;
        float nx = p[0], ny = p[1], nz = p[2];
        float cax = p[3], cay = p[4], caz = p[5];
        float cx = p[6], cy = p[7], cz = p[8];
        float v1x = cx - cax, v1y = cy - cay, v1z = cz - caz;
        float i1 = rsqrtf(v1x * v1x + v1y * v1y + v1z * v1z + 1e-8f);
        float e1x = v1x * i1, e1y = v1y * i1, e1z = v1z * i1;
        float v2x = nx - cax, v2y = ny - cay, v2z = nz - caz;
        float d = e1x * v2x + e1y * v2y + e1z * v2z;
        float wx = v2x - d * e1x, wy = v2y - d * e1y, wz = v2z - d * e1z;
        float i2 = rsqrtf(wx * wx + wy * wy + wz * wz + 1e-8f);
        float e2x = wx * i2, e2y = wy * i2, e2z = wz * i2;
        float e3x = e1y * e2z - e1z * e2y;
        float e3y = e1z * e2x - e1x * e2z;
        float e3z = e1x * e2y - e1y * e2x;
        float* R = Rb + (size_t)n * 9;
        R[0] = e1x; R[1] = e2x; R[2] = e3x;
        R[3] = e1y; R[4] = e2y; R[5] = e3y;
        R[6] = e1z; R[7] = e2z; R[8] = e3z;
        tb[(size_t)n * 3 + 0] = cax;
        tb[(size_t)n * 3 + 1] = cay;
        tb[(size_t)n * 3 + 2] = caz;
    } else if (b < 16906) {
        int i = (b - 16902) * 256 + tid;
        if (i >= 1024) return;
        bias2[i] = cn1_bs[i]; bias2[1024 + i] = cn1_bb[i]; bias2[2048 + i] = cn2_bs[i];
        bias2[3072 + i] = cn2_bb[i]; bias2[4096 + i] = cn3_bs[i]; bias2[5120 + i] = cn3_bb[i];
    } else {
        int i = (b - 16906) * 256 + tid;
        if (i >= 2048) return;
        biasg[i] = bg1[i]; biasg[2048 + i] = bg2[i];
    }
}

// ===== merged pack: qe/ke cols 0..63 + zeros (blocks<1536), points cols 64..88 =====
__global__ __launch_bounds__(256) void pack_attn(
    const float* __restrict__ qkc,
    const float* __restrict__ Rb, const float* __restrict__ tb,
    const float* __restrict__ gamma,
    u16* __restrict__ qe, u16* __restrict__ ke, float* __restrict__ vgt)
{
    int b = blockIdx.x;
    if (b < 1536) {
        int idx = b * 256 + threadIdx.x;
        int g = idx & 15;
        int t = idx >> 4;
        int n = t % NRES;
        int h = t / NRES;
        size_t o = ((size_t)h * NRES + n) * 128 + g * 8;
        if (g < 8) {
            const float4* q4 = (const float4*)(qkc + (size_t)n * LDQ + h * 64 + g * 8);
            const float4* k4 = (const float4*)(qkc + (size_t)n * LDQ + 1024 + h * 64 + g * 8);
            float4 qa = q4[0], qb2 = q4[1], ka = k4[0], kb2 = k4[1];
            short8 oq, ok;
            oq[0]=(short)f2b(0.125f*qa.x); oq[1]=(short)f2b(0.125f*qa.y);
            oq[2]=(short)f2b(0.125f*qa.z); oq[3]=(short)f2b(0.125f*qa.w);
            oq[4]=(short)f2b(0.125f*qb2.x); oq[5]=(short)f2b(0.125f*qb2.y);
            oq[6]=(short)f2b(0.125f*qb2.z); oq[7]=(short)f2b(0.125f*qb2.w);
            ok[0]=(short)f2b(ka.x); ok[1]=(short)f2b(ka.y); ok[2]=(short)f2b(ka.z); ok[3]=(short)f2b(ka.w);
            ok[4]=(short)f2b(kb2.x); ok[5]=(short)f2b(kb2.y); ok[6]=(short)f2b(kb2.z); ok[7]=(short)f2b(kb2.w);
            *(short8*)(qe + o) = oq;
            *(short8*)(ke + o) = ok;
        } else if (g >= 11) {
            short8 zz = {};
            *(short8*)(qe + o) = zz;
            *(short8*)(ke + o) = zz;
        }
        return;
    }
    int idx = (b - 1536) * 256 + threadIdx.x;
    if (idx >= NRES * NH) return;
    int n = idx >> 4, h = idx & 15;
    float R[9];
    #pragma unroll
    for (int a = 0; a < 9; ++a) R[a] = Rb[(size_t)n * 9 + a];
    float t0 = tb[(size_t)n * 3 + 0], t1 = tb[(size_t)n * 3 + 1], t2 = tb[(size_t)n * 3 + 2];
    float g = gamma[h];
    float sp = (g > 20.f) ? g : log1pf(expf(g));
    float ch = 0.5f * (1.f / 6.f) * sp;

    u16* qeh = qe + ((size_t)h * NRES + n) * 128;
    u16* keh = ke + ((size_t)h * NRES + n) * 128;
    const float* qp = qkc + (size_t)n * LDQ + 3072 + h * 24;
    const float* kp = qkc + (size_t)n * LDQ + 3456 + h * 24;
    const float* vp = qkc + (size_t)n * LDQ + 3840 + h * 24;
    float kn = 0.f;
    #pragma unroll
    for (int p = 0; p < 8; ++p) {
        {
            float x = qp[p*3], y = qp[p*3+1], z = qp[p*3+2];
            float g0 = R[0] * x + R[1] * y + R[2] * z + t0;
            float g1 = R[3] * x + R[4] * y + R[5] * z + t1;
            float g2 = R[6] * x + R[7] * y + R[8] * z + t2;
            qeh[64 + p * 3 + 0] = f2b(2.f * ch * g0);
            qeh[64 + p * 3 + 1] = f2b(2.f * ch * g1);
            qeh[64 + p * 3 + 2] = f2b(2.f * ch * g2);
        }
        {
            float x = kp[p*3], y = kp[p*3+1], z = kp[p*3+2];
            float g0 = R[0] * x + R[1] * y + R[2] * z + t0;
            float g1 = R[3] * x + R[4] * y + R[5] * z + t1;
            float g2 = R[6] * x + R[7] * y + R[8] * z + t2;
            keh[64 + p * 3 + 0] = f2b(g0);
            keh[64 + p * 3 + 1] = f2b(g1);
            keh[64 + p * 3 + 2] = f2b(g2);
            kn += g0 * g0 + g1 * g1 + g2 * g2;
        }
        {
            float x = vp[p*3], y = vp[p*3+1], z = vp[p*3+2];
            vgt[(size_t)n * 384 + h * 24 + p * 3 + 0] = R[0] * x + R[1] * y + R[2] * z + t0;
            vgt[(size_t)n * 384 + h * 24 + p * 3 + 1] = R[3] * x + R[4] * y + R[5] * z + t1;
            vgt[(size_t)n * 384 + h * 24 + p * 3 + 2] = R[6] * x + R[7] * y + R[8] * z + t2;
        }
    }
    qeh[88] = f2b(1.0f);
    keh[88] = f2b(-ch * kn);
}

// gm = silu(g1) * g2, 8-wide
__global__ __launch_bounds__(256) void glu_kernel(const u16* __restrict__ g12, u16* __restrict__ gm)
{
    int i = blockIdx.x * 256 + threadIdx.x;
    if (i >= NRES * 2048 / 8) return;
    size_t i0 = (size_t)i * 8;
    short8 a8 = *(const short8*)(g12 + i0);
    short8 b8 = *(const short8*)(g12 + (size_t)NRES * 2048 + i0);
    short8 o;
    #pragma unroll
    for (int j = 0; j < 8; ++j) {
        float a = b2f((u16)a8[j]);
        float b = b2f((u16)b8[j]);
        float s = a / (1.f + expf(-a));
        o[j] = (short)f2b(s * b);
    }
    *(short8*)(gm + i0) = o;
}

// ========================= host =========================
extern "C" void kernel_launch(void* const* d_in, const int* in_sizes, int n_in,
                              void* d_out, int out_size, void* d_ws, size_t ws_size,
                              hipStream_t stream)
{
    const float* local_in = (const float*)d_in[0];
    const float* pos      = (const float*)d_in[1];
    const float* cond     = (const float*)d_in[2];
    const float* pb       = (const float*)d_in[4];
    const float* w_f1     = (const float*)d_in[5];
    const float* b_f1     = (const float*)d_in[6];
    const float* w_f2     = (const float*)d_in[7];
    const float* b_f2     = (const float*)d_in[8];
    const float* cn1_ws   = (const float*)d_in[9];
    const float* cn1_bs   = (const float*)d_in[10];
    const float* cn1_wb   = (const float*)d_in[11];
    const float* cn1_bb   = (const float*)d_in[12];
    const float* wq       = (const float*)d_in[13];
    const float* wk       = (const float*)d_in[14];
    const float* wv       = (const float*)d_in[15];
    const float* wqp      = (const float*)d_in[16];
    const float* wkp      = (const float*)d_in[17];
    const float* wvp      = (const float*)d_in[18];
    const float* gamma    = (const float*)d_in[19];
    const float* wo       = (const float*)d_in[20];
    const float* bo       = (const float*)d_in[21];
    const float* cn2_ws   = (const float*)d_in[22];
    const float* cn2_bs   = (const float*)d_in[23];
    const float* cn2_wb   = (const float*)d_in[24];
    const float* cn2_bb   = (const float*)d_in[25];
    const float* wg1      = (const float*)d_in[26];
    const float* bg1      = (const float*)d_in[27];
    const float* wg2      = (const float*)d_in[28];
    const float* bg2      = (const float*)d_in[29];
    const float* wg3      = (const float*)d_in[30];
    const float* bg3      = (const float*)d_in[31];
    const float* cn3_ws   = (const float*)d_in[32];
    const float* cn3_bs   = (const float*)d_in[33];
    const float* cn3_wb   = (const float*)d_in[34];
    const float* cn3_bb   = (const float*)d_in[35];
    const float* w_vel    = (const float*)d_in[36];

    float* out = (float*)d_out;
    float* ws  = (float*)d_ws;

    size_t off = 0;
    auto alloc = [&](size_t nf) -> float* { float* p = ws + off; off += (nf + 7) & ~7ull; return p; };

    const size_t NN1 = (size_t)NRES * 1024;
    float* Rb    = alloc(NRES * 9);
    float* tb    = alloc(NRES * 3);
    float* loc   = alloc(NN1);
    u16*   cs6b  = (u16*)alloc(6 * NN1 / 2);
    u16*   condB = (u16*)alloc(NN1 / 2);
    u16*   normB = (u16*)alloc(NN1 / 2);
    float* bias2 = alloc(6 * 1024);
    float* biasg = alloc(2 * 2048);
    float* qkc   = alloc((size_t)NRES * LDQ);
    float* vgt   = alloc((size_t)NRES * 384);
    u16*   qeB   = (u16*)alloc((size_t)NH * NRES * 128 / 2);
    u16*   keB   = (u16*)alloc((size_t)NH * NRES * 128 / 2);
    u16*   vTB   = (u16*)alloc((size_t)NH * 96 * NRES / 2);
    u16*   featB = (u16*)alloc((size_t)NRES * 1536 / 2);
    u16*   g1sB  = (u16*)alloc((size_t)NRES * 2048 / 2);
    u16*   gmB   = (u16*)alloc((size_t)NRES * 2048 / 2);
    u16*   cnT9  = (u16*)alloc((size_t)9 * 1024 * 1024 / 2);
    u16*   ptsT  = (u16*)alloc((size_t)3 * 384 * 1024 / 2);
    u16*   wgT   = (u16*)alloc((size_t)2 * 2048 * 1024 / 2);
    u16*   wf1T  = (u16*)alloc((size_t)2048 * 5376 / 2);
    u16*   wf2T  = (u16*)alloc((size_t)1024 * 2048 / 2);
    u16*   woT   = (u16*)alloc((size_t)1024 * 1536 / 2);
    u16*   wg3T  = (u16*)alloc((size_t)1024 * 2048 / 2);
    u16*   wvT   = (u16*)alloc((size_t)42 * 1024 / 2 + 8);
    u16*   embB  = (u16*)alloc((size_t)NRES * 5376 / 2);
    u16*   hidB  = (u16*)alloc((size_t)NRES * 2048 / 2);
    u16*   pscr  = (u16*)alloc((size_t)2 * NRES * 2048 * 4 / 2);
    u16*   Opart = (u16*)alloc((size_t)KVS * NH * NRES * 96 / 2);
    float* mlprt = alloc((size_t)KVS * NH * NRES * 2);

    const float* nilf = nullptr;

    auto gemm = [&](int tnf, const u16* A, int lda, size_t zsA,
                    const u16* BT, int ldb, size_t zsB,
                    float* Cf, u16* Cb2, int ldc, size_t zsC,
                    const float* bias, size_t zsBias,
                    const float* resid, int ldr, size_t zsR,
                    int Nc, int Kd, int flags, int gz, int ksl) {
        int tn = tnf * 32;
        dim3 grid((Nc + tn - 1) / tn, NRES / 128, gz);
        if (tnf == 4)
            hipLaunchKernelGGL(gemm_t<4>, grid, dim3(256), 0, stream,
                               A, lda, zsA, BT, ldb, zsB, Cf, Cb2, ldc, zsC,
                               bias, zsBias, resid, ldr, zsR, Nc, Kd, flags, ksl);
        else
            hipLaunchKernelGGL(gemm_t<2>, grid, dim3(256), 0, stream,
                               A, lda, zsA, BT, ldb, zsB, Cf, Cb2, ldc, zsC,
                               bias, zsBias, resid, ldr, zsR, Nc, Kd, flags, ksl);
    };
    auto red = [&](const u16* part, size_t slice, int nsl, float* Cf, u16* Cb2,
                   const float* bias, const float* resid, int ldr, int Nc, int flags) {
        hipLaunchKernelGGL(reduce_epi, dim3(1024), dim3(256), 0, stream,
                           part, slice, nsl, Cf, Cb2, bias, resid, ldr, NRES, Nc, flags);
    };
    auto redcn = [&](const u16* part, size_t slice, int nsl,
                     const float* bias, const float* resid, float* locOut, int cnIdx) {
        hipLaunchKernelGGL(reduce_cn, dim3(NRES), dim3(256), 0, stream,
                           part, slice, nsl, bias, resid, locOut,
                           cs6b + (size_t)(2 * cnIdx) * NN1,
                           cs6b + (size_t)(2 * cnIdx + 1) * NN1, normB);
    };

    // ---- merged prologue ----
    hipLaunchKernelGGL(prologue_kernel, dim3(16914), dim3(256), 0, stream,
                       pos, cond, cn1_bs, cn1_bb, cn2_bs, cn2_bb, cn3_bs, cn3_bb,
                       bg1, bg2, Rb, tb, embB, condB, bias2, biasg);

    // ---- ALL weight transposes in ONE launch ----
    {
        TpMega J;
        int jn = 0, start = 0;
        auto addJob = [&](const float* src, u16* dst, int ldi, int ldo, int K, int N) {
            J.src[jn] = src; J.dst[jn] = dst;
            J.ldi[jn] = ldi; J.ldo[jn] = ldo; J.K[jn] = K; J.N[jn] = N;
            int bx = (N + 31) / 32, by = (K + 31) / 32;
            J.bx[jn] = bx; J.start[jn] = start;
            start += bx * by;
            ++jn;
        };
        const float* cn6[6] = {cn1_ws, cn1_wb, cn2_ws, cn2_wb, cn3_ws, cn3_wb};
        for (int i = 0; i < 6; ++i)
            addJob(cn6[i], cnT9 + (size_t)i * 1024 * 1024, 1024, 1024, 1024, 1024);
        addJob(wq, cnT9 + (size_t)6 * 1024 * 1024, 1024, 1024, 1024, 1024);
        addJob(wk, cnT9 + (size_t)7 * 1024 * 1024, 1024, 1024, 1024, 1024);
        addJob(wv, cnT9 + (size_t)8 * 1024 * 1024, 1024, 1024, 1024, 1024);
        addJob(wqp, ptsT,                        384, 1024, 1024, 384);
        addJob(wkp, ptsT + (size_t)384 * 1024,   384, 1024, 1024, 384);
        addJob(wvp, ptsT + (size_t)2 * 384 * 1024, 384, 1024, 1024, 384);
        addJob(wg1, wgT,                        2048, 1024, 1024, 2048);
        addJob(wg2, wgT + (size_t)2048 * 1024,  2048, 1024, 1024, 2048);
        addJob(w_f1, wf1T, 2048, 5376, 5376, 2048);
        addJob(w_f2, wf2T, 1024, 2048, 2048, 1024);
        addJob(wo,   woT,  1024, 1536, 1536, 1024);
        addJob(wg3,  wg3T, 1024, 2048, 2048, 1024);
        addJob(w_vel, wvT,   42, 1024, 1024, 42);
        hipLaunchKernelGGL(transpose_mega, dim3(start), dim3(256), 0, stream, J);
    }

    // ---- all 6 cond GEMMs (z=6, TN=64, bf16 out) ----
    gemm(2, condB, 1024, 0, cnT9, 1024, (size_t)1024 * 1024, nullptr, cs6b, 1024, NN1,
         bias2, 1024, nilf, 0, 0, 1024, 1024, F_BIAS | F_OUTBF, 6, 0);

    // ---- phase A: emb GEMM split-K=4, bf16 partials + reduce(silu->bf16) ----
    gemm(2, embB, 5376, 0, wf1T, 5376, 0, nullptr, pscr, 2048, (size_t)NRES * 2048,
         nilf, 0, nilf, 0, 0, 2048, 5376, F_OUTBF, 4, 1344);
    red(pscr, (size_t)NRES * 2048, 4, nullptr, hidB, b_f1, nilf, 0,
        2048, F_BIAS | F_SILU | F_OUTBF);
    gemm(2, hidB, 2048, 0, wf2T, 2048, 0, nullptr, pscr, 1024, NN1,
         nilf, 0, nilf, 0, 0, 1024, 2048, F_OUTBF, 4, 512);
    redcn(pscr, NN1, 4, b_f2, local_in, loc, 0);

    // ---- merged projections ----
    gemm(2, normB, 1024, 0, cnT9 + (size_t)6 * 1024 * 1024, 1024, 0,
         qkc, nullptr, LDQ, 0, nilf, 0, nilf, 0, 0, LDQ, 1024, 0, 1, 0);

    // ---- attention operands ----
    hipLaunchKernelGGL(pack_attn, dim3(1536 + 96), dim3(256), 0, stream,
                       qkc, Rb, tb, gamma, qeB, keB, vgt);
    hipLaunchKernelGGL(vt_pack, dim3(NRES / 32, 3, NH), dim3(256), 0, stream,
                       qkc, vgt, vTB);

    // ---- fused attention (split-KV=4, XCD-chunked) + merged combine+finalize ----
    hipLaunchKernelGGL(attn_kernel, dim3(NRES / 64, NH, KVS), dim3(256), 0, stream,
                       qeB, keB, vTB, pb, Opart, mlprt);
    hipLaunchKernelGGL(combine_fin, dim3(96), dim3(256), 0, stream,
                       Opart, mlprt, Rb, tb, featB);

    // ---- local += feat @ wo + bo : split-K=4, fused reduce+condnorm2 ----
    gemm(2, featB, 1536, 0, woT, 1536, 0, nullptr, pscr, 1024, NN1,
         nilf, 0, nilf, 0, 0, 1024, 1536, F_OUTBF, 4, 384);
    redcn(pscr, NN1, 4, bo, loc, loc, 1);

    // ---- gated MLP ----
    gemm(2, normB, 1024, 0, wgT, 1024, (size_t)2048 * 1024, nullptr, g1sB, 2048, (size_t)NRES * 2048,
         biasg, 2048, nilf, 0, 0, 2048, 1024, F_BIAS | F_OUTBF, 2, 0);
    u16* gmO = embB;
    hipLaunchKernelGGL(glu_kernel, dim3((NRES * 2048 / 8 + 255) / 256), dim3(256), 0, stream, g1sB, gmO);
    gemm(2, gmO, 2048, 0, wg3T, 2048, 0, nullptr, pscr, 1024, NN1,
         nilf, 0, nilf, 0, 0, 1024, 2048, F_OUTBF, 4, 512);
    redcn(pscr, NN1, 4, bg3, loc, out, 2);

    // ---- velocity (split-K=8, bf16 partials) ----
    gemm(2, normB, 1024, 0, wvT, 1024, 0, nullptr, pscr, 42, (size_t)NRES * 42,
         nilf, 0, nilf, 0, 0, 42, 1024, F_OUTBF, 8, 128);
    red(pscr, (size_t)NRES * 42, 8, out + (size_t)NRES * 1024, nullptr,
        nilf, nilf, 0, 42, 0);
}

// Round 14
// 449.433 us; speedup vs baseline: 1.5649x; 1.0339x over previous
//
#include <hip/hip_runtime.h>
#include <hip/hip_bf16.h>
#include <math.h>

#define NRES 1536
#define NH 16
#define NNF 2359296ull    // NRES*NRES
#define LOG2E 1.44269504f
#define KVS 4             // split-KV ways
#define LDQ 4224          // merged projection C leading dim
#define NTPJ 19           // transpose jobs
#define PROBLK 16914      // prologue block count inside prep_kernel

typedef unsigned short u16;
typedef __attribute__((ext_vector_type(8))) short short8;
typedef __attribute__((ext_vector_type(4))) unsigned short u16x4;
typedef __attribute__((ext_vector_type(4))) float f32x4;

typedef const __attribute__((address_space(1))) void gvoid;
typedef __attribute__((address_space(3))) void lvoid;

__device__ __forceinline__ u16 f2b(float x){
    __hip_bfloat16 h = __float2bfloat16(x);
    return *reinterpret_cast<u16*>(&h);
}
__device__ __forceinline__ float b2f(u16 u){
    unsigned v = ((unsigned)u) << 16;
    return __uint_as_float(v);
}

// ===================== bf16 MFMA GEMM (dbuf, 1 barrier/K-step, XCD swizzle) ==========
#define F_BIAS  1
#define F_SILU  2
#define F_RESID 8
#define F_OUTBF 16

template<int TNF>
__global__ __launch_bounds__(256) void gemm_t(
    const u16* __restrict__ A, int lda, size_t zsA,
    const u16* __restrict__ BT, int ldb, size_t zsB,
    float* __restrict__ Cf, u16* __restrict__ Cb, int ldc, size_t zsC,
    const float* __restrict__ bias, size_t zsBias,
    const float* __restrict__ resid, int ldr, size_t zsR,
    int Ncols, int Kd, int flags, int ksl)
{
    constexpr int TN = TNF * 32;
    __shared__ u16 As[2][128 * 64];
    __shared__ u16 Bs[2][TN * 64];

    unsigned gx = gridDim.x, gy = gridDim.y;
    unsigned nb = gx * gy * gridDim.z;
    unsigned bid = (blockIdx.z * gy + blockIdx.y) * gx + blockIdx.x;
    if ((nb & 7u) == 0u) bid = (bid & 7u) * (nb >> 3) + (bid >> 3);
    const int bxi = bid % gx;
    const int byi = (bid / gx) % gy;
    const int bz  = bid / (gx * gy);

    const int tid = threadIdx.x;
    const int l = tid & 63, w = tid >> 6;
    const int bm = byi * 128, bn = bxi * TN;

    A  += zsA * bz;
    BT += zsB * bz;

    const int kbeg = ksl ? bz * ksl : 0;
    const int kend = ksl ? kbeg + ksl : Kd;
    const int nk = (kend - kbeg) >> 6;

    const int arow   = l >> 3;
    const int aslot  = l & 7;
    const int srcslt = aslot ^ arow;

    const u16* aBase[4];
    const u16* bBase[TN / 32];
    #pragma unroll
    for (int t = 0; t < 4; ++t) {
        int ra = bm + (w * 4 + t) * 8 + arow;
        aBase[t] = A + (size_t)ra * lda + srcslt * 8;
    }
    #pragma unroll
    for (int t = 0; t < TN / 32; ++t) {
        int rb = bn + (w * (TN / 32) + t) * 8 + arow;
        if (rb > Ncols - 1) rb = Ncols - 1;
        bBase[t] = BT + (size_t)rb * ldb + srcslt * 8;
    }

    const int wr = w >> 1, wc = w & 1;
    const int fr = l & 15;
    const int fq = l >> 4;

    f32x4 acc[4][TNF];
    #pragma unroll
    for (int i = 0; i < 4; ++i)
        #pragma unroll
        for (int j = 0; j < TNF; ++j) acc[i][j] = (f32x4){0.f, 0.f, 0.f, 0.f};

    auto stage = [&](int buf, int k0) {
        #pragma unroll
        for (int t = 0; t < 4; ++t)
            __builtin_amdgcn_global_load_lds((gvoid*)(aBase[t] + k0),
                (lvoid*)((char*)As[buf] + (w * 4 + t) * 1024), 16, 0, 0);
        #pragma unroll
        for (int t = 0; t < TN / 32; ++t)
            __builtin_amdgcn_global_load_lds((gvoid*)(bBase[t] + k0),
                (lvoid*)((char*)Bs[buf] + (w * (TN / 32) + t) * 1024), 16, 0, 0);
    };

    stage(0, kbeg);
    __syncthreads();
    int cur = 0;

    for (int it = 0; it < nk; ++it) {
        if (it + 1 < nk) stage(cur ^ 1, kbeg + (it + 1) * 64);
        #pragma unroll
        for (int kk = 0; kk < 2; ++kk) {
            const int slotR = ((kk * 4) + fq) ^ (l & 7);
            short8 av[4], bv[TNF];
            #pragma unroll
            for (int m = 0; m < 4; ++m) {
                int r = wr * 64 + m * 16 + fr;
                av[m] = *(const short8*)((const char*)As[cur] + r * 128 + slotR * 16);
            }
            #pragma unroll
            for (int n = 0; n < TNF; ++n) {
                int r = wc * (TNF * 16) + n * 16 + fr;
                bv[n] = *(const short8*)((const char*)Bs[cur] + r * 128 + slotR * 16);
            }
            #pragma unroll
            for (int m = 0; m < 4; ++m)
                #pragma unroll
                for (int n = 0; n < TNF; ++n)
                    acc[m][n] = __builtin_amdgcn_mfma_f32_16x16x32_bf16(av[m], bv[n], acc[m][n], 0, 0, 0);
        }
        __syncthreads();
        cur ^= 1;
    }

    const float* residz = (flags & F_RESID) ? resid + zsR * bz : nullptr;
    const float* biasz  = (flags & F_BIAS)  ? bias + zsBias * bz : nullptr;
    float* cfz = Cf ? Cf + zsC * bz : nullptr;
    u16*   cbz = Cb ? Cb + zsC * bz : nullptr;

    #pragma unroll
    for (int m = 0; m < 4; ++m) {
        #pragma unroll
        for (int n = 0; n < TNF; ++n) {
            int gc = bn + wc * (TNF * 16) + n * 16 + fr;
            if (gc >= Ncols) continue;
            int gr0 = bm + wr * 64 + m * 16 + fq * 4;
            #pragma unroll
            for (int r = 0; r < 4; ++r) {
                int gr = gr0 + r;
                float v = acc[m][n][r];
                if (flags & F_BIAS)  v += biasz[gc];
                if (flags & F_SILU)  v = v / (1.f + expf(-v));
                if (flags & F_RESID) v += residz[(size_t)gr * ldr + gc];
                if (flags & F_OUTBF) cbz[(size_t)gr * ldc + gc] = f2b(v);
                else                 cfz[(size_t)gr * ldc + gc] = v;
            }
        }
    }
}

// ===================== dual-job GEMM (cond + emb in one launch) =====================
struct GJob {
    const u16* A;
    const u16* BT;
    u16* C;
    const float* bias;
    int lda, ldb, ldc;
    size_t zsA, zsB, zsC, zsBias;
    int Nc, Kd, ksl, flags;
    unsigned gx, gy, start, nb;
};

__global__ __launch_bounds__(256) void gemm_dual(GJob j0, GJob j1)
{
    __shared__ u16 As[2][128 * 64];
    __shared__ u16 Bs[2][64 * 64];

    GJob J = (blockIdx.x >= j1.start) ? j1 : j0;
    unsigned bid = blockIdx.x - J.start;
    if ((J.nb & 7u) == 0u) bid = (bid & 7u) * (J.nb >> 3) + (bid >> 3);
    const int bxi = bid % J.gx;
    const int byi = (bid / J.gx) % J.gy;
    const int bz  = bid / (J.gx * J.gy);

    const int tid = threadIdx.x;
    const int l = tid & 63, w = tid >> 6;
    const int bm = byi * 128, bn = bxi * 64;

    const u16* A  = J.A + J.zsA * bz;
    const u16* BT = J.BT + J.zsB * bz;

    const int kbeg = J.ksl ? bz * J.ksl : 0;
    const int kend = J.ksl ? kbeg + J.ksl : J.Kd;
    const int nk = (kend - kbeg) >> 6;

    const int arow   = l >> 3;
    const int aslot  = l & 7;
    const int srcslt = aslot ^ arow;

    const u16* aBase[4];
    const u16* bBase[2];
    #pragma unroll
    for (int t = 0; t < 4; ++t) {
        int ra = bm + (w * 4 + t) * 8 + arow;
        aBase[t] = A + (size_t)ra * J.lda + srcslt * 8;
    }
    #pragma unroll
    for (int t = 0; t < 2; ++t) {
        int rb = bn + (w * 2 + t) * 8 + arow;
        if (rb > J.Nc - 1) rb = J.Nc - 1;
        bBase[t] = BT + (size_t)rb * J.ldb + srcslt * 8;
    }

    const int wr = w >> 1, wc = w & 1;
    const int fr = l & 15;
    const int fq = l >> 4;

    f32x4 acc[4][2];
    #pragma unroll
    for (int i = 0; i < 4; ++i)
        #pragma unroll
        for (int j = 0; j < 2; ++j) acc[i][j] = (f32x4){0.f, 0.f, 0.f, 0.f};

    auto stage = [&](int buf, int k0) {
        #pragma unroll
        for (int t = 0; t < 4; ++t)
            __builtin_amdgcn_global_load_lds((gvoid*)(aBase[t] + k0),
                (lvoid*)((char*)As[buf] + (w * 4 + t) * 1024), 16, 0, 0);
        #pragma unroll
        for (int t = 0; t < 2; ++t)
            __builtin_amdgcn_global_load_lds((gvoid*)(bBase[t] + k0),
                (lvoid*)((char*)Bs[buf] + (w * 2 + t) * 1024), 16, 0, 0);
    };

    stage(0, kbeg);
    __syncthreads();
    int cur = 0;

    for (int it = 0; it < nk; ++it) {
        if (it + 1 < nk) stage(cur ^ 1, kbeg + (it + 1) * 64);
        #pragma unroll
        for (int kk = 0; kk < 2; ++kk) {
            const int slotR = ((kk * 4) + fq) ^ (l & 7);
            short8 av[4], bv[2];
            #pragma unroll
            for (int m = 0; m < 4; ++m) {
                int r = wr * 64 + m * 16 + fr;
                av[m] = *(const short8*)((const char*)As[cur] + r * 128 + slotR * 16);
            }
            #pragma unroll
            for (int n = 0; n < 2; ++n) {
                int r = wc * 32 + n * 16 + fr;
                bv[n] = *(const short8*)((const char*)Bs[cur] + r * 128 + slotR * 16);
            }
            #pragma unroll
            for (int m = 0; m < 4; ++m)
                #pragma unroll
                for (int n = 0; n < 2; ++n)
                    acc[m][n] = __builtin_amdgcn_mfma_f32_16x16x32_bf16(av[m], bv[n], acc[m][n], 0, 0, 0);
        }
        __syncthreads();
        cur ^= 1;
    }

    const float* biasz = (J.flags & F_BIAS) ? J.bias + J.zsBias * bz : nullptr;
    u16* cbz = J.C + J.zsC * bz;

    #pragma unroll
    for (int m = 0; m < 4; ++m) {
        #pragma unroll
        for (int n = 0; n < 2; ++n) {
            int gc = bn + wc * 32 + n * 16 + fr;
            if (gc >= J.Nc) continue;
            int gr0 = bm + wr * 64 + m * 16 + fq * 4;
            #pragma unroll
            for (int r = 0; r < 4; ++r) {
                int gr = gr0 + r;
                float v = acc[m][n][r];
                if (J.flags & F_BIAS) v += biasz[gc];
                cbz[(size_t)gr * J.ldc + gc] = f2b(v);
            }
        }
    }
}

// ===================== split-K reduce (bf16 partials) + fused epilogue ==========
__global__ __launch_bounds__(256) void reduce_epi(
    const u16* __restrict__ part, size_t slice, int nsl,
    float* __restrict__ Cf, u16* __restrict__ Cb,
    const float* __restrict__ bias,
    const float* __restrict__ resid, int ldr,
    int M, int Ncols, int flags)
{
    if ((Ncols & 7) == 0) {
        size_t total8 = (size_t)M * Ncols / 8;
        for (size_t i8 = (size_t)blockIdx.x * 256 + threadIdx.x; i8 < total8;
             i8 += (size_t)gridDim.x * 256) {
            size_t i0 = i8 * 8;
            int r = (int)(i0 / (unsigned)Ncols);
            int c0 = (int)(i0 - (size_t)r * Ncols);
            float v[8] = {0,0,0,0,0,0,0,0};
            for (int s = 0; s < nsl; ++s) {
                const u16x4* p = (const u16x4*)(part + (size_t)s * slice + i0);
                u16x4 a = p[0], b = p[1];
                v[0] += b2f(a.x); v[1] += b2f(a.y); v[2] += b2f(a.z); v[3] += b2f(a.w);
                v[4] += b2f(b.x); v[5] += b2f(b.y); v[6] += b2f(b.z); v[7] += b2f(b.w);
            }
            #pragma unroll
            for (int j = 0; j < 8; ++j) {
                if (flags & F_BIAS) v[j] += bias[c0 + j];
                if (flags & F_SILU) v[j] = v[j] / (1.f + expf(-v[j]));
            }
            if (flags & F_RESID) {
                const float4* rp = (const float4*)(resid + (size_t)r * ldr + c0);
                float4 r0 = rp[0], r1 = rp[1];
                v[0] += r0.x; v[1] += r0.y; v[2] += r0.z; v[3] += r0.w;
                v[4] += r1.x; v[5] += r1.y; v[6] += r1.z; v[7] += r1.w;
            }
            if (flags & F_OUTBF) {
                short8 o;
                #pragma unroll
                for (int j = 0; j < 8; ++j) o[j] = (short)f2b(v[j]);
                *(short8*)(Cb + i0) = o;
            } else {
                float4 o0 = {v[0], v[1], v[2], v[3]}, o1 = {v[4], v[5], v[6], v[7]};
                float4* cp = (float4*)(Cf + i0);
                cp[0] = o0; cp[1] = o1;
            }
        }
    } else {
        size_t total = (size_t)M * Ncols;
        for (size_t i = (size_t)blockIdx.x * 256 + threadIdx.x; i < total;
             i += (size_t)gridDim.x * 256) {
            float v = 0.f;
            for (int s = 0; s < nsl; ++s) v += b2f(part[(size_t)s * slice + i]);
            if (flags & F_OUTBF) Cb[i] = f2b(v);
            else                 Cf[i] = v;
        }
    }
}

// ===== fused split-K reduce -> local update -> cond LayerNorm -> bf16 =====
__global__ __launch_bounds__(256) void reduce_cn(
    const u16* __restrict__ part, size_t slice, int nsl,
    const float* __restrict__ bias, const float* __restrict__ resid,
    float* __restrict__ locOut,
    const u16* __restrict__ cs, const u16* __restrict__ cb,
    u16* __restrict__ normB)
{
    int row = blockIdx.x, tid = threadIdx.x;
    size_t base = (size_t)row * 1024 + tid * 4;
    float v[4];
    {
        float4 rv = *(const float4*)(resid + base);
        v[0] = rv.x; v[1] = rv.y; v[2] = rv.z; v[3] = rv.w;
    }
    for (int s = 0; s < nsl; ++s) {
        u16x4 p = *(const u16x4*)(part + (size_t)s * slice + base);
        v[0] += b2f(p.x); v[1] += b2f(p.y); v[2] += b2f(p.z); v[3] += b2f(p.w);
    }
    {
        float4 bv = *(const float4*)(bias + tid * 4);
        v[0] += bv.x; v[1] += bv.y; v[2] += bv.z; v[3] += bv.w;
    }
    *(float4*)(locOut + base) = (float4){v[0], v[1], v[2], v[3]};

    float s1 = v[0] + v[1] + v[2] + v[3];
    float s2 = v[0]*v[0] + v[1]*v[1] + v[2]*v[2] + v[3]*v[3];
    __shared__ float r1[256], r2[256];
    r1[tid] = s1; r2[tid] = s2;
    __syncthreads();
    for (int st = 128; st > 0; st >>= 1) {
        if (tid < st) { r1[tid] += r1[tid + st]; r2[tid] += r2[tid + st]; }
        __syncthreads();
    }
    float mean = r1[0] * (1.f / 1024.f);
    float var = r2[0] * (1.f / 1024.f) - mean * mean;
    float rs = rsqrtf(var + 1e-5f);
    u16x4 sv = *(const u16x4*)(cs + base);
    u16x4 bv = *(const u16x4*)(cb + base);
    u16x4 o;
    o.x = f2b((1.f / (1.f + expf(-b2f(sv.x)))) * (v[0] - mean) * rs + b2f(bv.x));
    o.y = f2b((1.f / (1.f + expf(-b2f(sv.y)))) * (v[1] - mean) * rs + b2f(bv.y));
    o.z = f2b((1.f / (1.f + expf(-b2f(sv.z)))) * (v[2] - mean) * rs + b2f(bv.z));
    o.w = f2b((1.f / (1.f + expf(-b2f(sv.w)))) * (v[3] - mean) * rs + b2f(bv.w));
    *(u16x4*)(normB + base) = o;
}

// ========== fused flash attention (split-KV=4, XCD-chunked swizzle, setprio) ==========
__global__ __launch_bounds__(256, 2) void attn_kernel(
    const u16* __restrict__ qe, const u16* __restrict__ ke,
    const u16* __restrict__ vt, const float* __restrict__ pb,
    u16* __restrict__ Opart, float* __restrict__ mlpart)
{
    __shared__ u16 Ks[2][64 * 128];
    __shared__ u16 Vs[2][96 * 64];
    __shared__ u16 Ps[64 * 64];

    unsigned gx = gridDim.x, gy = gridDim.y;
    unsigned nb = gx * gy * gridDim.z;
    unsigned bid = (blockIdx.z * gy + blockIdx.y) * gx + blockIdx.x;
    bid = (bid & 7u) * (nb >> 3) + (bid >> 3);
    const int qx = bid % gx;
    const int h  = (bid / gx) % gy;
    const int z  = bid / (gx * gy);

    const int tid = threadIdx.x;
    const int l = tid & 63, w = tid >> 6;
    const int q0 = qx * 64;
    const int fr = l & 15, fq = l >> 4;

    const u16* keh = ke + (size_t)h * NRES * 128;
    const u16* vth = vt + (size_t)h * 96 * NRES;

    const int kr4 = l >> 4, ks16 = l & 15;
    const int vr8 = l >> 3, vs8 = l & 7;

    short8 qv[4];
    {
        const u16* qrow = qe + ((size_t)h * NRES + (q0 + w * 16 + fr)) * 128 + fq * 8;
        #pragma unroll
        for (int kk = 0; kk < 4; ++kk)
            qv[kk] = *(const short8*)(qrow + kk * 32);
    }

    float m_run[4], l_run[4];
    f32x4 oacc[6];
    #pragma unroll
    for (int r = 0; r < 4; ++r) { m_run[r] = -1e30f; l_run[r] = 0.f; }
    #pragma unroll
    for (int n = 0; n < 6; ++n) oacc[n] = (f32x4){0.f, 0.f, 0.f, 0.f};

    const int NIT = NRES / 64 / KVS;
    const int jbase = z * (NRES / KVS);
    int cur = 0;

    auto stage = [&](int buf, int j0) {
        #pragma unroll
        for (int t = 0; t < 4; ++t) {
            int row = w * 16 + t * 4 + kr4;
            int ss = ks16 ^ (row & 7);
            __builtin_amdgcn_global_load_lds(
                (gvoid*)(keh + (size_t)(j0 + row) * 128 + ss * 8),
                (lvoid*)((char*)Ks[buf] + (w * 16 + t * 4) * 256), 16, 0, 0);
        }
        #pragma unroll
        for (int t = 0; t < 3; ++t) {
            int row = w * 24 + t * 8 + vr8;
            int ss = vs8 ^ (row & 7);
            __builtin_amdgcn_global_load_lds(
                (gvoid*)(vth + (size_t)row * NRES + j0 + ss * 8),
                (lvoid*)((char*)Vs[buf] + (w * 24 + t * 8) * 128), 16, 0, 0);
        }
    };
    const float* pbrow = pb + ((size_t)h * NRES + (q0 + w * 16 + fq * 4)) * NRES + fr;

    f32x4 pbv[4], pbn[4] = {};
    stage(0, jbase);
    #pragma unroll
    for (int n = 0; n < 4; ++n)
        #pragma unroll
        for (int r = 0; r < 4; ++r)
            pbv[n][r] = pbrow[(size_t)r * NRES + jbase + n * 16];
    __syncthreads();

    for (int it = 0; it < NIT; ++it) {
        if (it + 1 < NIT) {
            int j1 = jbase + (it + 1) * 64;
            stage(cur ^ 1, j1);
            #pragma unroll
            for (int n = 0; n < 4; ++n)
                #pragma unroll
                for (int r = 0; r < 4; ++r)
                    pbn[n][r] = pbrow[(size_t)r * NRES + j1 + n * 16];
        }

        f32x4 sacc[4];
        #pragma unroll
        for (int n = 0; n < 4; ++n) sacc[n] = (f32x4){0.f, 0.f, 0.f, 0.f};
        __builtin_amdgcn_s_setprio(1);
        #pragma unroll
        for (int kk = 0; kk < 4; ++kk) {
            #pragma unroll
            for (int n = 0; n < 4; ++n) {
                int row = n * 16 + fr;
                short8 bv = *(const short8*)((const char*)Ks[cur] + row * 256
                                             + (((kk * 4 + fq) ^ (fr & 7)) * 16));
                sacc[n] = __builtin_amdgcn_mfma_f32_16x16x32_bf16(qv[kk], bv, sacc[n], 0, 0, 0);
            }
        }
        __builtin_amdgcn_s_setprio(0);
        #pragma unroll
        for (int n = 0; n < 4; ++n) sacc[n] += pbv[n];

        float alpha[4];
        #pragma unroll
        for (int r = 0; r < 4; ++r) {
            float v = fmaxf(fmaxf(sacc[0][r], sacc[1][r]), fmaxf(sacc[2][r], sacc[3][r]));
            v = fmaxf(v, __shfl_xor(v, 1, 64));
            v = fmaxf(v, __shfl_xor(v, 2, 64));
            v = fmaxf(v, __shfl_xor(v, 4, 64));
            v = fmaxf(v, __shfl_xor(v, 8, 64));
            float mn = fmaxf(m_run[r], v);
            alpha[r] = exp2f((m_run[r] - mn) * LOG2E);
            m_run[r] = mn;
        }

        float psum[4] = {0.f, 0.f, 0.f, 0.f};
        #pragma unroll
        for (int n = 0; n < 4; ++n) {
            int col = n * 16 + fr;
            #pragma unroll
            for (int r = 0; r < 4; ++r) {
                float p = exp2f((sacc[n][r] - m_run[r]) * LOG2E);
                psum[r] += p;
                int rowf = w * 16 + fq * 4 + r;
                int byte = rowf * 128 + (((col >> 3) ^ (rowf & 7)) * 16) + (col & 7) * 2;
                *(u16*)((char*)Ps + byte) = f2b(p);
            }
        }
        #pragma unroll
        for (int r = 0; r < 4; ++r) {
            float v = psum[r];
            v += __shfl_xor(v, 1, 64);
            v += __shfl_xor(v, 2, 64);
            v += __shfl_xor(v, 4, 64);
            v += __shfl_xor(v, 8, 64);
            l_run[r] = l_run[r] * alpha[r] + v;
        }
        #pragma unroll
        for (int n = 0; n < 6; ++n)
            #pragma unroll
            for (int r = 0; r < 4; ++r)
                oacc[n][r] *= alpha[r];

        __builtin_amdgcn_s_setprio(1);
        #pragma unroll
        for (int kk = 0; kk < 2; ++kk) {
            int prow = w * 16 + fr;
            short8 pa = *(const short8*)((const char*)Ps + prow * 128
                                         + (((kk * 4 + fq) ^ (prow & 7)) * 16));
            #pragma unroll
            for (int n = 0; n < 6; ++n) {
                int vrow = n * 16 + fr;
                short8 vv = *(const short8*)((const char*)Vs[cur] + vrow * 128
                                             + (((kk * 4 + fq) ^ (fr & 7)) * 16));
                oacc[n] = __builtin_amdgcn_mfma_f32_16x16x32_bf16(pa, vv, oacc[n], 0, 0, 0);
            }
        }
        __builtin_amdgcn_s_setprio(0);

        __syncthreads();
        cur ^= 1;
        #pragma unroll
        for (int n = 0; n < 4; ++n) pbv[n] = pbn[n];
    }

    u16* Oz = Opart + ((size_t)z * NH + h) * NRES * 96;
    #pragma unroll
    for (int n = 0; n < 6; ++n) {
        int c = n * 16 + fr;
        #pragma unroll
        for (int r = 0; r < 4; ++r) {
            int row = q0 + w * 16 + fq * 4 + r;
            Oz[(size_t)row * 96 + c] = f2b(oacc[n][r]);
        }
    }
    if (fr == 0) {
        float* mlz = mlpart + ((size_t)z * NH + h) * NRES * 2;
        #pragma unroll
        for (int r = 0; r < 4; ++r) {
            int row = q0 + w * 16 + fq * 4 + r;
            mlz[row * 2 + 0] = m_run[r];
            mlz[row * 2 + 1] = l_run[r];
        }
    }
}

// ========== fused combine(split-KV) + finalize -> featB ==========
__global__ __launch_bounds__(256) void combine_fin(
    const u16* __restrict__ Opart, const float* __restrict__ mlpart,
    const float* __restrict__ Rb, const float* __restrict__ tb,
    u16* __restrict__ featB)
{
    int idx = blockIdx.x * 256 + threadIdx.x;
    if (idx >= NRES * NH) return;
    int n = idx >> 4, h = idx & 15;

    float m[KVS], lv[KVS], wgt[KVS];
    float mm = -1e30f;
    #pragma unroll
    for (int s = 0; s < KVS; ++s) {
        size_t rr = ((size_t)s * NH + h) * NRES + n;
        m[s] = mlpart[rr * 2];
        lv[s] = mlpart[rr * 2 + 1];
        mm = fmaxf(mm, m[s]);
    }
    float ll = 0.f;
    #pragma unroll
    for (int s = 0; s < KVS; ++s) {
        wgt[s] = exp2f((m[s] - mm) * LOG2E);
        ll += lv[s] * wgt[s];
    }
    float inv = 1.f / ll;
    const u16* op[KVS];
    #pragma unroll
    for (int s = 0; s < KVS; ++s)
        op[s] = Opart + (((size_t)s * NH + h) * NRES + n) * 96;

    u16* fb = featB + (size_t)n * 1536;
    #pragma unroll
    for (int k = 0; k < 64; ++k) {
        float v = 0.f;
        #pragma unroll
        for (int s = 0; s < KVS; ++s) v += b2f(op[s][k]) * wgt[s];
        fb[h * 64 + k] = f2b(v * inv);
    }

    float R[9];
    #pragma unroll
    for (int a = 0; a < 9; ++a) R[a] = Rb[(size_t)n * 9 + a];
    float t0 = tb[(size_t)n * 3 + 0], t1 = tb[(size_t)n * 3 + 1], t2 = tb[(size_t)n * 3 + 2];
    #pragma unroll
    for (int p = 0; p < 8; ++p) {
        float d[3];
        #pragma unroll
        for (int dd = 0; dd < 3; ++dd) {
            int c = 64 + p * 3 + dd;
            float v = 0.f;
            #pragma unroll
            for (int s = 0; s < KVS; ++s) v += b2f(op[s][c]) * wgt[s];
            d[dd] = v * inv;
        }
        float x = d[0] - t0, y = d[1] - t1, z = d[2] - t2;
        float a0 = R[0] * x + R[3] * y + R[6] * z;
        float a1 = R[1] * x + R[4] * y + R[7] * z;
        float a2 = R[2] * x + R[5] * y + R[8] * z;
        fb[1024 + h * 24 + p * 3 + 0] = f2b(a0);
        fb[1024 + h * 24 + p * 3 + 1] = f2b(a1);
        fb[1024 + h * 24 + p * 3 + 2] = f2b(a2);
        fb[1408 + h * 8 + p] = f2b(sqrtf(a0 * a0 + a1 * a1 + a2 * a2 + 1e-8f));
    }
}

// ============ prep: prologue + ALL weight transposes in ONE launch ============
struct TpMega {
    const float* src[NTPJ];
    u16* dst[NTPJ];
    int ldi[NTPJ], ldo[NTPJ], K[NTPJ], N[NTPJ];
    int bx[NTPJ], start[NTPJ];
};

__global__ __launch_bounds__(256) void prep_kernel(
    const float* __restrict__ pos, const float* __restrict__ cond,
    const float* __restrict__ cn1_bs, const float* __restrict__ cn1_bb,
    const float* __restrict__ cn2_bs, const float* __restrict__ cn2_bb,
    const float* __restrict__ cn3_bs, const float* __restrict__ cn3_bb,
    const float* __restrict__ bg1, const float* __restrict__ bg2,
    float* __restrict__ Rb, float* __restrict__ tb,
    u16* __restrict__ emb, u16* __restrict__ condB,
    float* __restrict__ bias2, float* __restrict__ biasg,
    TpMega J)
{
    __shared__ float t[32][33];
    int b = blockIdx.x, tid = threadIdx.x;
    if (b >= PROBLK) {
        // ---- transpose jobs ----
        int tb2 = b - PROBLK;
        int j = NTPJ - 1;
        while (J.start[j] > tb2) --j;
        int lb = tb2 - J.start[j];
        int bxn = J.bx[j];
        int n0 = (lb % bxn) * 32;
        int k0 = (lb / bxn) * 32;
        const float* in = J.src[j];
        u16* out = J.dst[j];
        int ldi = J.ldi[j], ldo = J.ldo[j], Kk = J.K[j], Nn = J.N[j];
        int tx = tid & 31, ty = tid >> 5;
        #pragma unroll
        for (int jj = 0; jj < 4; ++jj) {
            int k = k0 + ty + jj * 8;
            if (k < Kk && n0 + tx < Nn) t[ty + jj * 8][tx] = in[(size_t)k * ldi + n0 + tx];
        }
        __syncthreads();
        #pragma unroll
        for (int jj = 0; jj < 4; ++jj) {
            int n = n0 + ty + jj * 8;
            int k = k0 + tx;
            if (n < Nn && k < Kk) out[(size_t)n * ldo + k] = f2b(t[tx][ty + jj * 8]);
        }
        return;
    }
    if (b < 16128) {
        int idx = b * 256 + tid;
        int f = idx & 63;
        int rest = idx >> 6;
        int coord = rest % 42;
        int n = rest / 42;
        float tt = pos[(size_t)n * 42 + coord];
        const double l0 = -6.643856189774724;
        const double step = 14.643856189774724 / 63.0;
        float freq = exp2f((float)(l0 + f * step));
        float r = tt * freq;
        size_t o = (size_t)n * 5376 + (size_t)coord * 128 + 2 * f;
        emb[o]     = f2b(sinf(r));
        emb[o + 1] = f2b(cosf(r));
    } else if (b < 16896) {
        int i = (b - 16128) * 256 + tid;
        size_t i0 = (size_t)i * 8;
        const float4* p = (const float4*)(cond + i0);
        float4 a = p[0], bb = p[1];
        short8 o;
        o[0]=(short)f2b(a.x); o[1]=(short)f2b(a.y); o[2]=(short)f2b(a.z); o[3]=(short)f2b(a.w);
        o[4]=(short)f2b(bb.x); o[5]=(short)f2b(bb.y); o[6]=(short)f2b(bb.z); o[7]=(short)f2b(bb.w);
        *(short8*)(condB + i0) = o;
    } else if (b < 16902) {
        int n = (b - 16896) * 256 + tid;
        if (n >= NRES) return;
        const float* p = pos + (size_t)n * 42;
        float nx = p[0], ny = p[1], nz = p[2];
        float cax = p[3], cay = p[4], caz = p[5];
        float cx = p[6], cy = p[7], cz = p[8];
        float v1x = cx - cax, v1y = cy - cay, v1z = cz - caz;
        float i1 = rsqrtf(v1x * v1x + v1y * v1y + v1z * v1z + 1e-8f);
        float e1x = v1x * i1, e1y = v1y * i1, e1z = v1z * i1;
        float v2x = nx - cax, v2y = ny - cay, v2z = nz - caz;
        float d = e1x * v2x + e1y * v2y + e1z * v2z;
        float wx = v2x - d * e1x, wy = v2y - d * e1y, wz = v2z - d * e1z;
        float i2 = rsqrtf(wx * wx + wy * wy + wz * wz + 1e-8f);
        float e2x = wx * i2, e2y = wy * i2, e2z = wz * i2;
        float e3x = e1y * e2z - e1z * e2y;
        float e3y = e1z * e2x - e1x * e2z;
        float e3z = e1x * e2y - e1y * e2x;
        float* R = Rb + (size_t)n * 9;
        R[0] = e1x; R[1] = e2x; R[2] = e3x;
        R[3] = e1y; R[4] = e2y; R[5] = e3y;
        R[6] = e1z; R[7] = e2z; R[8] = e3z;
        tb[(size_t)n * 3 + 0] = cax;
        tb[(size_t)n * 3 + 1] = cay;
        tb[(size_t)n * 3 + 2] = caz;
    } else if (b < 16906) {
        int i = (b - 16902) * 256 + tid;
        if (i >= 1024) return;
        bias2[i] = cn1_bs[i]; bias2[1024 + i] = cn1_bb[i]; bias2[2048 + i] = cn2_bs[i];
        bias2[3072 + i] = cn2_bb[i]; bias2[4096 + i] = cn3_bs[i]; bias2[5120 + i] = cn3_bb[i];
    } else {
        int i = (b - 16906) * 256 + tid;
        if (i >= 2048) return;
        biasg[i] = bg1[i]; biasg[2048 + i] = bg2[i];
    }
}

// ===== vT pack: vt[h][96][NRES] from qkc (v cols) + vgt; zero rows 88..95 =====
__global__ __launch_bounds__(256) void vt_pack(
    const float* __restrict__ qkc, const float* __restrict__ vgt,
    u16* __restrict__ vt)
{
    __shared__ float t[32][33];
    int h = blockIdx.z, grp = blockIdx.y, n0 = blockIdx.x * 32;
    int tx = threadIdx.x & 31, ty = threadIdx.x >> 5;
    #pragma unroll
    for (int j = 0; j < 4; ++j) {
        int n = n0 + ty + j * 8;
        int c = grp * 32 + tx;
        float v = 0.f;
        if (c < 64) v = qkc[(size_t)n * LDQ + 2048 + h * 64 + c];
        else if (c < 88) v = vgt[(size_t)n * 384 + h * 24 + (c - 64)];
        t[ty + j * 8][tx] = v;
    }
    __syncthreads();
    #pragma unroll
    for (int j = 0; j < 4; ++j) {
        int r = grp * 32 + ty + j * 8;
        vt[((size_t)h * 96 + r) * NRES + n0 + tx] = f2b(t[tx][ty + j * 8]);
    }
}

// ===== merged pack: qe/ke cols 0..63 + zeros (blocks<1536), points cols 64..88 =====
__global__ __launch_bounds__(256) void pack_attn(
    const float* __restrict__ qkc,
    const float* __restrict__ Rb, const float* __restrict__ tb,
    const float* __restrict__ gamma,
    u16* __restrict__ qe, u16* __restrict__ ke, float* __restrict__ vgt)
{
    int b = blockIdx.x;
    if (b < 1536) {
        int idx = b * 256 + threadIdx.x;
        int g = idx & 15;
        int t = idx >> 4;
        int n = t % NRES;
        int h = t / NRES;
        size_t o = ((size_t)h * NRES + n) * 128 + g * 8;
        if (g < 8) {
            const float4* q4 = (const float4*)(qkc + (size_t)n * LDQ + h * 64 + g * 8);
            const float4* k4 = (const float4*)(qkc + (size_t)n * LDQ + 1024 + h * 64 + g * 8);
            float4 qa = q4[0], qb2 = q4[1], ka = k4[0], kb2 = k4[1];
            short8 oq, ok;
            oq[0]=(short)f2b(0.125f*qa.x); oq[1]=(short)f2b(0.125f*qa.y);
            oq[2]=(short)f2b(0.125f*qa.z); oq[3]=(short)f2b(0.125f*qa.w);
            oq[4]=(short)f2b(0.125f*qb2.x); oq[5]=(short)f2b(0.125f*qb2.y);
            oq[6]=(short)f2b(0.125f*qb2.z); oq[7]=(short)f2b(0.125f*qb2.w);
            ok[0]=(short)f2b(ka.x); ok[1]=(short)f2b(ka.y); ok[2]=(short)f2b(ka.z); ok[3]=(short)f2b(ka.w);
            ok[4]=(short)f2b(kb2.x); ok[5]=(short)f2b(kb2.y); ok[6]=(short)f2b(kb2.z); ok[7]=(short)f2b(kb2.w);
            *(short8*)(qe + o) = oq;
            *(short8*)(ke + o) = ok;
        } else if (g >= 11) {
            short8 zz = {};
            *(short8*)(qe + o) = zz;
            *(short8*)(ke + o) = zz;
        }
        return;
    }
    int idx = (b - 1536) * 256 + threadIdx.x;
    if (idx >= NRES * NH) return;
    int n = idx >> 4, h = idx & 15;
    float R[9];
    #pragma unroll
    for (int a = 0; a < 9; ++a) R[a] = Rb[(size_t)n * 9 + a];
    float t0 = tb[(size_t)n * 3 + 0], t1 = tb[(size_t)n * 3 + 1], t2 = tb[(size_t)n * 3 + 2];
    float g = gamma[h];
    float sp = (g > 20.f) ? g : log1pf(expf(g));
    float ch = 0.5f * (1.f / 6.f) * sp;

    u16* qeh = qe + ((size_t)h * NRES + n) * 128;
    u16* keh = ke + ((size_t)h * NRES + n) * 128;
    const float* qp = qkc + (size_t)n * LDQ + 3072 + h * 24;
    const float* kp = qkc + (size_t)n * LDQ + 3456 + h * 24;
    const float* vp = qkc + (size_t)n * LDQ + 3840 + h * 24;
    float kn = 0.f;
    #pragma unroll
    for (int p = 0; p < 8; ++p) {
        {
            float x = qp[p*3], y = qp[p*3+1], z = qp[p*3+2];
            float g0 = R[0] * x + R[1] * y + R[2] * z + t0;
            float g1 = R[3] * x + R[4] * y + R[5] * z + t1;
            float g2 = R[6] * x + R[7] * y + R[8] * z + t2;
            qeh[64 + p * 3 + 0] = f2b(2.f * ch * g0);
            qeh[64 + p * 3 + 1] = f2b(2.f * ch * g1);
            qeh[64 + p * 3 + 2] = f2b(2.f * ch * g2);
        }
        {
            float x = kp[p*3], y = kp[p*3+1], z = kp[p*3+2];
            float g0 = R[0] * x + R[1] * y + R[2] * z + t0;
            float g1 = R[3] * x + R[4] * y + R[5] * z + t1;
            float g2 = R[6] * x + R[7] * y + R[8] * z + t2;
            keh[64 + p * 3 + 0] = f2b(g0);
            keh[64 + p * 3 + 1] = f2b(g1);
            keh[64 + p * 3 + 2] = f2b(g2);
            kn += g0 * g0 + g1 * g1 + g2 * g2;
        }
        {
            float x = vp[p*3], y = vp[p*3+1], z = vp[p*3+2];
            vgt[(size_t)n * 384 + h * 24 + p * 3 + 0] = R[0] * x + R[1] * y + R[2] * z + t0;
            vgt[(size_t)n * 384 + h * 24 + p * 3 + 1] = R[3] * x + R[4] * y + R[5] * z + t1;
            vgt[(size_t)n * 384 + h * 24 + p * 3 + 2] = R[6] * x + R[7] * y + R[8] * z + t2;
        }
    }
    qeh[88] = f2b(1.0f);
    keh[88] = f2b(-ch * kn);
}

// gm = silu(g1) * g2, 8-wide
__global__ __launch_bounds__(256) void glu_kernel(const u16* __restrict__ g12, u16* __restrict__ gm)
{
    int i = blockIdx.x * 256 + threadIdx.x;
    if (i >= NRES * 2048 / 8) return;
    size_t i0 = (size_t)i * 8;
    short8 a8 = *(const short8*)(g12 + i0);
    short8 b8 = *(const short8*)(g12 + (size_t)NRES * 2048 + i0);
    short8 o;
    #pragma unroll
    for (int j = 0; j < 8; ++j) {
        float a = b2f((u16)a8[j]);
        float b = b2f((u16)b8[j]);
        float s = a / (1.f + expf(-a));
        o[j] = (short)f2b(s * b);
    }
    *(short8*)(gm + i0) = o;
}

// ========================= host =========================
extern "C" void kernel_launch(void* const* d_in, const int* in_sizes, int n_in,
                              void* d_out, int out_size, void* d_ws, size_t ws_size,
                              hipStream_t stream)
{
    const float* local_in = (const float*)d_in[0];
    const float* pos      = (const float*)d_in[1];
    const float* cond     = (const float*)d_in[2];
    const float* pb       = (const float*)d_in[4];
    const float* w_f1     = (const float*)d_in[5];
    const float* b_f1     = (const float*)d_in[6];
    const float* w_f2     = (const float*)d_in[7];
    const float* b_f2     = (const float*)d_in[8];
    const float* cn1_ws   = (const float*)d_in[9];
    const float* cn1_bs   = (const float*)d_in[10];
    const float* cn1_wb   = (const float*)d_in[11];
    const float* cn1_bb   = (const float*)d_in[12];
    const float* wq       = (const float*)d_in[13];
    const float* wk       = (const float*)d_in[14];
    const float* wv       = (const float*)d_in[15];
    const float* wqp      = (const float*)d_in[16];
    const float* wkp      = (const float*)d_in[17];
    const float* wvp      = (const float*)d_in[18];
    const float* gamma    = (const float*)d_in[19];
    const float* wo       = (const float*)d_in[20];
    const float* bo       = (const float*)d_in[21];
    const float* cn2_ws   = (const float*)d_in[22];
    const float* cn2_bs   = (const float*)d_in[23];
    const float* cn2_wb   = (const float*)d_in[24];
    const float* cn2_bb   = (const float*)d_in[25];
    const float* wg1      = (const float*)d_in[26];
    const float* bg1      = (const float*)d_in[27];
    const float* wg2      = (const float*)d_in[28];
    const float* bg2      = (const float*)d_in[29];
    const float* wg3      = (const float*)d_in[30];
    const float* bg3      = (const float*)d_in[31];
    const float* cn3_ws   = (const float*)d_in[32];
    const float* cn3_bs   = (const float*)d_in[33];
    const float* cn3_wb   = (const float*)d_in[34];
    const float* cn3_bb   = (const float*)d_in[35];
    const float* w_vel    = (const float*)d_in[36];

    float* out = (float*)d_out;
    float* ws  = (float*)d_ws;

    size_t off = 0;
    auto alloc = [&](size_t nf) -> float* { float* p = ws + off; off += (nf + 7) & ~7ull; return p; };

    const size_t NN1 = (size_t)NRES * 1024;
    float* Rb    = alloc(NRES * 9);
    float* tb    = alloc(NRES * 3);
    float* loc   = alloc(NN1);
    u16*   cs6b  = (u16*)alloc(6 * NN1 / 2);
    u16*   condB = (u16*)alloc(NN1 / 2);
    u16*   normB = (u16*)alloc(NN1 / 2);
    float* bias2 = alloc(6 * 1024);
    float* biasg = alloc(2 * 2048);
    float* qkc   = alloc((size_t)NRES * LDQ);
    float* vgt   = alloc((size_t)NRES * 384);
    u16*   qeB   = (u16*)alloc((size_t)NH * NRES * 128 / 2);
    u16*   keB   = (u16*)alloc((size_t)NH * NRES * 128 / 2);
    u16*   vTB   = (u16*)alloc((size_t)NH * 96 * NRES / 2);
    u16*   featB = (u16*)alloc((size_t)NRES * 1536 / 2);
    u16*   g1sB  = (u16*)alloc((size_t)NRES * 2048 / 2);
    u16*   gmB   = (u16*)alloc((size_t)NRES * 2048 / 2);
    u16*   cnT9  = (u16*)alloc((size_t)9 * 1024 * 1024 / 2);
    u16*   ptsT  = (u16*)alloc((size_t)3 * 384 * 1024 / 2);
    u16*   wgT   = (u16*)alloc((size_t)2 * 2048 * 1024 / 2);
    u16*   wf1T  = (u16*)alloc((size_t)2048 * 5376 / 2);
    u16*   wf2T  = (u16*)alloc((size_t)1024 * 2048 / 2);
    u16*   woT   = (u16*)alloc((size_t)1024 * 1536 / 2);
    u16*   wg3T  = (u16*)alloc((size_t)1024 * 2048 / 2);
    u16*   wvT   = (u16*)alloc((size_t)42 * 1024 / 2 + 8);
    u16*   embB  = (u16*)alloc((size_t)NRES * 5376 / 2);
    u16*   hidB  = (u16*)alloc((size_t)NRES * 2048 / 2);
    u16*   pscr  = (u16*)alloc((size_t)2 * NRES * 2048 * 4 / 2);
    u16*   Opart = (u16*)alloc((size_t)KVS * NH * NRES * 96 / 2);
    float* mlprt = alloc((size_t)KVS * NH * NRES * 2);

    const float* nilf = nullptr;

    auto gemm = [&](int tnf, const u16* A, int lda, size_t zsA,
                    const u16* BT, int ldb, size_t zsB,
                    float* Cf, u16* Cb2, int ldc, size_t zsC,
                    const float* bias, size_t zsBias,
                    const float* resid, int ldr, size_t zsR,
                    int Nc, int Kd, int flags, int gz, int ksl) {
        int tn = tnf * 32;
        dim3 grid((Nc + tn - 1) / tn, NRES / 128, gz);
        if (tnf == 4)
            hipLaunchKernelGGL(gemm_t<4>, grid, dim3(256), 0, stream,
                               A, lda, zsA, BT, ldb, zsB, Cf, Cb2, ldc, zsC,
                               bias, zsBias, resid, ldr, zsR, Nc, Kd, flags, ksl);
        else
            hipLaunchKernelGGL(gemm_t<2>, grid, dim3(256), 0, stream,
                               A, lda, zsA, BT, ldb, zsB, Cf, Cb2, ldc, zsC,
                               bias, zsBias, resid, ldr, zsR, Nc, Kd, flags, ksl);
    };
    auto red = [&](const u16* part, size_t slice, int nsl, float* Cf, u16* Cb2,
                   const float* bias, const float* resid, int ldr, int Nc, int flags) {
        hipLaunchKernelGGL(reduce_epi, dim3(1024), dim3(256), 0, stream,
                           part, slice, nsl, Cf, Cb2, bias, resid, ldr, NRES, Nc, flags);
    };
    auto redcn = [&](const u16* part, size_t slice, int nsl,
                     const float* bias, const float* resid, float* locOut, int cnIdx) {
        hipLaunchKernelGGL(reduce_cn, dim3(NRES), dim3(256), 0, stream,
                           part, slice, nsl, bias, resid, locOut,
                           cs6b + (size_t)(2 * cnIdx) * NN1,
                           cs6b + (size_t)(2 * cnIdx + 1) * NN1, normB);
    };

    // ---- prep: prologue + all weight transposes in ONE launch ----
    {
        TpMega J;
        int jn = 0, start = 0;
        auto addJob = [&](const float* src, u16* dst, int ldi, int ldo, int K, int N) {
            J.src[jn] = src; J.dst[jn] = dst;
            J.ldi[jn] = ldi; J.ldo[jn] = ldo; J.K[jn] = K; J.N[jn] = N;
            int bx = (N + 31) / 32, by = (K + 31) / 32;
            J.bx[jn] = bx; J.start[jn] = start;
            start += bx * by;
            ++jn;
        };
        const float* cn6[6] = {cn1_ws, cn1_wb, cn2_ws, cn2_wb, cn3_ws, cn3_wb};
        for (int i = 0; i < 6; ++i)
            addJob(cn6[i], cnT9 + (size_t)i * 1024 * 1024, 1024, 1024, 1024, 1024);
        addJob(wq, cnT9 + (size_t)6 * 1024 * 1024, 1024, 1024, 1024, 1024);
        addJob(wk, cnT9 + (size_t)7 * 1024 * 1024, 1024, 1024, 1024, 1024);
        addJob(wv, cnT9 + (size_t)8 * 1024 * 1024, 1024, 1024, 1024, 1024);
        addJob(wqp, ptsT,                        384, 1024, 1024, 384);
        addJob(wkp, ptsT + (size_t)384 * 1024,   384, 1024, 1024, 384);
        addJob(wvp, ptsT + (size_t)2 * 384 * 1024, 384, 1024, 1024, 384);
        addJob(wg1, wgT,                        2048, 1024, 1024, 2048);
        addJob(wg2, wgT + (size_t)2048 * 1024,  2048, 1024, 1024, 2048);
        addJob(w_f1, wf1T, 2048, 5376, 5376, 2048);
        addJob(w_f2, wf2T, 1024, 2048, 2048, 1024);
        addJob(wo,   woT,  1024, 1536, 1536, 1024);
        addJob(wg3,  wg3T, 1024, 2048, 2048, 1024);
        addJob(w_vel, wvT,   42, 1024, 1024, 42);
        hipLaunchKernelGGL(prep_kernel, dim3(PROBLK + start), dim3(256), 0, stream,
                           pos, cond, cn1_bs, cn1_bb, cn2_bs, cn2_bb, cn3_bs, cn3_bb,
                           bg1, bg2, Rb, tb, embB, condB, bias2, biasg, J);
    }

    // ---- cond (z=6) + emb (split-K=4) GEMMs fused in ONE launch ----
    {
        GJob jc, je;
        jc.A = condB; jc.BT = cnT9; jc.C = cs6b; jc.bias = bias2;
        jc.lda = 1024; jc.ldb = 1024; jc.ldc = 1024;
        jc.zsA = 0; jc.zsB = (size_t)1024 * 1024; jc.zsC = NN1; jc.zsBias = 1024;
        jc.Nc = 1024; jc.Kd = 1024; jc.ksl = 0; jc.flags = F_BIAS;
        jc.gx = 16; jc.gy = 12; jc.start = 0; jc.nb = 16 * 12 * 6;          // 1152
        je.A = embB; je.BT = wf1T; je.C = pscr; je.bias = nullptr;
        je.lda = 5376; je.ldb = 5376; je.ldc = 2048;
        je.zsA = 0; je.zsB = 0; je.zsC = (size_t)NRES * 2048; je.zsBias = 0;
        je.Nc = 2048; je.Kd = 5376; je.ksl = 1344; je.flags = 0;
        je.gx = 32; je.gy = 12; je.start = jc.nb; je.nb = 32 * 12 * 4;      // 1536
        hipLaunchKernelGGL(gemm_dual, dim3(jc.nb + je.nb), dim3(256), 0, stream, jc, je);
    }
    red(pscr, (size_t)NRES * 2048, 4, nullptr, hidB, b_f1, nilf, 0,
        2048, F_BIAS | F_SILU | F_OUTBF);
    gemm(2, hidB, 2048, 0, wf2T, 2048, 0, nullptr, pscr, 1024, NN1,
         nilf, 0, nilf, 0, 0, 1024, 2048, F_OUTBF, 4, 512);
    redcn(pscr, NN1, 4, b_f2, local_in, loc, 0);

    // ---- merged projections ----
    gemm(2, normB, 1024, 0, cnT9 + (size_t)6 * 1024 * 1024, 1024, 0,
         qkc, nullptr, LDQ, 0, nilf, 0, nilf, 0, 0, LDQ, 1024, 0, 1, 0);

    // ---- attention operands ----
    hipLaunchKernelGGL(pack_attn, dim3(1536 + 96), dim3(256), 0, stream,
                       qkc, Rb, tb, gamma, qeB, keB, vgt);
    hipLaunchKernelGGL(vt_pack, dim3(NRES / 32, 3, NH), dim3(256), 0, stream,
                       qkc, vgt, vTB);

    // ---- fused attention (split-KV=4, XCD-chunked) + merged combine+finalize ----
    hipLaunchKernelGGL(attn_kernel, dim3(NRES / 64, NH, KVS), dim3(256), 0, stream,
                       qeB, keB, vTB, pb, Opart, mlprt);
    hipLaunchKernelGGL(combine_fin, dim3(96), dim3(256), 0, stream,
                       Opart, mlprt, Rb, tb, featB);

    // ---- local += feat @ wo + bo : split-K=4, fused reduce+condnorm2 ----
    gemm(2, featB, 1536, 0, woT, 1536, 0, nullptr, pscr, 1024, NN1,
         nilf, 0, nilf, 0, 0, 1024, 1536, F_OUTBF, 4, 384);
    redcn(pscr, NN1, 4, bo, loc, loc, 1);

    // ---- gated MLP ----
    gemm(2, normB, 1024, 0, wgT, 1024, (size_t)2048 * 1024, nullptr, g1sB, 2048, (size_t)NRES * 2048,
         biasg, 2048, nilf, 0, 0, 2048, 1024, F_BIAS | F_OUTBF, 2, 0);
    u16* gmO = embB;
    hipLaunchKernelGGL(glu_kernel, dim3((NRES * 2048 / 8 + 255) / 256), dim3(256), 0, stream, g1sB, gmO);
    gemm(2, gmO, 2048, 0, wg3T, 2048, 0, nullptr, pscr, 1024, NN1,
         nilf, 0, nilf, 0, 0, 1024, 2048, F_OUTBF, 4, 512);
    redcn(pscr, NN1, 4, bg3, loc, out, 2);

    // ---- velocity (split-K=8, bf16 partials) ----
    gemm(2, normB, 1024, 0, wvT, 1024, 0, nullptr, pscr, 42, (size_t)NRES * 42,
         nilf, 0, nilf, 0, 0, 42, 1024, F_OUTBF, 8, 128);
    red(pscr, (size_t)NRES * 42, 8, out + (size_t)NRES * 1024, nullptr,
        nilf, nilf, 0, 42, 0);
}